// Round 1
// baseline (1298.169 us; speedup 1.0000x reference)
//
#include <hip/hip_runtime.h>
#include <math.h>

constexpr int Bq  = 2;
constexpr int Tq  = 1024;
constexpr int Cq  = 768;
constexpr int NHq = 12;
constexpr int HTq = 48;
constexpr int DHq = 64;
constexpr float SCALE = 0.125f;     // 64^-0.5
constexpr float NEG_BIG = -1e30f;

// ---------------------------------------------------------------------------
// Generic fp32 GEMM: Out[M,N] = A[M,K] @ W[N,K]^T (+ bias[n])
// 64x64 tile, BK=32, 256 threads, 4x4 micro-tile
// ---------------------------------------------------------------------------
__global__ __launch_bounds__(256) void gemm_nt_kernel(
    const float* __restrict__ A, const float* __restrict__ W,
    const float* __restrict__ bias, float* __restrict__ Out,
    int M, int N, int K)
{
    __shared__ float sA[32][68];
    __shared__ float sB[32][68];
    int tid = threadIdx.x;
    int tx = tid & 15, ty = tid >> 4;
    int m0 = blockIdx.x * 64, n0 = blockIdx.y * 64;
    float acc[4][4] = {};
    for (int k0 = 0; k0 < K; k0 += 32) {
        __syncthreads();
        for (int l = tid; l < 64 * 8; l += 256) {
            int r = l >> 3, c4 = l & 7;
            float4 v = *(const float4*)(A + (size_t)(m0 + r) * K + k0 + c4 * 4);
            sA[c4 * 4 + 0][r] = v.x; sA[c4 * 4 + 1][r] = v.y;
            sA[c4 * 4 + 2][r] = v.z; sA[c4 * 4 + 3][r] = v.w;
        }
        for (int l = tid; l < 64 * 8; l += 256) {
            int r = l >> 3, c4 = l & 7;
            float4 v = *(const float4*)(W + (size_t)(n0 + r) * K + k0 + c4 * 4);
            sB[c4 * 4 + 0][r] = v.x; sB[c4 * 4 + 1][r] = v.y;
            sB[c4 * 4 + 2][r] = v.z; sB[c4 * 4 + 3][r] = v.w;
        }
        __syncthreads();
        #pragma unroll
        for (int kk = 0; kk < 32; kk++) {
            float4 av = *(const float4*)&sA[kk][ty * 4];
            float4 bv = *(const float4*)&sB[kk][tx * 4];
            float a_[4] = {av.x, av.y, av.z, av.w};
            float b_[4] = {bv.x, bv.y, bv.z, bv.w};
            #pragma unroll
            for (int i = 0; i < 4; i++)
                #pragma unroll
                for (int j = 0; j < 4; j++)
                    acc[i][j] += a_[i] * b_[j];
        }
    }
    #pragma unroll
    for (int j = 0; j < 4; j++) {
        int n = n0 + tx * 4 + j;
        float bv = bias ? bias[n] : 0.0f;
        #pragma unroll
        for (int i = 0; i < 4; i++) {
            int m = m0 + ty * 4 + i;
            Out[(size_t)m * N + n] = acc[i][j] + bv;
        }
    }
}

// ---------------------------------------------------------------------------
// Fused wedge + rope.  in layout: (b*T + t, in_heads, 64).  out: (b*T+t, 48, 64)
// wedge(x)_e = x_e * (1 + bias[h][e]) + sum_d x_d * skew[d][e],
//   skew = wedge_A - wedge_A^T, base head = h % in_heads.
// rope: x1 = even idx, x2 = odd idx; out[0:32]=x1*cos - x2*sin; out[32:64]=x1*sin + x2*cos
// Uniform trip count (1024 blocks * 4 waves, 98304 rows -> exactly 24 iters).
// ---------------------------------------------------------------------------
__global__ __launch_bounds__(256) void wedge_rope_kernel(
    const float* __restrict__ in, float* __restrict__ out,
    const float* __restrict__ wedge_A, const float* __restrict__ wedge_bias,
    int in_heads)
{
    __shared__ float skew[64 * 64];
    __shared__ float buf[4][64];
    __shared__ float buf2[4][64];
    int tid = threadIdx.x;
    for (int l = tid; l < 4096; l += 256) {
        int d = l >> 6, e = l & 63;
        skew[l] = wedge_A[l] - wedge_A[e * 64 + d];
    }
    __syncthreads();
    int wave = tid >> 6, lane = tid & 63;
    const int nrows = Bq * Tq * HTq;   // 98304
    for (int row = blockIdx.x * 4 + wave; row < nrows; row += 4096) {
        int h = row % HTq;
        int bt = row / HTq;
        int t = bt % Tq;
        const float* src = in + ((size_t)bt * in_heads + (h % in_heads)) * 64;
        float x = src[lane];
        buf[wave][lane] = x;
        __syncthreads();
        float acc = 0.0f;
        #pragma unroll 8
        for (int d = 0; d < 64; d++)
            acc += buf[wave][d] * skew[d * 64 + lane];
        float bia = wedge_bias[h * 64 + lane];
        float wz = x * (1.0f + bia) + acc;
        buf2[wave][lane] = wz;
        __syncthreads();
        int i = lane & 31;
        float x1 = buf2[wave][2 * i];
        float x2 = buf2[wave][2 * i + 1];
        float invf = powf(10000.0f, -(float)i * (1.0f / 32.0f));
        float ang = (float)t * invf;
        float cv = cosf(ang), sv = sinf(ang);
        float o = (lane < 32) ? (x1 * cv - x2 * sv) : (x1 * sv + x2 * cv);
        out[((size_t)bt * HTq + h) * 64 + lane] = o;
    }
}

// ---------------------------------------------------------------------------
// Attention core: scores + online softmax (incl. sink) + per-row top-4 + marker.
// Layouts: Qr/Kr = (b, t, 48, 64).  marker = (b*48+h, t, 64). psink = (b*48+h, t).
// Block: 256 threads (4 waves), covers one (b,h) and 32 query rows.
// Lane l handles scores s = tile*64 + l. Per-lane online (m,Z) + top-4, merged
// across the wave at the end.
// ---------------------------------------------------------------------------
__global__ __launch_bounds__(256) void attn_topk_kernel(
    const float* __restrict__ Qr, const float* __restrict__ Kr,
    const float* __restrict__ sink, float* __restrict__ marker,
    float* __restrict__ psink)
{
    __shared__ float K_lds[64][68];
    __shared__ float q_lds[32][68];
    const int nchunk = Tq / 32;             // 32
    int idx = blockIdx.x;
    int bh = idx / nchunk;
    int t0 = (idx % nchunk) * 32;
    int b = bh / HTq, h = bh % HTq;
    int tid = threadIdx.x;
    // stage 32 q rows
    for (int l = tid; l < 32 * 16; l += 256) {
        int r = l >> 4, c4 = l & 15;
        *(float4*)&q_lds[r][c4 * 4] =
            *(const float4*)(Qr + (((size_t)(b * Tq + t0 + r) * HTq + h) << 6) + c4 * 4);
    }
    int wave = tid >> 6, lane = tid & 63;
    float m_[8], Z_[8], tv[8][4];
    int ti[8][4];
    #pragma unroll
    for (int q = 0; q < 8; q++) {
        m_[q] = NEG_BIG; Z_[q] = 0.0f;
        #pragma unroll
        for (int r = 0; r < 4; r++) { tv[q][r] = -INFINITY; ti[q][r] = 0; }
    }
    int ntiles = (t0 + 32 + 63) >> 6;
    for (int tile = 0; tile < ntiles; tile++) {
        int s0 = tile << 6;
        __syncthreads();
        for (int l = tid; l < 64 * 16; l += 256) {
            int r = l >> 4, c4 = l & 15;
            *(float4*)&K_lds[r][c4 * 4] =
                *(const float4*)(Kr + (((size_t)(b * Tq + s0 + r) * HTq + h) << 6) + c4 * 4);
        }
        __syncthreads();
        float accq[8];
        #pragma unroll
        for (int q = 0; q < 8; q++) accq[q] = 0.0f;
        #pragma unroll
        for (int d4 = 0; d4 < 16; d4++) {
            float4 kv = *(const float4*)&K_lds[lane][d4 * 4];
            #pragma unroll
            for (int q = 0; q < 8; q++) {
                float4 qv = *(const float4*)&q_lds[wave * 8 + q][d4 * 4];
                accq[q] += kv.x * qv.x + kv.y * qv.y + kv.z * qv.z + kv.w * qv.w;
            }
        }
        int sidx = s0 + lane;
        #pragma unroll
        for (int q = 0; q < 8; q++) {
            int trow = t0 + wave * 8 + q;
            float sv = (sidx <= trow) ? accq[q] * SCALE : -INFINITY;
            float nm = fmaxf(m_[q], sv);
            Z_[q] = Z_[q] * __expf(m_[q] - nm) + __expf(sv - nm);
            m_[q] = nm;
            float v = sv; int id = sidx;
            #pragma unroll
            for (int r = 0; r < 4; r++) {
                bool sw = v > tv[q][r];
                float ov = tv[q][r]; int oi = ti[q][r];
                tv[q][r] = sw ? v : ov;  ti[q][r] = sw ? id : oi;
                v = sw ? ov : v;         id = sw ? oi : id;
            }
        }
    }
    float sk = sink[h];
    #pragma unroll
    for (int q = 0; q < 8; q++) {
        int trow = t0 + wave * 8 + q;
        // wave-reduce running max / Z
        float mr = m_[q];
        #pragma unroll
        for (int off = 32; off; off >>= 1) mr = fmaxf(mr, __shfl_xor(mr, off));
        float z = Z_[q] * __expf(m_[q] - mr);
        #pragma unroll
        for (int off = 32; off; off >>= 1) z += __shfl_xor(z, off);
        float mf = fmaxf(mr, sk);
        float Zf = z * __expf(mr - mf) + __expf(sk - mf);
        float ps = __expf(sk - mf) / Zf;
        // merge per-lane top-4 -> global top-4 (argmax + pop, 4 rounds)
        float a0 = tv[q][0], a1 = tv[q][1], a2 = tv[q][2], a3 = tv[q][3];
        int   i0 = ti[q][0], i1 = ti[q][1], i2 = ti[q][2], i3 = ti[q][3];
        float bestv[4]; int besti[4];
        #pragma unroll
        for (int r = 0; r < 4; r++) {
            float hv = a0;
            float mv = hv;
            #pragma unroll
            for (int off = 32; off; off >>= 1) mv = fmaxf(mv, __shfl_xor(mv, off));
            unsigned long long ball = __ballot(hv == mv);
            int src = __ffsll(ball) - 1;
            int win_i = __shfl(i0, src);
            bestv[r] = mv; besti[r] = win_i;
            bool winner = (lane == src);
            a0 = winner ? a1 : a0;  i0 = winner ? i1 : i0;
            a1 = winner ? a2 : a1;  i1 = winner ? i2 : i1;
            a2 = winner ? a3 : a2;  i2 = winner ? i3 : i2;
            a3 = winner ? -INFINITY : a3;
        }
        float e0 = __expf(bestv[0] - mf), e1 = __expf(bestv[1] - mf);
        float e2 = __expf(bestv[2] - mf), e3 = __expf(bestv[3] - mf);
        float v0 = e0 / Zf, v1 = e1 / Zf, v2 = e2 / Zf, v3 = e3 / Zf;
        float wsum = v0 + v1 + v2 + v3 + 1e-9f;
        float w0 = v0 / wsum, w1 = v1 / wsum, w2 = v2 / wsum, w3 = v3 / wsum;
        float md = w0 * Kr[(((size_t)(b * Tq + besti[0]) * HTq + h) << 6) + lane]
                 + w1 * Kr[(((size_t)(b * Tq + besti[1]) * HTq + h) << 6) + lane]
                 + w2 * Kr[(((size_t)(b * Tq + besti[2]) * HTq + h) << 6) + lane]
                 + w3 * Kr[(((size_t)(b * Tq + besti[3]) * HTq + h) << 6) + lane];
        marker[(((size_t)bh * Tq + trow) << 6) + lane] = md;
        if (lane == 0) psink[(size_t)bh * Tq + trow] = ps;
    }
}

// ---------------------------------------------------------------------------
// Fused MLP: ctx = gelu(marker @ V1^T + b1) @ V2^T + b2 + psink * v_null[h]
// written into (b, n, t, 768) layout.  64 rows/block, hidden chunked by 64.
// ---------------------------------------------------------------------------
__global__ __launch_bounds__(256) void mlp_kernel(
    const float* __restrict__ marker, const float* __restrict__ psink,
    const float* __restrict__ V1w, const float* __restrict__ V1b,
    const float* __restrict__ V2w, const float* __restrict__ V2b,
    const float* __restrict__ vnulls, float* __restrict__ ctx)
{
    __shared__ float M_lds[64][68];
    __shared__ float W_lds[64][68];
    __shared__ float G_lds[64][68];
    int tid = threadIdx.x;
    int tx = tid & 15, ty = tid >> 4;
    int r0 = blockIdx.x * 64;
    for (int l = tid; l < 64 * 16; l += 256) {
        int r = l >> 4, c4 = l & 15;
        *(float4*)&M_lds[r][c4 * 4] =
            *(const float4*)(marker + ((size_t)(r0 + r) << 6) + c4 * 4);
    }
    float oacc[4][4] = {};
    for (int ch = 0; ch < 4; ch++) {
        __syncthreads();
        for (int l = tid; l < 64 * 16; l += 256) {
            int r = l >> 4, c4 = l & 15;
            *(float4*)&W_lds[r][c4 * 4] =
                *(const float4*)(V1w + (((size_t)(ch * 64 + r)) << 6) + c4 * 4);
        }
        __syncthreads();
        float hacc[4][4] = {};
        #pragma unroll
        for (int k4 = 0; k4 < 16; k4++) {
            float4 a_[4], b_[4];
            #pragma unroll
            for (int i = 0; i < 4; i++) a_[i] = *(const float4*)&M_lds[ty * 4 + i][k4 * 4];
            #pragma unroll
            for (int j = 0; j < 4; j++) b_[j] = *(const float4*)&W_lds[tx * 4 + j][k4 * 4];
            #pragma unroll
            for (int i = 0; i < 4; i++)
                #pragma unroll
                for (int j = 0; j < 4; j++)
                    hacc[i][j] += a_[i].x * b_[j].x + a_[i].y * b_[j].y
                                + a_[i].z * b_[j].z + a_[i].w * b_[j].w;
        }
        __syncthreads();
        #pragma unroll
        for (int i = 0; i < 4; i++)
            #pragma unroll
            for (int j = 0; j < 4; j++) {
                float x = hacc[i][j] + V1b[ch * 64 + tx * 4 + j];
                float g = 0.5f * x * (1.0f + erff(x * 0.70710678118654752f));
                G_lds[ty * 4 + i][tx * 4 + j] = g;
            }
        for (int l = tid; l < 64 * 16; l += 256) {
            int r = l >> 4, c4 = l & 15;
            *(float4*)&W_lds[r][c4 * 4] =
                *(const float4*)(V2w + (size_t)r * 256 + ch * 64 + c4 * 4);
        }
        __syncthreads();
        #pragma unroll
        for (int k4 = 0; k4 < 16; k4++) {
            float4 a_[4], b_[4];
            #pragma unroll
            for (int i = 0; i < 4; i++) a_[i] = *(const float4*)&G_lds[ty * 4 + i][k4 * 4];
            #pragma unroll
            for (int j = 0; j < 4; j++) b_[j] = *(const float4*)&W_lds[tx * 4 + j][k4 * 4];
            #pragma unroll
            for (int i = 0; i < 4; i++)
                #pragma unroll
                for (int j = 0; j < 4; j++)
                    oacc[i][j] += a_[i].x * b_[j].x + a_[i].y * b_[j].y
                                + a_[i].z * b_[j].z + a_[i].w * b_[j].w;
        }
    }
    #pragma unroll
    for (int i = 0; i < 4; i++) {
        int rr = r0 + ty * 4 + i;
        int t = rr & 1023;
        int bh = rr >> 10;
        int b = bh / HTq, h = bh % HTq;
        int n = h / NHq, head = h % NHq;
        float ps = psink[rr];
        float* dst = ctx + ((size_t)((b * 4 + n) * 1024 + t)) * 768 + head * 64;
        #pragma unroll
        for (int j = 0; j < 4; j++) {
            int d = tx * 4 + j;
            dst[d] = oacc[i][j] + V2b[d] + ps * vnulls[h * 64 + d];
        }
    }
}

// ---------------------------------------------------------------------------
// y[b*1024+t, d] = 0.25 * ( sum_n sum_c ctx[(b*4+n)*1024+t, c] * WO_w[n,c,d]
//                           + sum_n WO_b[n,d] )
// ---------------------------------------------------------------------------
__global__ __launch_bounds__(256) void gemm_wo_kernel(
    const float* __restrict__ ctx, const float* __restrict__ WOw,
    const float* __restrict__ WOb, float* __restrict__ Out)
{
    __shared__ float sA[32][68];
    __shared__ float sB[32][68];
    int tid = threadIdx.x;
    int tx = tid & 15, ty = tid >> 4;
    int m0 = blockIdx.x * 64, n0 = blockIdx.y * 64;
    int b = m0 >> 10, t0 = m0 & 1023;
    float acc[4][4] = {};
    for (int n = 0; n < 4; n++) {
        const float* Ab = ctx + ((size_t)(b * 4 + n) * 1024 + t0) * 768;
        const float* Bb = WOw + (size_t)n * 768 * 768;
        for (int k0 = 0; k0 < 768; k0 += 32) {
            __syncthreads();
            for (int l = tid; l < 64 * 8; l += 256) {
                int r = l >> 3, c4 = l & 7;
                float4 v = *(const float4*)(Ab + (size_t)r * 768 + k0 + c4 * 4);
                sA[c4 * 4 + 0][r] = v.x; sA[c4 * 4 + 1][r] = v.y;
                sA[c4 * 4 + 2][r] = v.z; sA[c4 * 4 + 3][r] = v.w;
            }
            for (int l = tid; l < 32 * 16; l += 256) {
                int kr = l >> 4, c4 = l & 15;
                *(float4*)&sB[kr][c4 * 4] =
                    *(const float4*)(Bb + (size_t)(k0 + kr) * 768 + n0 + c4 * 4);
            }
            __syncthreads();
            #pragma unroll
            for (int kk = 0; kk < 32; kk++) {
                float4 av = *(const float4*)&sA[kk][ty * 4];
                float4 bv = *(const float4*)&sB[kk][tx * 4];
                float a_[4] = {av.x, av.y, av.z, av.w};
                float b_[4] = {bv.x, bv.y, bv.z, bv.w};
                #pragma unroll
                for (int i = 0; i < 4; i++)
                    #pragma unroll
                    for (int j = 0; j < 4; j++)
                        acc[i][j] += a_[i] * b_[j];
            }
        }
    }
    #pragma unroll
    for (int j = 0; j < 4; j++) {
        int d = n0 + tx * 4 + j;
        float bm = WOb[d] + WOb[768 + d] + WOb[1536 + d] + WOb[2304 + d];
        #pragma unroll
        for (int i = 0; i < 4; i++) {
            int m = m0 + ty * 4 + i;
            Out[(size_t)m * 768 + d] = 0.25f * (acc[i][j] + bm);
        }
    }
}

// ---------------------------------------------------------------------------
extern "C" void kernel_launch(void* const* d_in, const int* in_sizes, int n_in,
                              void* d_out, int out_size, void* d_ws, size_t ws_size,
                              hipStream_t stream) {
    const float* A      = (const float*)d_in[0];
    const float* X      = (const float*)d_in[1];
    const float* WKw    = (const float*)d_in[2];
    const float* WKb    = (const float*)d_in[3];
    const float* WQw    = (const float*)d_in[4];
    const float* wA     = (const float*)d_in[5];
    const float* wB     = (const float*)d_in[6];
    const float* sink   = (const float*)d_in[7];
    const float* vnulls = (const float*)d_in[8];
    const float* V1w    = (const float*)d_in[9];
    const float* V1b    = (const float*)d_in[10];
    const float* V2w    = (const float*)d_in[11];
    const float* V2b    = (const float*)d_in[12];
    const float* WOw    = (const float*)d_in[13];
    const float* WOb    = (const float*)d_in[14];
    float* out = (float*)d_out;
    (void)in_sizes; (void)n_in; (void)out_size; (void)ws_size;

    float* ws     = (float*)d_ws;
    const size_t QRSZ = (size_t)Bq * Tq * HTq * DHq;  // 6,291,456
    float* Qr     = ws;
    float* Kr     = Qr + QRSZ;
    float* kbase  = Kr + QRSZ;
    float* marker = kbase + (size_t)Bq * Tq * Cq;
    float* psink  = marker + QRSZ;
    float* ctx    = Qr;   // safe alias: Qr dead after attention

    // Q = A @ WQ^T  -> (b,t,48,64)
    gemm_nt_kernel<<<dim3(32, 48), 256, 0, stream>>>(A, WQw, nullptr, Qr, 2048, 3072, 768);
    // k_base = X @ WK^T + WK_b -> (b,t,12,64)
    gemm_nt_kernel<<<dim3(32, 12), 256, 0, stream>>>(X, WKw, WKb, kbase, 2048, 768, 768);
    // wedge + rope
    wedge_rope_kernel<<<1024, 256, 0, stream>>>(Qr, Qr, wA, wB, 48);
    wedge_rope_kernel<<<1024, 256, 0, stream>>>(kbase, Kr, wA, wB, 12);
    // attention + top4 + marker
    attn_topk_kernel<<<Bq * HTq * (Tq / 32), 256, 0, stream>>>(Qr, Kr, sink, marker, psink);
    // MLP + sink context
    mlp_kernel<<<(Bq * HTq * Tq) / 64, 256, 0, stream>>>(marker, psink, V1w, V1b, V2w, V2b, vnulls, ctx);
    // output projection + branch mean
    gemm_wo_kernel<<<dim3(32, 12), 256, 0, stream>>>(ctx, WOw, WOb, out);
}

// Round 2
// 958.306 us; speedup vs baseline: 1.3547x; 1.3547x over previous
//
#include <hip/hip_runtime.h>
#include <math.h>

constexpr int Bq  = 2;
constexpr int Tq  = 1024;
constexpr int NHq = 12;
constexpr int HTq = 48;
constexpr float SCALE = 0.125f;     // 64^-0.5
constexpr float NEG_BIG = -1e30f;

typedef __attribute__((ext_vector_type(8))) short short8;
typedef __attribute__((ext_vector_type(4))) float f32x4;

__device__ inline unsigned short f2bf(float x) {
    unsigned u = __float_as_uint(x);
    return (unsigned short)((u + 0x7FFF + ((u >> 16) & 1)) >> 16);
}

// exact-erf GELU via Abramowitz-Stegun 7.1.26 (|eps_erf| <= 1.5e-7)
__device__ inline float gelu_f(float x) {
    float z = 0.70710678118654752f * x;
    float az = fabsf(z);
    float t = __frcp_rn(1.0f + 0.3275911f * az);
    float poly = t * (0.254829592f + t * (-0.284496736f + t * (1.421413741f
               + t * (-1.453152027f + t * 1.061405429f))));
    float er = 1.0f - poly * __expf(-az * az);
    er = (z < 0.0f) ? -er : er;
    return 0.5f * x * (1.0f + er);
}

// ---------------------------------------------------------------------------
// fp32 GEMM: Out[M,N] = A[M,K] @ W[N,K]^T (+ bias[n]).  128x128 tile, BK=16,
// 8x8 micro-tile, 256 threads.  Exact fp32 (protects top-k score path).
// ---------------------------------------------------------------------------
__global__ __launch_bounds__(256) void gemm_f32_kernel(
    const float* __restrict__ A, const float* __restrict__ W,
    const float* __restrict__ bias, float* __restrict__ Out,
    int M, int N, int K)
{
    __shared__ float sA[16][132];
    __shared__ float sB[16][132];
    int tid = threadIdx.x;
    int tx = tid & 15, ty = tid >> 4;
    int m0 = blockIdx.x * 128, n0 = blockIdx.y * 128;
    float acc[8][8] = {};
    for (int k0 = 0; k0 < K; k0 += 16) {
        __syncthreads();
        #pragma unroll
        for (int s = 0; s < 2; s++) {
            int c = tid * 2 + s;
            int r = c >> 2, k4 = c & 3;
            float4 v = *(const float4*)(A + (size_t)(m0 + r) * K + k0 + k4 * 4);
            sA[k4 * 4 + 0][r] = v.x; sA[k4 * 4 + 1][r] = v.y;
            sA[k4 * 4 + 2][r] = v.z; sA[k4 * 4 + 3][r] = v.w;
            float4 u = *(const float4*)(W + (size_t)(n0 + r) * K + k0 + k4 * 4);
            sB[k4 * 4 + 0][r] = u.x; sB[k4 * 4 + 1][r] = u.y;
            sB[k4 * 4 + 2][r] = u.z; sB[k4 * 4 + 3][r] = u.w;
        }
        __syncthreads();
        #pragma unroll
        for (int kk = 0; kk < 16; kk++) {
            float a_[8], b_[8];
            *(float4*)&a_[0] = *(const float4*)&sA[kk][ty * 8];
            *(float4*)&a_[4] = *(const float4*)&sA[kk][ty * 8 + 4];
            *(float4*)&b_[0] = *(const float4*)&sB[kk][tx * 8];
            *(float4*)&b_[4] = *(const float4*)&sB[kk][tx * 8 + 4];
            #pragma unroll
            for (int i = 0; i < 8; i++)
                #pragma unroll
                for (int j = 0; j < 8; j++)
                    acc[i][j] += a_[i] * b_[j];
        }
    }
    #pragma unroll
    for (int j = 0; j < 8; j++) {
        int col = n0 + tx * 8 + j;
        float bv = bias ? bias[col] : 0.0f;
        #pragma unroll
        for (int i = 0; i < 8; i++) {
            int row = m0 + ty * 8 + i;
            Out[(size_t)row * N + col] = acc[i][j] + bv;
        }
    }
}

// ---------------------------------------------------------------------------
// Fused wedge + rope (unchanged from round 1, exact fp32).
// ---------------------------------------------------------------------------
__global__ __launch_bounds__(256) void wedge_rope_kernel(
    const float* __restrict__ in, float* __restrict__ out,
    const float* __restrict__ wedge_A, const float* __restrict__ wedge_bias,
    int in_heads)
{
    __shared__ float skew[64 * 64];
    __shared__ float buf[4][64];
    __shared__ float buf2[4][64];
    int tid = threadIdx.x;
    for (int l = tid; l < 4096; l += 256) {
        int e = l & 63;
        int d = l >> 6;
        skew[l] = wedge_A[l] - wedge_A[e * 64 + d];
    }
    __syncthreads();
    int wave = tid >> 6, lane = tid & 63;
    const int nrows = Bq * Tq * HTq;   // 98304
    for (int row = blockIdx.x * 4 + wave; row < nrows; row += 4096) {
        int h = row % HTq;
        int bt = row / HTq;
        int t = bt % Tq;
        const float* src = in + ((size_t)bt * in_heads + (h % in_heads)) * 64;
        float x = src[lane];
        buf[wave][lane] = x;
        __syncthreads();
        float acc = 0.0f;
        #pragma unroll 8
        for (int d = 0; d < 64; d++)
            acc += buf[wave][d] * skew[d * 64 + lane];
        float bia = wedge_bias[h * 64 + lane];
        float wz = x * (1.0f + bia) + acc;
        buf2[wave][lane] = wz;
        __syncthreads();
        int i = lane & 31;
        float x1 = buf2[wave][2 * i];
        float x2 = buf2[wave][2 * i + 1];
        float invf = powf(10000.0f, -(float)i * (1.0f / 32.0f));
        float ang = (float)t * invf;
        float cv = cosf(ang), sv = sinf(ang);
        float o = (lane < 32) ? (x1 * cv - x2 * sv) : (x1 * sv + x2 * cv);
        out[((size_t)bt * HTq + h) * 64 + lane] = o;
    }
}

// ---------------------------------------------------------------------------
// Attention core (fp32 scores, exact top-k path).  marker now written as bf16.
// ---------------------------------------------------------------------------
__global__ __launch_bounds__(256) void attn_topk_kernel(
    const float* __restrict__ Qr, const float* __restrict__ Kr,
    const float* __restrict__ sink, unsigned short* __restrict__ markerb,
    float* __restrict__ psink)
{
    __shared__ float K_lds[64][68];
    __shared__ float q_lds[32][68];
    const int nchunk = Tq / 32;             // 32
    int idx = blockIdx.x;
    int bh = idx / nchunk;
    int t0 = (idx % nchunk) * 32;
    int b = bh / HTq, h = bh % HTq;
    int tid = threadIdx.x;
    for (int l = tid; l < 32 * 16; l += 256) {
        int r = l >> 4, c4 = l & 15;
        *(float4*)&q_lds[r][c4 * 4] =
            *(const float4*)(Qr + (((size_t)(b * Tq + t0 + r) * HTq + h) << 6) + c4 * 4);
    }
    int wave = tid >> 6, lane = tid & 63;
    float m_[8], Z_[8], tv[8][4];
    int ti[8][4];
    #pragma unroll
    for (int q = 0; q < 8; q++) {
        m_[q] = NEG_BIG; Z_[q] = 0.0f;
        #pragma unroll
        for (int r = 0; r < 4; r++) { tv[q][r] = -INFINITY; ti[q][r] = 0; }
    }
    int ntiles = (t0 + 32 + 63) >> 6;
    for (int tile = 0; tile < ntiles; tile++) {
        int s0 = tile << 6;
        __syncthreads();
        for (int l = tid; l < 64 * 16; l += 256) {
            int r = l >> 4, c4 = l & 15;
            *(float4*)&K_lds[r][c4 * 4] =
                *(const float4*)(Kr + (((size_t)(b * Tq + s0 + r) * HTq + h) << 6) + c4 * 4);
        }
        __syncthreads();
        float accq[8];
        #pragma unroll
        for (int q = 0; q < 8; q++) accq[q] = 0.0f;
        #pragma unroll
        for (int d4 = 0; d4 < 16; d4++) {
            float4 kv = *(const float4*)&K_lds[lane][d4 * 4];
            #pragma unroll
            for (int q = 0; q < 8; q++) {
                float4 qv = *(const float4*)&q_lds[wave * 8 + q][d4 * 4];
                accq[q] += kv.x * qv.x + kv.y * qv.y + kv.z * qv.z + kv.w * qv.w;
            }
        }
        int sidx = s0 + lane;
        #pragma unroll
        for (int q = 0; q < 8; q++) {
            int trow = t0 + wave * 8 + q;
            float sv = (sidx <= trow) ? accq[q] * SCALE : -INFINITY;
            float nm = fmaxf(m_[q], sv);
            Z_[q] = Z_[q] * __expf(m_[q] - nm) + __expf(sv - nm);
            m_[q] = nm;
            float v = sv; int id = sidx;
            #pragma unroll
            for (int r = 0; r < 4; r++) {
                bool sw = v > tv[q][r];
                float ov = tv[q][r]; int oi = ti[q][r];
                tv[q][r] = sw ? v : ov;  ti[q][r] = sw ? id : oi;
                v = sw ? ov : v;         id = sw ? oi : id;
            }
        }
    }
    float sk = sink[h];
    #pragma unroll
    for (int q = 0; q < 8; q++) {
        int trow = t0 + wave * 8 + q;
        float mr = m_[q];
        #pragma unroll
        for (int off = 32; off; off >>= 1) mr = fmaxf(mr, __shfl_xor(mr, off));
        float z = Z_[q] * __expf(m_[q] - mr);
        #pragma unroll
        for (int off = 32; off; off >>= 1) z += __shfl_xor(z, off);
        float mf = fmaxf(mr, sk);
        float Zf = z * __expf(mr - mf) + __expf(sk - mf);
        float ps = __expf(sk - mf) / Zf;
        float a0 = tv[q][0], a1 = tv[q][1], a2 = tv[q][2], a3 = tv[q][3];
        int   i0 = ti[q][0], i1 = ti[q][1], i2 = ti[q][2], i3 = ti[q][3];
        float bestv[4]; int besti[4];
        #pragma unroll
        for (int r = 0; r < 4; r++) {
            float hv = a0;
            float mv = hv;
            #pragma unroll
            for (int off = 32; off; off >>= 1) mv = fmaxf(mv, __shfl_xor(mv, off));
            unsigned long long ball = __ballot(hv == mv);
            int src = __ffsll(ball) - 1;
            int win_i = __shfl(i0, src);
            bestv[r] = mv; besti[r] = win_i;
            bool winner = (lane == src);
            a0 = winner ? a1 : a0;  i0 = winner ? i1 : i0;
            a1 = winner ? a2 : a1;  i1 = winner ? i2 : i1;
            a2 = winner ? a3 : a2;  i2 = winner ? i3 : i2;
            a3 = winner ? -INFINITY : a3;
        }
        float e0 = __expf(bestv[0] - mf), e1 = __expf(bestv[1] - mf);
        float e2 = __expf(bestv[2] - mf), e3 = __expf(bestv[3] - mf);
        float v0 = e0 / Zf, v1 = e1 / Zf, v2 = e2 / Zf, v3 = e3 / Zf;
        float wsum = v0 + v1 + v2 + v3 + 1e-9f;
        float w0 = v0 / wsum, w1 = v1 / wsum, w2 = v2 / wsum, w3 = v3 / wsum;
        float md = w0 * Kr[(((size_t)(b * Tq + besti[0]) * HTq + h) << 6) + lane]
                 + w1 * Kr[(((size_t)(b * Tq + besti[1]) * HTq + h) << 6) + lane]
                 + w2 * Kr[(((size_t)(b * Tq + besti[2]) * HTq + h) << 6) + lane]
                 + w3 * Kr[(((size_t)(b * Tq + besti[3]) * HTq + h) << 6) + lane];
        markerb[(((size_t)bh * Tq + trow) << 6) + lane] = f2bf(md);
        if (lane == 0) psink[(size_t)bh * Tq + trow] = ps;
    }
}

// ---------------------------------------------------------------------------
// cvt fp32 -> bf16 (vectorized x4)
// ---------------------------------------------------------------------------
__global__ void cvt_bf16_kernel(const float* __restrict__ in,
                                unsigned short* __restrict__ out, int n4)
{
    int i = blockIdx.x * 256 + threadIdx.x;
    if (i < n4) {
        float4 v = ((const float4*)in)[i];
        ushort4 o;
        o.x = f2bf(v.x); o.y = f2bf(v.y); o.z = f2bf(v.z); o.w = f2bf(v.w);
        ((ushort4*)out)[i] = o;
    }
}

// ---------------------------------------------------------------------------
// WO transpose + cvt: WOt[n][d][c] = bf16(WOw[n][c][d])
// ---------------------------------------------------------------------------
__global__ __launch_bounds__(256) void wo_transpose_kernel(
    const float* __restrict__ WOw, unsigned short* __restrict__ WOt)
{
    __shared__ float tl[64][65];
    int tid = threadIdx.x;
    int n = blockIdx.z;
    int c0 = blockIdx.x * 64, d0 = blockIdx.y * 64;
    const float* src = WOw + (size_t)n * 768 * 768;
    for (int l = tid; l < 64 * 16; l += 256) {
        int r = l >> 4, q = l & 15;
        float4 v = *(const float4*)(src + (size_t)(c0 + r) * 768 + d0 + q * 4);
        tl[r][q * 4 + 0] = v.x; tl[r][q * 4 + 1] = v.y;
        tl[r][q * 4 + 2] = v.z; tl[r][q * 4 + 3] = v.w;
    }
    __syncthreads();
    for (int l = tid; l < 64 * 16; l += 256) {
        int d = l >> 4, q = l & 15;
        ushort4 o;
        o.x = f2bf(tl[q * 4 + 0][d]); o.y = f2bf(tl[q * 4 + 1][d]);
        o.z = f2bf(tl[q * 4 + 2][d]); o.w = f2bf(tl[q * 4 + 3][d]);
        *(ushort4*)(WOt + (size_t)n * 768 * 768 + (size_t)(d0 + d) * 768 + c0 + q * 4) = o;
    }
}

// ---------------------------------------------------------------------------
// Fused MLP via MFMA: ctx = gelu(marker @ V1^T + b1) @ V2^T + b2 + psink*v_null
// 64 rows/block, 4 waves; wave w owns rows 16w..16w+15 (no cross-wave h deps,
// barriers kept for LDS write->read safety).  Output ctx written bf16 into
// (b, n, t, 768) layout.
// ---------------------------------------------------------------------------
__global__ __launch_bounds__(256) void mlp_mfma_kernel(
    const unsigned short* __restrict__ markerb, const float* __restrict__ psink,
    const unsigned short* __restrict__ V1b16, const float* __restrict__ V1bias,
    const unsigned short* __restrict__ V2b16, const float* __restrict__ V2bias,
    const float* __restrict__ vnulls, unsigned short* __restrict__ ctxb)
{
    __shared__ float h_lds[4][16][65];
    int tid = threadIdx.x;
    int w = tid >> 6, lane = tid & 63;
    int rf = lane & 15, kg = lane >> 4;
    size_t r0 = (size_t)blockIdx.x * 64 + 16 * w;

    short8 a1[2];
    #pragma unroll
    for (int kk = 0; kk < 2; kk++)
        a1[kk] = *(const short8*)(markerb + (r0 + rf) * 64 + kk * 32 + kg * 8);

    f32x4 acc2[4] = {};
    for (int ch = 0; ch < 4; ch++) {
        f32x4 acc1[4] = {};
        #pragma unroll
        for (int nj = 0; nj < 4; nj++)
            #pragma unroll
            for (int kk = 0; kk < 2; kk++) {
                short8 b1 = *(const short8*)(V1b16 + (size_t)(ch * 64 + nj * 16 + rf) * 64 + kk * 32 + kg * 8);
                acc1[nj] = __builtin_amdgcn_mfma_f32_16x16x32_bf16(a1[kk], b1, acc1[nj], 0, 0, 0);
            }
        __syncthreads();   // protect h_lds reuse from previous chunk's reads
        #pragma unroll
        for (int nj = 0; nj < 4; nj++) {
            float bb = V1bias[ch * 64 + nj * 16 + rf];
            #pragma unroll
            for (int r = 0; r < 4; r++) {
                float x = acc1[nj][r] + bb;
                h_lds[w][kg * 4 + r][nj * 16 + rf] = gelu_f(x);
            }
        }
        __syncthreads();   // h writes visible before reads
        #pragma unroll
        for (int kk = 0; kk < 2; kk++) {
            const float* hp = &h_lds[w][rf][kk * 32 + kg * 8];
            float4 p0 = *(const float4*)hp;
            float4 p1 = *(const float4*)(hp + 4);
            short8 a2;
            a2[0] = (short)f2bf(p0.x); a2[1] = (short)f2bf(p0.y);
            a2[2] = (short)f2bf(p0.z); a2[3] = (short)f2bf(p0.w);
            a2[4] = (short)f2bf(p1.x); a2[5] = (short)f2bf(p1.y);
            a2[6] = (short)f2bf(p1.z); a2[7] = (short)f2bf(p1.w);
            #pragma unroll
            for (int njo = 0; njo < 4; njo++) {
                short8 b2 = *(const short8*)(V2b16 + (size_t)(njo * 16 + rf) * 256 + ch * 64 + kk * 32 + kg * 8);
                acc2[njo] = __builtin_amdgcn_mfma_f32_16x16x32_bf16(a2, b2, acc2[njo], 0, 0, 0);
            }
        }
    }
    #pragma unroll
    for (int r = 0; r < 4; r++) {
        size_t R = r0 + kg * 4 + r;
        int bh = (int)(R >> 10), t = (int)(R & 1023);
        int b = bh / 48, h = bh % 48;
        int n = h / 12, head = h % 12;
        float ps = psink[R];
        size_t base = ((size_t)((b * 4 + n) * 1024 + t)) * 768 + head * 64;
        #pragma unroll
        for (int njo = 0; njo < 4; njo++) {
            int d = njo * 16 + rf;
            float v = acc2[njo][r] + V2bias[d] + ps * vnulls[h * 64 + d];
            ctxb[base + d] = f2bf(v);
        }
    }
}

// ---------------------------------------------------------------------------
// WO projection via MFMA: Out[2048,768] = 0.25*(sum_n ctx_n @ WOt_n^T-ish + sum_n b_n)
// 64x64 tile, 4 waves (2x2), XOR-swizzled bf16 LDS tiles.
// ---------------------------------------------------------------------------
__global__ __launch_bounds__(256) void gemm_wo_mfma(
    const unsigned short* __restrict__ ctxb, const unsigned short* __restrict__ WOtb,
    const float* __restrict__ WOb, float* __restrict__ Out)
{
    __shared__ unsigned short sA[64 * 64];
    __shared__ unsigned short sB[64 * 64];
    int tid = threadIdx.x;
    int w = tid >> 6, lane = tid & 63;
    int wm = w >> 1, wn = w & 1;
    int rf = lane & 15, kg = lane >> 4;
    int m0 = blockIdx.x * 64, n0 = blockIdx.y * 64;
    int b = m0 >> 10, t0 = m0 & 1023;
    int c0 = tid * 2, c1 = tid * 2 + 1;
    int ra = c0 >> 3, ca = c0 & 7, rb = c1 >> 3, cb = c1 & 7;
    f32x4 acc[2][2] = {};
    for (int n = 0; n < 4; n++) {
        const unsigned short* Ab = ctxb + ((size_t)((b * 4 + n) * 1024 + t0)) * 768;
        const unsigned short* Bb = WOtb + (size_t)n * 768 * 768 + (size_t)n0 * 768;
        for (int k0 = 0; k0 < 768; k0 += 64) {
            __syncthreads();
            *(short8*)&sA[ra * 64 + ((ca ^ (ra & 7)) * 8)] = *(const short8*)(Ab + (size_t)ra * 768 + k0 + ca * 8);
            *(short8*)&sA[rb * 64 + ((cb ^ (rb & 7)) * 8)] = *(const short8*)(Ab + (size_t)rb * 768 + k0 + cb * 8);
            *(short8*)&sB[ra * 64 + ((ca ^ (ra & 7)) * 8)] = *(const short8*)(Bb + (size_t)ra * 768 + k0 + ca * 8);
            *(short8*)&sB[rb * 64 + ((cb ^ (rb & 7)) * 8)] = *(const short8*)(Bb + (size_t)rb * 768 + k0 + cb * 8);
            __syncthreads();
            #pragma unroll
            for (int kk = 0; kk < 2; kk++) {
                int kc = kk * 4 + kg;
                int rA0 = wm * 32 + rf, rA1 = wm * 32 + 16 + rf;
                int rB0 = wn * 32 + rf, rB1 = wn * 32 + 16 + rf;
                short8 a0v = *(const short8*)&sA[rA0 * 64 + ((kc ^ (rA0 & 7)) * 8)];
                short8 a1v = *(const short8*)&sA[rA1 * 64 + ((kc ^ (rA1 & 7)) * 8)];
                short8 b0v = *(const short8*)&sB[rB0 * 64 + ((kc ^ (rB0 & 7)) * 8)];
                short8 b1v = *(const short8*)&sB[rB1 * 64 + ((kc ^ (rB1 & 7)) * 8)];
                acc[0][0] = __builtin_amdgcn_mfma_f32_16x16x32_bf16(a0v, b0v, acc[0][0], 0, 0, 0);
                acc[0][1] = __builtin_amdgcn_mfma_f32_16x16x32_bf16(a0v, b1v, acc[0][1], 0, 0, 0);
                acc[1][0] = __builtin_amdgcn_mfma_f32_16x16x32_bf16(a1v, b0v, acc[1][0], 0, 0, 0);
                acc[1][1] = __builtin_amdgcn_mfma_f32_16x16x32_bf16(a1v, b1v, acc[1][1], 0, 0, 0);
            }
        }
    }
    #pragma unroll
    for (int nj = 0; nj < 2; nj++) {
        int col = n0 + wn * 32 + nj * 16 + rf;
        float bm = WOb[col] + WOb[768 + col] + WOb[1536 + col] + WOb[2304 + col];
        #pragma unroll
        for (int mi = 0; mi < 2; mi++)
            #pragma unroll
            for (int r = 0; r < 4; r++) {
                int row = m0 + wm * 32 + mi * 16 + kg * 4 + r;
                Out[(size_t)row * 768 + col] = 0.25f * (acc[mi][nj][r] + bm);
            }
    }
}

// ---------------------------------------------------------------------------
extern "C" void kernel_launch(void* const* d_in, const int* in_sizes, int n_in,
                              void* d_out, int out_size, void* d_ws, size_t ws_size,
                              hipStream_t stream) {
    const float* A      = (const float*)d_in[0];
    const float* X      = (const float*)d_in[1];
    const float* WKw    = (const float*)d_in[2];
    const float* WKb    = (const float*)d_in[3];
    const float* WQw    = (const float*)d_in[4];
    const float* wA     = (const float*)d_in[5];
    const float* wB     = (const float*)d_in[6];
    const float* sink   = (const float*)d_in[7];
    const float* vnulls = (const float*)d_in[8];
    const float* V1w    = (const float*)d_in[9];
    const float* V1b    = (const float*)d_in[10];
    const float* V2w    = (const float*)d_in[11];
    const float* V2b    = (const float*)d_in[12];
    const float* WOw    = (const float*)d_in[13];
    const float* WOb    = (const float*)d_in[14];
    float* out = (float*)d_out;
    (void)in_sizes; (void)n_in; (void)out_size; (void)ws_size;

    float* ws = (float*)d_ws;
    const size_t QRSZ = (size_t)Bq * Tq * HTq * 64;        // 6,291,456
    float* Qr    = ws;                                      // 6.29M f
    float* Kr    = Qr + QRSZ;                               // 6.29M f
    float* kbase = Kr + QRSZ;                               // 1.57M f (dead after rope)
    float* psink = kbase;                                   // alias (98304 f)
    unsigned short* markerb = (unsigned short*)(kbase + (size_t)Bq * Tq * 768);
    unsigned short* V1b16 = markerb + QRSZ;                 // 16384 us
    unsigned short* V2b16 = V1b16 + 16384;                  // 16384 us
    unsigned short* WOtb  = V2b16 + 16384;                  // 2,359,296 us
    unsigned short* ctxb  = (unsigned short*)Qr;            // alias (Qr dead after attn)

    // projections (exact fp32 — protects top-k ordering)
    gemm_f32_kernel<<<dim3(16, 24), 256, 0, stream>>>(A, WQw, nullptr, Qr, 2048, 3072, 768);
    gemm_f32_kernel<<<dim3(16, 6), 256, 0, stream>>>(X, WKw, WKb, kbase, 2048, 768, 768);
    // wedge + rope (fp32)
    wedge_rope_kernel<<<1024, 256, 0, stream>>>(Qr, Qr, wA, wB, 48);
    wedge_rope_kernel<<<1024, 256, 0, stream>>>(kbase, Kr, wA, wB, 12);
    // weight conversions for the post-topk (smooth) path
    cvt_bf16_kernel<<<16, 256, 0, stream>>>(V1w, V1b16, 4096);
    cvt_bf16_kernel<<<16, 256, 0, stream>>>(V2w, V2b16, 4096);
    wo_transpose_kernel<<<dim3(12, 12, 4), 256, 0, stream>>>(WOw, WOtb);
    // attention + top4 + marker (bf16 out)
    attn_topk_kernel<<<Bq * HTq * (Tq / 32), 256, 0, stream>>>(Qr, Kr, sink, markerb, psink);
    // fused MLP (MFMA)
    mlp_mfma_kernel<<<(Bq * HTq * Tq) / 64, 256, 0, stream>>>(markerb, psink, V1b16, V1b, V2b16, V2b, vnulls, ctxb);
    // output projection + branch mean (MFMA)
    gemm_wo_mfma<<<dim3(32, 12), 256, 0, stream>>>(ctxb, WOtb, WOb, out);
}

// Round 3
// 596.673 us; speedup vs baseline: 2.1757x; 1.6061x over previous
//
#include <hip/hip_runtime.h>
#include <math.h>

constexpr int Bq  = 2;
constexpr int Tq  = 1024;
constexpr int NHq = 12;
constexpr int HTq = 48;
constexpr float SCALE = 0.125f;     // 64^-0.5

typedef __attribute__((ext_vector_type(8))) short short8;
typedef __attribute__((ext_vector_type(4))) float f32x4;

__device__ inline unsigned short f2bf(float x) {
    unsigned u = __float_as_uint(x);
    return (unsigned short)((u + 0x7FFF + ((u >> 16) & 1)) >> 16);
}

// exact-erf GELU via Abramowitz-Stegun 7.1.26 (|eps_erf| <= 1.5e-7)
__device__ inline float gelu_f(float x) {
    float z = 0.70710678118654752f * x;
    float az = fabsf(z);
    float t = __frcp_rn(1.0f + 0.3275911f * az);
    float poly = t * (0.254829592f + t * (-0.284496736f + t * (1.421413741f
               + t * (-1.453152027f + t * 1.061405429f))));
    float er = 1.0f - poly * __expf(-az * az);
    er = (z < 0.0f) ? -er : er;
    return 0.5f * x * (1.0f + er);
}

// ---------------------------------------------------------------------------
// fp32 GEMM: Out[M,N] = A[M,K] @ W[N,K]^T (+ bias[n]).  128x128 tile, BK=16,
// 8x8 micro-tile, 256 threads.  Exact fp32 (protects top-k score path).
// ---------------------------------------------------------------------------
__global__ __launch_bounds__(256) void gemm_f32_kernel(
    const float* __restrict__ A, const float* __restrict__ W,
    const float* __restrict__ bias, float* __restrict__ Out,
    int M, int N, int K)
{
    __shared__ float sA[16][132];
    __shared__ float sB[16][132];
    int tid = threadIdx.x;
    int tx = tid & 15, ty = tid >> 4;
    int m0 = blockIdx.x * 128, n0 = blockIdx.y * 128;
    float acc[8][8] = {};
    for (int k0 = 0; k0 < K; k0 += 16) {
        __syncthreads();
        #pragma unroll
        for (int s = 0; s < 2; s++) {
            int c = tid * 2 + s;
            int r = c >> 2, k4 = c & 3;
            float4 v = *(const float4*)(A + (size_t)(m0 + r) * K + k0 + k4 * 4);
            sA[k4 * 4 + 0][r] = v.x; sA[k4 * 4 + 1][r] = v.y;
            sA[k4 * 4 + 2][r] = v.z; sA[k4 * 4 + 3][r] = v.w;
            float4 u = *(const float4*)(W + (size_t)(n0 + r) * K + k0 + k4 * 4);
            sB[k4 * 4 + 0][r] = u.x; sB[k4 * 4 + 1][r] = u.y;
            sB[k4 * 4 + 2][r] = u.z; sB[k4 * 4 + 3][r] = u.w;
        }
        __syncthreads();
        #pragma unroll
        for (int kk = 0; kk < 16; kk++) {
            float a_[8], b_[8];
            *(float4*)&a_[0] = *(const float4*)&sA[kk][ty * 8];
            *(float4*)&a_[4] = *(const float4*)&sA[kk][ty * 8 + 4];
            *(float4*)&b_[0] = *(const float4*)&sB[kk][tx * 8];
            *(float4*)&b_[4] = *(const float4*)&sB[kk][tx * 8 + 4];
            #pragma unroll
            for (int i = 0; i < 8; i++)
                #pragma unroll
                for (int j = 0; j < 8; j++)
                    acc[i][j] += a_[i] * b_[j];
        }
    }
    #pragma unroll
    for (int j = 0; j < 8; j++) {
        int col = n0 + tx * 8 + j;
        float bv = bias ? bias[col] : 0.0f;
        #pragma unroll
        for (int i = 0; i < 8; i++) {
            int row = m0 + ty * 8 + i;
            Out[(size_t)row * N + col] = acc[i][j] + bv;
        }
    }
}

// ---------------------------------------------------------------------------
// Fused wedge + rope.  in: (b*T + t, in_heads, 64).
// out32/out16 (head-major): [((b*48+h)*1024 + t)*64 + d]
// Same fp32 summation order as round 1/2 (d ascending, single accumulator).
// ---------------------------------------------------------------------------
__global__ __launch_bounds__(256) void wedge_rope_kernel(
    const float* __restrict__ in, float* __restrict__ out32,
    unsigned short* __restrict__ out16,
    const float* __restrict__ wedge_A, const float* __restrict__ wedge_bias,
    int in_heads)
{
    __shared__ float skewT[64 * 68];
    __shared__ float buf[4][64];
    __shared__ float buf2[4][64];
    int tid = threadIdx.x;
    for (int l = tid; l < 4096; l += 256) {
        int d = l >> 6, e = l & 63;
        skewT[e * 68 + d] = wedge_A[l] - wedge_A[e * 64 + d];
    }
    __syncthreads();
    int wave = tid >> 6, lane = tid & 63;
    const int nrows = Bq * Tq * HTq;   // 98304; exactly 24 uniform iterations
    for (int row = blockIdx.x * 4 + wave; row < nrows; row += 4096) {
        int h = row % HTq;
        int bt = row / HTq;
        int t = bt % Tq;
        int b = bt / Tq;
        const float* src = in + ((size_t)bt * in_heads + (h % in_heads)) * 64;
        float x = src[lane];
        buf[wave][lane] = x;
        __syncthreads();
        float acc = 0.0f;
        #pragma unroll
        for (int d4 = 0; d4 < 16; d4++) {
            float4 sv4 = *(const float4*)&skewT[lane * 68 + d4 * 4];
            float4 bv4 = *(const float4*)&buf[wave][d4 * 4];
            acc += bv4.x * sv4.x; acc += bv4.y * sv4.y;
            acc += bv4.z * sv4.z; acc += bv4.w * sv4.w;
        }
        float bia = wedge_bias[h * 64 + lane];
        float wz = x * (1.0f + bia) + acc;
        buf2[wave][lane] = wz;
        __syncthreads();
        int i = lane & 31;
        float x1 = buf2[wave][2 * i];
        float x2 = buf2[wave][2 * i + 1];
        float invf = powf(10000.0f, -(float)i * (1.0f / 32.0f));
        float ang = (float)t * invf;
        float cv = cosf(ang), sv = sinf(ang);
        float o = (lane < 32) ? (x1 * cv - x2 * sv) : (x1 * sv + x2 * cv);
        size_t oidx = (((size_t)(b * HTq + h)) * Tq + t) * 64 + lane;
        out32[oidx] = o;
        if (out16) out16[oidx] = f2bf(o);
    }
}

// ---------------------------------------------------------------------------
// Attention core, MFMA edition: bf16 MFMA scores -> online (m,Z) + per-lane
// top-4; per q-row merge to top-8 shortlist -> exact fp32 re-score -> stable
// top-4 -> weights -> marker.  4 independent waves, no LDS, no barriers.
// ---------------------------------------------------------------------------
__global__ __launch_bounds__(256) void attn_mfma_topk_kernel(
    const float* __restrict__ Qr, const float* __restrict__ Kr,
    const unsigned short* __restrict__ Kb, const float* __restrict__ sink,
    unsigned short* __restrict__ markerb, float* __restrict__ psink)
{
    const int bh = blockIdx.x;                 // 0..95
    const int qb = 15 - (int)blockIdx.y;       // longest blocks first
    const int w = threadIdx.x >> 6, lane = threadIdx.x & 63;
    const int rf = lane & 15, kg = lane >> 4;
    const int h = bh % HTq;
    const int q0 = qb * 64 + w * 16;
    const size_t rowbase = (size_t)bh * Tq;

    short8 a0, a1;
    {
        const float* qp = Qr + (rowbase + q0 + rf) * 64 + kg * 8;
        float4 u0 = *(const float4*)qp;
        float4 u1 = *(const float4*)(qp + 4);
        float4 u2 = *(const float4*)(qp + 32);
        float4 u3 = *(const float4*)(qp + 36);
        a0[0]=(short)f2bf(u0.x); a0[1]=(short)f2bf(u0.y); a0[2]=(short)f2bf(u0.z); a0[3]=(short)f2bf(u0.w);
        a0[4]=(short)f2bf(u1.x); a0[5]=(short)f2bf(u1.y); a0[6]=(short)f2bf(u1.z); a0[7]=(short)f2bf(u1.w);
        a1[0]=(short)f2bf(u2.x); a1[1]=(short)f2bf(u2.y); a1[2]=(short)f2bf(u2.z); a1[3]=(short)f2bf(u2.w);
        a1[4]=(short)f2bf(u3.x); a1[5]=(short)f2bf(u3.y); a1[6]=(short)f2bf(u3.z); a1[7]=(short)f2bf(u3.w);
    }

    float m_[4], Z_[4], tv[4][4];
    int ti[4][4];
    #pragma unroll
    for (int r = 0; r < 4; r++) {
        m_[r] = -1e30f; Z_[r] = 0.0f;
        #pragma unroll
        for (int p = 0; p < 4; p++) { tv[r][p] = -INFINITY; ti[r][p] = -1; }
    }

    const int T = (q0 + 15) / 64 + 1;
    const unsigned short* Kbb = Kb + rowbase * 64;
    for (int tile = 0; tile < T; tile++) {
        const int s0 = tile << 6;
        f32x4 accs[4];
        #pragma unroll
        for (int kc = 0; kc < 4; kc++) {
            const unsigned short* kp = Kbb + (size_t)(s0 + kc * 16 + rf) * 64 + kg * 8;
            short8 b0 = *(const short8*)kp;
            short8 b1 = *(const short8*)(kp + 32);
            f32x4 acc = {0.f, 0.f, 0.f, 0.f};
            acc = __builtin_amdgcn_mfma_f32_16x16x32_bf16(a0, b0, acc, 0, 0, 0);
            acc = __builtin_amdgcn_mfma_f32_16x16x32_bf16(a1, b1, acc, 0, 0, 0);
            accs[kc] = acc;
        }
        const bool lastt = (tile == T - 1);
        #pragma unroll
        for (int r = 0; r < 4; r++) {
            const int trow = q0 + kg * 4 + r;
            float sv[4];
            #pragma unroll
            for (int kc = 0; kc < 4; kc++) {
                int k = s0 + kc * 16 + rf;
                float s = accs[kc][r] * SCALE;
                sv[kc] = (lastt && k > trow) ? -INFINITY : s;
            }
            float tm = fmaxf(fmaxf(sv[0], sv[1]), fmaxf(sv[2], sv[3]));
            float nm = fmaxf(m_[r], tm);
            float zz = Z_[r] * __expf(m_[r] - nm);
            #pragma unroll
            for (int kc = 0; kc < 4; kc++) zz += __expf(sv[kc] - nm);
            Z_[r] = zz; m_[r] = nm;
            #pragma unroll
            for (int kc = 0; kc < 4; kc++) {
                float v = sv[kc]; int id = s0 + kc * 16 + rf;
                #pragma unroll
                for (int p = 0; p < 4; p++) {
                    bool sw = v > tv[r][p];
                    float ov = tv[r][p]; int oi = ti[r][p];
                    tv[r][p] = sw ? v : ov;  ti[r][p] = sw ? id : oi;
                    v = sw ? ov : v;          id = sw ? oi : id;
                }
            }
        }
    }

    const float sk = sink[h];
    #pragma unroll 1
    for (int r = 0; r < 4; r++) {
        const int q = q0 + kg * 4 + r;
        float m = m_[r], Z = Z_[r];
        #pragma unroll
        for (int off = 1; off < 16; off <<= 1) {
            float om = __shfl_xor(m, off);
            float oz = __shfl_xor(Z, off);
            float nm = fmaxf(m, om);
            Z = Z * __expf(m - nm) + oz * __expf(om - nm);
            m = nm;
        }
        float av[4]; int ai[4];
        #pragma unroll
        for (int p = 0; p < 4; p++) { av[p] = tv[r][p]; ai[p] = ti[r][p]; }
        float cvv[8]; int ci[8];
        #pragma unroll
        for (int rd = 0; rd < 8; rd++) {
            float v = av[0]; int id = ai[0];
            #pragma unroll
            for (int off = 1; off < 16; off <<= 1) {
                float ov = __shfl_xor(v, off);
                int oi = __shfl_xor(id, off);
                bool take = (ov > v) || ((ov == v) && ((unsigned)oi < (unsigned)id));
                v = take ? ov : v; id = take ? oi : id;
            }
            cvv[rd] = v; ci[rd] = id;
            bool own = (ai[0] == id) && (av[0] == v);
            av[0] = own ? av[1] : av[0];  ai[0] = own ? ai[1] : ai[0];
            av[1] = own ? av[2] : av[1];  ai[1] = own ? ai[2] : ai[1];
            av[2] = own ? av[3] : av[2];  ai[2] = own ? ai[3] : ai[2];
            av[3] = own ? -INFINITY : av[3]; ai[3] = own ? -1 : ai[3];
        }
        const float4 qv = *(const float4*)(Qr + (rowbase + q) * 64 + rf * 4);
        float sc[8];
        #pragma unroll
        for (int c = 0; c < 8; c++) {
            int idx = ci[c] < 0 ? 0 : ci[c];
            const float4 kv = *(const float4*)(Kr + (rowbase + idx) * 64 + rf * 4);
            float p = qv.x * kv.x + qv.y * kv.y + qv.z * kv.z + qv.w * kv.w;
            #pragma unroll
            for (int off = 1; off < 16; off <<= 1) p += __shfl_xor(p, off);
            sc[c] = (ci[c] < 0) ? -1e30f : p * SCALE;
        }
        float bv[4]; int bi[4];
        #pragma unroll
        for (int rd = 0; rd < 4; rd++) {
            float v = sc[0]; int id = ci[0];
            #pragma unroll
            for (int c = 1; c < 8; c++) {
                bool take = (sc[c] > v) || ((sc[c] == v) && ((unsigned)ci[c] < (unsigned)id));
                v = take ? sc[c] : v; id = take ? ci[c] : id;
            }
            bv[rd] = v; bi[rd] = id;
            #pragma unroll
            for (int c = 0; c < 8; c++) {
                bool kill = (ci[c] == id) && (sc[c] == v);
                sc[c] = kill ? -3e30f : sc[c];
            }
        }
        float mf = fmaxf(m, sk);
        float Zf = Z * __expf(m - mf) + __expf(sk - mf);
        float e0 = __expf(bv[0] - mf), e1 = __expf(bv[1] - mf);
        float e2 = __expf(bv[2] - mf), e3 = __expf(bv[3] - mf);
        float wsum = e0 + e1 + e2 + e3 + Zf * 1e-9f;
        float w0 = e0 / wsum, w1 = e1 / wsum, w2 = e2 / wsum, w3 = e3 / wsum;
        int i0 = bi[0] < 0 ? 0 : bi[0];
        int i1 = bi[1] < 0 ? 0 : bi[1];
        int i2 = bi[2] < 0 ? 0 : bi[2];
        int i3 = bi[3] < 0 ? 0 : bi[3];
        const float4 k0 = *(const float4*)(Kr + (rowbase + i0) * 64 + rf * 4);
        const float4 k1 = *(const float4*)(Kr + (rowbase + i1) * 64 + rf * 4);
        const float4 k2 = *(const float4*)(Kr + (rowbase + i2) * 64 + rf * 4);
        const float4 k3 = *(const float4*)(Kr + (rowbase + i3) * 64 + rf * 4);
        float mx = w0 * k0.x + w1 * k1.x + w2 * k2.x + w3 * k3.x;
        float my = w0 * k0.y + w1 * k1.y + w2 * k2.y + w3 * k3.y;
        float mz = w0 * k0.z + w1 * k1.z + w2 * k2.z + w3 * k3.z;
        float mw = w0 * k0.w + w1 * k1.w + w2 * k2.w + w3 * k3.w;
        ushort4 mo;
        mo.x = f2bf(mx); mo.y = f2bf(my); mo.z = f2bf(mz); mo.w = f2bf(mw);
        *(ushort4*)(markerb + (rowbase + q) * 64 + rf * 4) = mo;
        if (rf == 0) psink[rowbase + q] = __expf(sk - mf) / Zf;
    }
}

// ---------------------------------------------------------------------------
__global__ void cvt_bf16_kernel(const float* __restrict__ in,
                                unsigned short* __restrict__ out, int n4)
{
    int i = blockIdx.x * 256 + threadIdx.x;
    if (i < n4) {
        float4 v = ((const float4*)in)[i];
        ushort4 o;
        o.x = f2bf(v.x); o.y = f2bf(v.y); o.z = f2bf(v.z); o.w = f2bf(v.w);
        ((ushort4*)out)[i] = o;
    }
}

// ---------------------------------------------------------------------------
__global__ __launch_bounds__(256) void wo_transpose_kernel(
    const float* __restrict__ WOw, unsigned short* __restrict__ WOt)
{
    __shared__ float tl[64][65];
    int tid = threadIdx.x;
    int n = blockIdx.z;
    int c0 = blockIdx.x * 64, d0 = blockIdx.y * 64;
    const float* src = WOw + (size_t)n * 768 * 768;
    for (int l = tid; l < 64 * 16; l += 256) {
        int r = l >> 4, q = l & 15;
        float4 v = *(const float4*)(src + (size_t)(c0 + r) * 768 + d0 + q * 4);
        tl[r][q * 4 + 0] = v.x; tl[r][q * 4 + 1] = v.y;
        tl[r][q * 4 + 2] = v.z; tl[r][q * 4 + 3] = v.w;
    }
    __syncthreads();
    for (int l = tid; l < 64 * 16; l += 256) {
        int d = l >> 4, q = l & 15;
        ushort4 o;
        o.x = f2bf(tl[q * 4 + 0][d]); o.y = f2bf(tl[q * 4 + 1][d]);
        o.z = f2bf(tl[q * 4 + 2][d]); o.w = f2bf(tl[q * 4 + 3][d]);
        *(ushort4*)(WOt + (size_t)n * 768 * 768 + (size_t)(d0 + d) * 768 + c0 + q * 4) = o;
    }
}

// ---------------------------------------------------------------------------
__global__ __launch_bounds__(256) void mlp_mfma_kernel(
    const unsigned short* __restrict__ markerb, const float* __restrict__ psink,
    const unsigned short* __restrict__ V1b16, const float* __restrict__ V1bias,
    const unsigned short* __restrict__ V2b16, const float* __restrict__ V2bias,
    const float* __restrict__ vnulls, unsigned short* __restrict__ ctxb)
{
    __shared__ float h_lds[4][16][65];
    int tid = threadIdx.x;
    int w = tid >> 6, lane = tid & 63;
    int rf = lane & 15, kg = lane >> 4;
    size_t r0 = (size_t)blockIdx.x * 64 + 16 * w;

    short8 a1[2];
    #pragma unroll
    for (int kk = 0; kk < 2; kk++)
        a1[kk] = *(const short8*)(markerb + (r0 + rf) * 64 + kk * 32 + kg * 8);

    f32x4 acc2[4] = {};
    for (int ch = 0; ch < 4; ch++) {
        f32x4 acc1[4] = {};
        #pragma unroll
        for (int nj = 0; nj < 4; nj++)
            #pragma unroll
            for (int kk = 0; kk < 2; kk++) {
                short8 b1 = *(const short8*)(V1b16 + (size_t)(ch * 64 + nj * 16 + rf) * 64 + kk * 32 + kg * 8);
                acc1[nj] = __builtin_amdgcn_mfma_f32_16x16x32_bf16(a1[kk], b1, acc1[nj], 0, 0, 0);
            }
        __syncthreads();
        #pragma unroll
        for (int nj = 0; nj < 4; nj++) {
            float bb = V1bias[ch * 64 + nj * 16 + rf];
            #pragma unroll
            for (int r = 0; r < 4; r++) {
                float x = acc1[nj][r] + bb;
                h_lds[w][kg * 4 + r][nj * 16 + rf] = gelu_f(x);
            }
        }
        __syncthreads();
        #pragma unroll
        for (int kk = 0; kk < 2; kk++) {
            const float* hp = &h_lds[w][rf][kk * 32 + kg * 8];
            float4 p0 = *(const float4*)hp;
            float4 p1 = *(const float4*)(hp + 4);
            short8 a2;
            a2[0] = (short)f2bf(p0.x); a2[1] = (short)f2bf(p0.y);
            a2[2] = (short)f2bf(p0.z); a2[3] = (short)f2bf(p0.w);
            a2[4] = (short)f2bf(p1.x); a2[5] = (short)f2bf(p1.y);
            a2[6] = (short)f2bf(p1.z); a2[7] = (short)f2bf(p1.w);
            #pragma unroll
            for (int njo = 0; njo < 4; njo++) {
                short8 b2 = *(const short8*)(V2b16 + (size_t)(njo * 16 + rf) * 256 + ch * 64 + kk * 32 + kg * 8);
                acc2[njo] = __builtin_amdgcn_mfma_f32_16x16x32_bf16(a2, b2, acc2[njo], 0, 0, 0);
            }
        }
    }
    #pragma unroll
    for (int r = 0; r < 4; r++) {
        size_t R = r0 + kg * 4 + r;
        int bh = (int)(R >> 10), t = (int)(R & 1023);
        int b = bh / 48, h = bh % 48;
        int n = h / 12, head = h % 12;
        float ps = psink[R];
        size_t base = ((size_t)((b * 4 + n) * 1024 + t)) * 768 + head * 64;
        #pragma unroll
        for (int njo = 0; njo < 4; njo++) {
            int d = njo * 16 + rf;
            float v = acc2[njo][r] + V2bias[d] + ps * vnulls[h * 64 + d];
            ctxb[base + d] = f2bf(v);
        }
    }
}

// ---------------------------------------------------------------------------
__global__ __launch_bounds__(256) void gemm_wo_mfma(
    const unsigned short* __restrict__ ctxb, const unsigned short* __restrict__ WOtb,
    const float* __restrict__ WOb, float* __restrict__ Out)
{
    __shared__ unsigned short sA[64 * 64];
    __shared__ unsigned short sB[64 * 64];
    int tid = threadIdx.x;
    int w = tid >> 6, lane = tid & 63;
    int wm = w >> 1, wn = w & 1;
    int rf = lane & 15, kg = lane >> 4;
    int m0 = blockIdx.x * 64, n0 = blockIdx.y * 64;
    int b = m0 >> 10, t0 = m0 & 1023;
    int c0 = tid * 2, c1 = tid * 2 + 1;
    int ra = c0 >> 3, ca = c0 & 7, rb = c1 >> 3, cb = c1 & 7;
    f32x4 acc[2][2] = {};
    for (int n = 0; n < 4; n++) {
        const unsigned short* Ab = ctxb + ((size_t)((b * 4 + n) * 1024 + t0)) * 768;
        const unsigned short* Bb = WOtb + (size_t)n * 768 * 768 + (size_t)n0 * 768;
        for (int k0 = 0; k0 < 768; k0 += 64) {
            __syncthreads();
            *(short8*)&sA[ra * 64 + ((ca ^ (ra & 7)) * 8)] = *(const short8*)(Ab + (size_t)ra * 768 + k0 + ca * 8);
            *(short8*)&sA[rb * 64 + ((cb ^ (rb & 7)) * 8)] = *(const short8*)(Ab + (size_t)rb * 768 + k0 + cb * 8);
            *(short8*)&sB[ra * 64 + ((ca ^ (ra & 7)) * 8)] = *(const short8*)(Bb + (size_t)ra * 768 + k0 + ca * 8);
            *(short8*)&sB[rb * 64 + ((cb ^ (rb & 7)) * 8)] = *(const short8*)(Bb + (size_t)rb * 768 + k0 + cb * 8);
            __syncthreads();
            #pragma unroll
            for (int kk = 0; kk < 2; kk++) {
                int kc = kk * 4 + kg;
                int rA0 = wm * 32 + rf, rA1 = wm * 32 + 16 + rf;
                int rB0 = wn * 32 + rf, rB1 = wn * 32 + 16 + rf;
                short8 a0v = *(const short8*)&sA[rA0 * 64 + ((kc ^ (rA0 & 7)) * 8)];
                short8 a1v = *(const short8*)&sA[rA1 * 64 + ((kc ^ (rA1 & 7)) * 8)];
                short8 b0v = *(const short8*)&sB[rB0 * 64 + ((kc ^ (rB0 & 7)) * 8)];
                short8 b1v = *(const short8*)&sB[rB1 * 64 + ((kc ^ (rB1 & 7)) * 8)];
                acc[0][0] = __builtin_amdgcn_mfma_f32_16x16x32_bf16(a0v, b0v, acc[0][0], 0, 0, 0);
                acc[0][1] = __builtin_amdgcn_mfma_f32_16x16x32_bf16(a0v, b1v, acc[0][1], 0, 0, 0);
                acc[1][0] = __builtin_amdgcn_mfma_f32_16x16x32_bf16(a1v, b0v, acc[1][0], 0, 0, 0);
                acc[1][1] = __builtin_amdgcn_mfma_f32_16x16x32_bf16(a1v, b1v, acc[1][1], 0, 0, 0);
            }
        }
    }
    #pragma unroll
    for (int nj = 0; nj < 2; nj++) {
        int col = n0 + wn * 32 + nj * 16 + rf;
        float bm = WOb[col] + WOb[768 + col] + WOb[1536 + col] + WOb[2304 + col];
        #pragma unroll
        for (int mi = 0; mi < 2; mi++)
            #pragma unroll
            for (int r = 0; r < 4; r++) {
                int row = m0 + wm * 32 + mi * 16 + kg * 4 + r;
                Out[(size_t)row * 768 + col] = 0.25f * (acc[mi][nj][r] + bm);
            }
    }
}

// ---------------------------------------------------------------------------
extern "C" void kernel_launch(void* const* d_in, const int* in_sizes, int n_in,
                              void* d_out, int out_size, void* d_ws, size_t ws_size,
                              hipStream_t stream) {
    const float* A      = (const float*)d_in[0];
    const float* X      = (const float*)d_in[1];
    const float* WKw    = (const float*)d_in[2];
    const float* WKb    = (const float*)d_in[3];
    const float* WQw    = (const float*)d_in[4];
    const float* wA     = (const float*)d_in[5];
    const float* wB     = (const float*)d_in[6];
    const float* sink   = (const float*)d_in[7];
    const float* vnulls = (const float*)d_in[8];
    const float* V1w    = (const float*)d_in[9];
    const float* V1b    = (const float*)d_in[10];
    const float* V2w    = (const float*)d_in[11];
    const float* V2b    = (const float*)d_in[12];
    const float* WOw    = (const float*)d_in[13];
    const float* WOb    = (const float*)d_in[14];
    float* out = (float*)d_out;
    (void)in_sizes; (void)n_in; (void)out_size; (void)ws_size;

    float* ws = (float*)d_ws;
    const size_t QRSZ = (size_t)Bq * Tq * HTq * 64;        // 6,291,456
    float* Qr    = ws;                                      // head-major fp32 Q
    float* Kr    = Qr + QRSZ;                               // head-major fp32 K (also temp for raw Q)
    float* kbase = Kr + QRSZ;                               // raw K proj (bt,12,64)
    float* psink = kbase;                                   // alias (dead after rope-K)
    unsigned short* markerb = (unsigned short*)(kbase + (size_t)Bq * Tq * 768);
    unsigned short* Kb16    = markerb + QRSZ;               // head-major bf16 K
    unsigned short* V1b16 = Kb16;                           // overlay: Kb16 dead after attn
    unsigned short* V2b16 = V1b16 + 16384;
    unsigned short* WOtb  = V2b16 + 16384;
    unsigned short* ctxb  = (unsigned short*)Qr;            // overlay: Qr dead after attn

    // Q proj -> temp (Kr slot, (bt,48,64)); rope Q: temp -> Qr (head-major)
    gemm_f32_kernel<<<dim3(16, 24), 256, 0, stream>>>(A, WQw, nullptr, Kr, 2048, 3072, 768);
    wedge_rope_kernel<<<1024, 256, 0, stream>>>(Kr, Qr, nullptr, wA, wB, 48);
    // K proj -> kbase ((bt,12,64)); rope K: kbase -> Kr (fp32) + Kb16 (bf16)
    gemm_f32_kernel<<<dim3(16, 6), 256, 0, stream>>>(X, WKw, WKb, kbase, 2048, 768, 768);
    wedge_rope_kernel<<<1024, 256, 0, stream>>>(kbase, Kr, Kb16, wA, wB, 12);
    // attention: scores via MFMA, exact fp32 top-4 via shortlist re-score
    attn_mfma_topk_kernel<<<dim3(96, 16), 256, 0, stream>>>(Qr, Kr, Kb16, sink, markerb, psink);
    // post-top-k smooth path (bf16/MFMA); these overlay Kb16, so launch after attn
    cvt_bf16_kernel<<<16, 256, 0, stream>>>(V1w, V1b16, 4096);
    cvt_bf16_kernel<<<16, 256, 0, stream>>>(V2w, V2b16, 4096);
    wo_transpose_kernel<<<dim3(12, 12, 4), 256, 0, stream>>>(WOw, WOtb);
    mlp_mfma_kernel<<<(Bq * HTq * Tq) / 64, 256, 0, stream>>>(markerb, psink, V1b16, V1b, V2b16, V2b, vnulls, ctxb);
    gemm_wo_mfma<<<dim3(32, 12), 256, 0, stream>>>(ctxb, WOtb, WOb, out);
}

// Round 4
// 595.542 us; speedup vs baseline: 2.1798x; 1.0019x over previous
//
#include <hip/hip_runtime.h>
#include <math.h>

constexpr int Bq  = 2;
constexpr int Tq  = 1024;
constexpr int HTq = 48;
constexpr float SCALE = 0.125f;     // 64^-0.5

typedef __attribute__((ext_vector_type(8))) short short8;
typedef __attribute__((ext_vector_type(4))) float f32x4;

__device__ inline unsigned short f2bf(float x) {
    unsigned u = __float_as_uint(x);
    return (unsigned short)((u + 0x7FFF + ((u >> 16) & 1)) >> 16);
}

// exact-erf GELU via Abramowitz-Stegun 7.1.26 (|eps_erf| <= 1.5e-7)
__device__ inline float gelu_f(float x) {
    float z = 0.70710678118654752f * x;
    float az = fabsf(z);
    float t = __frcp_rn(1.0f + 0.3275911f * az);
    float poly = t * (0.254829592f + t * (-0.284496736f + t * (1.421413741f
               + t * (-1.453152027f + t * 1.061405429f))));
    float er = 1.0f - poly * __expf(-az * az);
    er = (z < 0.0f) ? -er : er;
    return 0.5f * x * (1.0f + er);
}

// ---------------------------------------------------------------------------
// trig table: cos at [t*32+i], sin at [32768 + t*32+i].
// EXACT same expressions as the round-1..3 inline rope (bitwise identical).
// ---------------------------------------------------------------------------
__global__ void trig_kernel(float* __restrict__ trig) {
    int i = blockIdx.x * 256 + threadIdx.x;   // 32768
    int t = i >> 5, f = i & 31;
    float invf = powf(10000.0f, -(float)f * (1.0f / 32.0f));
    float ang = (float)t * invf;
    trig[i] = cosf(ang);
    trig[32768 + i] = sinf(ang);
}

// ---------------------------------------------------------------------------
// Weight fold: skew = wA - wA^T.
// mode 0 (Q): Wdst[h*64+e][c] = Wsrc[h*64+e][c]*(1+bias[h][e]) + sum_d skew[d][e]*Wsrc[h*64+d][c]
//   grid (48, 6)
// mode 1 (K): Wdst[hb*64+e][c] = Wsrc[hb*64+e][c] + sum_d skew[d][e]*Wsrc[hb*64+d][c]
//   plus raw copy into rows [768, 1536).  grid (12, 6)
// ---------------------------------------------------------------------------
__global__ __launch_bounds__(256) void fold_kernel(
    const float* __restrict__ Wsrc, const float* __restrict__ wA,
    const float* __restrict__ wbias, float* __restrict__ Wdst, int mode)
{
    __shared__ float sw[64][132];
    __shared__ float sk[64][65];
    int h = blockIdx.x, cb = blockIdx.y;
    int tid = threadIdx.x;
    const float* Wh = Wsrc + (size_t)h * 64 * 768 + cb * 128;
    for (int l = tid; l < 64 * 32; l += 256) {
        int d = l >> 5, c4 = l & 31;
        *(float4*)&sw[d][c4 * 4] = *(const float4*)(Wh + (size_t)d * 768 + c4 * 4);
    }
    for (int l = tid; l < 4096; l += 256) {
        int d = l >> 6, e = l & 63;
        sk[d][e] = wA[l] - wA[e * 64 + d];
    }
    __syncthreads();
    int tx = tid & 15, ty = tid >> 4;      // e = ty*4+i, c = tx*8+j
    float acc4[4][8] = {};
    for (int d = 0; d < 64; d++) {
        float s0 = sk[d][ty * 4 + 0], s1 = sk[d][ty * 4 + 1];
        float s2 = sk[d][ty * 4 + 2], s3 = sk[d][ty * 4 + 3];
        float w_[8];
        *(float4*)&w_[0] = *(const float4*)&sw[d][tx * 8];
        *(float4*)&w_[4] = *(const float4*)&sw[d][tx * 8 + 4];
        #pragma unroll
        for (int j = 0; j < 8; j++) {
            acc4[0][j] += s0 * w_[j];
            acc4[1][j] += s1 * w_[j];
            acc4[2][j] += s2 * w_[j];
            acc4[3][j] += s3 * w_[j];
        }
    }
    #pragma unroll
    for (int i = 0; i < 4; i++) {
        int e = ty * 4 + i;
        float scale = (mode == 0) ? (1.0f + wbias[h * 64 + e]) : 1.0f;
        float* dst = Wdst + (size_t)(h * 64 + e) * 768 + cb * 128;
        #pragma unroll
        for (int j = 0; j < 8; j++) {
            int cl = tx * 8 + j;
            dst[cl] = sw[e][cl] * scale + acc4[i][j];
        }
        if (mode == 1) {
            float* dst2 = Wdst + (size_t)(768 + h * 64 + e) * 768 + cb * 128;
            #pragma unroll
            for (int j = 0; j < 8; j++) dst2[tx * 8 + j] = sw[e][tx * 8 + j];
        }
    }
}

// ---------------------------------------------------------------------------
// K bias fold: bcat[e<768] = WKb[e] + sum_d skew[d][e&63]*WKb[(e>>6)*64+d];
//              bcat[768+r] = WKb[r]
// ---------------------------------------------------------------------------
__global__ void kbias_kernel(const float* __restrict__ WKb, const float* __restrict__ wA,
                             float* __restrict__ bcat) {
    int e = blockIdx.x * 256 + threadIdx.x;   // 1536
    if (e < 768) {
        int hb = e >> 6, el = e & 63;
        float acc = 0.0f;
        for (int d = 0; d < 64; d++) {
            float sk = wA[d * 64 + el] - wA[el * 64 + d];
            acc += WKb[hb * 64 + d] * sk;
        }
        bcat[e] = WKb[e] + acc;
    } else if (e < 1536) {
        bcat[e] = WKb[e - 768];
    }
}

// ---------------------------------------------------------------------------
// Merged projection GEMM, fp32, 128x256 tile, BK=32, 8x16 micro-tile,
// register-prefetch double buffer.  K dim = 768 fixed.
// blocks [0,192): Q job -> rope epilogue, writes Qr head-major fp32.
// blocks [192,288): K job -> plain +bias write to O2[2048][1536].
// ---------------------------------------------------------------------------
__global__ __launch_bounds__(256, 2) void proj_gemm_kernel(
    const float* __restrict__ Aq, const float* __restrict__ WQf,
    const float* __restrict__ Xi, const float* __restrict__ WKcat,
    const float* __restrict__ bcat, const float* __restrict__ trig,
    float* __restrict__ Qr, float* __restrict__ O2)
{
    __shared__ float sA[32][132];
    __shared__ float sB[32][260];
    int id = blockIdx.x;
    bool isQ = (id < 192);
    const float* Abase; const float* Wbase; int m0, n0;
    if (isQ) { Abase = Aq; Wbase = WQf; m0 = (id & 15) * 128; n0 = (id >> 4) * 256; }
    else { int k = id - 192; Abase = Xi; Wbase = WKcat; m0 = (k & 15) * 128; n0 = (k >> 4) * 256; }
    int tid = threadIdx.x;
    int tx = tid & 15, ty = tid >> 4;
    float acc[8][16] = {};
    float4 pa[4], pb[8];

    auto load_regs = [&](int k0) {
        #pragma unroll
        for (int s = 0; s < 4; s++) {
            int f = tid + s * 256;
            pa[s] = *(const float4*)(Abase + (size_t)(m0 + (f >> 3)) * 768 + k0 + (f & 7) * 4);
        }
        #pragma unroll
        for (int s = 0; s < 8; s++) {
            int f = tid + s * 256;
            pb[s] = *(const float4*)(Wbase + (size_t)(n0 + (f >> 3)) * 768 + k0 + (f & 7) * 4);
        }
    };
    auto store_lds = [&]() {
        #pragma unroll
        for (int s = 0; s < 4; s++) {
            int f = tid + s * 256; int r = f >> 3, c4 = f & 7;
            sA[c4 * 4 + 0][r] = pa[s].x; sA[c4 * 4 + 1][r] = pa[s].y;
            sA[c4 * 4 + 2][r] = pa[s].z; sA[c4 * 4 + 3][r] = pa[s].w;
        }
        #pragma unroll
        for (int s = 0; s < 8; s++) {
            int f = tid + s * 256; int r = f >> 3, c4 = f & 7;
            sB[c4 * 4 + 0][r] = pb[s].x; sB[c4 * 4 + 1][r] = pb[s].y;
            sB[c4 * 4 + 2][r] = pb[s].z; sB[c4 * 4 + 3][r] = pb[s].w;
        }
    };

    load_regs(0);
    store_lds();
    __syncthreads();
    for (int t = 0; t < 24; t++) {
        if (t < 23) load_regs((t + 1) * 32);
        #pragma unroll 8
        for (int kk = 0; kk < 32; kk++) {
            float a_[8], b_[16];
            *(float4*)&a_[0] = *(const float4*)&sA[kk][ty * 4];
            *(float4*)&a_[4] = *(const float4*)&sA[kk][64 + ty * 4];
            *(float4*)&b_[0]  = *(const float4*)&sB[kk][tx * 4];
            *(float4*)&b_[4]  = *(const float4*)&sB[kk][64 + tx * 4];
            *(float4*)&b_[8]  = *(const float4*)&sB[kk][128 + tx * 4];
            *(float4*)&b_[12] = *(const float4*)&sB[kk][192 + tx * 4];
            #pragma unroll
            for (int i = 0; i < 8; i++)
                #pragma unroll
                for (int j = 0; j < 16; j++)
                    acc[i][j] += a_[i] * b_[j];
        }
        if (t < 23) {
            __syncthreads();
            store_lds();
            __syncthreads();
        }
    }

    if (isQ) {
        // rope epilogue: cols 4tx..4tx+3 of head h are wz pairs (i0=2tx, i1=2tx+1)
        #pragma unroll
        for (int ib = 0; ib < 2; ib++)
            #pragma unroll
            for (int ii = 0; ii < 4; ii++) {
                int m = m0 + ib * 64 + ty * 4 + ii;
                int b = m >> 10, tq = m & 1023;
                float2 cv = *(const float2*)&trig[tq * 32 + 2 * tx];
                float2 sv = *(const float2*)&trig[32768 + tq * 32 + 2 * tx];
                #pragma unroll
                for (int jb = 0; jb < 4; jb++) {
                    int h = (n0 >> 6) + jb;
                    float a0 = acc[ib * 4 + ii][jb * 4 + 0];
                    float a1 = acc[ib * 4 + ii][jb * 4 + 1];
                    float a2 = acc[ib * 4 + ii][jb * 4 + 2];
                    float a3 = acc[ib * 4 + ii][jb * 4 + 3];
                    float2 lo, hi;
                    lo.x = a0 * cv.x - a1 * sv.x;
                    lo.y = a2 * cv.y - a3 * sv.y;
                    hi.x = a0 * sv.x + a1 * cv.x;
                    hi.y = a2 * sv.y + a3 * cv.y;
                    size_t base = ((size_t)(b * 48 + h) * 1024 + tq) * 64;
                    *(float2*)&Qr[base + 2 * tx] = lo;
                    *(float2*)&Qr[base + 32 + 2 * tx] = hi;
                }
            }
    } else {
        #pragma unroll
        for (int jb = 0; jb < 4; jb++)
            #pragma unroll
            for (int jj = 0; jj < 4; jj++) {
                int col = n0 + jb * 64 + tx * 4 + jj;
                float bv = bcat[col];
                #pragma unroll
                for (int ib = 0; ib < 2; ib++)
                    #pragma unroll
                    for (int ii = 0; ii < 4; ii++) {
                        int m = m0 + ib * 64 + ty * 4 + ii;
                        O2[(size_t)m * 1536 + col] = acc[ib * 4 + ii][jb * 4 + jj] + bv;
                    }
            }
    }
}

// ---------------------------------------------------------------------------
// K finish: wz_h = y + x*bias_h (y = x + skew-dot from GEMM), then rope.
// Writes Kr fp32 + Kb16 bf16, head-major (b*48+h, t, 64).
// ---------------------------------------------------------------------------
__global__ void k_finish_kernel(const float* __restrict__ O2, const float* __restrict__ trig,
                                const float* __restrict__ wbias,
                                float* __restrict__ Kr, unsigned short* __restrict__ Kb16)
{
    int idx = blockIdx.x * 256 + threadIdx.x;   // 786432
    int pr = idx & 31;
    int tmp = idx >> 5;
    int hb = tmp % 12;
    int bt = tmp / 12;
    int t = bt & 1023, b = bt >> 10;
    const float* yx = O2 + (size_t)bt * 1536 + hb * 64 + pr * 2;
    float y0 = yx[0], y1 = yx[1];
    float x0 = yx[768], x1 = yx[769];
    float cv = trig[t * 32 + pr], sv = trig[32768 + t * 32 + pr];
    #pragma unroll
    for (int r = 0; r < 4; r++) {
        int h = hb + 12 * r;
        float b0 = wbias[h * 64 + 2 * pr], b1 = wbias[h * 64 + 2 * pr + 1];
        float wz0 = y0 + x0 * b0;
        float wz1 = y1 + x1 * b1;
        float lo = wz0 * cv - wz1 * sv;
        float hi = wz0 * sv + wz1 * cv;
        size_t base = ((size_t)(b * 48 + h) * 1024 + t) * 64;
        Kr[base + pr] = lo;
        Kr[base + 32 + pr] = hi;
        Kb16[base + pr] = f2bf(lo);
        Kb16[base + 32 + pr] = f2bf(hi);
    }
}

// ---------------------------------------------------------------------------
// Attention core (unchanged from round 3): bf16 MFMA scores -> online (m,Z) +
// per-lane top-4; merge to top-8 shortlist -> exact fp32 re-score -> stable
// top-4 -> weights -> marker.  4 independent waves, no LDS, no barriers.
// ---------------------------------------------------------------------------
__global__ __launch_bounds__(256) void attn_mfma_topk_kernel(
    const float* __restrict__ Qr, const float* __restrict__ Kr,
    const unsigned short* __restrict__ Kb, const float* __restrict__ sink,
    unsigned short* __restrict__ markerb, float* __restrict__ psink)
{
    const int bh = blockIdx.x;                 // 0..95
    const int qb = 15 - (int)blockIdx.y;       // longest blocks first
    const int w = threadIdx.x >> 6, lane = threadIdx.x & 63;
    const int rf = lane & 15, kg = lane >> 4;
    const int h = bh % HTq;
    const int q0 = qb * 64 + w * 16;
    const size_t rowbase = (size_t)bh * Tq;

    short8 a0, a1;
    {
        const float* qp = Qr + (rowbase + q0 + rf) * 64 + kg * 8;
        float4 u0 = *(const float4*)qp;
        float4 u1 = *(const float4*)(qp + 4);
        float4 u2 = *(const float4*)(qp + 32);
        float4 u3 = *(const float4*)(qp + 36);
        a0[0]=(short)f2bf(u0.x); a0[1]=(short)f2bf(u0.y); a0[2]=(short)f2bf(u0.z); a0[3]=(short)f2bf(u0.w);
        a0[4]=(short)f2bf(u1.x); a0[5]=(short)f2bf(u1.y); a0[6]=(short)f2bf(u1.z); a0[7]=(short)f2bf(u1.w);
        a1[0]=(short)f2bf(u2.x); a1[1]=(short)f2bf(u2.y); a1[2]=(short)f2bf(u2.z); a1[3]=(short)f2bf(u2.w);
        a1[4]=(short)f2bf(u3.x); a1[5]=(short)f2bf(u3.y); a1[6]=(short)f2bf(u3.z); a1[7]=(short)f2bf(u3.w);
    }

    float m_[4], Z_[4], tv[4][4];
    int ti[4][4];
    #pragma unroll
    for (int r = 0; r < 4; r++) {
        m_[r] = -1e30f; Z_[r] = 0.0f;
        #pragma unroll
        for (int p = 0; p < 4; p++) { tv[r][p] = -INFINITY; ti[r][p] = -1; }
    }

    const int T = (q0 + 15) / 64 + 1;
    const unsigned short* Kbb = Kb + rowbase * 64;
    for (int tile = 0; tile < T; tile++) {
        const int s0 = tile << 6;
        f32x4 accs[4];
        #pragma unroll
        for (int kc = 0; kc < 4; kc++) {
            const unsigned short* kp = Kbb + (size_t)(s0 + kc * 16 + rf) * 64 + kg * 8;
            short8 b0 = *(const short8*)kp;
            short8 b1 = *(const short8*)(kp + 32);
            f32x4 acc = {0.f, 0.f, 0.f, 0.f};
            acc = __builtin_amdgcn_mfma_f32_16x16x32_bf16(a0, b0, acc, 0, 0, 0);
            acc = __builtin_amdgcn_mfma_f32_16x16x32_bf16(a1, b1, acc, 0, 0, 0);
            accs[kc] = acc;
        }
        const bool lastt = (tile == T - 1);
        #pragma unroll
        for (int r = 0; r < 4; r++) {
            const int trow = q0 + kg * 4 + r;
            float sv[4];
            #pragma unroll
            for (int kc = 0; kc < 4; kc++) {
                int k = s0 + kc * 16 + rf;
                float s = accs[kc][r] * SCALE;
                sv[kc] = (lastt && k > trow) ? -INFINITY : s;
            }
            float tm = fmaxf(fmaxf(sv[0], sv[1]), fmaxf(sv[2], sv[3]));
            float nm = fmaxf(m_[r], tm);
            float zz = Z_[r] * __expf(m_[r] - nm);
            #pragma unroll
            for (int kc = 0; kc < 4; kc++) zz += __expf(sv[kc] - nm);
            Z_[r] = zz; m_[r] = nm;
            #pragma unroll
            for (int kc = 0; kc < 4; kc++) {
                float v = sv[kc]; int id = s0 + kc * 16 + rf;
                #pragma unroll
                for (int p = 0; p < 4; p++) {
                    bool sw = v > tv[r][p];
                    float ov = tv[r][p]; int oi = ti[r][p];
                    tv[r][p] = sw ? v : ov;  ti[r][p] = sw ? id : oi;
                    v = sw ? ov : v;          id = sw ? oi : id;
                }
            }
        }
    }

    const float sk = sink[h];
    #pragma unroll 1
    for (int r = 0; r < 4; r++) {
        const int q = q0 + kg * 4 + r;
        float m = m_[r], Z = Z_[r];
        #pragma unroll
        for (int off = 1; off < 16; off <<= 1) {
            float om = __shfl_xor(m, off);
            float oz = __shfl_xor(Z, off);
            float nm = fmaxf(m, om);
            Z = Z * __expf(m - nm) + oz * __expf(om - nm);
            m = nm;
        }
        float av[4]; int ai[4];
        #pragma unroll
        for (int p = 0; p < 4; p++) { av[p] = tv[r][p]; ai[p] = ti[r][p]; }
        float cvv[8]; int ci[8];
        #pragma unroll
        for (int rd = 0; rd < 8; rd++) {
            float v = av[0]; int id = ai[0];
            #pragma unroll
            for (int off = 1; off < 16; off <<= 1) {
                float ov = __shfl_xor(v, off);
                int oi = __shfl_xor(id, off);
                bool take = (ov > v) || ((ov == v) && ((unsigned)oi < (unsigned)id));
                v = take ? ov : v; id = take ? oi : id;
            }
            cvv[rd] = v; ci[rd] = id;
            bool own = (ai[0] == id) && (av[0] == v);
            av[0] = own ? av[1] : av[0];  ai[0] = own ? ai[1] : ai[0];
            av[1] = own ? av[2] : av[1];  ai[1] = own ? ai[2] : ai[1];
            av[2] = own ? av[3] : av[2];  ai[2] = own ? ai[3] : ai[2];
            av[3] = own ? -INFINITY : av[3]; ai[3] = own ? -1 : ai[3];
        }
        const float4 qv = *(const float4*)(Qr + (rowbase + q) * 64 + rf * 4);
        float sc[8];
        #pragma unroll
        for (int c = 0; c < 8; c++) {
            int idx = ci[c] < 0 ? 0 : ci[c];
            const float4 kv = *(const float4*)(Kr + (rowbase + idx) * 64 + rf * 4);
            float p = qv.x * kv.x + qv.y * kv.y + qv.z * kv.z + qv.w * kv.w;
            #pragma unroll
            for (int off = 1; off < 16; off <<= 1) p += __shfl_xor(p, off);
            sc[c] = (ci[c] < 0) ? -1e30f : p * SCALE;
        }
        float bv[4]; int bi[4];
        #pragma unroll
        for (int rd = 0; rd < 4; rd++) {
            float v = sc[0]; int id = ci[0];
            #pragma unroll
            for (int c = 1; c < 8; c++) {
                bool take = (sc[c] > v) || ((sc[c] == v) && ((unsigned)ci[c] < (unsigned)id));
                v = take ? sc[c] : v; id = take ? ci[c] : id;
            }
            bv[rd] = v; bi[rd] = id;
            #pragma unroll
            for (int c = 0; c < 8; c++) {
                bool kill = (ci[c] == id) && (sc[c] == v);
                sc[c] = kill ? -3e30f : sc[c];
            }
        }
        float mf = fmaxf(m, sk);
        float Zf = Z * __expf(m - mf) + __expf(sk - mf);
        float e0 = __expf(bv[0] - mf), e1 = __expf(bv[1] - mf);
        float e2 = __expf(bv[2] - mf), e3 = __expf(bv[3] - mf);
        float wsum = e0 + e1 + e2 + e3 + Zf * 1e-9f;
        float w0 = e0 / wsum, w1 = e1 / wsum, w2 = e2 / wsum, w3 = e3 / wsum;
        int i0 = bi[0] < 0 ? 0 : bi[0];
        int i1 = bi[1] < 0 ? 0 : bi[1];
        int i2 = bi[2] < 0 ? 0 : bi[2];
        int i3 = bi[3] < 0 ? 0 : bi[3];
        const float4 k0 = *(const float4*)(Kr + (rowbase + i0) * 64 + rf * 4);
        const float4 k1 = *(const float4*)(Kr + (rowbase + i1) * 64 + rf * 4);
        const float4 k2 = *(const float4*)(Kr + (rowbase + i2) * 64 + rf * 4);
        const float4 k3 = *(const float4*)(Kr + (rowbase + i3) * 64 + rf * 4);
        float mx = w0 * k0.x + w1 * k1.x + w2 * k2.x + w3 * k3.x;
        float my = w0 * k0.y + w1 * k1.y + w2 * k2.y + w3 * k3.y;
        float mz = w0 * k0.z + w1 * k1.z + w2 * k2.z + w3 * k3.z;
        float mw = w0 * k0.w + w1 * k1.w + w2 * k2.w + w3 * k3.w;
        ushort4 mo;
        mo.x = f2bf(mx); mo.y = f2bf(my); mo.z = f2bf(mz); mo.w = f2bf(mw);
        *(ushort4*)(markerb + (rowbase + q) * 64 + rf * 4) = mo;
        if (rf == 0) psink[rowbase + q] = __expf(sk - mf) / Zf;
    }
}

// ---------------------------------------------------------------------------
__global__ void cvt_bf16_kernel(const float* __restrict__ in,
                                unsigned short* __restrict__ out, int n4)
{
    int i = blockIdx.x * 256 + threadIdx.x;
    if (i < n4) {
        float4 v = ((const float4*)in)[i];
        ushort4 o;
        o.x = f2bf(v.x); o.y = f2bf(v.y); o.z = f2bf(v.z); o.w = f2bf(v.w);
        ((ushort4*)out)[i] = o;
    }
}

// ---------------------------------------------------------------------------
__global__ __launch_bounds__(256) void wo_transpose_kernel(
    const float* __restrict__ WOw, unsigned short* __restrict__ WOt)
{
    __shared__ float tl[64][65];
    int tid = threadIdx.x;
    int n = blockIdx.z;
    int c0 = blockIdx.x * 64, d0 = blockIdx.y * 64;
    const float* src = WOw + (size_t)n * 768 * 768;
    for (int l = tid; l < 64 * 16; l += 256) {
        int r = l >> 4, q = l & 15;
        float4 v = *(const float4*)(src + (size_t)(c0 + r) * 768 + d0 + q * 4);
        tl[r][q * 4 + 0] = v.x; tl[r][q * 4 + 1] = v.y;
        tl[r][q * 4 + 2] = v.z; tl[r][q * 4 + 3] = v.w;
    }
    __syncthreads();
    for (int l = tid; l < 64 * 16; l += 256) {
        int d = l >> 4, q = l & 15;
        ushort4 o;
        o.x = f2bf(tl[q * 4 + 0][d]); o.y = f2bf(tl[q * 4 + 1][d]);
        o.z = f2bf(tl[q * 4 + 2][d]); o.w = f2bf(tl[q * 4 + 3][d]);
        *(ushort4*)(WOt + (size_t)n * 768 * 768 + (size_t)(d0 + d) * 768 + c0 + q * 4) = o;
    }
}

// ---------------------------------------------------------------------------
__global__ __launch_bounds__(256) void mlp_mfma_kernel(
    const unsigned short* __restrict__ markerb, const float* __restrict__ psink,
    const unsigned short* __restrict__ V1b16, const float* __restrict__ V1bias,
    const unsigned short* __restrict__ V2b16, const float* __restrict__ V2bias,
    const float* __restrict__ vnulls, unsigned short* __restrict__ ctxb)
{
    __shared__ float h_lds[4][16][65];
    int tid = threadIdx.x;
    int w = tid >> 6, lane = tid & 63;
    int rf = lane & 15, kg = lane >> 4;
    size_t r0 = (size_t)blockIdx.x * 64 + 16 * w;

    short8 a1[2];
    #pragma unroll
    for (int kk = 0; kk < 2; kk++)
        a1[kk] = *(const short8*)(markerb + (r0 + rf) * 64 + kk * 32 + kg * 8);

    f32x4 acc2[4] = {};
    for (int ch = 0; ch < 4; ch++) {
        f32x4 acc1[4] = {};
        #pragma unroll
        for (int nj = 0; nj < 4; nj++)
            #pragma unroll
            for (int kk = 0; kk < 2; kk++) {
                short8 b1 = *(const short8*)(V1b16 + (size_t)(ch * 64 + nj * 16 + rf) * 64 + kk * 32 + kg * 8);
                acc1[nj] = __builtin_amdgcn_mfma_f32_16x16x32_bf16(a1[kk], b1, acc1[nj], 0, 0, 0);
            }
        __syncthreads();
        #pragma unroll
        for (int nj = 0; nj < 4; nj++) {
            float bb = V1bias[ch * 64 + nj * 16 + rf];
            #pragma unroll
            for (int r = 0; r < 4; r++) {
                float x = acc1[nj][r] + bb;
                h_lds[w][kg * 4 + r][nj * 16 + rf] = gelu_f(x);
            }
        }
        __syncthreads();
        #pragma unroll
        for (int kk = 0; kk < 2; kk++) {
            const float* hp = &h_lds[w][rf][kk * 32 + kg * 8];
            float4 p0 = *(const float4*)hp;
            float4 p1 = *(const float4*)(hp + 4);
            short8 a2;
            a2[0] = (short)f2bf(p0.x); a2[1] = (short)f2bf(p0.y);
            a2[2] = (short)f2bf(p0.z); a2[3] = (short)f2bf(p0.w);
            a2[4] = (short)f2bf(p1.x); a2[5] = (short)f2bf(p1.y);
            a2[6] = (short)f2bf(p1.z); a2[7] = (short)f2bf(p1.w);
            #pragma unroll
            for (int njo = 0; njo < 4; njo++) {
                short8 b2 = *(const short8*)(V2b16 + (size_t)(njo * 16 + rf) * 256 + ch * 64 + kk * 32 + kg * 8);
                acc2[njo] = __builtin_amdgcn_mfma_f32_16x16x32_bf16(a2, b2, acc2[njo], 0, 0, 0);
            }
        }
    }
    #pragma unroll
    for (int r = 0; r < 4; r++) {
        size_t R = r0 + kg * 4 + r;
        int bh = (int)(R >> 10), t = (int)(R & 1023);
        int b = bh / 48, h = bh % 48;
        int n = h / 12, head = h % 12;
        float ps = psink[R];
        size_t base = ((size_t)((b * 4 + n) * 1024 + t)) * 768 + head * 64;
        #pragma unroll
        for (int njo = 0; njo < 4; njo++) {
            int d = njo * 16 + rf;
            float v = acc2[njo][r] + V2bias[d] + ps * vnulls[h * 64 + d];
            ctxb[base + d] = f2bf(v);
        }
    }
}

// ---------------------------------------------------------------------------
__global__ __launch_bounds__(256) void gemm_wo_mfma(
    const unsigned short* __restrict__ ctxb, const unsigned short* __restrict__ WOtb,
    const float* __restrict__ WOb, float* __restrict__ Out)
{
    __shared__ unsigned short sA[64 * 64];
    __shared__ unsigned short sB[64 * 64];
    int tid = threadIdx.x;
    int w = tid >> 6, lane = tid & 63;
    int wm = w >> 1, wn = w & 1;
    int rf = lane & 15, kg = lane >> 4;
    int m0 = blockIdx.x * 64, n0 = blockIdx.y * 64;
    int b = m0 >> 10, t0 = m0 & 1023;
    int c0 = tid * 2, c1 = tid * 2 + 1;
    int ra = c0 >> 3, ca = c0 & 7, rb = c1 >> 3, cb = c1 & 7;
    f32x4 acc[2][2] = {};
    for (int n = 0; n < 4; n++) {
        const unsigned short* Ab = ctxb + ((size_t)((b * 4 + n) * 1024 + t0)) * 768;
        const unsigned short* Bb = WOtb + (size_t)n * 768 * 768 + (size_t)n0 * 768;
        for (int k0 = 0; k0 < 768; k0 += 64) {
            __syncthreads();
            *(short8*)&sA[ra * 64 + ((ca ^ (ra & 7)) * 8)] = *(const short8*)(Ab + (size_t)ra * 768 + k0 + ca * 8);
            *(short8*)&sA[rb * 64 + ((cb ^ (rb & 7)) * 8)] = *(const short8*)(Ab + (size_t)rb * 768 + k0 + cb * 8);
            *(short8*)&sB[ra * 64 + ((ca ^ (ra & 7)) * 8)] = *(const short8*)(Bb + (size_t)ra * 768 + k0 + ca * 8);
            *(short8*)&sB[rb * 64 + ((cb ^ (rb & 7)) * 8)] = *(const short8*)(Bb + (size_t)rb * 768 + k0 + cb * 8);
            __syncthreads();
            #pragma unroll
            for (int kk = 0; kk < 2; kk++) {
                int kc = kk * 4 + kg;
                int rA0 = wm * 32 + rf, rA1 = wm * 32 + 16 + rf;
                int rB0 = wn * 32 + rf, rB1 = wn * 32 + 16 + rf;
                short8 a0v = *(const short8*)&sA[rA0 * 64 + ((kc ^ (rA0 & 7)) * 8)];
                short8 a1v = *(const short8*)&sA[rA1 * 64 + ((kc ^ (rA1 & 7)) * 8)];
                short8 b0v = *(const short8*)&sB[rB0 * 64 + ((kc ^ (rB0 & 7)) * 8)];
                short8 b1v = *(const short8*)&sB[rB1 * 64 + ((kc ^ (rB1 & 7)) * 8)];
                acc[0][0] = __builtin_amdgcn_mfma_f32_16x16x32_bf16(a0v, b0v, acc[0][0], 0, 0, 0);
                acc[0][1] = __builtin_amdgcn_mfma_f32_16x16x32_bf16(a0v, b1v, acc[0][1], 0, 0, 0);
                acc[1][0] = __builtin_amdgcn_mfma_f32_16x16x32_bf16(a1v, b0v, acc[1][0], 0, 0, 0);
                acc[1][1] = __builtin_amdgcn_mfma_f32_16x16x32_bf16(a1v, b1v, acc[1][1], 0, 0, 0);
            }
        }
    }
    #pragma unroll
    for (int nj = 0; nj < 2; nj++) {
        int col = n0 + wn * 32 + nj * 16 + rf;
        float bm = WOb[col] + WOb[768 + col] + WOb[1536 + col] + WOb[2304 + col];
        #pragma unroll
        for (int mi = 0; mi < 2; mi++)
            #pragma unroll
            for (int r = 0; r < 4; r++) {
                int row = m0 + wm * 32 + mi * 16 + kg * 4 + r;
                Out[(size_t)row * 768 + col] = 0.25f * (acc[mi][nj][r] + bm);
            }
    }
}

// ---------------------------------------------------------------------------
extern "C" void kernel_launch(void* const* d_in, const int* in_sizes, int n_in,
                              void* d_out, int out_size, void* d_ws, size_t ws_size,
                              hipStream_t stream) {
    const float* A      = (const float*)d_in[0];
    const float* X      = (const float*)d_in[1];
    const float* WKw    = (const float*)d_in[2];
    const float* WKb    = (const float*)d_in[3];
    const float* WQw    = (const float*)d_in[4];
    const float* wA     = (const float*)d_in[5];
    const float* wB     = (const float*)d_in[6];
    const float* sink   = (const float*)d_in[7];
    const float* vnulls = (const float*)d_in[8];
    const float* V1w    = (const float*)d_in[9];
    const float* V1b    = (const float*)d_in[10];
    const float* V2w    = (const float*)d_in[11];
    const float* V2b    = (const float*)d_in[12];
    const float* WOw    = (const float*)d_in[13];
    const float* WOb    = (const float*)d_in[14];
    float* out = (float*)d_out;
    (void)in_sizes; (void)n_in; (void)out_size; (void)ws_size;

    float* ws = (float*)d_ws;
    size_t off = 0;
    float* Qr = ws + off;                         off += 6291456;   // head-major fp32 Q (rope'd)
    float* Kr = ws + off;                         off += 6291456;   // head-major fp32 K (rope'd)
    unsigned short* markerb = (unsigned short*)(ws + off); off += 3145728;
    unsigned short* Kb16    = (unsigned short*)(ws + off); off += 3145728;
    float* psink = ws + off;                      off += 98304;
    float* trig  = ws + off;                      off += 65536;
    float* WQf   = ws + off;                      off += 2359296;   // folded Q weights [3072][768]
    float* WKcat = ws + off;                      off += 1179648;   // [1536][768]: folded + raw WK
    float* bcat  = ws + off;                      off += 1536;
    float* O2    = ws + off;                      off += 3145728;   // [2048][1536]: y | x
    // overlays (dead-buffer reuse)
    unsigned short* V1b16 = (unsigned short*)WQf;          // WQf dead after proj_gemm
    unsigned short* V2b16 = V1b16 + 16384;
    unsigned short* WOtb  = V2b16 + 16384;
    unsigned short* ctxb  = (unsigned short*)Qr;           // Qr dead after attn

    // prep: trig table + wedge-folded weights
    trig_kernel<<<128, 256, 0, stream>>>(trig);
    fold_kernel<<<dim3(48, 6), 256, 0, stream>>>(WQw, wA, wB, WQf, 0);
    fold_kernel<<<dim3(12, 6), 256, 0, stream>>>(WKw, wA, wB, WKcat, 1);
    kbias_kernel<<<6, 256, 0, stream>>>(WKb, wA, bcat);
    // merged Q+K projection (Q gets rope epilogue -> Qr; K -> O2)
    proj_gemm_kernel<<<288, 256, 0, stream>>>(A, WQf, X, WKcat, bcat, trig, Qr, O2);
    // finish K: per-h bias wedge term + rope -> Kr fp32 + Kb16 bf16
    k_finish_kernel<<<3072, 256, 0, stream>>>(O2, trig, wB, Kr, Kb16);
    // attention: MFMA scores, exact fp32 top-4 via shortlist re-score
    attn_mfma_topk_kernel<<<dim3(96, 16), 256, 0, stream>>>(Qr, Kr, Kb16, sink, markerb, psink);
    // post-top-k smooth path (bf16/MFMA)
    cvt_bf16_kernel<<<16, 256, 0, stream>>>(V1w, V1b16, 4096);
    cvt_bf16_kernel<<<16, 256, 0, stream>>>(V2w, V2b16, 4096);
    wo_transpose_kernel<<<dim3(12, 12, 4), 256, 0, stream>>>(WOw, WOtb);
    mlp_mfma_kernel<<<1536, 256, 0, stream>>>(markerb, psink, V1b16, V1b, V2b16, V2b, vnulls, ctxb);
    gemm_wo_mfma<<<dim3(32, 12), 256, 0, stream>>>(ctxb, WOtb, WOb, out);
}

// Round 6
// 465.232 us; speedup vs baseline: 2.7904x; 1.2801x over previous
//
#include <hip/hip_runtime.h>
#include <math.h>

constexpr int Bq  = 2;
constexpr int Tq  = 1024;
constexpr int HTq = 48;
constexpr float SCALE = 0.125f;     // 64^-0.5

typedef __attribute__((ext_vector_type(8))) short short8;
typedef __attribute__((ext_vector_type(4))) float f32x4;

__device__ inline unsigned short f2bf(float x) {
    unsigned u = __float_as_uint(x);
    return (unsigned short)((u + 0x7FFF + ((u >> 16) & 1)) >> 16);
}

// exact 3-plane bf16 split: x = p0 + p1 + p2 + O(2^-27 |x|)
__device__ inline void split3(float x, unsigned short& p0, unsigned short& p1, unsigned short& p2) {
    p0 = f2bf(x);
    float f0 = __uint_as_float((unsigned)p0 << 16);
    float r0 = x - f0;
    p1 = f2bf(r0);
    float f1 = __uint_as_float((unsigned)p1 << 16);
    float r1 = r0 - f1;
    p2 = f2bf(r1);
}

// exact-erf GELU via Abramowitz-Stegun 7.1.26 (|eps_erf| <= 1.5e-7)
__device__ inline float gelu_f(float x) {
    float z = 0.70710678118654752f * x;
    float az = fabsf(z);
    float t = __frcp_rn(1.0f + 0.3275911f * az);
    float poly = t * (0.254829592f + t * (-0.284496736f + t * (1.421413741f
               + t * (-1.453152027f + t * 1.061405429f))));
    float er = 1.0f - poly * __expf(-az * az);
    er = (z < 0.0f) ? -er : er;
    return 0.5f * x * (1.0f + er);
}

// ---------------------------------------------------------------------------
// trig table: cos at [t*32+i], sin at [32768 + t*32+i].
// ---------------------------------------------------------------------------
__global__ void trig_kernel(float* __restrict__ trig) {
    int i = blockIdx.x * 256 + threadIdx.x;   // 32768
    int t = i >> 5, f = i & 31;
    float invf = powf(10000.0f, -(float)f * (1.0f / 32.0f));
    float ang = (float)t * invf;
    trig[i] = cosf(ang);
    trig[32768 + i] = sinf(ang);
}

// ---------------------------------------------------------------------------
// Weight fold + 3-plane split.  skew = wA - wA^T.
// mode 0 (Q): rows h*64+e = split3( W*(1+bias) + skew-fold ), grid (48,6)
// mode 1 (K): rows 3072+h*64+e = split3( W + skew-fold ),
//             rows 3840+h*64+e = split3( W raw ),  grid (12,6)
// ---------------------------------------------------------------------------
__global__ __launch_bounds__(256) void fold_split_kernel(
    const float* __restrict__ Wsrc, const float* __restrict__ wA,
    const float* __restrict__ wbias, unsigned short* __restrict__ Wsp, int mode)
{
    const size_t WPL = (size_t)4608 * 768;
    __shared__ float sw[64][132];
    __shared__ float sk[64][65];
    int h = blockIdx.x, cb = blockIdx.y;
    int tid = threadIdx.x;
    const float* Wh = Wsrc + (size_t)h * 64 * 768 + cb * 128;
    for (int l = tid; l < 64 * 32; l += 256) {
        int d = l >> 5, c4 = l & 31;
        *(float4*)&sw[d][c4 * 4] = *(const float4*)(Wh + (size_t)d * 768 + c4 * 4);
    }
    for (int l = tid; l < 4096; l += 256) {
        int d = l >> 6, e = l & 63;
        sk[d][e] = wA[l] - wA[e * 64 + d];
    }
    __syncthreads();
    int tx = tid & 15, ty = tid >> 4;      // e = ty*4+i, c = tx*8+j
    float acc4[4][8] = {};
    for (int d = 0; d < 64; d++) {
        float s0 = sk[d][ty * 4 + 0], s1 = sk[d][ty * 4 + 1];
        float s2 = sk[d][ty * 4 + 2], s3 = sk[d][ty * 4 + 3];
        float w_[8];
        *(float4*)&w_[0] = *(const float4*)&sw[d][tx * 8];
        *(float4*)&w_[4] = *(const float4*)&sw[d][tx * 8 + 4];
        #pragma unroll
        for (int j = 0; j < 8; j++) {
            acc4[0][j] += s0 * w_[j];
            acc4[1][j] += s1 * w_[j];
            acc4[2][j] += s2 * w_[j];
            acc4[3][j] += s3 * w_[j];
        }
    }
    #pragma unroll
    for (int i = 0; i < 4; i++) {
        int e = ty * 4 + i;
        float scale = (mode == 0) ? (1.0f + wbias[h * 64 + e]) : 1.0f;
        size_t row = (mode == 0) ? (size_t)(h * 64 + e) : (size_t)(3072 + h * 64 + e);
        #pragma unroll
        for (int j = 0; j < 8; j++) {
            int cl = tx * 8 + j;
            float wv = sw[e][cl] * scale + acc4[i][j];
            unsigned short p0, p1, p2;
            split3(wv, p0, p1, p2);
            size_t idx = row * 768 + cb * 128 + cl;
            Wsp[idx] = p0; Wsp[WPL + idx] = p1; Wsp[2 * WPL + idx] = p2;
        }
        if (mode == 1) {
            size_t row2 = (size_t)(3840 + h * 64 + e);
            #pragma unroll
            for (int j = 0; j < 8; j++) {
                int cl = tx * 8 + j;
                unsigned short p0, p1, p2;
                split3(sw[e][cl], p0, p1, p2);
                size_t idx = row2 * 768 + cb * 128 + cl;
                Wsp[idx] = p0; Wsp[WPL + idx] = p1; Wsp[2 * WPL + idx] = p2;
            }
        }
    }
}

// ---------------------------------------------------------------------------
// K bias fold: bcat[e<768] = WKb[e] + skew-dot;  bcat[768+r] = WKb[r]
// ---------------------------------------------------------------------------
__global__ void kbias_kernel(const float* __restrict__ WKb, const float* __restrict__ wA,
                             float* __restrict__ bcat) {
    int e = blockIdx.x * 256 + threadIdx.x;   // 1536
    if (e < 768) {
        int hb = e >> 6, el = e & 63;
        float acc = 0.0f;
        for (int d = 0; d < 64; d++) {
            float sk = wA[d * 64 + el] - wA[el * 64 + d];
            acc += WKb[hb * 64 + d] * sk;
        }
        bcat[e] = WKb[e] + acc;
    } else if (e < 1536) {
        bcat[e] = WKb[e - 768];
    }
}

// ---------------------------------------------------------------------------
// Activation 3-plane split: A, X (2048x768 fp32) -> Asp, Xsp (3 planes ushort)
// ---------------------------------------------------------------------------
__global__ void split_act_kernel(const float* __restrict__ A, const float* __restrict__ X,
                                 unsigned short* __restrict__ Asp, unsigned short* __restrict__ Xsp)
{
    const size_t APL = (size_t)2048 * 768;
    int i = blockIdx.x * 256 + threadIdx.x;   // 393216 quads
    if (i >= 393216) return;
    float4 va = ((const float4*)A)[i];
    float4 vx = ((const float4*)X)[i];
    ushort4 a0, a1, a2, x0, x1, x2;
    split3(va.x, a0.x, a1.x, a2.x); split3(va.y, a0.y, a1.y, a2.y);
    split3(va.z, a0.z, a1.z, a2.z); split3(va.w, a0.w, a1.w, a2.w);
    split3(vx.x, x0.x, x1.x, x2.x); split3(vx.y, x0.y, x1.y, x2.y);
    split3(vx.z, x0.z, x1.z, x2.z); split3(vx.w, x0.w, x1.w, x2.w);
    ((ushort4*)(Asp))[i] = a0;
    ((ushort4*)(Asp + APL))[i] = a1;
    ((ushort4*)(Asp + 2 * APL))[i] = a2;
    ((ushort4*)(Xsp))[i] = x0;
    ((ushort4*)(Xsp + APL))[i] = x1;
    ((ushort4*)(Xsp + 2 * APL))[i] = x2;
}

// ---------------------------------------------------------------------------
// Projection GEMM via split-precision bf16 MFMA (fp32-equivalent, ~2^-23).
// 6 plane-products {00,01,10,11,02,20} accumulated in fp32 AGPRs.
// 128x128 tile, 4 waves (2m x 2n), no LDS, fragments straight from global.
// ---------------------------------------------------------------------------
__global__ __launch_bounds__(256) void proj_mfma_kernel(
    const unsigned short* __restrict__ Asp, const unsigned short* __restrict__ Xsp,
    const unsigned short* __restrict__ Wsp, const float* __restrict__ bcat,
    const float* __restrict__ trig, float* __restrict__ Qr, float* __restrict__ O2)
{
    const size_t APL = (size_t)2048 * 768;
    const size_t WPL = (size_t)4608 * 768;
    int nb = blockIdx.x;        // 0..35
    int mb = blockIdx.y;        // 0..15
    bool isQ = (nb < 24);
    const unsigned short* Ab = isQ ? Asp : Xsp;
    int m0 = mb * 128, n0 = nb * 128;
    int tid = threadIdx.x;
    int w = tid >> 6, lane = tid & 63;
    int wm = w & 1, wn = w >> 1;
    int rf = lane & 15, kg = lane >> 4;
    int mbase = m0 + wm * 64, nbase = n0 + wn * 64;

    f32x4 acc[4][4] = {};
    for (int k0 = 0; k0 < 768; k0 += 32) {
        short8 a[3][4], b[3][4];
        #pragma unroll
        for (int p = 0; p < 3; p++)
            #pragma unroll
            for (int mi = 0; mi < 4; mi++)
                a[p][mi] = *(const short8*)(Ab + p * APL + (size_t)(mbase + mi * 16 + rf) * 768 + k0 + kg * 8);
        #pragma unroll
        for (int p = 0; p < 3; p++)
            #pragma unroll
            for (int nj = 0; nj < 4; nj++)
                b[p][nj] = *(const short8*)(Wsp + p * WPL + (size_t)(nbase + nj * 16 + rf) * 768 + k0 + kg * 8);
        #pragma unroll
        for (int mi = 0; mi < 4; mi++)
            #pragma unroll
            for (int nj = 0; nj < 4; nj++)
                acc[mi][nj] = __builtin_amdgcn_mfma_f32_16x16x32_bf16(a[0][mi], b[0][nj], acc[mi][nj], 0, 0, 0);
        #pragma unroll
        for (int mi = 0; mi < 4; mi++)
            #pragma unroll
            for (int nj = 0; nj < 4; nj++)
                acc[mi][nj] = __builtin_amdgcn_mfma_f32_16x16x32_bf16(a[0][mi], b[1][nj], acc[mi][nj], 0, 0, 0);
        #pragma unroll
        for (int mi = 0; mi < 4; mi++)
            #pragma unroll
            for (int nj = 0; nj < 4; nj++)
                acc[mi][nj] = __builtin_amdgcn_mfma_f32_16x16x32_bf16(a[1][mi], b[0][nj], acc[mi][nj], 0, 0, 0);
        #pragma unroll
        for (int mi = 0; mi < 4; mi++)
            #pragma unroll
            for (int nj = 0; nj < 4; nj++)
                acc[mi][nj] = __builtin_amdgcn_mfma_f32_16x16x32_bf16(a[1][mi], b[1][nj], acc[mi][nj], 0, 0, 0);
        #pragma unroll
        for (int mi = 0; mi < 4; mi++)
            #pragma unroll
            for (int nj = 0; nj < 4; nj++)
                acc[mi][nj] = __builtin_amdgcn_mfma_f32_16x16x32_bf16(a[0][mi], b[2][nj], acc[mi][nj], 0, 0, 0);
        #pragma unroll
        for (int mi = 0; mi < 4; mi++)
            #pragma unroll
            for (int nj = 0; nj < 4; nj++)
                acc[mi][nj] = __builtin_amdgcn_mfma_f32_16x16x32_bf16(a[2][mi], b[0][nj], acc[mi][nj], 0, 0, 0);
    }

    if (isQ) {
        // rope epilogue; lane pair (rf even/odd) holds (x1, x2) = cols (2i, 2i+1)
        #pragma unroll
        for (int mi = 0; mi < 4; mi++) {
            #pragma unroll
            for (int r = 0; r < 4; r++) {
                int m = mbase + mi * 16 + kg * 4 + r;
                int b_ = m >> 10, t = m & 1023;
                int h = nb * 2 + wn;
                size_t base = ((size_t)(b_ * 48 + h) * 1024 + t) * 64;
                #pragma unroll
                for (int nj = 0; nj < 4; nj++) {
                    int d = nj * 16 + rf;
                    int i = d >> 1;
                    float v = acc[mi][nj][r];
                    float pv = __shfl_xor(v, 1);
                    float c = trig[t * 32 + i];
                    float s = trig[32768 + t * 32 + i];
                    float outv = (rf & 1) ? (pv * s + v * c) : (v * c - pv * s);
                    int col = (rf & 1) ? (32 + i) : i;
                    Qr[base + col] = outv;
                }
            }
        }
    } else {
        #pragma unroll
        for (int nj = 0; nj < 4; nj++) {
            int col = (n0 - 3072) + wn * 64 + nj * 16 + rf;
            float bv = bcat[col];
            #pragma unroll
            for (int mi = 0; mi < 4; mi++)
                #pragma unroll
                for (int r = 0; r < 4; r++) {
                    int m = mbase + mi * 16 + kg * 4 + r;
                    O2[(size_t)m * 1536 + col] = acc[mi][nj][r] + bv;
                }
        }
    }
}

// ---------------------------------------------------------------------------
// K finish: wz_h = y + x*bias_h, then rope.  Kr fp32 + Kb16 bf16, head-major.
// ---------------------------------------------------------------------------
__global__ void k_finish_kernel(const float* __restrict__ O2, const float* __restrict__ trig,
                                const float* __restrict__ wbias,
                                float* __restrict__ Kr, unsigned short* __restrict__ Kb16)
{
    int idx = blockIdx.x * 256 + threadIdx.x;   // 786432
    int pr = idx & 31;
    int tmp = idx >> 5;
    int hb = tmp % 12;
    int bt = tmp / 12;
    int t = bt & 1023, b = bt >> 10;
    const float* yx = O2 + (size_t)bt * 1536 + hb * 64 + pr * 2;
    float y0 = yx[0], y1 = yx[1];
    float x0 = yx[768], x1 = yx[769];
    float cv = trig[t * 32 + pr], sv = trig[32768 + t * 32 + pr];
    #pragma unroll
    for (int r = 0; r < 4; r++) {
        int h = hb + 12 * r;
        float b0 = wbias[h * 64 + 2 * pr], b1 = wbias[h * 64 + 2 * pr + 1];
        float wz0 = y0 + x0 * b0;
        float wz1 = y1 + x1 * b1;
        float lo = wz0 * cv - wz1 * sv;
        float hi = wz0 * sv + wz1 * cv;
        size_t base = ((size_t)(b * 48 + h) * 1024 + t) * 64;
        Kr[base + pr] = lo;
        Kr[base + 32 + pr] = hi;
        Kb16[base + pr] = f2bf(lo);
        Kb16[base + 32 + pr] = f2bf(hi);
    }
}

// ---------------------------------------------------------------------------
// Attention core: bf16 MFMA scores -> online (m,Z) + per-lane top-4; merge to
// top-8 shortlist -> exact fp32 re-score -> stable top-4 -> weights -> marker.
// 4 independent waves, no LDS, no barriers.
// ---------------------------------------------------------------------------
__global__ __launch_bounds__(256) void attn_mfma_topk_kernel(
    const float* __restrict__ Qr, const float* __restrict__ Kr,
    const unsigned short* __restrict__ Kb, const float* __restrict__ sink,
    unsigned short* __restrict__ markerb, float* __restrict__ psink)
{
    const int bh = blockIdx.x;                 // 0..95
    const int qb = 15 - (int)blockIdx.y;       // longest blocks first
    const int w = threadIdx.x >> 6, lane = threadIdx.x & 63;
    const int rf = lane & 15, kg = lane >> 4;
    const int h = bh % HTq;
    const int q0 = qb * 64 + w * 16;
    const size_t rowbase = (size_t)bh * Tq;

    short8 a0, a1;
    {
        const float* qp = Qr + (rowbase + q0 + rf) * 64 + kg * 8;
        float4 u0 = *(const float4*)qp;
        float4 u1 = *(const float4*)(qp + 4);
        float4 u2 = *(const float4*)(qp + 32);
        float4 u3 = *(const float4*)(qp + 36);
        a0[0]=(short)f2bf(u0.x); a0[1]=(short)f2bf(u0.y); a0[2]=(short)f2bf(u0.z); a0[3]=(short)f2bf(u0.w);
        a0[4]=(short)f2bf(u1.x); a0[5]=(short)f2bf(u1.y); a0[6]=(short)f2bf(u1.z); a0[7]=(short)f2bf(u1.w);
        a1[0]=(short)f2bf(u2.x); a1[1]=(short)f2bf(u2.y); a1[2]=(short)f2bf(u2.z); a1[3]=(short)f2bf(u2.w);
        a1[4]=(short)f2bf(u3.x); a1[5]=(short)f2bf(u3.y); a1[6]=(short)f2bf(u3.z); a1[7]=(short)f2bf(u3.w);
    }

    float m_[4], Z_[4], tv[4][4];
    int ti[4][4];
    #pragma unroll
    for (int r = 0; r < 4; r++) {
        m_[r] = -1e30f; Z_[r] = 0.0f;
        #pragma unroll
        for (int p = 0; p < 4; p++) { tv[r][p] = -INFINITY; ti[r][p] = -1; }
    }

    const int T = (q0 + 15) / 64 + 1;
    const unsigned short* Kbb = Kb + rowbase * 64;
    for (int tile = 0; tile < T; tile++) {
        const int s0 = tile << 6;
        f32x4 accs[4];
        #pragma unroll
        for (int kc = 0; kc < 4; kc++) {
            const unsigned short* kp = Kbb + (size_t)(s0 + kc * 16 + rf) * 64 + kg * 8;
            short8 b0 = *(const short8*)kp;
            short8 b1 = *(const short8*)(kp + 32);
            f32x4 acc = {0.f, 0.f, 0.f, 0.f};
            acc = __builtin_amdgcn_mfma_f32_16x16x32_bf16(a0, b0, acc, 0, 0, 0);
            acc = __builtin_amdgcn_mfma_f32_16x16x32_bf16(a1, b1, acc, 0, 0, 0);
            accs[kc] = acc;
        }
        const bool lastt = (tile == T - 1);
        #pragma unroll
        for (int r = 0; r < 4; r++) {
            const int trow = q0 + kg * 4 + r;
            float sv[4];
            #pragma unroll
            for (int kc = 0; kc < 4; kc++) {
                int k = s0 + kc * 16 + rf;
                float s = accs[kc][r] * SCALE;
                sv[kc] = (lastt && k > trow) ? -INFINITY : s;
            }
            float tm = fmaxf(fmaxf(sv[0], sv[1]), fmaxf(sv[2], sv[3]));
            float nm = fmaxf(m_[r], tm);
            float zz = Z_[r] * __expf(m_[r] - nm);
            #pragma unroll
            for (int kc = 0; kc < 4; kc++) zz += __expf(sv[kc] - nm);
            Z_[r] = zz; m_[r] = nm;
            #pragma unroll
            for (int kc = 0; kc < 4; kc++) {
                float v = sv[kc]; int id = s0 + kc * 16 + rf;
                #pragma unroll
                for (int p = 0; p < 4; p++) {
                    bool sw = v > tv[r][p];
                    float ov = tv[r][p]; int oi = ti[r][p];
                    tv[r][p] = sw ? v : ov;  ti[r][p] = sw ? id : oi;
                    v = sw ? ov : v;          id = sw ? oi : id;
                }
            }
        }
    }

    const float sk = sink[h];
    #pragma unroll 1
    for (int r = 0; r < 4; r++) {
        const int q = q0 + kg * 4 + r;
        float m = m_[r], Z = Z_[r];
        #pragma unroll
        for (int off = 1; off < 16; off <<= 1) {
            float om = __shfl_xor(m, off);
            float oz = __shfl_xor(Z, off);
            float nm = fmaxf(m, om);
            Z = Z * __expf(m - nm) + oz * __expf(om - nm);
            m = nm;
        }
        float av[4]; int ai[4];
        #pragma unroll
        for (int p = 0; p < 4; p++) { av[p] = tv[r][p]; ai[p] = ti[r][p]; }
        float cvv[8]; int ci[8];
        #pragma unroll
        for (int rd = 0; rd < 8; rd++) {
            float v = av[0]; int id = ai[0];
            #pragma unroll
            for (int off = 1; off < 16; off <<= 1) {
                float ov = __shfl_xor(v, off);
                int oi = __shfl_xor(id, off);
                bool take = (ov > v) || ((ov == v) && ((unsigned)oi < (unsigned)id));
                v = take ? ov : v; id = take ? oi : id;
            }
            cvv[rd] = v; ci[rd] = id;
            bool own = (ai[0] == id) && (av[0] == v);
            av[0] = own ? av[1] : av[0];  ai[0] = own ? ai[1] : ai[0];
            av[1] = own ? av[2] : av[1];  ai[1] = own ? ai[2] : ai[1];
            av[2] = own ? av[3] : av[2];  ai[2] = own ? ai[3] : ai[2];
            av[3] = own ? -INFINITY : av[3]; ai[3] = own ? -1 : ai[3];
        }
        const float4 qv = *(const float4*)(Qr + (rowbase + q) * 64 + rf * 4);
        float sc[8];
        #pragma unroll
        for (int c = 0; c < 8; c++) {
            int idx = ci[c] < 0 ? 0 : ci[c];
            const float4 kv = *(const float4*)(Kr + (rowbase + idx) * 64 + rf * 4);
            float p = qv.x * kv.x + qv.y * kv.y + qv.z * kv.z + qv.w * kv.w;
            #pragma unroll
            for (int off = 1; off < 16; off <<= 1) p += __shfl_xor(p, off);
            sc[c] = (ci[c] < 0) ? -1e30f : p * SCALE;
        }
        float bv[4]; int bi[4];
        #pragma unroll
        for (int rd = 0; rd < 4; rd++) {
            float v = sc[0]; int id = ci[0];
            #pragma unroll
            for (int c = 1; c < 8; c++) {
                bool take = (sc[c] > v) || ((sc[c] == v) && ((unsigned)ci[c] < (unsigned)id));
                v = take ? sc[c] : v; id = take ? ci[c] : id;
            }
            bv[rd] = v; bi[rd] = id;
            #pragma unroll
            for (int c = 0; c < 8; c++) {
                bool kill = (ci[c] == id) && (sc[c] == v);
                sc[c] = kill ? -3e30f : sc[c];
            }
        }
        float mf = fmaxf(m, sk);
        float Zf = Z * __expf(m - mf) + __expf(sk - mf);
        float e0 = __expf(bv[0] - mf), e1 = __expf(bv[1] - mf);
        float e2 = __expf(bv[2] - mf), e3 = __expf(bv[3] - mf);
        float wsum = e0 + e1 + e2 + e3 + Zf * 1e-9f;
        float w0 = e0 / wsum, w1 = e1 / wsum, w2 = e2 / wsum, w3 = e3 / wsum;
        int i0 = bi[0] < 0 ? 0 : bi[0];
        int i1 = bi[1] < 0 ? 0 : bi[1];
        int i2 = bi[2] < 0 ? 0 : bi[2];
        int i3 = bi[3] < 0 ? 0 : bi[3];
        const float4 k0 = *(const float4*)(Kr + (rowbase + i0) * 64 + rf * 4);
        const float4 k1 = *(const float4*)(Kr + (rowbase + i1) * 64 + rf * 4);
        const float4 k2 = *(const float4*)(Kr + (rowbase + i2) * 64 + rf * 4);
        const float4 k3 = *(const float4*)(Kr + (rowbase + i3) * 64 + rf * 4);
        float mx = w0 * k0.x + w1 * k1.x + w2 * k2.x + w3 * k3.x;
        float my = w0 * k0.y + w1 * k1.y + w2 * k2.y + w3 * k3.y;
        float mz = w0 * k0.z + w1 * k1.z + w2 * k2.z + w3 * k3.z;
        float mw = w0 * k0.w + w1 * k1.w + w2 * k2.w + w3 * k3.w;
        ushort4 mo;
        mo.x = f2bf(mx); mo.y = f2bf(my); mo.z = f2bf(mz); mo.w = f2bf(mw);
        *(ushort4*)(markerb + (rowbase + q) * 64 + rf * 4) = mo;
        if (rf == 0) psink[rowbase + q] = __expf(sk - mf) / Zf;
    }
}

// ---------------------------------------------------------------------------
__global__ void cvt_bf16_kernel(const float* __restrict__ in,
                                unsigned short* __restrict__ out, int n4)
{
    int i = blockIdx.x * 256 + threadIdx.x;
    if (i < n4) {
        float4 v = ((const float4*)in)[i];
        ushort4 o;
        o.x = f2bf(v.x); o.y = f2bf(v.y); o.z = f2bf(v.z); o.w = f2bf(v.w);
        ((ushort4*)out)[i] = o;
    }
}

// ---------------------------------------------------------------------------
__global__ __launch_bounds__(256) void wo_transpose_kernel(
    const float* __restrict__ WOw, unsigned short* __restrict__ WOt)
{
    __shared__ float tl[64][65];
    int tid = threadIdx.x;
    int n = blockIdx.z;
    int c0 = blockIdx.x * 64, d0 = blockIdx.y * 64;
    const float* src = WOw + (size_t)n * 768 * 768;
    for (int l = tid; l < 64 * 16; l += 256) {
        int r = l >> 4, q = l & 15;
        float4 v = *(const float4*)(src + (size_t)(c0 + r) * 768 + d0 + q * 4);
        tl[r][q * 4 + 0] = v.x; tl[r][q * 4 + 1] = v.y;
        tl[r][q * 4 + 2] = v.z; tl[r][q * 4 + 3] = v.w;
    }
    __syncthreads();
    for (int l = tid; l < 64 * 16; l += 256) {
        int d = l >> 4, q = l & 15;
        ushort4 o;
        o.x = f2bf(tl[q * 4 + 0][d]); o.y = f2bf(tl[q * 4 + 1][d]);
        o.z = f2bf(tl[q * 4 + 2][d]); o.w = f2bf(tl[q * 4 + 3][d]);
        *(ushort4*)(WOt + (size_t)n * 768 * 768 + (size_t)(d0 + d) * 768 + c0 + q * 4) = o;
    }
}

// ---------------------------------------------------------------------------
__global__ __launch_bounds__(256) void mlp_mfma_kernel(
    const unsigned short* __restrict__ markerb, const float* __restrict__ psink,
    const unsigned short* __restrict__ V1b16, const float* __restrict__ V1bias,
    const unsigned short* __restrict__ V2b16, const float* __restrict__ V2bias,
    const float* __restrict__ vnulls, unsigned short* __restrict__ ctxb)
{
    __shared__ float h_lds[4][16][65];
    int tid = threadIdx.x;
    int w = tid >> 6, lane = tid & 63;
    int rf = lane & 15, kg = lane >> 4;
    size_t r0 = (size_t)blockIdx.x * 64 + 16 * w;

    short8 a1[2];
    #pragma unroll
    for (int kk = 0; kk < 2; kk++)
        a1[kk] = *(const short8*)(markerb + (r0 + rf) * 64 + kk * 32 + kg * 8);

    f32x4 acc2[4] = {};
    for (int ch = 0; ch < 4; ch++) {
        f32x4 acc1[4] = {};
        #pragma unroll
        for (int nj = 0; nj < 4; nj++)
            #pragma unroll
            for (int kk = 0; kk < 2; kk++) {
                short8 b1 = *(const short8*)(V1b16 + (size_t)(ch * 64 + nj * 16 + rf) * 64 + kk * 32 + kg * 8);
                acc1[nj] = __builtin_amdgcn_mfma_f32_16x16x32_bf16(a1[kk], b1, acc1[nj], 0, 0, 0);
            }
        __syncthreads();
        #pragma unroll
        for (int nj = 0; nj < 4; nj++) {
            float bb = V1bias[ch * 64 + nj * 16 + rf];
            #pragma unroll
            for (int r = 0; r < 4; r++) {
                float x = acc1[nj][r] + bb;
                h_lds[w][kg * 4 + r][nj * 16 + rf] = gelu_f(x);
            }
        }
        __syncthreads();
        #pragma unroll
        for (int kk = 0; kk < 2; kk++) {
            const float* hp = &h_lds[w][rf][kk * 32 + kg * 8];
            float4 p0 = *(const float4*)hp;
            float4 p1 = *(const float4*)(hp + 4);
            short8 a2;
            a2[0] = (short)f2bf(p0.x); a2[1] = (short)f2bf(p0.y);
            a2[2] = (short)f2bf(p0.z); a2[3] = (short)f2bf(p0.w);
            a2[4] = (short)f2bf(p1.x); a2[5] = (short)f2bf(p1.y);
            a2[6] = (short)f2bf(p1.z); a2[7] = (short)f2bf(p1.w);
            #pragma unroll
            for (int njo = 0; njo < 4; njo++) {
                short8 b2 = *(const short8*)(V2b16 + (size_t)(njo * 16 + rf) * 256 + ch * 64 + kk * 32 + kg * 8);
                acc2[njo] = __builtin_amdgcn_mfma_f32_16x16x32_bf16(a2, b2, acc2[njo], 0, 0, 0);
            }
        }
    }
    #pragma unroll
    for (int r = 0; r < 4; r++) {
        size_t R = r0 + kg * 4 + r;
        int bh = (int)(R >> 10), t = (int)(R & 1023);
        int b = bh / 48, h = bh % 48;
        int n = h / 12, head = h % 12;
        float ps = psink[R];
        size_t base = ((size_t)((b * 4 + n) * 1024 + t)) * 768 + head * 64;
        #pragma unroll
        for (int njo = 0; njo < 4; njo++) {
            int d = njo * 16 + rf;
            float v = acc2[njo][r] + V2bias[d] + ps * vnulls[h * 64 + d];
            ctxb[base + d] = f2bf(v);
        }
    }
}

// ---------------------------------------------------------------------------
__global__ __launch_bounds__(256) void gemm_wo_mfma(
    const unsigned short* __restrict__ ctxb, const unsigned short* __restrict__ WOtb,
    const float* __restrict__ WOb, float* __restrict__ Out)
{
    __shared__ unsigned short sA[64 * 64];
    __shared__ unsigned short sB[64 * 64];
    int tid = threadIdx.x;
    int w = tid >> 6, lane = tid & 63;
    int wm = w >> 1, wn = w & 1;
    int rf = lane & 15, kg = lane >> 4;
    int m0 = blockIdx.x * 64, n0 = blockIdx.y * 64;
    int b = m0 >> 10, t0 = m0 & 1023;
    int c0 = tid * 2, c1 = tid * 2 + 1;
    int ra = c0 >> 3, ca = c0 & 7, rb = c1 >> 3, cb = c1 & 7;
    f32x4 acc[2][2] = {};
    for (int n = 0; n < 4; n++) {
        const unsigned short* Ab = ctxb + ((size_t)((b * 4 + n) * 1024 + t0)) * 768;
        const unsigned short* Bb = WOtb + (size_t)n * 768 * 768 + (size_t)n0 * 768;
        for (int k0 = 0; k0 < 768; k0 += 64) {
            __syncthreads();
            *(short8*)&sA[ra * 64 + ((ca ^ (ra & 7)) * 8)] = *(const short8*)(Ab + (size_t)ra * 768 + k0 + ca * 8);
            *(short8*)&sA[rb * 64 + ((cb ^ (rb & 7)) * 8)] = *(const short8*)(Ab + (size_t)rb * 768 + k0 + cb * 8);
            *(short8*)&sB[ra * 64 + ((ca ^ (ra & 7)) * 8)] = *(const short8*)(Bb + (size_t)ra * 768 + k0 + ca * 8);
            *(short8*)&sB[rb * 64 + ((cb ^ (rb & 7)) * 8)] = *(const short8*)(Bb + (size_t)rb * 768 + k0 + cb * 8);
            __syncthreads();
            #pragma unroll
            for (int kk = 0; kk < 2; kk++) {
                int kc = kk * 4 + kg;
                int rA0 = wm * 32 + rf, rA1 = wm * 32 + 16 + rf;
                int rB0 = wn * 32 + rf, rB1 = wn * 32 + 16 + rf;
                short8 a0v = *(const short8*)&sA[rA0 * 64 + ((kc ^ (rA0 & 7)) * 8)];
                short8 a1v = *(const short8*)&sA[rA1 * 64 + ((kc ^ (rA1 & 7)) * 8)];
                short8 b0v = *(const short8*)&sB[rB0 * 64 + ((kc ^ (rB0 & 7)) * 8)];
                short8 b1v = *(const short8*)&sB[rB1 * 64 + ((kc ^ (rB1 & 7)) * 8)];
                acc[0][0] = __builtin_amdgcn_mfma_f32_16x16x32_bf16(a0v, b0v, acc[0][0], 0, 0, 0);
                acc[0][1] = __builtin_amdgcn_mfma_f32_16x16x32_bf16(a0v, b1v, acc[0][1], 0, 0, 0);
                acc[1][0] = __builtin_amdgcn_mfma_f32_16x16x32_bf16(a1v, b0v, acc[1][0], 0, 0, 0);
                acc[1][1] = __builtin_amdgcn_mfma_f32_16x16x32_bf16(a1v, b1v, acc[1][1], 0, 0, 0);
            }
        }
    }
    #pragma unroll
    for (int nj = 0; nj < 2; nj++) {
        int col = n0 + wn * 32 + nj * 16 + rf;
        float bm = WOb[col] + WOb[768 + col] + WOb[1536 + col] + WOb[2304 + col];
        #pragma unroll
        for (int mi = 0; mi < 2; mi++)
            #pragma unroll
            for (int r = 0; r < 4; r++) {
                int row = m0 + wm * 32 + mi * 16 + kg * 4 + r;
                Out[(size_t)row * 768 + col] = 0.25f * (acc[mi][nj][r] + bm);
            }
    }
}

// ---------------------------------------------------------------------------
extern "C" void kernel_launch(void* const* d_in, const int* in_sizes, int n_in,
                              void* d_out, int out_size, void* d_ws, size_t ws_size,
                              hipStream_t stream) {
    const float* A      = (const float*)d_in[0];
    const float* X      = (const float*)d_in[1];
    const float* WKw    = (const float*)d_in[2];
    const float* WKb    = (const float*)d_in[3];
    const float* WQw    = (const float*)d_in[4];
    const float* wA     = (const float*)d_in[5];
    const float* wB     = (const float*)d_in[6];
    const float* sink   = (const float*)d_in[7];
    const float* vnulls = (const float*)d_in[8];
    const float* V1w    = (const float*)d_in[9];
    const float* V1b    = (const float*)d_in[10];
    const float* V2w    = (const float*)d_in[11];
    const float* V2b    = (const float*)d_in[12];
    const float* WOw    = (const float*)d_in[13];
    const float* WOb    = (const float*)d_in[14];
    float* out = (float*)d_out;
    (void)in_sizes; (void)n_in; (void)out_size; (void)ws_size;

    float* ws = (float*)d_ws;
    size_t off = 0;
    float* Qr   = ws + off;  off += 6291456;   // head-major fp32 Q (rope'd)
    float* Kr   = ws + off;  off += 6291456;   // head-major fp32 K (rope'd)
    float* trig = ws + off;  off += 65536;
    float* bcat = ws + off;  off += 2048;
    float* O2   = ws + off;  off += 3145728;   // [2048][1536]: y | x
    float* Wsp_f = ws + off; off += 5308416;   // 3 planes x 4608x768 ushort
    unsigned short* Wsp = (unsigned short*)Wsp_f;
    unsigned short* Asp = (unsigned short*)(ws + off); off += 2359296;  // 3 planes x 2048x768
    unsigned short* Xsp = (unsigned short*)(ws + off); off += 2359296;
    // overlays (dead-buffer reuse) — audited lifetimes:
    //   markerb = O2 (FULL 3,145,728 floats; O2 dead after k_finish)
    //   Kb16 = Wsp floats [0, 3145728); psink = Wsp floats [3145728, 3244032)
    //     (Wsp dead after proj; Kb16/psink written by k_finish/attn; no overlap)
    unsigned short* markerb = (unsigned short*)O2;
    unsigned short* Kb16 = Wsp;
    float* psink = Wsp_f + 3145728;
    unsigned short* V1b16 = Xsp;                         // Xsp dead after proj
    unsigned short* V2b16 = V1b16 + 16384;
    unsigned short* WOtb  = Asp;                         // Asp dead after proj
    unsigned short* ctxb  = (unsigned short*)Qr;         // Qr dead after attn

    // prep: trig + folded/split weights + split activations
    trig_kernel<<<128, 256, 0, stream>>>(trig);
    fold_split_kernel<<<dim3(48, 6), 256, 0, stream>>>(WQw, wA, wB, Wsp, 0);
    fold_split_kernel<<<dim3(12, 6), 256, 0, stream>>>(WKw, wA, wB, Wsp, 1);
    kbias_kernel<<<6, 256, 0, stream>>>(WKb, wA, bcat);
    split_act_kernel<<<1536, 256, 0, stream>>>(A, X, Asp, Xsp);
    // split-precision MFMA projection (Q -> rope -> Qr; Kcat -> O2)
    proj_mfma_kernel<<<dim3(36, 16), 256, 0, stream>>>(Asp, Xsp, Wsp, bcat, trig, Qr, O2);
    // finish K: per-h bias wedge term + rope -> Kr fp32 + Kb16 bf16
    k_finish_kernel<<<3072, 256, 0, stream>>>(O2, trig, wB, Kr, Kb16);
    // attention: MFMA scores, exact fp32 top-4 via shortlist re-score
    attn_mfma_topk_kernel<<<dim3(96, 16), 256, 0, stream>>>(Qr, Kr, Kb16, sink, markerb, psink);
    // post-top-k smooth path (bf16/MFMA)
    cvt_bf16_kernel<<<16, 256, 0, stream>>>(V1w, V1b16, 4096);
    cvt_bf16_kernel<<<16, 256, 0, stream>>>(V2w, V2b16, 4096);
    wo_transpose_kernel<<<dim3(12, 12, 4), 256, 0, stream>>>(WOw, WOtb);
    mlp_mfma_kernel<<<1536, 256, 0, stream>>>(markerb, psink, V1b16, V1b, V2b16, V2b, vnulls, ctxb);
    gemm_wo_mfma<<<dim3(32, 12), 256, 0, stream>>>(ctxb, WOtb, WOb, out);
}

// Round 7
// 362.683 us; speedup vs baseline: 3.5794x; 1.2828x over previous
//
#include <hip/hip_runtime.h>
#include <math.h>

constexpr int Bq  = 2;
constexpr int Tq  = 1024;
constexpr int HTq = 48;
constexpr float SCALE = 0.125f;     // 64^-0.5

typedef __attribute__((ext_vector_type(8))) short short8;
typedef __attribute__((ext_vector_type(4))) float f32x4;

__device__ inline unsigned short f2bf(float x) {
    unsigned u = __float_as_uint(x);
    return (unsigned short)((u + 0x7FFF + ((u >> 16) & 1)) >> 16);
}

// exact 3-plane bf16 split: x = p0 + p1 + p2 + O(2^-27 |x|)
__device__ inline void split3(float x, unsigned short& p0, unsigned short& p1, unsigned short& p2) {
    p0 = f2bf(x);
    float f0 = __uint_as_float((unsigned)p0 << 16);
    float r0 = x - f0;
    p1 = f2bf(r0);
    float f1 = __uint_as_float((unsigned)p1 << 16);
    float r1 = r0 - f1;
    p2 = f2bf(r1);
}

// exact-erf GELU via Abramowitz-Stegun 7.1.26 (|eps_erf| <= 1.5e-7)
__device__ inline float gelu_f(float x) {
    float z = 0.70710678118654752f * x;
    float az = fabsf(z);
    float t = __frcp_rn(1.0f + 0.3275911f * az);
    float poly = t * (0.254829592f + t * (-0.284496736f + t * (1.421413741f
               + t * (-1.453152027f + t * 1.061405429f))));
    float er = 1.0f - poly * __expf(-az * az);
    er = (z < 0.0f) ? -er : er;
    return 0.5f * x * (1.0f + er);
}

// ---------------------------------------------------------------------------
// trig table: cos at [t*32+i], sin at [32768 + t*32+i].
// ---------------------------------------------------------------------------
__global__ void trig_kernel(float* __restrict__ trig) {
    int i = blockIdx.x * 256 + threadIdx.x;   // 32768
    int t = i >> 5, f = i & 31;
    float invf = powf(10000.0f, -(float)f * (1.0f / 32.0f));
    float ang = (float)t * invf;
    trig[i] = cosf(ang);
    trig[32768 + i] = sinf(ang);
}

// ---------------------------------------------------------------------------
// Weight fold + 3-plane split.  skew = wA - wA^T.
// mode 0 (Q): rows h*64+e = split3( W*(1+bias) + skew-fold ), grid (48,6)
// mode 1 (K): rows 3072+h*64+e = split3( W + skew-fold ),
//             rows 3840+h*64+e = split3( W raw ),  grid (12,6)
// ---------------------------------------------------------------------------
__global__ __launch_bounds__(256) void fold_split_kernel(
    const float* __restrict__ Wsrc, const float* __restrict__ wA,
    const float* __restrict__ wbias, unsigned short* __restrict__ Wsp, int mode)
{
    const size_t WPL = (size_t)4608 * 768;
    __shared__ float sw[64][132];
    __shared__ float sk[64][65];
    int h = blockIdx.x, cb = blockIdx.y;
    int tid = threadIdx.x;
    const float* Wh = Wsrc + (size_t)h * 64 * 768 + cb * 128;
    for (int l = tid; l < 64 * 32; l += 256) {
        int d = l >> 5, c4 = l & 31;
        *(float4*)&sw[d][c4 * 4] = *(const float4*)(Wh + (size_t)d * 768 + c4 * 4);
    }
    for (int l = tid; l < 4096; l += 256) {
        int d = l >> 6, e = l & 63;
        sk[d][e] = wA[l] - wA[e * 64 + d];
    }
    __syncthreads();
    int tx = tid & 15, ty = tid >> 4;      // e = ty*4+i, c = tx*8+j
    float acc4[4][8] = {};
    for (int d = 0; d < 64; d++) {
        float s0 = sk[d][ty * 4 + 0], s1 = sk[d][ty * 4 + 1];
        float s2 = sk[d][ty * 4 + 2], s3 = sk[d][ty * 4 + 3];
        float w_[8];
        *(float4*)&w_[0] = *(const float4*)&sw[d][tx * 8];
        *(float4*)&w_[4] = *(const float4*)&sw[d][tx * 8 + 4];
        #pragma unroll
        for (int j = 0; j < 8; j++) {
            acc4[0][j] += s0 * w_[j];
            acc4[1][j] += s1 * w_[j];
            acc4[2][j] += s2 * w_[j];
            acc4[3][j] += s3 * w_[j];
        }
    }
    #pragma unroll
    for (int i = 0; i < 4; i++) {
        int e = ty * 4 + i;
        float scale = (mode == 0) ? (1.0f + wbias[h * 64 + e]) : 1.0f;
        size_t row = (mode == 0) ? (size_t)(h * 64 + e) : (size_t)(3072 + h * 64 + e);
        #pragma unroll
        for (int j = 0; j < 8; j++) {
            int cl = tx * 8 + j;
            float wv = sw[e][cl] * scale + acc4[i][j];
            unsigned short p0, p1, p2;
            split3(wv, p0, p1, p2);
            size_t idx = row * 768 + cb * 128 + cl;
            Wsp[idx] = p0; Wsp[WPL + idx] = p1; Wsp[2 * WPL + idx] = p2;
        }
        if (mode == 1) {
            size_t row2 = (size_t)(3840 + h * 64 + e);
            #pragma unroll
            for (int j = 0; j < 8; j++) {
                int cl = tx * 8 + j;
                unsigned short p0, p1, p2;
                split3(sw[e][cl], p0, p1, p2);
                size_t idx = row2 * 768 + cb * 128 + cl;
                Wsp[idx] = p0; Wsp[WPL + idx] = p1; Wsp[2 * WPL + idx] = p2;
            }
        }
    }
}

// ---------------------------------------------------------------------------
// K bias fold: bcat[e<768] = WKb[e] + skew-dot;  bcat[768+r] = WKb[r]
// ---------------------------------------------------------------------------
__global__ void kbias_kernel(const float* __restrict__ WKb, const float* __restrict__ wA,
                             float* __restrict__ bcat) {
    int e = blockIdx.x * 256 + threadIdx.x;   // 1536
    if (e < 768) {
        int hb = e >> 6, el = e & 63;
        float acc = 0.0f;
        for (int d = 0; d < 64; d++) {
            float sk = wA[d * 64 + el] - wA[el * 64 + d];
            acc += WKb[hb * 64 + d] * sk;
        }
        bcat[e] = WKb[e] + acc;
    } else if (e < 1536) {
        bcat[e] = WKb[e - 768];
    }
}

// ---------------------------------------------------------------------------
// Activation 3-plane split: A, X (2048x768 fp32) -> Asp, Xsp (3 planes ushort)
// ---------------------------------------------------------------------------
__global__ void split_act_kernel(const float* __restrict__ A, const float* __restrict__ X,
                                 unsigned short* __restrict__ Asp, unsigned short* __restrict__ Xsp)
{
    const size_t APL = (size_t)2048 * 768;
    int i = blockIdx.x * 256 + threadIdx.x;   // 393216 quads
    if (i >= 393216) return;
    float4 va = ((const float4*)A)[i];
    float4 vx = ((const float4*)X)[i];
    ushort4 a0, a1, a2, x0, x1, x2;
    split3(va.x, a0.x, a1.x, a2.x); split3(va.y, a0.y, a1.y, a2.y);
    split3(va.z, a0.z, a1.z, a2.z); split3(va.w, a0.w, a1.w, a2.w);
    split3(vx.x, x0.x, x1.x, x2.x); split3(vx.y, x0.y, x1.y, x2.y);
    split3(vx.z, x0.z, x1.z, x2.z); split3(vx.w, x0.w, x1.w, x2.w);
    ((ushort4*)(Asp))[i] = a0;
    ((ushort4*)(Asp + APL))[i] = a1;
    ((ushort4*)(Asp + 2 * APL))[i] = a2;
    ((ushort4*)(Xsp))[i] = x0;
    ((ushort4*)(Xsp + APL))[i] = x1;
    ((ushort4*)(Xsp + 2 * APL))[i] = x2;
}

// ---------------------------------------------------------------------------
// Projection GEMM via split-precision bf16 MFMA, LDS-staged.
// 128x128 tile, BK=32, 512 threads (8 waves, 2m x 4n, 64x32 per wave).
// LDS: 3 planes x 128 rows x (32+8 pad) ushort per operand (row stride 80B ->
// 2-way bank aliasing only, free).  6 plane products ordered 00,01,02,10,11,20
// for minimal fragment liveness.  XCD-bijective block swizzle (576 = 72 x 8).
// ---------------------------------------------------------------------------
__global__ __launch_bounds__(512) void proj_mfma_kernel(
    const unsigned short* __restrict__ Asp, const unsigned short* __restrict__ Xsp,
    const unsigned short* __restrict__ Wsp, const float* __restrict__ bcat,
    const float* __restrict__ trig, float* __restrict__ Qr, float* __restrict__ O2)
{
    const size_t APL = (size_t)2048 * 768;
    const size_t WPL = (size_t)4608 * 768;
    __shared__ unsigned short sA[3 * 128 * 40];
    __shared__ unsigned short sB[3 * 128 * 40];
    int bid = blockIdx.x;
    int swz = (bid & 7) * 72 + (bid >> 3);   // bijective: 576 = 8 * 72
    int nb = swz >> 4;        // 0..35  (consecutive swz share nb -> W locality per XCD)
    int mb = swz & 15;        // 0..15
    bool isQ = (nb < 24);
    const unsigned short* Ab = isQ ? Asp : Xsp;
    int m0 = mb * 128, n0 = nb * 128;
    int tid = threadIdx.x;
    int w = tid >> 6, lane = tid & 63;
    int wm = w & 1, wn = w >> 1;          // wave tile: rows wm*64, cols wn*32
    int rf = lane & 15, kg = lane >> 4;
    int mbase = m0 + wm * 64;

    // stage mapping: s = tid + i*512 in [0,1536): p = s>>9, r = (s>>2)&127, slot = s&3
    int sp_[3], sr_[3], ss_[3];
    #pragma unroll
    for (int i = 0; i < 3; i++) {
        int s = tid + i * 512;
        sp_[i] = s >> 9; sr_[i] = (s >> 2) & 127; ss_[i] = s & 3;
    }

    f32x4 acc[4][2] = {};
    for (int k0 = 0; k0 < 768; k0 += 32) {
        __syncthreads();
        #pragma unroll
        for (int i = 0; i < 3; i++) {
            short8 va = *(const short8*)(Ab + (size_t)sp_[i] * APL + (size_t)(m0 + sr_[i]) * 768 + k0 + ss_[i] * 8);
            short8 vb = *(const short8*)(Wsp + (size_t)sp_[i] * WPL + (size_t)(n0 + sr_[i]) * 768 + k0 + ss_[i] * 8);
            *(short8*)&sA[sp_[i] * 5120 + sr_[i] * 40 + ss_[i] * 8] = va;
            *(short8*)&sB[sp_[i] * 5120 + sr_[i] * 40 + ss_[i] * 8] = vb;
        }
        __syncthreads();

        short8 a0[4], a1[4], a2[4], b0[2], b1[2], b2[2];
        #pragma unroll
        for (int mi = 0; mi < 4; mi++) {
            int row = wm * 64 + mi * 16 + rf;
            a0[mi] = *(const short8*)&sA[0 * 5120 + row * 40 + kg * 8];
        }
        #pragma unroll
        for (int nj = 0; nj < 2; nj++) {
            int row = wn * 32 + nj * 16 + rf;
            b0[nj] = *(const short8*)&sB[0 * 5120 + row * 40 + kg * 8];
        }
        #pragma unroll
        for (int mi = 0; mi < 4; mi++)
            #pragma unroll
            for (int nj = 0; nj < 2; nj++)
                acc[mi][nj] = __builtin_amdgcn_mfma_f32_16x16x32_bf16(a0[mi], b0[nj], acc[mi][nj], 0, 0, 0);
        #pragma unroll
        for (int nj = 0; nj < 2; nj++) {
            int row = wn * 32 + nj * 16 + rf;
            b1[nj] = *(const short8*)&sB[1 * 5120 + row * 40 + kg * 8];
        }
        #pragma unroll
        for (int mi = 0; mi < 4; mi++)
            #pragma unroll
            for (int nj = 0; nj < 2; nj++)
                acc[mi][nj] = __builtin_amdgcn_mfma_f32_16x16x32_bf16(a0[mi], b1[nj], acc[mi][nj], 0, 0, 0);
        #pragma unroll
        for (int nj = 0; nj < 2; nj++) {
            int row = wn * 32 + nj * 16 + rf;
            b2[nj] = *(const short8*)&sB[2 * 5120 + row * 40 + kg * 8];
        }
        #pragma unroll
        for (int mi = 0; mi < 4; mi++)
            #pragma unroll
            for (int nj = 0; nj < 2; nj++)
                acc[mi][nj] = __builtin_amdgcn_mfma_f32_16x16x32_bf16(a0[mi], b2[nj], acc[mi][nj], 0, 0, 0);
        #pragma unroll
        for (int mi = 0; mi < 4; mi++) {
            int row = wm * 64 + mi * 16 + rf;
            a1[mi] = *(const short8*)&sA[1 * 5120 + row * 40 + kg * 8];
        }
        #pragma unroll
        for (int mi = 0; mi < 4; mi++)
            #pragma unroll
            for (int nj = 0; nj < 2; nj++)
                acc[mi][nj] = __builtin_amdgcn_mfma_f32_16x16x32_bf16(a1[mi], b0[nj], acc[mi][nj], 0, 0, 0);
        #pragma unroll
        for (int mi = 0; mi < 4; mi++)
            #pragma unroll
            for (int nj = 0; nj < 2; nj++)
                acc[mi][nj] = __builtin_amdgcn_mfma_f32_16x16x32_bf16(a1[mi], b1[nj], acc[mi][nj], 0, 0, 0);
        #pragma unroll
        for (int mi = 0; mi < 4; mi++) {
            int row = wm * 64 + mi * 16 + rf;
            a2[mi] = *(const short8*)&sA[2 * 5120 + row * 40 + kg * 8];
        }
        #pragma unroll
        for (int mi = 0; mi < 4; mi++)
            #pragma unroll
            for (int nj = 0; nj < 2; nj++)
                acc[mi][nj] = __builtin_amdgcn_mfma_f32_16x16x32_bf16(a2[mi], b0[nj], acc[mi][nj], 0, 0, 0);
    }

    if (isQ) {
        // rope epilogue: col_local = wn*32 + nj*16 + rf; pair via shfl_xor(1)
        #pragma unroll
        for (int mi = 0; mi < 4; mi++) {
            #pragma unroll
            for (int r = 0; r < 4; r++) {
                int m = mbase + mi * 16 + kg * 4 + r;
                int b_ = m >> 10, t = m & 1023;
                #pragma unroll
                for (int nj = 0; nj < 2; nj++) {
                    int col_local = wn * 32 + nj * 16 + rf;
                    int h = nb * 2 + (col_local >> 6);
                    int d = col_local & 63;
                    int i = d >> 1;
                    float v = acc[mi][nj][r];
                    float pv = __shfl_xor(v, 1);
                    float c = trig[t * 32 + i];
                    float s = trig[32768 + t * 32 + i];
                    float outv = (rf & 1) ? (pv * s + v * c) : (v * c - pv * s);
                    int col = (rf & 1) ? (32 + i) : i;
                    size_t base = ((size_t)(b_ * 48 + h) * 1024 + t) * 64;
                    Qr[base + col] = outv;
                }
            }
        }
    } else {
        #pragma unroll
        for (int nj = 0; nj < 2; nj++) {
            int col = (n0 - 3072) + wn * 32 + nj * 16 + rf;
            float bv = bcat[col];
            #pragma unroll
            for (int mi = 0; mi < 4; mi++)
                #pragma unroll
                for (int r = 0; r < 4; r++) {
                    int m = mbase + mi * 16 + kg * 4 + r;
                    O2[(size_t)m * 1536 + col] = acc[mi][nj][r] + bv;
                }
        }
    }
}

// ---------------------------------------------------------------------------
// K finish: wz_h = y + x*bias_h, then rope.  Kr fp32 + Kb16 bf16, head-major.
// ---------------------------------------------------------------------------
__global__ void k_finish_kernel(const float* __restrict__ O2, const float* __restrict__ trig,
                                const float* __restrict__ wbias,
                                float* __restrict__ Kr, unsigned short* __restrict__ Kb16)
{
    int idx = blockIdx.x * 256 + threadIdx.x;   // 786432
    int pr = idx & 31;
    int tmp = idx >> 5;
    int hb = tmp % 12;
    int bt = tmp / 12;
    int t = bt & 1023, b = bt >> 10;
    const float* yx = O2 + (size_t)bt * 1536 + hb * 64 + pr * 2;
    float y0 = yx[0], y1 = yx[1];
    float x0 = yx[768], x1 = yx[769];
    float cv = trig[t * 32 + pr], sv = trig[32768 + t * 32 + pr];
    #pragma unroll
    for (int r = 0; r < 4; r++) {
        int h = hb + 12 * r;
        float b0 = wbias[h * 64 + 2 * pr], b1 = wbias[h * 64 + 2 * pr + 1];
        float wz0 = y0 + x0 * b0;
        float wz1 = y1 + x1 * b1;
        float lo = wz0 * cv - wz1 * sv;
        float hi = wz0 * sv + wz1 * cv;
        size_t base = ((size_t)(b * 48 + h) * 1024 + t) * 64;
        Kr[base + pr] = lo;
        Kr[base + 32 + pr] = hi;
        Kb16[base + pr] = f2bf(lo);
        Kb16[base + 32 + pr] = f2bf(hi);
    }
}

// ---------------------------------------------------------------------------
// Attention core: bf16 MFMA scores -> online (m,Z) + per-lane top-4; merge to
// top-8 shortlist -> exact fp32 re-score -> stable top-4 -> weights -> marker.
// 4 independent waves, no LDS, no barriers.
// ---------------------------------------------------------------------------
__global__ __launch_bounds__(256) void attn_mfma_topk_kernel(
    const float* __restrict__ Qr, const float* __restrict__ Kr,
    const unsigned short* __restrict__ Kb, const float* __restrict__ sink,
    unsigned short* __restrict__ markerb, float* __restrict__ psink)
{
    const int bh = blockIdx.x;                 // 0..95
    const int qb = 15 - (int)blockIdx.y;       // longest blocks first
    const int w = threadIdx.x >> 6, lane = threadIdx.x & 63;
    const int rf = lane & 15, kg = lane >> 4;
    const int h = bh % HTq;
    const int q0 = qb * 64 + w * 16;
    const size_t rowbase = (size_t)bh * Tq;

    short8 a0, a1;
    {
        const float* qp = Qr + (rowbase + q0 + rf) * 64 + kg * 8;
        float4 u0 = *(const float4*)qp;
        float4 u1 = *(const float4*)(qp + 4);
        float4 u2 = *(const float4*)(qp + 32);
        float4 u3 = *(const float4*)(qp + 36);
        a0[0]=(short)f2bf(u0.x); a0[1]=(short)f2bf(u0.y); a0[2]=(short)f2bf(u0.z); a0[3]=(short)f2bf(u0.w);
        a0[4]=(short)f2bf(u1.x); a0[5]=(short)f2bf(u1.y); a0[6]=(short)f2bf(u1.z); a0[7]=(short)f2bf(u1.w);
        a1[0]=(short)f2bf(u2.x); a1[1]=(short)f2bf(u2.y); a1[2]=(short)f2bf(u2.z); a1[3]=(short)f2bf(u2.w);
        a1[4]=(short)f2bf(u3.x); a1[5]=(short)f2bf(u3.y); a1[6]=(short)f2bf(u3.z); a1[7]=(short)f2bf(u3.w);
    }

    float m_[4], Z_[4], tv[4][4];
    int ti[4][4];
    #pragma unroll
    for (int r = 0; r < 4; r++) {
        m_[r] = -1e30f; Z_[r] = 0.0f;
        #pragma unroll
        for (int p = 0; p < 4; p++) { tv[r][p] = -INFINITY; ti[r][p] = -1; }
    }

    const int T = (q0 + 15) / 64 + 1;
    const unsigned short* Kbb = Kb + rowbase * 64;
    for (int tile = 0; tile < T; tile++) {
        const int s0 = tile << 6;
        f32x4 accs[4];
        #pragma unroll
        for (int kc = 0; kc < 4; kc++) {
            const unsigned short* kp = Kbb + (size_t)(s0 + kc * 16 + rf) * 64 + kg * 8;
            short8 b0 = *(const short8*)kp;
            short8 b1 = *(const short8*)(kp + 32);
            f32x4 acc = {0.f, 0.f, 0.f, 0.f};
            acc = __builtin_amdgcn_mfma_f32_16x16x32_bf16(a0, b0, acc, 0, 0, 0);
            acc = __builtin_amdgcn_mfma_f32_16x16x32_bf16(a1, b1, acc, 0, 0, 0);
            accs[kc] = acc;
        }
        const bool lastt = (tile == T - 1);
        #pragma unroll
        for (int r = 0; r < 4; r++) {
            const int trow = q0 + kg * 4 + r;
            float sv[4];
            #pragma unroll
            for (int kc = 0; kc < 4; kc++) {
                int k = s0 + kc * 16 + rf;
                float s = accs[kc][r] * SCALE;
                sv[kc] = (lastt && k > trow) ? -INFINITY : s;
            }
            float tm = fmaxf(fmaxf(sv[0], sv[1]), fmaxf(sv[2], sv[3]));
            float nm = fmaxf(m_[r], tm);
            float zz = Z_[r] * __expf(m_[r] - nm);
            #pragma unroll
            for (int kc = 0; kc < 4; kc++) zz += __expf(sv[kc] - nm);
            Z_[r] = zz; m_[r] = nm;
            #pragma unroll
            for (int kc = 0; kc < 4; kc++) {
                float v = sv[kc]; int id = s0 + kc * 16 + rf;
                #pragma unroll
                for (int p = 0; p < 4; p++) {
                    bool sw = v > tv[r][p];
                    float ov = tv[r][p]; int oi = ti[r][p];
                    tv[r][p] = sw ? v : ov;  ti[r][p] = sw ? id : oi;
                    v = sw ? ov : v;          id = sw ? oi : id;
                }
            }
        }
    }

    const float sk = sink[h];
    #pragma unroll 1
    for (int r = 0; r < 4; r++) {
        const int q = q0 + kg * 4 + r;
        float m = m_[r], Z = Z_[r];
        #pragma unroll
        for (int off = 1; off < 16; off <<= 1) {
            float om = __shfl_xor(m, off);
            float oz = __shfl_xor(Z, off);
            float nm = fmaxf(m, om);
            Z = Z * __expf(m - nm) + oz * __expf(om - nm);
            m = nm;
        }
        float av[4]; int ai[4];
        #pragma unroll
        for (int p = 0; p < 4; p++) { av[p] = tv[r][p]; ai[p] = ti[r][p]; }
        float cvv[8]; int ci[8];
        #pragma unroll
        for (int rd = 0; rd < 8; rd++) {
            float v = av[0]; int id = ai[0];
            #pragma unroll
            for (int off = 1; off < 16; off <<= 1) {
                float ov = __shfl_xor(v, off);
                int oi = __shfl_xor(id, off);
                bool take = (ov > v) || ((ov == v) && ((unsigned)oi < (unsigned)id));
                v = take ? ov : v; id = take ? oi : id;
            }
            cvv[rd] = v; ci[rd] = id;
            bool own = (ai[0] == id) && (av[0] == v);
            av[0] = own ? av[1] : av[0];  ai[0] = own ? ai[1] : ai[0];
            av[1] = own ? av[2] : av[1];  ai[1] = own ? ai[2] : ai[1];
            av[2] = own ? av[3] : av[2];  ai[2] = own ? ai[3] : ai[2];
            av[3] = own ? -INFINITY : av[3]; ai[3] = own ? -1 : ai[3];
        }
        const float4 qv = *(const float4*)(Qr + (rowbase + q) * 64 + rf * 4);
        float sc[8];
        #pragma unroll
        for (int c = 0; c < 8; c++) {
            int idx = ci[c] < 0 ? 0 : ci[c];
            const float4 kv = *(const float4*)(Kr + (rowbase + idx) * 64 + rf * 4);
            float p = qv.x * kv.x + qv.y * kv.y + qv.z * kv.z + qv.w * kv.w;
            #pragma unroll
            for (int off = 1; off < 16; off <<= 1) p += __shfl_xor(p, off);
            sc[c] = (ci[c] < 0) ? -1e30f : p * SCALE;
        }
        float bv[4]; int bi[4];
        #pragma unroll
        for (int rd = 0; rd < 4; rd++) {
            float v = sc[0]; int id = ci[0];
            #pragma unroll
            for (int c = 1; c < 8; c++) {
                bool take = (sc[c] > v) || ((sc[c] == v) && ((unsigned)ci[c] < (unsigned)id));
                v = take ? sc[c] : v; id = take ? ci[c] : id;
            }
            bv[rd] = v; bi[rd] = id;
            #pragma unroll
            for (int c = 0; c < 8; c++) {
                bool kill = (ci[c] == id) && (sc[c] == v);
                sc[c] = kill ? -3e30f : sc[c];
            }
        }
        float mf = fmaxf(m, sk);
        float Zf = Z * __expf(m - mf) + __expf(sk - mf);
        float e0 = __expf(bv[0] - mf), e1 = __expf(bv[1] - mf);
        float e2 = __expf(bv[2] - mf), e3 = __expf(bv[3] - mf);
        float wsum = e0 + e1 + e2 + e3 + Zf * 1e-9f;
        float w0 = e0 / wsum, w1 = e1 / wsum, w2 = e2 / wsum, w3 = e3 / wsum;
        int i0 = bi[0] < 0 ? 0 : bi[0];
        int i1 = bi[1] < 0 ? 0 : bi[1];
        int i2 = bi[2] < 0 ? 0 : bi[2];
        int i3 = bi[3] < 0 ? 0 : bi[3];
        const float4 k0 = *(const float4*)(Kr + (rowbase + i0) * 64 + rf * 4);
        const float4 k1 = *(const float4*)(Kr + (rowbase + i1) * 64 + rf * 4);
        const float4 k2 = *(const float4*)(Kr + (rowbase + i2) * 64 + rf * 4);
        const float4 k3 = *(const float4*)(Kr + (rowbase + i3) * 64 + rf * 4);
        float mx = w0 * k0.x + w1 * k1.x + w2 * k2.x + w3 * k3.x;
        float my = w0 * k0.y + w1 * k1.y + w2 * k2.y + w3 * k3.y;
        float mz = w0 * k0.z + w1 * k1.z + w2 * k2.z + w3 * k3.z;
        float mw = w0 * k0.w + w1 * k1.w + w2 * k2.w + w3 * k3.w;
        ushort4 mo;
        mo.x = f2bf(mx); mo.y = f2bf(my); mo.z = f2bf(mz); mo.w = f2bf(mw);
        *(ushort4*)(markerb + (rowbase + q) * 64 + rf * 4) = mo;
        if (rf == 0) psink[rowbase + q] = __expf(sk - mf) / Zf;
    }
}

// ---------------------------------------------------------------------------
__global__ void cvt_bf16_kernel(const float* __restrict__ in,
                                unsigned short* __restrict__ out, int n4)
{
    int i = blockIdx.x * 256 + threadIdx.x;
    if (i < n4) {
        float4 v = ((const float4*)in)[i];
        ushort4 o;
        o.x = f2bf(v.x); o.y = f2bf(v.y); o.z = f2bf(v.z); o.w = f2bf(v.w);
        ((ushort4*)out)[i] = o;
    }
}

// ---------------------------------------------------------------------------
__global__ __launch_bounds__(256) void wo_transpose_kernel(
    const float* __restrict__ WOw, unsigned short* __restrict__ WOt)
{
    __shared__ float tl[64][65];
    int tid = threadIdx.x;
    int n = blockIdx.z;
    int c0 = blockIdx.x * 64, d0 = blockIdx.y * 64;
    const float* src = WOw + (size_t)n * 768 * 768;
    for (int l = tid; l < 64 * 16; l += 256) {
        int r = l >> 4, q = l & 15;
        float4 v = *(const float4*)(src + (size_t)(c0 + r) * 768 + d0 + q * 4);
        tl[r][q * 4 + 0] = v.x; tl[r][q * 4 + 1] = v.y;
        tl[r][q * 4 + 2] = v.z; tl[r][q * 4 + 3] = v.w;
    }
    __syncthreads();
    for (int l = tid; l < 64 * 16; l += 256) {
        int d = l >> 4, q = l & 15;
        ushort4 o;
        o.x = f2bf(tl[q * 4 + 0][d]); o.y = f2bf(tl[q * 4 + 1][d]);
        o.z = f2bf(tl[q * 4 + 2][d]); o.w = f2bf(tl[q * 4 + 3][d]);
        *(ushort4*)(WOt + (size_t)n * 768 * 768 + (size_t)(d0 + d) * 768 + c0 + q * 4) = o;
    }
}

// ---------------------------------------------------------------------------
__global__ __launch_bounds__(256) void mlp_mfma_kernel(
    const unsigned short* __restrict__ markerb, const float* __restrict__ psink,
    const unsigned short* __restrict__ V1b16, const float* __restrict__ V1bias,
    const unsigned short* __restrict__ V2b16, const float* __restrict__ V2bias,
    const float* __restrict__ vnulls, unsigned short* __restrict__ ctxb)
{
    __shared__ float h_lds[4][16][65];
    int tid = threadIdx.x;
    int w = tid >> 6, lane = tid & 63;
    int rf = lane & 15, kg = lane >> 4;
    size_t r0 = (size_t)blockIdx.x * 64 + 16 * w;

    short8 a1[2];
    #pragma unroll
    for (int kk = 0; kk < 2; kk++)
        a1[kk] = *(const short8*)(markerb + (r0 + rf) * 64 + kk * 32 + kg * 8);

    f32x4 acc2[4] = {};
    for (int ch = 0; ch < 4; ch++) {
        f32x4 acc1[4] = {};
        #pragma unroll
        for (int nj = 0; nj < 4; nj++)
            #pragma unroll
            for (int kk = 0; kk < 2; kk++) {
                short8 b1 = *(const short8*)(V1b16 + (size_t)(ch * 64 + nj * 16 + rf) * 64 + kk * 32 + kg * 8);
                acc1[nj] = __builtin_amdgcn_mfma_f32_16x16x32_bf16(a1[kk], b1, acc1[nj], 0, 0, 0);
            }
        __syncthreads();
        #pragma unroll
        for (int nj = 0; nj < 4; nj++) {
            float bb = V1bias[ch * 64 + nj * 16 + rf];
            #pragma unroll
            for (int r = 0; r < 4; r++) {
                float x = acc1[nj][r] + bb;
                h_lds[w][kg * 4 + r][nj * 16 + rf] = gelu_f(x);
            }
        }
        __syncthreads();
        #pragma unroll
        for (int kk = 0; kk < 2; kk++) {
            const float* hp = &h_lds[w][rf][kk * 32 + kg * 8];
            float4 p0 = *(const float4*)hp;
            float4 p1 = *(const float4*)(hp + 4);
            short8 a2;
            a2[0] = (short)f2bf(p0.x); a2[1] = (short)f2bf(p0.y);
            a2[2] = (short)f2bf(p0.z); a2[3] = (short)f2bf(p0.w);
            a2[4] = (short)f2bf(p1.x); a2[5] = (short)f2bf(p1.y);
            a2[6] = (short)f2bf(p1.z); a2[7] = (short)f2bf(p1.w);
            #pragma unroll
            for (int njo = 0; njo < 4; njo++) {
                short8 b2 = *(const short8*)(V2b16 + (size_t)(njo * 16 + rf) * 256 + ch * 64 + kk * 32 + kg * 8);
                acc2[njo] = __builtin_amdgcn_mfma_f32_16x16x32_bf16(a2, b2, acc2[njo], 0, 0, 0);
            }
        }
    }
    #pragma unroll
    for (int r = 0; r < 4; r++) {
        size_t R = r0 + kg * 4 + r;
        int bh = (int)(R >> 10), t = (int)(R & 1023);
        int b = bh / 48, h = bh % 48;
        int n = h / 12, head = h % 12;
        float ps = psink[R];
        size_t base = ((size_t)((b * 4 + n) * 1024 + t)) * 768 + head * 64;
        #pragma unroll
        for (int njo = 0; njo < 4; njo++) {
            int d = njo * 16 + rf;
            float v = acc2[njo][r] + V2bias[d] + ps * vnulls[h * 64 + d];
            ctxb[base + d] = f2bf(v);
        }
    }
}

// ---------------------------------------------------------------------------
__global__ __launch_bounds__(256) void gemm_wo_mfma(
    const unsigned short* __restrict__ ctxb, const unsigned short* __restrict__ WOtb,
    const float* __restrict__ WOb, float* __restrict__ Out)
{
    __shared__ unsigned short sA[64 * 64];
    __shared__ unsigned short sB[64 * 64];
    int tid = threadIdx.x;
    int w = tid >> 6, lane = tid & 63;
    int wm = w >> 1, wn = w & 1;
    int rf = lane & 15, kg = lane >> 4;
    int m0 = blockIdx.x * 64, n0 = blockIdx.y * 64;
    int b = m0 >> 10, t0 = m0 & 1023;
    int c0 = tid * 2, c1 = tid * 2 + 1;
    int ra = c0 >> 3, ca = c0 & 7, rb = c1 >> 3, cb = c1 & 7;
    f32x4 acc[2][2] = {};
    for (int n = 0; n < 4; n++) {
        const unsigned short* Ab = ctxb + ((size_t)((b * 4 + n) * 1024 + t0)) * 768;
        const unsigned short* Bb = WOtb + (size_t)n * 768 * 768 + (size_t)n0 * 768;
        for (int k0 = 0; k0 < 768; k0 += 64) {
            __syncthreads();
            *(short8*)&sA[ra * 64 + ((ca ^ (ra & 7)) * 8)] = *(const short8*)(Ab + (size_t)ra * 768 + k0 + ca * 8);
            *(short8*)&sA[rb * 64 + ((cb ^ (rb & 7)) * 8)] = *(const short8*)(Ab + (size_t)rb * 768 + k0 + cb * 8);
            *(short8*)&sB[ra * 64 + ((ca ^ (ra & 7)) * 8)] = *(const short8*)(Bb + (size_t)ra * 768 + k0 + ca * 8);
            *(short8*)&sB[rb * 64 + ((cb ^ (rb & 7)) * 8)] = *(const short8*)(Bb + (size_t)rb * 768 + k0 + cb * 8);
            __syncthreads();
            #pragma unroll
            for (int kk = 0; kk < 2; kk++) {
                int kc = kk * 4 + kg;
                int rA0 = wm * 32 + rf, rA1 = wm * 32 + 16 + rf;
                int rB0 = wn * 32 + rf, rB1 = wn * 32 + 16 + rf;
                short8 a0v = *(const short8*)&sA[rA0 * 64 + ((kc ^ (rA0 & 7)) * 8)];
                short8 a1v = *(const short8*)&sA[rA1 * 64 + ((kc ^ (rA1 & 7)) * 8)];
                short8 b0v = *(const short8*)&sB[rB0 * 64 + ((kc ^ (rB0 & 7)) * 8)];
                short8 b1v = *(const short8*)&sB[rB1 * 64 + ((kc ^ (rB1 & 7)) * 8)];
                acc[0][0] = __builtin_amdgcn_mfma_f32_16x16x32_bf16(a0v, b0v, acc[0][0], 0, 0, 0);
                acc[0][1] = __builtin_amdgcn_mfma_f32_16x16x32_bf16(a0v, b1v, acc[0][1], 0, 0, 0);
                acc[1][0] = __builtin_amdgcn_mfma_f32_16x16x32_bf16(a1v, b0v, acc[1][0], 0, 0, 0);
                acc[1][1] = __builtin_amdgcn_mfma_f32_16x16x32_bf16(a1v, b1v, acc[1][1], 0, 0, 0);
            }
        }
    }
    #pragma unroll
    for (int nj = 0; nj < 2; nj++) {
        int col = n0 + wn * 32 + nj * 16 + rf;
        float bm = WOb[col] + WOb[768 + col] + WOb[1536 + col] + WOb[2304 + col];
        #pragma unroll
        for (int mi = 0; mi < 2; mi++)
            #pragma unroll
            for (int r = 0; r < 4; r++) {
                int row = m0 + wm * 32 + mi * 16 + kg * 4 + r;
                Out[(size_t)row * 768 + col] = 0.25f * (acc[mi][nj][r] + bm);
            }
    }
}

// ---------------------------------------------------------------------------
extern "C" void kernel_launch(void* const* d_in, const int* in_sizes, int n_in,
                              void* d_out, int out_size, void* d_ws, size_t ws_size,
                              hipStream_t stream) {
    const float* A      = (const float*)d_in[0];
    const float* X      = (const float*)d_in[1];
    const float* WKw    = (const float*)d_in[2];
    const float* WKb    = (const float*)d_in[3];
    const float* WQw    = (const float*)d_in[4];
    const float* wA     = (const float*)d_in[5];
    const float* wB     = (const float*)d_in[6];
    const float* sink   = (const float*)d_in[7];
    const float* vnulls = (const float*)d_in[8];
    const float* V1w    = (const float*)d_in[9];
    const float* V1b    = (const float*)d_in[10];
    const float* V2w    = (const float*)d_in[11];
    const float* V2b    = (const float*)d_in[12];
    const float* WOw    = (const float*)d_in[13];
    const float* WOb    = (const float*)d_in[14];
    float* out = (float*)d_out;
    (void)in_sizes; (void)n_in; (void)out_size; (void)ws_size;

    float* ws = (float*)d_ws;
    size_t off = 0;
    float* Qr   = ws + off;  off += 6291456;   // head-major fp32 Q (rope'd)
    float* Kr   = ws + off;  off += 6291456;   // head-major fp32 K (rope'd)
    float* trig = ws + off;  off += 65536;
    float* bcat = ws + off;  off += 2048;
    float* O2   = ws + off;  off += 3145728;   // [2048][1536]: y | x
    float* Wsp_f = ws + off; off += 5308416;   // 3 planes x 4608x768 ushort
    unsigned short* Wsp = (unsigned short*)Wsp_f;
    unsigned short* Asp = (unsigned short*)(ws + off); off += 2359296;  // 3 planes x 2048x768
    unsigned short* Xsp = (unsigned short*)(ws + off); off += 2359296;
    // overlays (dead-buffer reuse) — audited lifetimes:
    //   markerb = O2 (FULL 3,145,728 floats; O2 dead after k_finish)
    //   Kb16 = Wsp floats [0, 3145728); psink = Wsp floats [3145728, 3244032)
    unsigned short* markerb = (unsigned short*)O2;
    unsigned short* Kb16 = Wsp;
    float* psink = Wsp_f + 3145728;
    unsigned short* V1b16 = Xsp;                         // Xsp dead after proj
    unsigned short* V2b16 = V1b16 + 16384;
    unsigned short* WOtb  = Asp;                         // Asp dead after proj
    unsigned short* ctxb  = (unsigned short*)Qr;         // Qr dead after attn

    // prep: trig + folded/split weights + split activations
    trig_kernel<<<128, 256, 0, stream>>>(trig);
    fold_split_kernel<<<dim3(48, 6), 256, 0, stream>>>(WQw, wA, wB, Wsp, 0);
    fold_split_kernel<<<dim3(12, 6), 256, 0, stream>>>(WKw, wA, wB, Wsp, 1);
    kbias_kernel<<<6, 256, 0, stream>>>(WKb, wA, bcat);
    split_act_kernel<<<1536, 256, 0, stream>>>(A, X, Asp, Xsp);
    // split-precision MFMA projection, LDS-staged (Q -> rope -> Qr; Kcat -> O2)
    proj_mfma_kernel<<<576, 512, 0, stream>>>(Asp, Xsp, Wsp, bcat, trig, Qr, O2);
    // finish K: per-h bias wedge term + rope -> Kr fp32 + Kb16 bf16
    k_finish_kernel<<<3072, 256, 0, stream>>>(O2, trig, wB, Kr, Kb16);
    // attention: MFMA scores, exact fp32 top-4 via shortlist re-score
    attn_mfma_topk_kernel<<<dim3(96, 16), 256, 0, stream>>>(Qr, Kr, Kb16, sink, markerb, psink);
    // post-top-k smooth path (bf16/MFMA)
    cvt_bf16_kernel<<<16, 256, 0, stream>>>(V1w, V1b16, 4096);
    cvt_bf16_kernel<<<16, 256, 0, stream>>>(V2w, V2b16, 4096);
    wo_transpose_kernel<<<dim3(12, 12, 4), 256, 0, stream>>>(WOw, WOtb);
    mlp_mfma_kernel<<<1536, 256, 0, stream>>>(markerb, psink, V1b16, V1b, V2b16, V2b, vnulls, ctxb);
    gemm_wo_mfma<<<dim3(32, 12), 256, 0, stream>>>(ctxb, WOtb, WOb, out);
}

// Round 8
// 353.707 us; speedup vs baseline: 3.6702x; 1.0254x over previous
//
#include <hip/hip_runtime.h>
#include <math.h>

constexpr int Bq  = 2;
constexpr int Tq  = 1024;
constexpr int HTq = 48;
constexpr float SCALE = 0.125f;     // 64^-0.5

typedef __attribute__((ext_vector_type(8))) short short8;
typedef __attribute__((ext_vector_type(4))) float f32x4;

__device__ inline unsigned short f2bf(float x) {
    unsigned u = __float_as_uint(x);
    return (unsigned short)((u + 0x7FFF + ((u >> 16) & 1)) >> 16);
}

// exact 3-plane bf16 split: x = p0 + p1 + p2 + O(2^-27 |x|)
__device__ inline void split3(float x, unsigned short& p0, unsigned short& p1, unsigned short& p2) {
    p0 = f2bf(x);
    float f0 = __uint_as_float((unsigned)p0 << 16);
    float r0 = x - f0;
    p1 = f2bf(r0);
    float f1 = __uint_as_float((unsigned)p1 << 16);
    float r1 = r0 - f1;
    p2 = f2bf(r1);
}

// exact-erf GELU via Abramowitz-Stegun 7.1.26 (|eps_erf| <= 1.5e-7)
__device__ inline float gelu_f(float x) {
    float z = 0.70710678118654752f * x;
    float az = fabsf(z);
    float t = __frcp_rn(1.0f + 0.3275911f * az);
    float poly = t * (0.254829592f + t * (-0.284496736f + t * (1.421413741f
               + t * (-1.453152027f + t * 1.061405429f))));
    float er = 1.0f - poly * __expf(-az * az);
    er = (z < 0.0f) ? -er : er;
    return 0.5f * x * (1.0f + er);
}

// ---------------------------------------------------------------------------
// trig table: cos at [t*32+i], sin at [32768 + t*32+i].
// ---------------------------------------------------------------------------
__global__ void trig_kernel(float* __restrict__ trig) {
    int i = blockIdx.x * 256 + threadIdx.x;   // 32768
    int t = i >> 5, f = i & 31;
    float invf = powf(10000.0f, -(float)f * (1.0f / 32.0f));
    float ang = (float)t * invf;
    trig[i] = cosf(ang);
    trig[32768 + i] = sinf(ang);
}

// ---------------------------------------------------------------------------
// Weight fold + 3-plane split.  skew = wA - wA^T.
// ---------------------------------------------------------------------------
__global__ __launch_bounds__(256) void fold_split_kernel(
    const float* __restrict__ Wsrc, const float* __restrict__ wA,
    const float* __restrict__ wbias, unsigned short* __restrict__ Wsp, int mode)
{
    const size_t WPL = (size_t)4608 * 768;
    __shared__ float sw[64][132];
    __shared__ float sk[64][65];
    int h = blockIdx.x, cb = blockIdx.y;
    int tid = threadIdx.x;
    const float* Wh = Wsrc + (size_t)h * 64 * 768 + cb * 128;
    for (int l = tid; l < 64 * 32; l += 256) {
        int d = l >> 5, c4 = l & 31;
        *(float4*)&sw[d][c4 * 4] = *(const float4*)(Wh + (size_t)d * 768 + c4 * 4);
    }
    for (int l = tid; l < 4096; l += 256) {
        int d = l >> 6, e = l & 63;
        sk[d][e] = wA[l] - wA[e * 64 + d];
    }
    __syncthreads();
    int tx = tid & 15, ty = tid >> 4;
    float acc4[4][8] = {};
    for (int d = 0; d < 64; d++) {
        float s0 = sk[d][ty * 4 + 0], s1 = sk[d][ty * 4 + 1];
        float s2 = sk[d][ty * 4 + 2], s3 = sk[d][ty * 4 + 3];
        float w_[8];
        *(float4*)&w_[0] = *(const float4*)&sw[d][tx * 8];
        *(float4*)&w_[4] = *(const float4*)&sw[d][tx * 8 + 4];
        #pragma unroll
        for (int j = 0; j < 8; j++) {
            acc4[0][j] += s0 * w_[j];
            acc4[1][j] += s1 * w_[j];
            acc4[2][j] += s2 * w_[j];
            acc4[3][j] += s3 * w_[j];
        }
    }
    #pragma unroll
    for (int i = 0; i < 4; i++) {
        int e = ty * 4 + i;
        float scale = (mode == 0) ? (1.0f + wbias[h * 64 + e]) : 1.0f;
        size_t row = (mode == 0) ? (size_t)(h * 64 + e) : (size_t)(3072 + h * 64 + e);
        #pragma unroll
        for (int j = 0; j < 8; j++) {
            int cl = tx * 8 + j;
            float wv = sw[e][cl] * scale + acc4[i][j];
            unsigned short p0, p1, p2;
            split3(wv, p0, p1, p2);
            size_t idx = row * 768 + cb * 128 + cl;
            Wsp[idx] = p0; Wsp[WPL + idx] = p1; Wsp[2 * WPL + idx] = p2;
        }
        if (mode == 1) {
            size_t row2 = (size_t)(3840 + h * 64 + e);
            #pragma unroll
            for (int j = 0; j < 8; j++) {
                int cl = tx * 8 + j;
                unsigned short p0, p1, p2;
                split3(sw[e][cl], p0, p1, p2);
                size_t idx = row2 * 768 + cb * 128 + cl;
                Wsp[idx] = p0; Wsp[WPL + idx] = p1; Wsp[2 * WPL + idx] = p2;
            }
        }
    }
}

// ---------------------------------------------------------------------------
__global__ void kbias_kernel(const float* __restrict__ WKb, const float* __restrict__ wA,
                             float* __restrict__ bcat) {
    int e = blockIdx.x * 256 + threadIdx.x;   // 1536
    if (e < 768) {
        int hb = e >> 6, el = e & 63;
        float acc = 0.0f;
        for (int d = 0; d < 64; d++) {
            float sk = wA[d * 64 + el] - wA[el * 64 + d];
            acc += WKb[hb * 64 + d] * sk;
        }
        bcat[e] = WKb[e] + acc;
    } else if (e < 1536) {
        bcat[e] = WKb[e - 768];
    }
}

// ---------------------------------------------------------------------------
__global__ void split_act_kernel(const float* __restrict__ A, const float* __restrict__ X,
                                 unsigned short* __restrict__ Asp, unsigned short* __restrict__ Xsp)
{
    const size_t APL = (size_t)2048 * 768;
    int i = blockIdx.x * 256 + threadIdx.x;   // 393216 quads
    if (i >= 393216) return;
    float4 va = ((const float4*)A)[i];
    float4 vx = ((const float4*)X)[i];
    ushort4 a0, a1, a2, x0, x1, x2;
    split3(va.x, a0.x, a1.x, a2.x); split3(va.y, a0.y, a1.y, a2.y);
    split3(va.z, a0.z, a1.z, a2.z); split3(va.w, a0.w, a1.w, a2.w);
    split3(vx.x, x0.x, x1.x, x2.x); split3(vx.y, x0.y, x1.y, x2.y);
    split3(vx.z, x0.z, x1.z, x2.z); split3(vx.w, x0.w, x1.w, x2.w);
    ((ushort4*)(Asp))[i] = a0;
    ((ushort4*)(Asp + APL))[i] = a1;
    ((ushort4*)(Asp + 2 * APL))[i] = a2;
    ((ushort4*)(Xsp))[i] = x0;
    ((ushort4*)(Xsp + APL))[i] = x1;
    ((ushort4*)(Xsp + 2 * APL))[i] = x2;
}

// ---------------------------------------------------------------------------
// Projection GEMM via split-precision bf16 MFMA, LDS-staged (round-7 verbatim).
// ---------------------------------------------------------------------------
__global__ __launch_bounds__(512) void proj_mfma_kernel(
    const unsigned short* __restrict__ Asp, const unsigned short* __restrict__ Xsp,
    const unsigned short* __restrict__ Wsp, const float* __restrict__ bcat,
    const float* __restrict__ trig, float* __restrict__ Qr, float* __restrict__ O2)
{
    const size_t APL = (size_t)2048 * 768;
    const size_t WPL = (size_t)4608 * 768;
    __shared__ unsigned short sA[3 * 128 * 40];
    __shared__ unsigned short sB[3 * 128 * 40];
    int bid = blockIdx.x;
    int swz = (bid & 7) * 72 + (bid >> 3);
    int nb = swz >> 4;
    int mb = swz & 15;
    bool isQ = (nb < 24);
    const unsigned short* Ab = isQ ? Asp : Xsp;
    int m0 = mb * 128, n0 = nb * 128;
    int tid = threadIdx.x;
    int w = tid >> 6, lane = tid & 63;
    int wm = w & 1, wn = w >> 1;
    int rf = lane & 15, kg = lane >> 4;
    int mbase = m0 + wm * 64;

    int sp_[3], sr_[3], ss_[3];
    #pragma unroll
    for (int i = 0; i < 3; i++) {
        int s = tid + i * 512;
        sp_[i] = s >> 9; sr_[i] = (s >> 2) & 127; ss_[i] = s & 3;
    }

    f32x4 acc[4][2] = {};
    for (int k0 = 0; k0 < 768; k0 += 32) {
        __syncthreads();
        #pragma unroll
        for (int i = 0; i < 3; i++) {
            short8 va = *(const short8*)(Ab + (size_t)sp_[i] * APL + (size_t)(m0 + sr_[i]) * 768 + k0 + ss_[i] * 8);
            short8 vb = *(const short8*)(Wsp + (size_t)sp_[i] * WPL + (size_t)(n0 + sr_[i]) * 768 + k0 + ss_[i] * 8);
            *(short8*)&sA[sp_[i] * 5120 + sr_[i] * 40 + ss_[i] * 8] = va;
            *(short8*)&sB[sp_[i] * 5120 + sr_[i] * 40 + ss_[i] * 8] = vb;
        }
        __syncthreads();

        short8 a0[4], a1[4], a2[4], b0[2], b1[2], b2[2];
        #pragma unroll
        for (int mi = 0; mi < 4; mi++) {
            int row = wm * 64 + mi * 16 + rf;
            a0[mi] = *(const short8*)&sA[0 * 5120 + row * 40 + kg * 8];
        }
        #pragma unroll
        for (int nj = 0; nj < 2; nj++) {
            int row = wn * 32 + nj * 16 + rf;
            b0[nj] = *(const short8*)&sB[0 * 5120 + row * 40 + kg * 8];
        }
        #pragma unroll
        for (int mi = 0; mi < 4; mi++)
            #pragma unroll
            for (int nj = 0; nj < 2; nj++)
                acc[mi][nj] = __builtin_amdgcn_mfma_f32_16x16x32_bf16(a0[mi], b0[nj], acc[mi][nj], 0, 0, 0);
        #pragma unroll
        for (int nj = 0; nj < 2; nj++) {
            int row = wn * 32 + nj * 16 + rf;
            b1[nj] = *(const short8*)&sB[1 * 5120 + row * 40 + kg * 8];
        }
        #pragma unroll
        for (int mi = 0; mi < 4; mi++)
            #pragma unroll
            for (int nj = 0; nj < 2; nj++)
                acc[mi][nj] = __builtin_amdgcn_mfma_f32_16x16x32_bf16(a0[mi], b1[nj], acc[mi][nj], 0, 0, 0);
        #pragma unroll
        for (int nj = 0; nj < 2; nj++) {
            int row = wn * 32 + nj * 16 + rf;
            b2[nj] = *(const short8*)&sB[2 * 5120 + row * 40 + kg * 8];
        }
        #pragma unroll
        for (int mi = 0; mi < 4; mi++)
            #pragma unroll
            for (int nj = 0; nj < 2; nj++)
                acc[mi][nj] = __builtin_amdgcn_mfma_f32_16x16x32_bf16(a0[mi], b2[nj], acc[mi][nj], 0, 0, 0);
        #pragma unroll
        for (int mi = 0; mi < 4; mi++) {
            int row = wm * 64 + mi * 16 + rf;
            a1[mi] = *(const short8*)&sA[1 * 5120 + row * 40 + kg * 8];
        }
        #pragma unroll
        for (int mi = 0; mi < 4; mi++)
            #pragma unroll
            for (int nj = 0; nj < 2; nj++)
                acc[mi][nj] = __builtin_amdgcn_mfma_f32_16x16x32_bf16(a1[mi], b0[nj], acc[mi][nj], 0, 0, 0);
        #pragma unroll
        for (int mi = 0; mi < 4; mi++)
            #pragma unroll
            for (int nj = 0; nj < 2; nj++)
                acc[mi][nj] = __builtin_amdgcn_mfma_f32_16x16x32_bf16(a1[mi], b1[nj], acc[mi][nj], 0, 0, 0);
        #pragma unroll
        for (int mi = 0; mi < 4; mi++) {
            int row = wm * 64 + mi * 16 + rf;
            a2[mi] = *(const short8*)&sA[2 * 5120 + row * 40 + kg * 8];
        }
        #pragma unroll
        for (int mi = 0; mi < 4; mi++)
            #pragma unroll
            for (int nj = 0; nj < 2; nj++)
                acc[mi][nj] = __builtin_amdgcn_mfma_f32_16x16x32_bf16(a2[mi], b0[nj], acc[mi][nj], 0, 0, 0);
    }

    if (isQ) {
        #pragma unroll
        for (int mi = 0; mi < 4; mi++) {
            #pragma unroll
            for (int r = 0; r < 4; r++) {
                int m = mbase + mi * 16 + kg * 4 + r;
                int b_ = m >> 10, t = m & 1023;
                #pragma unroll
                for (int nj = 0; nj < 2; nj++) {
                    int col_local = wn * 32 + nj * 16 + rf;
                    int h = nb * 2 + (col_local >> 6);
                    int d = col_local & 63;
                    int i = d >> 1;
                    float v = acc[mi][nj][r];
                    float pv = __shfl_xor(v, 1);
                    float c = trig[t * 32 + i];
                    float s = trig[32768 + t * 32 + i];
                    float outv = (rf & 1) ? (pv * s + v * c) : (v * c - pv * s);
                    int col = (rf & 1) ? (32 + i) : i;
                    size_t base = ((size_t)(b_ * 48 + h) * 1024 + t) * 64;
                    Qr[base + col] = outv;
                }
            }
        }
    } else {
        #pragma unroll
        for (int nj = 0; nj < 2; nj++) {
            int col = (n0 - 3072) + wn * 32 + nj * 16 + rf;
            float bv = bcat[col];
            #pragma unroll
            for (int mi = 0; mi < 4; mi++)
                #pragma unroll
                for (int r = 0; r < 4; r++) {
                    int m = mbase + mi * 16 + kg * 4 + r;
                    O2[(size_t)m * 1536 + col] = acc[mi][nj][r] + bv;
                }
        }
    }
}

// ---------------------------------------------------------------------------
__global__ void k_finish_kernel(const float* __restrict__ O2, const float* __restrict__ trig,
                                const float* __restrict__ wbias,
                                float* __restrict__ Kr, unsigned short* __restrict__ Kb16)
{
    int idx = blockIdx.x * 256 + threadIdx.x;   // 786432
    int pr = idx & 31;
    int tmp = idx >> 5;
    int hb = tmp % 12;
    int bt = tmp / 12;
    int t = bt & 1023, b = bt >> 10;
    const float* yx = O2 + (size_t)bt * 1536 + hb * 64 + pr * 2;
    float y0 = yx[0], y1 = yx[1];
    float x0 = yx[768], x1 = yx[769];
    float cv = trig[t * 32 + pr], sv = trig[32768 + t * 32 + pr];
    #pragma unroll
    for (int r = 0; r < 4; r++) {
        int h = hb + 12 * r;
        float b0 = wbias[h * 64 + 2 * pr], b1 = wbias[h * 64 + 2 * pr + 1];
        float wz0 = y0 + x0 * b0;
        float wz1 = y1 + x1 * b1;
        float lo = wz0 * cv - wz1 * sv;
        float hi = wz0 * sv + wz1 * cv;
        size_t base = ((size_t)(b * 48 + h) * 1024 + t) * 64;
        Kr[base + pr] = lo;
        Kr[base + 32 + pr] = hi;
        Kb16[base + pr] = f2bf(lo);
        Kb16[base + 32 + pr] = f2bf(hi);
    }
}

// ---------------------------------------------------------------------------
// Attention core v2: packed-key (22-bit score | 10-bit idx) top-4 via
// v_max/v_min_u32, diagonal-tile peel, register prefetch, uniform qb pairing.
// Final ranking = exact fp32 re-score + round-7 stable top-4 (unchanged).
// Grid (96, 8); wave does qb = 15-y then qb = y (17 tiles total, uniform).
// ---------------------------------------------------------------------------
__global__ __launch_bounds__(256) void attn_mfma_topk_kernel(
    const float* __restrict__ Qr, const float* __restrict__ Kr,
    const unsigned short* __restrict__ Kb, const float* __restrict__ sink,
    unsigned short* __restrict__ markerb, float* __restrict__ psink)
{
    const int bh = blockIdx.x;                 // 0..95
    const int y  = blockIdx.y;                 // 0..7
    const int w = threadIdx.x >> 6, lane = threadIdx.x & 63;
    const int rf = lane & 15, kg = lane >> 4;
    const int h = bh % HTq;
    const size_t rowbase = (size_t)bh * Tq;
    const unsigned short* Kbb = Kb + rowbase * 64;
    const float sk = sink[h];

    #pragma unroll 1
    for (int g = 0; g < 2; g++) {
        const int qb = g ? y : 15 - y;
        const int q0 = qb * 64 + w * 16;

        // Q fragments for rows q0..q0+15
        short8 a0, a1;
        {
            const float* qp = Qr + (rowbase + q0 + rf) * 64 + kg * 8;
            float4 u0 = *(const float4*)qp;
            float4 u1 = *(const float4*)(qp + 4);
            float4 u2 = *(const float4*)(qp + 32);
            float4 u3 = *(const float4*)(qp + 36);
            a0[0]=(short)f2bf(u0.x); a0[1]=(short)f2bf(u0.y); a0[2]=(short)f2bf(u0.z); a0[3]=(short)f2bf(u0.w);
            a0[4]=(short)f2bf(u1.x); a0[5]=(short)f2bf(u1.y); a0[6]=(short)f2bf(u1.z); a0[7]=(short)f2bf(u1.w);
            a1[0]=(short)f2bf(u2.x); a1[1]=(short)f2bf(u2.y); a1[2]=(short)f2bf(u2.z); a1[3]=(short)f2bf(u2.w);
            a1[4]=(short)f2bf(u3.x); a1[5]=(short)f2bf(u3.y); a1[6]=(short)f2bf(u3.z); a1[7]=(short)f2bf(u3.w);
        }

        float m_[4], Z_[4];
        unsigned t_[4][4];           // packed top-4, descending, 0 = empty
        #pragma unroll
        for (int r = 0; r < 4; r++) {
            m_[r] = -1e30f; Z_[r] = 0.0f;
            t_[r][0] = 0u; t_[r][1] = 0u; t_[r][2] = 0u; t_[r][3] = 0u;
        }

        short8 cA0[4], cA1[4], cB0[4], cB1[4];
        // load tile 0 into A
        {
            const unsigned short* p = Kbb + (size_t)rf * 64 + kg * 8;
            #pragma unroll
            for (int kc = 0; kc < 4; kc++) {
                cA0[kc] = *(const short8*)(p + kc * 1024);
                cA1[kc] = *(const short8*)(p + kc * 1024 + 32);
            }
        }

        // full-tile body: MFMA on cb, prefetch tile+1 into nb, unmasked postproc
        auto body = [&](short8 (&cb0)[4], short8 (&cb1)[4],
                        short8 (&nb0)[4], short8 (&nb1)[4], int tile) {
            f32x4 accs[4];
            #pragma unroll
            for (int kc = 0; kc < 4; kc++) {
                f32x4 acc = {0.f, 0.f, 0.f, 0.f};
                acc = __builtin_amdgcn_mfma_f32_16x16x32_bf16(a0, cb0[kc], acc, 0, 0, 0);
                acc = __builtin_amdgcn_mfma_f32_16x16x32_bf16(a1, cb1[kc], acc, 0, 0, 0);
                accs[kc] = acc;
            }
            // prefetch next tile (tile+1 <= qb always)
            const unsigned short* np = Kbb + (size_t)((tile + 1) * 64 + rf) * 64 + kg * 8;
            #pragma unroll
            for (int kc = 0; kc < 4; kc++) {
                nb0[kc] = *(const short8*)(np + kc * 1024);
                nb1[kc] = *(const short8*)(np + kc * 1024 + 32);
            }
            const int s0 = tile << 6;
            #pragma unroll
            for (int r = 0; r < 4; r++) {
                float sv[4];
                #pragma unroll
                for (int kc = 0; kc < 4; kc++) sv[kc] = accs[kc][r] * SCALE;
                #pragma unroll
                for (int kc = 0; kc < 4; kc++) {
                    unsigned u = __float_as_uint(sv[kc]);
                    unsigned key = u ^ ((unsigned)(((int)u) >> 31) | 0x80000000u);
                    unsigned c = (key & 0xFFFFFC00u) | (unsigned)(s0 + kc * 16 + rf);
                    unsigned n;
                    n = t_[r][0] > c ? t_[r][0] : c;  c = t_[r][0] > c ? c : t_[r][0];  t_[r][0] = n;
                    n = t_[r][1] > c ? t_[r][1] : c;  c = t_[r][1] > c ? c : t_[r][1];  t_[r][1] = n;
                    n = t_[r][2] > c ? t_[r][2] : c;  c = t_[r][2] > c ? c : t_[r][2];  t_[r][2] = n;
                    t_[r][3] = t_[r][3] > c ? t_[r][3] : c;
                }
                float tm = fmaxf(fmaxf(sv[0], sv[1]), fmaxf(sv[2], sv[3]));
                float nm = fmaxf(m_[r], tm);
                float zz = Z_[r] * __expf(m_[r] - nm);
                #pragma unroll
                for (int kc = 0; kc < 4; kc++) zz += __expf(sv[kc] - nm);
                Z_[r] = zz; m_[r] = nm;
            }
        };

        int tile = 0;
        for (; tile + 1 < qb; tile += 2) {
            body(cA0, cA1, cB0, cB1, tile);
            body(cB0, cB1, cA0, cA1, tile + 1);
        }
        if (tile < qb) {   // one leftover full tile; diagonal lands in B -> copy back
            body(cA0, cA1, cB0, cB1, tile);
            #pragma unroll
            for (int kc = 0; kc < 4; kc++) { cA0[kc] = cB0[kc]; cA1[kc] = cB1[kc]; }
        }

        // diagonal tile (in A), masked postproc
        {
            f32x4 accs[4];
            #pragma unroll
            for (int kc = 0; kc < 4; kc++) {
                f32x4 acc = {0.f, 0.f, 0.f, 0.f};
                acc = __builtin_amdgcn_mfma_f32_16x16x32_bf16(a0, cA0[kc], acc, 0, 0, 0);
                acc = __builtin_amdgcn_mfma_f32_16x16x32_bf16(a1, cA1[kc], acc, 0, 0, 0);
                accs[kc] = acc;
            }
            const int s0 = qb << 6;
            #pragma unroll
            for (int r = 0; r < 4; r++) {
                const int trow = q0 + kg * 4 + r;
                float sv[4];
                unsigned pk[4];
                #pragma unroll
                for (int kc = 0; kc < 4; kc++) {
                    int k = s0 + kc * 16 + rf;
                    bool ok = (k <= trow);
                    float s = accs[kc][r] * SCALE;
                    sv[kc] = ok ? s : -INFINITY;
                    unsigned u = __float_as_uint(s);
                    unsigned key = u ^ ((unsigned)(((int)u) >> 31) | 0x80000000u);
                    unsigned c = (key & 0xFFFFFC00u) | (unsigned)k;
                    pk[kc] = ok ? c : 0u;
                }
                #pragma unroll
                for (int kc = 0; kc < 4; kc++) {
                    unsigned c = pk[kc], n;
                    n = t_[r][0] > c ? t_[r][0] : c;  c = t_[r][0] > c ? c : t_[r][0];  t_[r][0] = n;
                    n = t_[r][1] > c ? t_[r][1] : c;  c = t_[r][1] > c ? c : t_[r][1];  t_[r][1] = n;
                    n = t_[r][2] > c ? t_[r][2] : c;  c = t_[r][2] > c ? c : t_[r][2];  t_[r][2] = n;
                    t_[r][3] = t_[r][3] > c ? t_[r][3] : c;
                }
                float tm = fmaxf(fmaxf(sv[0], sv[1]), fmaxf(sv[2], sv[3]));
                float nm = fmaxf(m_[r], tm);
                float zz = Z_[r] * __expf(m_[r] - nm);
                #pragma unroll
                for (int kc = 0; kc < 4; kc++) zz += __expf(sv[kc] - nm);
                Z_[r] = zz; m_[r] = nm;
            }
        }

        // epilogue per row
        #pragma unroll 1
        for (int r = 0; r < 4; r++) {
            const int q = q0 + kg * 4 + r;
            float m = m_[r], Z = Z_[r];
            #pragma unroll
            for (int off = 1; off < 16; off <<= 1) {
                float om = __shfl_xor(m, off);
                float oz = __shfl_xor(Z, off);
                float nm = fmaxf(m, om);
                Z = Z * __expf(m - nm) + oz * __expf(om - nm);
                m = nm;
            }
            // merge 16 per-lane packed top-4 -> global top-8 (argmax + pop)
            unsigned l0 = t_[r][0], l1 = t_[r][1], l2 = t_[r][2], l3 = t_[r][3];
            unsigned ck[8];
            #pragma unroll
            for (int rd = 0; rd < 8; rd++) {
                unsigned v = l0;
                #pragma unroll
                for (int off = 1; off < 16; off <<= 1) {
                    unsigned ov = (unsigned)__shfl_xor((int)v, off);
                    v = v > ov ? v : ov;
                }
                ck[rd] = v;
                bool own = (l0 == v);
                l0 = own ? l1 : l0;
                l1 = own ? l2 : l1;
                l2 = own ? l3 : l2;
                l3 = own ? 0u : l3;
            }
            // exact fp32 re-score of shortlist
            const float4 qv = *(const float4*)(Qr + (rowbase + q) * 64 + rf * 4);
            float sc[8]; int ci[8];
            #pragma unroll
            for (int c = 0; c < 8; c++) {
                bool valid = (ck[c] != 0u);
                int idx = (int)(ck[c] & 1023u);
                int lidx = valid ? idx : 0;
                const float4 kv = *(const float4*)(Kr + (rowbase + lidx) * 64 + rf * 4);
                float p = qv.x * kv.x + qv.y * kv.y + qv.z * kv.z + qv.w * kv.w;
                #pragma unroll
                for (int off = 1; off < 16; off <<= 1) p += __shfl_xor(p, off);
                sc[c] = valid ? p * SCALE : -1e30f;
                ci[c] = valid ? idx : -1;
            }
            // stable top-4 of the 8 exact scores (value desc, index asc)
            float bv[4]; int bi[4];
            #pragma unroll
            for (int rd = 0; rd < 4; rd++) {
                float v = sc[0]; int id = ci[0];
                #pragma unroll
                for (int c = 1; c < 8; c++) {
                    bool take = (sc[c] > v) || ((sc[c] == v) && ((unsigned)ci[c] < (unsigned)id));
                    v = take ? sc[c] : v; id = take ? ci[c] : id;
                }
                bv[rd] = v; bi[rd] = id;
                #pragma unroll
                for (int c = 0; c < 8; c++) {
                    bool kill = (ci[c] == id) && (sc[c] == v);
                    sc[c] = kill ? -3e30f : sc[c];
                }
            }
            float mf = fmaxf(m, sk);
            float Zf = Z * __expf(m - mf) + __expf(sk - mf);
            float e0 = __expf(bv[0] - mf), e1 = __expf(bv[1] - mf);
            float e2 = __expf(bv[2] - mf), e3 = __expf(bv[3] - mf);
            float wsum = e0 + e1 + e2 + e3 + Zf * 1e-9f;
            float w0 = e0 / wsum, w1 = e1 / wsum, w2 = e2 / wsum, w3 = e3 / wsum;
            int i0 = bi[0] < 0 ? 0 : bi[0];
            int i1 = bi[1] < 0 ? 0 : bi[1];
            int i2 = bi[2] < 0 ? 0 : bi[2];
            int i3 = bi[3] < 0 ? 0 : bi[3];
            const float4 k0 = *(const float4*)(Kr + (rowbase + i0) * 64 + rf * 4);
            const float4 k1 = *(const float4*)(Kr + (rowbase + i1) * 64 + rf * 4);
            const float4 k2 = *(const float4*)(Kr + (rowbase + i2) * 64 + rf * 4);
            const float4 k3 = *(const float4*)(Kr + (rowbase + i3) * 64 + rf * 4);
            float mx = w0 * k0.x + w1 * k1.x + w2 * k2.x + w3 * k3.x;
            float my = w0 * k0.y + w1 * k1.y + w2 * k2.y + w3 * k3.y;
            float mz = w0 * k0.z + w1 * k1.z + w2 * k2.z + w3 * k3.z;
            float mw = w0 * k0.w + w1 * k1.w + w2 * k2.w + w3 * k3.w;
            ushort4 mo;
            mo.x = f2bf(mx); mo.y = f2bf(my); mo.z = f2bf(mz); mo.w = f2bf(mw);
            *(ushort4*)(markerb + (rowbase + q) * 64 + rf * 4) = mo;
            if (rf == 0) psink[rowbase + q] = __expf(sk - mf) / Zf;
        }
    }
}

// ---------------------------------------------------------------------------
__global__ void cvt_bf16_kernel(const float* __restrict__ in,
                                unsigned short* __restrict__ out, int n4)
{
    int i = blockIdx.x * 256 + threadIdx.x;
    if (i < n4) {
        float4 v = ((const float4*)in)[i];
        ushort4 o;
        o.x = f2bf(v.x); o.y = f2bf(v.y); o.z = f2bf(v.z); o.w = f2bf(v.w);
        ((ushort4*)out)[i] = o;
    }
}

// ---------------------------------------------------------------------------
__global__ __launch_bounds__(256) void wo_transpose_kernel(
    const float* __restrict__ WOw, unsigned short* __restrict__ WOt)
{
    __shared__ float tl[64][65];
    int tid = threadIdx.x;
    int n = blockIdx.z;
    int c0 = blockIdx.x * 64, d0 = blockIdx.y * 64;
    const float* src = WOw + (size_t)n * 768 * 768;
    for (int l = tid; l < 64 * 16; l += 256) {
        int r = l >> 4, q = l & 15;
        float4 v = *(const float4*)(src + (size_t)(c0 + r) * 768 + d0 + q * 4);
        tl[r][q * 4 + 0] = v.x; tl[r][q * 4 + 1] = v.y;
        tl[r][q * 4 + 2] = v.z; tl[r][q * 4 + 3] = v.w;
    }
    __syncthreads();
    for (int l = tid; l < 64 * 16; l += 256) {
        int d = l >> 4, q = l & 15;
        ushort4 o;
        o.x = f2bf(tl[q * 4 + 0][d]); o.y = f2bf(tl[q * 4 + 1][d]);
        o.z = f2bf(tl[q * 4 + 2][d]); o.w = f2bf(tl[q * 4 + 3][d]);
        *(ushort4*)(WOt + (size_t)n * 768 * 768 + (size_t)(d0 + d) * 768 + c0 + q * 4) = o;
    }
}

// ---------------------------------------------------------------------------
__global__ __launch_bounds__(256) void mlp_mfma_kernel(
    const unsigned short* __restrict__ markerb, const float* __restrict__ psink,
    const unsigned short* __restrict__ V1b16, const float* __restrict__ V1bias,
    const unsigned short* __restrict__ V2b16, const float* __restrict__ V2bias,
    const float* __restrict__ vnulls, unsigned short* __restrict__ ctxb)
{
    __shared__ float h_lds[4][16][65];
    int tid = threadIdx.x;
    int w = tid >> 6, lane = tid & 63;
    int rf = lane & 15, kg = lane >> 4;
    size_t r0 = (size_t)blockIdx.x * 64 + 16 * w;

    short8 a1[2];
    #pragma unroll
    for (int kk = 0; kk < 2; kk++)
        a1[kk] = *(const short8*)(markerb + (r0 + rf) * 64 + kk * 32 + kg * 8);

    f32x4 acc2[4] = {};
    for (int ch = 0; ch < 4; ch++) {
        f32x4 acc1[4] = {};
        #pragma unroll
        for (int nj = 0; nj < 4; nj++)
            #pragma unroll
            for (int kk = 0; kk < 2; kk++) {
                short8 b1 = *(const short8*)(V1b16 + (size_t)(ch * 64 + nj * 16 + rf) * 64 + kk * 32 + kg * 8);
                acc1[nj] = __builtin_amdgcn_mfma_f32_16x16x32_bf16(a1[kk], b1, acc1[nj], 0, 0, 0);
            }
        __syncthreads();
        #pragma unroll
        for (int nj = 0; nj < 4; nj++) {
            float bb = V1bias[ch * 64 + nj * 16 + rf];
            #pragma unroll
            for (int r = 0; r < 4; r++) {
                float x = acc1[nj][r] + bb;
                h_lds[w][kg * 4 + r][nj * 16 + rf] = gelu_f(x);
            }
        }
        __syncthreads();
        #pragma unroll
        for (int kk = 0; kk < 2; kk++) {
            const float* hp = &h_lds[w][rf][kk * 32 + kg * 8];
            float4 p0 = *(const float4*)hp;
            float4 p1 = *(const float4*)(hp + 4);
            short8 a2;
            a2[0] = (short)f2bf(p0.x); a2[1] = (short)f2bf(p0.y);
            a2[2] = (short)f2bf(p0.z); a2[3] = (short)f2bf(p0.w);
            a2[4] = (short)f2bf(p1.x); a2[5] = (short)f2bf(p1.y);
            a2[6] = (short)f2bf(p1.z); a2[7] = (short)f2bf(p1.w);
            #pragma unroll
            for (int njo = 0; njo < 4; njo++) {
                short8 b2 = *(const short8*)(V2b16 + (size_t)(njo * 16 + rf) * 256 + ch * 64 + kk * 32 + kg * 8);
                acc2[njo] = __builtin_amdgcn_mfma_f32_16x16x32_bf16(a2, b2, acc2[njo], 0, 0, 0);
            }
        }
    }
    #pragma unroll
    for (int r = 0; r < 4; r++) {
        size_t R = r0 + kg * 4 + r;
        int bh = (int)(R >> 10), t = (int)(R & 1023);
        int b = bh / 48, h = bh % 48;
        int n = h / 12, head = h % 12;
        float ps = psink[R];
        size_t base = ((size_t)((b * 4 + n) * 1024 + t)) * 768 + head * 64;
        #pragma unroll
        for (int njo = 0; njo < 4; njo++) {
            int d = njo * 16 + rf;
            float v = acc2[njo][r] + V2bias[d] + ps * vnulls[h * 64 + d];
            ctxb[base + d] = f2bf(v);
        }
    }
}

// ---------------------------------------------------------------------------
__global__ __launch_bounds__(256) void gemm_wo_mfma(
    const unsigned short* __restrict__ ctxb, const unsigned short* __restrict__ WOtb,
    const float* __restrict__ WOb, float* __restrict__ Out)
{
    __shared__ unsigned short sA[64 * 64];
    __shared__ unsigned short sB[64 * 64];
    int tid = threadIdx.x;
    int w = tid >> 6, lane = tid & 63;
    int wm = w >> 1, wn = w & 1;
    int rf = lane & 15, kg = lane >> 4;
    int m0 = blockIdx.x * 64, n0 = blockIdx.y * 64;
    int b = m0 >> 10, t0 = m0 & 1023;
    int c0 = tid * 2, c1 = tid * 2 + 1;
    int ra = c0 >> 3, ca = c0 & 7, rb = c1 >> 3, cb = c1 & 7;
    f32x4 acc[2][2] = {};
    for (int n = 0; n < 4; n++) {
        const unsigned short* Ab = ctxb + ((size_t)((b * 4 + n) * 1024 + t0)) * 768;
        const unsigned short* Bb = WOtb + (size_t)n * 768 * 768 + (size_t)n0 * 768;
        for (int k0 = 0; k0 < 768; k0 += 64) {
            __syncthreads();
            *(short8*)&sA[ra * 64 + ((ca ^ (ra & 7)) * 8)] = *(const short8*)(Ab + (size_t)ra * 768 + k0 + ca * 8);
            *(short8*)&sA[rb * 64 + ((cb ^ (rb & 7)) * 8)] = *(const short8*)(Ab + (size_t)rb * 768 + k0 + cb * 8);
            *(short8*)&sB[ra * 64 + ((ca ^ (ra & 7)) * 8)] = *(const short8*)(Bb + (size_t)ra * 768 + k0 + ca * 8);
            *(short8*)&sB[rb * 64 + ((cb ^ (rb & 7)) * 8)] = *(const short8*)(Bb + (size_t)rb * 768 + k0 + cb * 8);
            __syncthreads();
            #pragma unroll
            for (int kk = 0; kk < 2; kk++) {
                int kc = kk * 4 + kg;
                int rA0 = wm * 32 + rf, rA1 = wm * 32 + 16 + rf;
                int rB0 = wn * 32 + rf, rB1 = wn * 32 + 16 + rf;
                short8 a0v = *(const short8*)&sA[rA0 * 64 + ((kc ^ (rA0 & 7)) * 8)];
                short8 a1v = *(const short8*)&sA[rA1 * 64 + ((kc ^ (rA1 & 7)) * 8)];
                short8 b0v = *(const short8*)&sB[rB0 * 64 + ((kc ^ (rB0 & 7)) * 8)];
                short8 b1v = *(const short8*)&sB[rB1 * 64 + ((kc ^ (rB1 & 7)) * 8)];
                acc[0][0] = __builtin_amdgcn_mfma_f32_16x16x32_bf16(a0v, b0v, acc[0][0], 0, 0, 0);
                acc[0][1] = __builtin_amdgcn_mfma_f32_16x16x32_bf16(a0v, b1v, acc[0][1], 0, 0, 0);
                acc[1][0] = __builtin_amdgcn_mfma_f32_16x16x32_bf16(a1v, b0v, acc[1][0], 0, 0, 0);
                acc[1][1] = __builtin_amdgcn_mfma_f32_16x16x32_bf16(a1v, b1v, acc[1][1], 0, 0, 0);
            }
        }
    }
    #pragma unroll
    for (int nj = 0; nj < 2; nj++) {
        int col = n0 + wn * 32 + nj * 16 + rf;
        float bm = WOb[col] + WOb[768 + col] + WOb[1536 + col] + WOb[2304 + col];
        #pragma unroll
        for (int mi = 0; mi < 2; mi++)
            #pragma unroll
            for (int r = 0; r < 4; r++) {
                int row = m0 + wm * 32 + mi * 16 + kg * 4 + r;
                Out[(size_t)row * 768 + col] = 0.25f * (acc[mi][nj][r] + bm);
            }
    }
}

// ---------------------------------------------------------------------------
extern "C" void kernel_launch(void* const* d_in, const int* in_sizes, int n_in,
                              void* d_out, int out_size, void* d_ws, size_t ws_size,
                              hipStream_t stream) {
    const float* A      = (const float*)d_in[0];
    const float* X      = (const float*)d_in[1];
    const float* WKw    = (const float*)d_in[2];
    const float* WKb    = (const float*)d_in[3];
    const float* WQw    = (const float*)d_in[4];
    const float* wA     = (const float*)d_in[5];
    const float* wB     = (const float*)d_in[6];
    const float* sink   = (const float*)d_in[7];
    const float* vnulls = (const float*)d_in[8];
    const float* V1w    = (const float*)d_in[9];
    const float* V1b    = (const float*)d_in[10];
    const float* V2w    = (const float*)d_in[11];
    const float* V2b    = (const float*)d_in[12];
    const float* WOw    = (const float*)d_in[13];
    const float* WOb    = (const float*)d_in[14];
    float* out = (float*)d_out;
    (void)in_sizes; (void)n_in; (void)out_size; (void)ws_size;

    float* ws = (float*)d_ws;
    size_t off = 0;
    float* Qr   = ws + off;  off += 6291456;   // head-major fp32 Q (rope'd)
    float* Kr   = ws + off;  off += 6291456;   // head-major fp32 K (rope'd)
    float* trig = ws + off;  off += 65536;
    float* bcat = ws + off;  off += 2048;
    float* O2   = ws + off;  off += 3145728;   // [2048][1536]: y | x
    float* Wsp_f = ws + off; off += 5308416;   // 3 planes x 4608x768 ushort
    unsigned short* Wsp = (unsigned short*)Wsp_f;
    unsigned short* Asp = (unsigned short*)(ws + off); off += 2359296;  // 3 planes x 2048x768
    unsigned short* Xsp = (unsigned short*)(ws + off); off += 2359296;
    // overlays (dead-buffer reuse) — audited lifetimes:
    //   markerb = O2 (FULL 3,145,728 floats; O2 dead after k_finish)
    //   Kb16 = Wsp floats [0, 3145728); psink = Wsp floats [3145728, 3244032)
    unsigned short* markerb = (unsigned short*)O2;
    unsigned short* Kb16 = Wsp;
    float* psink = Wsp_f + 3145728;
    unsigned short* V1b16 = Xsp;                         // Xsp dead after proj
    unsigned short* V2b16 = V1b16 + 16384;
    unsigned short* WOtb  = Asp;                         // Asp dead after proj
    unsigned short* ctxb  = (unsigned short*)Qr;         // Qr dead after attn

    // prep: trig + folded/split weights + split activations
    trig_kernel<<<128, 256, 0, stream>>>(trig);
    fold_split_kernel<<<dim3(48, 6), 256, 0, stream>>>(WQw, wA, wB, Wsp, 0);
    fold_split_kernel<<<dim3(12, 6), 256, 0, stream>>>(WKw, wA, wB, Wsp, 1);
    kbias_kernel<<<6, 256, 0, stream>>>(WKb, wA, bcat);
    split_act_kernel<<<1536, 256, 0, stream>>>(A, X, Asp, Xsp);
    // split-precision MFMA projection, LDS-staged (Q -> rope -> Qr; Kcat -> O2)
    proj_mfma_kernel<<<576, 512, 0, stream>>>(Asp, Xsp, Wsp, bcat, trig, Qr, O2);
    // finish K: per-h bias wedge term + rope -> Kr fp32 + Kb16 bf16
    k_finish_kernel<<<3072, 256, 0, stream>>>(O2, trig, wB, Kr, Kb16);
    // attention: MFMA scores, packed-key shortlist, exact fp32 top-4
    attn_mfma_topk_kernel<<<dim3(96, 8), 256, 0, stream>>>(Qr, Kr, Kb16, sink, markerb, psink);
    // post-top-k smooth path (bf16/MFMA)
    cvt_bf16_kernel<<<16, 256, 0, stream>>>(V1w, V1b16, 4096);
    cvt_bf16_kernel<<<16, 256, 0, stream>>>(V2w, V2b16, 4096);
    wo_transpose_kernel<<<dim3(12, 12, 4), 256, 0, stream>>>(WOw, WOtb);
    mlp_mfma_kernel<<<1536, 256, 0, stream>>>(markerb, psink, V1b16, V1b, V2b16, V2b, vnulls, ctxb);
    gemm_wo_mfma<<<dim3(32, 12), 256, 0, stream>>>(ctxb, WOtb, WOb, out);
}

// Round 9
// 353.486 us; speedup vs baseline: 3.6725x; 1.0006x over previous
//
#include <hip/hip_runtime.h>
#include <math.h>

constexpr int Bq  = 2;
constexpr int Tq  = 1024;
constexpr int HTq = 48;
constexpr float SCALE = 0.125f;     // 64^-0.5

typedef __attribute__((ext_vector_type(8))) short short8;
typedef __attribute__((ext_vector_type(4))) float f32x4;

__device__ inline unsigned short f2bf(float x) {
    unsigned u = __float_as_uint(x);
    return (unsigned short)((u + 0x7FFF + ((u >> 16) & 1)) >> 16);
}

// exact 3-plane bf16 split: x = p0 + p1 + p2 + O(2^-27 |x|)
__device__ inline void split3(float x, unsigned short& p0, unsigned short& p1, unsigned short& p2) {
    p0 = f2bf(x);
    float f0 = __uint_as_float((unsigned)p0 << 16);
    float r0 = x - f0;
    p1 = f2bf(r0);
    float f1 = __uint_as_float((unsigned)p1 << 16);
    float r1 = r0 - f1;
    p2 = f2bf(r1);
}

// exact-erf GELU via Abramowitz-Stegun 7.1.26 (|eps_erf| <= 1.5e-7)
__device__ inline float gelu_f(float x) {
    float z = 0.70710678118654752f * x;
    float az = fabsf(z);
    float t = __frcp_rn(1.0f + 0.3275911f * az);
    float poly = t * (0.254829592f + t * (-0.284496736f + t * (1.421413741f
               + t * (-1.453152027f + t * 1.061405429f))));
    float er = 1.0f - poly * __expf(-az * az);
    er = (z < 0.0f) ? -er : er;
    return 0.5f * x * (1.0f + er);
}

// ---------------------------------------------------------------------------
// trig table: cos at [t*32+i], sin at [32768 + t*32+i].
// ---------------------------------------------------------------------------
__global__ void trig_kernel(float* __restrict__ trig) {
    int i = blockIdx.x * 256 + threadIdx.x;   // 32768
    int t = i >> 5, f = i & 31;
    float invf = powf(10000.0f, -(float)f * (1.0f / 32.0f));
    float ang = (float)t * invf;
    trig[i] = cosf(ang);
    trig[32768 + i] = sinf(ang);
}

// ---------------------------------------------------------------------------
// Weight fold + 3-plane split.  skew = wA - wA^T.
// ---------------------------------------------------------------------------
__global__ __launch_bounds__(256) void fold_split_kernel(
    const float* __restrict__ Wsrc, const float* __restrict__ wA,
    const float* __restrict__ wbias, unsigned short* __restrict__ Wsp, int mode)
{
    const size_t WPL = (size_t)4608 * 768;
    __shared__ float sw[64][132];
    __shared__ float sk[64][65];
    int h = blockIdx.x, cb = blockIdx.y;
    int tid = threadIdx.x;
    const float* Wh = Wsrc + (size_t)h * 64 * 768 + cb * 128;
    for (int l = tid; l < 64 * 32; l += 256) {
        int d = l >> 5, c4 = l & 31;
        *(float4*)&sw[d][c4 * 4] = *(const float4*)(Wh + (size_t)d * 768 + c4 * 4);
    }
    for (int l = tid; l < 4096; l += 256) {
        int d = l >> 6, e = l & 63;
        sk[d][e] = wA[l] - wA[e * 64 + d];
    }
    __syncthreads();
    int tx = tid & 15, ty = tid >> 4;
    float acc4[4][8] = {};
    for (int d = 0; d < 64; d++) {
        float s0 = sk[d][ty * 4 + 0], s1 = sk[d][ty * 4 + 1];
        float s2 = sk[d][ty * 4 + 2], s3 = sk[d][ty * 4 + 3];
        float w_[8];
        *(float4*)&w_[0] = *(const float4*)&sw[d][tx * 8];
        *(float4*)&w_[4] = *(const float4*)&sw[d][tx * 8 + 4];
        #pragma unroll
        for (int j = 0; j < 8; j++) {
            acc4[0][j] += s0 * w_[j];
            acc4[1][j] += s1 * w_[j];
            acc4[2][j] += s2 * w_[j];
            acc4[3][j] += s3 * w_[j];
        }
    }
    #pragma unroll
    for (int i = 0; i < 4; i++) {
        int e = ty * 4 + i;
        float scale = (mode == 0) ? (1.0f + wbias[h * 64 + e]) : 1.0f;
        size_t row = (mode == 0) ? (size_t)(h * 64 + e) : (size_t)(3072 + h * 64 + e);
        #pragma unroll
        for (int j = 0; j < 8; j++) {
            int cl = tx * 8 + j;
            float wv = sw[e][cl] * scale + acc4[i][j];
            unsigned short p0, p1, p2;
            split3(wv, p0, p1, p2);
            size_t idx = row * 768 + cb * 128 + cl;
            Wsp[idx] = p0; Wsp[WPL + idx] = p1; Wsp[2 * WPL + idx] = p2;
        }
        if (mode == 1) {
            size_t row2 = (size_t)(3840 + h * 64 + e);
            #pragma unroll
            for (int j = 0; j < 8; j++) {
                int cl = tx * 8 + j;
                unsigned short p0, p1, p2;
                split3(sw[e][cl], p0, p1, p2);
                size_t idx = row2 * 768 + cb * 128 + cl;
                Wsp[idx] = p0; Wsp[WPL + idx] = p1; Wsp[2 * WPL + idx] = p2;
            }
        }
    }
}

// ---------------------------------------------------------------------------
__global__ void kbias_kernel(const float* __restrict__ WKb, const float* __restrict__ wA,
                             float* __restrict__ bcat) {
    int e = blockIdx.x * 256 + threadIdx.x;   // 1536
    if (e < 768) {
        int hb = e >> 6, el = e & 63;
        float acc = 0.0f;
        for (int d = 0; d < 64; d++) {
            float sk = wA[d * 64 + el] - wA[el * 64 + d];
            acc += WKb[hb * 64 + d] * sk;
        }
        bcat[e] = WKb[e] + acc;
    } else if (e < 1536) {
        bcat[e] = WKb[e - 768];
    }
}

// ---------------------------------------------------------------------------
__global__ void split_act_kernel(const float* __restrict__ A, const float* __restrict__ X,
                                 unsigned short* __restrict__ Asp, unsigned short* __restrict__ Xsp)
{
    const size_t APL = (size_t)2048 * 768;
    int i = blockIdx.x * 256 + threadIdx.x;   // 393216 quads
    if (i >= 393216) return;
    float4 va = ((const float4*)A)[i];
    float4 vx = ((const float4*)X)[i];
    ushort4 a0, a1, a2, x0, x1, x2;
    split3(va.x, a0.x, a1.x, a2.x); split3(va.y, a0.y, a1.y, a2.y);
    split3(va.z, a0.z, a1.z, a2.z); split3(va.w, a0.w, a1.w, a2.w);
    split3(vx.x, x0.x, x1.x, x2.x); split3(vx.y, x0.y, x1.y, x2.y);
    split3(vx.z, x0.z, x1.z, x2.z); split3(vx.w, x0.w, x1.w, x2.w);
    ((ushort4*)(Asp))[i] = a0;
    ((ushort4*)(Asp + APL))[i] = a1;
    ((ushort4*)(Asp + 2 * APL))[i] = a2;
    ((ushort4*)(Xsp))[i] = x0;
    ((ushort4*)(Xsp + APL))[i] = x1;
    ((ushort4*)(Xsp + 2 * APL))[i] = x2;
}

// ---------------------------------------------------------------------------
// Projection GEMM via split-precision bf16 MFMA, LDS-staged (round-7 verbatim).
// ---------------------------------------------------------------------------
__global__ __launch_bounds__(512) void proj_mfma_kernel(
    const unsigned short* __restrict__ Asp, const unsigned short* __restrict__ Xsp,
    const unsigned short* __restrict__ Wsp, const float* __restrict__ bcat,
    const float* __restrict__ trig, float* __restrict__ Qr, float* __restrict__ O2)
{
    const size_t APL = (size_t)2048 * 768;
    const size_t WPL = (size_t)4608 * 768;
    __shared__ unsigned short sA[3 * 128 * 40];
    __shared__ unsigned short sB[3 * 128 * 40];
    int bid = blockIdx.x;
    int swz = (bid & 7) * 72 + (bid >> 3);
    int nb = swz >> 4;
    int mb = swz & 15;
    bool isQ = (nb < 24);
    const unsigned short* Ab = isQ ? Asp : Xsp;
    int m0 = mb * 128, n0 = nb * 128;
    int tid = threadIdx.x;
    int w = tid >> 6, lane = tid & 63;
    int wm = w & 1, wn = w >> 1;
    int rf = lane & 15, kg = lane >> 4;
    int mbase = m0 + wm * 64;

    int sp_[3], sr_[3], ss_[3];
    #pragma unroll
    for (int i = 0; i < 3; i++) {
        int s = tid + i * 512;
        sp_[i] = s >> 9; sr_[i] = (s >> 2) & 127; ss_[i] = s & 3;
    }

    f32x4 acc[4][2] = {};
    for (int k0 = 0; k0 < 768; k0 += 32) {
        __syncthreads();
        #pragma unroll
        for (int i = 0; i < 3; i++) {
            short8 va = *(const short8*)(Ab + (size_t)sp_[i] * APL + (size_t)(m0 + sr_[i]) * 768 + k0 + ss_[i] * 8);
            short8 vb = *(const short8*)(Wsp + (size_t)sp_[i] * WPL + (size_t)(n0 + sr_[i]) * 768 + k0 + ss_[i] * 8);
            *(short8*)&sA[sp_[i] * 5120 + sr_[i] * 40 + ss_[i] * 8] = va;
            *(short8*)&sB[sp_[i] * 5120 + sr_[i] * 40 + ss_[i] * 8] = vb;
        }
        __syncthreads();

        short8 a0[4], a1[4], a2[4], b0[2], b1[2], b2[2];
        #pragma unroll
        for (int mi = 0; mi < 4; mi++) {
            int row = wm * 64 + mi * 16 + rf;
            a0[mi] = *(const short8*)&sA[0 * 5120 + row * 40 + kg * 8];
        }
        #pragma unroll
        for (int nj = 0; nj < 2; nj++) {
            int row = wn * 32 + nj * 16 + rf;
            b0[nj] = *(const short8*)&sB[0 * 5120 + row * 40 + kg * 8];
        }
        #pragma unroll
        for (int mi = 0; mi < 4; mi++)
            #pragma unroll
            for (int nj = 0; nj < 2; nj++)
                acc[mi][nj] = __builtin_amdgcn_mfma_f32_16x16x32_bf16(a0[mi], b0[nj], acc[mi][nj], 0, 0, 0);
        #pragma unroll
        for (int nj = 0; nj < 2; nj++) {
            int row = wn * 32 + nj * 16 + rf;
            b1[nj] = *(const short8*)&sB[1 * 5120 + row * 40 + kg * 8];
        }
        #pragma unroll
        for (int mi = 0; mi < 4; mi++)
            #pragma unroll
            for (int nj = 0; nj < 2; nj++)
                acc[mi][nj] = __builtin_amdgcn_mfma_f32_16x16x32_bf16(a0[mi], b1[nj], acc[mi][nj], 0, 0, 0);
        #pragma unroll
        for (int nj = 0; nj < 2; nj++) {
            int row = wn * 32 + nj * 16 + rf;
            b2[nj] = *(const short8*)&sB[2 * 5120 + row * 40 + kg * 8];
        }
        #pragma unroll
        for (int mi = 0; mi < 4; mi++)
            #pragma unroll
            for (int nj = 0; nj < 2; nj++)
                acc[mi][nj] = __builtin_amdgcn_mfma_f32_16x16x32_bf16(a0[mi], b2[nj], acc[mi][nj], 0, 0, 0);
        #pragma unroll
        for (int mi = 0; mi < 4; mi++) {
            int row = wm * 64 + mi * 16 + rf;
            a1[mi] = *(const short8*)&sA[1 * 5120 + row * 40 + kg * 8];
        }
        #pragma unroll
        for (int mi = 0; mi < 4; mi++)
            #pragma unroll
            for (int nj = 0; nj < 2; nj++)
                acc[mi][nj] = __builtin_amdgcn_mfma_f32_16x16x32_bf16(a1[mi], b0[nj], acc[mi][nj], 0, 0, 0);
        #pragma unroll
        for (int mi = 0; mi < 4; mi++)
            #pragma unroll
            for (int nj = 0; nj < 2; nj++)
                acc[mi][nj] = __builtin_amdgcn_mfma_f32_16x16x32_bf16(a1[mi], b1[nj], acc[mi][nj], 0, 0, 0);
        #pragma unroll
        for (int mi = 0; mi < 4; mi++) {
            int row = wm * 64 + mi * 16 + rf;
            a2[mi] = *(const short8*)&sA[2 * 5120 + row * 40 + kg * 8];
        }
        #pragma unroll
        for (int mi = 0; mi < 4; mi++)
            #pragma unroll
            for (int nj = 0; nj < 2; nj++)
                acc[mi][nj] = __builtin_amdgcn_mfma_f32_16x16x32_bf16(a2[mi], b0[nj], acc[mi][nj], 0, 0, 0);
    }

    if (isQ) {
        #pragma unroll
        for (int mi = 0; mi < 4; mi++) {
            #pragma unroll
            for (int r = 0; r < 4; r++) {
                int m = mbase + mi * 16 + kg * 4 + r;
                int b_ = m >> 10, t = m & 1023;
                #pragma unroll
                for (int nj = 0; nj < 2; nj++) {
                    int col_local = wn * 32 + nj * 16 + rf;
                    int h = nb * 2 + (col_local >> 6);
                    int d = col_local & 63;
                    int i = d >> 1;
                    float v = acc[mi][nj][r];
                    float pv = __shfl_xor(v, 1);
                    float c = trig[t * 32 + i];
                    float s = trig[32768 + t * 32 + i];
                    float outv = (rf & 1) ? (pv * s + v * c) : (v * c - pv * s);
                    int col = (rf & 1) ? (32 + i) : i;
                    size_t base = ((size_t)(b_ * 48 + h) * 1024 + t) * 64;
                    Qr[base + col] = outv;
                }
            }
        }
    } else {
        #pragma unroll
        for (int nj = 0; nj < 2; nj++) {
            int col = (n0 - 3072) + wn * 32 + nj * 16 + rf;
            float bv = bcat[col];
            #pragma unroll
            for (int mi = 0; mi < 4; mi++)
                #pragma unroll
                for (int r = 0; r < 4; r++) {
                    int m = mbase + mi * 16 + kg * 4 + r;
                    O2[(size_t)m * 1536 + col] = acc[mi][nj][r] + bv;
                }
        }
    }
}

// ---------------------------------------------------------------------------
__global__ void k_finish_kernel(const float* __restrict__ O2, const float* __restrict__ trig,
                                const float* __restrict__ wbias,
                                float* __restrict__ Kr, unsigned short* __restrict__ Kb16)
{
    int idx = blockIdx.x * 256 + threadIdx.x;   // 786432
    int pr = idx & 31;
    int tmp = idx >> 5;
    int hb = tmp % 12;
    int bt = tmp / 12;
    int t = bt & 1023, b = bt >> 10;
    const float* yx = O2 + (size_t)bt * 1536 + hb * 64 + pr * 2;
    float y0 = yx[0], y1 = yx[1];
    float x0 = yx[768], x1 = yx[769];
    float cv = trig[t * 32 + pr], sv = trig[32768 + t * 32 + pr];
    #pragma unroll
    for (int r = 0; r < 4; r++) {
        int h = hb + 12 * r;
        float b0 = wbias[h * 64 + 2 * pr], b1 = wbias[h * 64 + 2 * pr + 1];
        float wz0 = y0 + x0 * b0;
        float wz1 = y1 + x1 * b1;
        float lo = wz0 * cv - wz1 * sv;
        float hi = wz0 * sv + wz1 * cv;
        size_t base = ((size_t)(b * 48 + h) * 1024 + t) * 64;
        Kr[base + pr] = lo;
        Kr[base + 32 + pr] = hi;
        Kb16[base + pr] = f2bf(lo);
        Kb16[base + 32 + pr] = f2bf(hi);
    }
}

// ---------------------------------------------------------------------------
// Attention core v2: packed-key (22-bit score | 10-bit idx) top-4 via
// v_max/v_min_u32, diagonal-tile peel, register prefetch, uniform qb pairing.
// Final ranking = exact fp32 re-score + round-7 stable top-4 (unchanged).
// Grid (96, 8); wave does qb = 15-y then qb = y (17 tiles total, uniform).
// ---------------------------------------------------------------------------
__global__ __launch_bounds__(256) void attn_mfma_topk_kernel(
    const float* __restrict__ Qr, const float* __restrict__ Kr,
    const unsigned short* __restrict__ Kb, const float* __restrict__ sink,
    unsigned short* __restrict__ markerb, float* __restrict__ psink)
{
    const int bh = blockIdx.x;                 // 0..95
    const int y  = blockIdx.y;                 // 0..7
    const int w = threadIdx.x >> 6, lane = threadIdx.x & 63;
    const int rf = lane & 15, kg = lane >> 4;
    const int h = bh % HTq;
    const size_t rowbase = (size_t)bh * Tq;
    const unsigned short* Kbb = Kb + rowbase * 64;
    const float sk = sink[h];

    #pragma unroll 1
    for (int g = 0; g < 2; g++) {
        const int qb = g ? y : 15 - y;
        const int q0 = qb * 64 + w * 16;

        // Q fragments for rows q0..q0+15
        short8 a0, a1;
        {
            const float* qp = Qr + (rowbase + q0 + rf) * 64 + kg * 8;
            float4 u0 = *(const float4*)qp;
            float4 u1 = *(const float4*)(qp + 4);
            float4 u2 = *(const float4*)(qp + 32);
            float4 u3 = *(const float4*)(qp + 36);
            a0[0]=(short)f2bf(u0.x); a0[1]=(short)f2bf(u0.y); a0[2]=(short)f2bf(u0.z); a0[3]=(short)f2bf(u0.w);
            a0[4]=(short)f2bf(u1.x); a0[5]=(short)f2bf(u1.y); a0[6]=(short)f2bf(u1.z); a0[7]=(short)f2bf(u1.w);
            a1[0]=(short)f2bf(u2.x); a1[1]=(short)f2bf(u2.y); a1[2]=(short)f2bf(u2.z); a1[3]=(short)f2bf(u2.w);
            a1[4]=(short)f2bf(u3.x); a1[5]=(short)f2bf(u3.y); a1[6]=(short)f2bf(u3.z); a1[7]=(short)f2bf(u3.w);
        }

        float m_[4], Z_[4];
        unsigned t_[4][4];           // packed top-4, descending, 0 = empty
        #pragma unroll
        for (int r = 0; r < 4; r++) {
            m_[r] = -1e30f; Z_[r] = 0.0f;
            t_[r][0] = 0u; t_[r][1] = 0u; t_[r][2] = 0u; t_[r][3] = 0u;
        }

        short8 cA0[4], cA1[4], cB0[4], cB1[4];
        // load tile 0 into A
        {
            const unsigned short* p = Kbb + (size_t)rf * 64 + kg * 8;
            #pragma unroll
            for (int kc = 0; kc < 4; kc++) {
                cA0[kc] = *(const short8*)(p + kc * 1024);
                cA1[kc] = *(const short8*)(p + kc * 1024 + 32);
            }
        }

        // full-tile body: MFMA on cb, prefetch tile+1 into nb, unmasked postproc
        auto body = [&](short8 (&cb0)[4], short8 (&cb1)[4],
                        short8 (&nb0)[4], short8 (&nb1)[4], int tile) {
            f32x4 accs[4];
            #pragma unroll
            for (int kc = 0; kc < 4; kc++) {
                f32x4 acc = {0.f, 0.f, 0.f, 0.f};
                acc = __builtin_amdgcn_mfma_f32_16x16x32_bf16(a0, cb0[kc], acc, 0, 0, 0);
                acc = __builtin_amdgcn_mfma_f32_16x16x32_bf16(a1, cb1[kc], acc, 0, 0, 0);
                accs[kc] = acc;
            }
            // prefetch next tile (tile+1 <= qb always)
            const unsigned short* np = Kbb + (size_t)((tile + 1) * 64 + rf) * 64 + kg * 8;
            #pragma unroll
            for (int kc = 0; kc < 4; kc++) {
                nb0[kc] = *(const short8*)(np + kc * 1024);
                nb1[kc] = *(const short8*)(np + kc * 1024 + 32);
            }
            const int s0 = tile << 6;
            #pragma unroll
            for (int r = 0; r < 4; r++) {
                float sv[4];
                #pragma unroll
                for (int kc = 0; kc < 4; kc++) sv[kc] = accs[kc][r] * SCALE;
                #pragma unroll
                for (int kc = 0; kc < 4; kc++) {
                    unsigned u = __float_as_uint(sv[kc]);
                    unsigned key = u ^ ((unsigned)(((int)u) >> 31) | 0x80000000u);
                    unsigned c = (key & 0xFFFFFC00u) | (unsigned)(s0 + kc * 16 + rf);
                    unsigned n;
                    n = t_[r][0] > c ? t_[r][0] : c;  c = t_[r][0] > c ? c : t_[r][0];  t_[r][0] = n;
                    n = t_[r][1] > c ? t_[r][1] : c;  c = t_[r][1] > c ? c : t_[r][1];  t_[r][1] = n;
                    n = t_[r][2] > c ? t_[r][2] : c;  c = t_[r][2] > c ? c : t_[r][2];  t_[r][2] = n;
                    t_[r][3] = t_[r][3] > c ? t_[r][3] : c;
                }
                float tm = fmaxf(fmaxf(sv[0], sv[1]), fmaxf(sv[2], sv[3]));
                float nm = fmaxf(m_[r], tm);
                float zz = Z_[r] * __expf(m_[r] - nm);
                #pragma unroll
                for (int kc = 0; kc < 4; kc++) zz += __expf(sv[kc] - nm);
                Z_[r] = zz; m_[r] = nm;
            }
        };

        int tile = 0;
        for (; tile + 1 < qb; tile += 2) {
            body(cA0, cA1, cB0, cB1, tile);
            body(cB0, cB1, cA0, cA1, tile + 1);
        }
        if (tile < qb) {   // one leftover full tile; diagonal lands in B -> copy back
            body(cA0, cA1, cB0, cB1, tile);
            #pragma unroll
            for (int kc = 0; kc < 4; kc++) { cA0[kc] = cB0[kc]; cA1[kc] = cB1[kc]; }
        }

        // diagonal tile (in A), masked postproc
        {
            f32x4 accs[4];
            #pragma unroll
            for (int kc = 0; kc < 4; kc++) {
                f32x4 acc = {0.f, 0.f, 0.f, 0.f};
                acc = __builtin_amdgcn_mfma_f32_16x16x32_bf16(a0, cA0[kc], acc, 0, 0, 0);
                acc = __builtin_amdgcn_mfma_f32_16x16x32_bf16(a1, cA1[kc], acc, 0, 0, 0);
                accs[kc] = acc;
            }
            const int s0 = qb << 6;
            #pragma unroll
            for (int r = 0; r < 4; r++) {
                const int trow = q0 + kg * 4 + r;
                float sv[4];
                unsigned pk[4];
                #pragma unroll
                for (int kc = 0; kc < 4; kc++) {
                    int k = s0 + kc * 16 + rf;
                    bool ok = (k <= trow);
                    float s = accs[kc][r] * SCALE;
                    sv[kc] = ok ? s : -INFINITY;
                    unsigned u = __float_as_uint(s);
                    unsigned key = u ^ ((unsigned)(((int)u) >> 31) | 0x80000000u);
                    unsigned c = (key & 0xFFFFFC00u) | (unsigned)k;
                    pk[kc] = ok ? c : 0u;
                }
                #pragma unroll
                for (int kc = 0; kc < 4; kc++) {
                    unsigned c = pk[kc], n;
                    n = t_[r][0] > c ? t_[r][0] : c;  c = t_[r][0] > c ? c : t_[r][0];  t_[r][0] = n;
                    n = t_[r][1] > c ? t_[r][1] : c;  c = t_[r][1] > c ? c : t_[r][1];  t_[r][1] = n;
                    n = t_[r][2] > c ? t_[r][2] : c;  c = t_[r][2] > c ? c : t_[r][2];  t_[r][2] = n;
                    t_[r][3] = t_[r][3] > c ? t_[r][3] : c;
                }
                float tm = fmaxf(fmaxf(sv[0], sv[1]), fmaxf(sv[2], sv[3]));
                float nm = fmaxf(m_[r], tm);
                float zz = Z_[r] * __expf(m_[r] - nm);
                #pragma unroll
                for (int kc = 0; kc < 4; kc++) zz += __expf(sv[kc] - nm);
                Z_[r] = zz; m_[r] = nm;
            }
        }

        // epilogue per row
        #pragma unroll 1
        for (int r = 0; r < 4; r++) {
            const int q = q0 + kg * 4 + r;
            float m = m_[r], Z = Z_[r];
            #pragma unroll
            for (int off = 1; off < 16; off <<= 1) {
                float om = __shfl_xor(m, off);
                float oz = __shfl_xor(Z, off);
                float nm = fmaxf(m, om);
                Z = Z * __expf(m - nm) + oz * __expf(om - nm);
                m = nm;
            }
            // merge 16 per-lane packed top-4 -> global top-8 (argmax + pop)
            unsigned l0 = t_[r][0], l1 = t_[r][1], l2 = t_[r][2], l3 = t_[r][3];
            unsigned ck[8];
            #pragma unroll
            for (int rd = 0; rd < 8; rd++) {
                unsigned v = l0;
                #pragma unroll
                for (int off = 1; off < 16; off <<= 1) {
                    unsigned ov = (unsigned)__shfl_xor((int)v, off);
                    v = v > ov ? v : ov;
                }
                ck[rd] = v;
                bool own = (l0 == v);
                l0 = own ? l1 : l0;
                l1 = own ? l2 : l1;
                l2 = own ? l3 : l2;
                l3 = own ? 0u : l3;
            }
            // exact fp32 re-score of shortlist
            const float4 qv = *(const float4*)(Qr + (rowbase + q) * 64 + rf * 4);
            float sc[8]; int ci[8];
            #pragma unroll
            for (int c = 0; c < 8; c++) {
                bool valid = (ck[c] != 0u);
                int idx = (int)(ck[c] & 1023u);
                int lidx = valid ? idx : 0;
                const float4 kv = *(const float4*)(Kr + (rowbase + lidx) * 64 + rf * 4);
                float p = qv.x * kv.x + qv.y * kv.y + qv.z * kv.z + qv.w * kv.w;
                #pragma unroll
                for (int off = 1; off < 16; off <<= 1) p += __shfl_xor(p, off);
                sc[c] = valid ? p * SCALE : -1e30f;
                ci[c] = valid ? idx : -1;
            }
            // stable top-4 of the 8 exact scores (value desc, index asc)
            float bv[4]; int bi[4];
            #pragma unroll
            for (int rd = 0; rd < 4; rd++) {
                float v = sc[0]; int id = ci[0];
                #pragma unroll
                for (int c = 1; c < 8; c++) {
                    bool take = (sc[c] > v) || ((sc[c] == v) && ((unsigned)ci[c] < (unsigned)id));
                    v = take ? sc[c] : v; id = take ? ci[c] : id;
                }
                bv[rd] = v; bi[rd] = id;
                #pragma unroll
                for (int c = 0; c < 8; c++) {
                    bool kill = (ci[c] == id) && (sc[c] == v);
                    sc[c] = kill ? -3e30f : sc[c];
                }
            }
            float mf = fmaxf(m, sk);
            float Zf = Z * __expf(m - mf) + __expf(sk - mf);
            float e0 = __expf(bv[0] - mf), e1 = __expf(bv[1] - mf);
            float e2 = __expf(bv[2] - mf), e3 = __expf(bv[3] - mf);
            float wsum = e0 + e1 + e2 + e3 + Zf * 1e-9f;
            float w0 = e0 / wsum, w1 = e1 / wsum, w2 = e2 / wsum, w3 = e3 / wsum;
            int i0 = bi[0] < 0 ? 0 : bi[0];
            int i1 = bi[1] < 0 ? 0 : bi[1];
            int i2 = bi[2] < 0 ? 0 : bi[2];
            int i3 = bi[3] < 0 ? 0 : bi[3];
            const float4 k0 = *(const float4*)(Kr + (rowbase + i0) * 64 + rf * 4);
            const float4 k1 = *(const float4*)(Kr + (rowbase + i1) * 64 + rf * 4);
            const float4 k2 = *(const float4*)(Kr + (rowbase + i2) * 64 + rf * 4);
            const float4 k3 = *(const float4*)(Kr + (rowbase + i3) * 64 + rf * 4);
            float mx = w0 * k0.x + w1 * k1.x + w2 * k2.x + w3 * k3.x;
            float my = w0 * k0.y + w1 * k1.y + w2 * k2.y + w3 * k3.y;
            float mz = w0 * k0.z + w1 * k1.z + w2 * k2.z + w3 * k3.z;
            float mw = w0 * k0.w + w1 * k1.w + w2 * k2.w + w3 * k3.w;
            ushort4 mo;
            mo.x = f2bf(mx); mo.y = f2bf(my); mo.z = f2bf(mz); mo.w = f2bf(mw);
            *(ushort4*)(markerb + (rowbase + q) * 64 + rf * 4) = mo;
            if (rf == 0) psink[rowbase + q] = __expf(sk - mf) / Zf;
        }
    }
}

// ---------------------------------------------------------------------------
__global__ void cvt_bf16_kernel(const float* __restrict__ in,
                                unsigned short* __restrict__ out, int n4)
{
    int i = blockIdx.x * 256 + threadIdx.x;
    if (i < n4) {
        float4 v = ((const float4*)in)[i];
        ushort4 o;
        o.x = f2bf(v.x); o.y = f2bf(v.y); o.z = f2bf(v.z); o.w = f2bf(v.w);
        ((ushort4*)out)[i] = o;
    }
}

// ---------------------------------------------------------------------------
__global__ __launch_bounds__(256) void wo_transpose_kernel(
    const float* __restrict__ WOw, unsigned short* __restrict__ WOt)
{
    __shared__ float tl[64][65];
    int tid = threadIdx.x;
    int n = blockIdx.z;
    int c0 = blockIdx.x * 64, d0 = blockIdx.y * 64;
    const float* src = WOw + (size_t)n * 768 * 768;
    for (int l = tid; l < 64 * 16; l += 256) {
        int r = l >> 4, q = l & 15;
        float4 v = *(const float4*)(src + (size_t)(c0 + r) * 768 + d0 + q * 4);
        tl[r][q * 4 + 0] = v.x; tl[r][q * 4 + 1] = v.y;
        tl[r][q * 4 + 2] = v.z; tl[r][q * 4 + 3] = v.w;
    }
    __syncthreads();
    for (int l = tid; l < 64 * 16; l += 256) {
        int d = l >> 4, q = l & 15;
        ushort4 o;
        o.x = f2bf(tl[q * 4 + 0][d]); o.y = f2bf(tl[q * 4 + 1][d]);
        o.z = f2bf(tl[q * 4 + 2][d]); o.w = f2bf(tl[q * 4 + 3][d]);
        *(ushort4*)(WOt + (size_t)n * 768 * 768 + (size_t)(d0 + d) * 768 + c0 + q * 4) = o;
    }
}

// ---------------------------------------------------------------------------
__global__ __launch_bounds__(256) void mlp_mfma_kernel(
    const unsigned short* __restrict__ markerb, const float* __restrict__ psink,
    const unsigned short* __restrict__ V1b16, const float* __restrict__ V1bias,
    const unsigned short* __restrict__ V2b16, const float* __restrict__ V2bias,
    const float* __restrict__ vnulls, unsigned short* __restrict__ ctxb)
{
    __shared__ float h_lds[4][16][65];
    int tid = threadIdx.x;
    int w = tid >> 6, lane = tid & 63;
    int rf = lane & 15, kg = lane >> 4;
    size_t r0 = (size_t)blockIdx.x * 64 + 16 * w;

    short8 a1[2];
    #pragma unroll
    for (int kk = 0; kk < 2; kk++)
        a1[kk] = *(const short8*)(markerb + (r0 + rf) * 64 + kk * 32 + kg * 8);

    f32x4 acc2[4] = {};
    for (int ch = 0; ch < 4; ch++) {
        f32x4 acc1[4] = {};
        #pragma unroll
        for (int nj = 0; nj < 4; nj++)
            #pragma unroll
            for (int kk = 0; kk < 2; kk++) {
                short8 b1 = *(const short8*)(V1b16 + (size_t)(ch * 64 + nj * 16 + rf) * 64 + kk * 32 + kg * 8);
                acc1[nj] = __builtin_amdgcn_mfma_f32_16x16x32_bf16(a1[kk], b1, acc1[nj], 0, 0, 0);
            }
        __syncthreads();
        #pragma unroll
        for (int nj = 0; nj < 4; nj++) {
            float bb = V1bias[ch * 64 + nj * 16 + rf];
            #pragma unroll
            for (int r = 0; r < 4; r++) {
                float x = acc1[nj][r] + bb;
                h_lds[w][kg * 4 + r][nj * 16 + rf] = gelu_f(x);
            }
        }
        __syncthreads();
        #pragma unroll
        for (int kk = 0; kk < 2; kk++) {
            const float* hp = &h_lds[w][rf][kk * 32 + kg * 8];
            float4 p0 = *(const float4*)hp;
            float4 p1 = *(const float4*)(hp + 4);
            short8 a2;
            a2[0] = (short)f2bf(p0.x); a2[1] = (short)f2bf(p0.y);
            a2[2] = (short)f2bf(p0.z); a2[3] = (short)f2bf(p0.w);
            a2[4] = (short)f2bf(p1.x); a2[5] = (short)f2bf(p1.y);
            a2[6] = (short)f2bf(p1.z); a2[7] = (short)f2bf(p1.w);
            #pragma unroll
            for (int njo = 0; njo < 4; njo++) {
                short8 b2 = *(const short8*)(V2b16 + (size_t)(njo * 16 + rf) * 256 + ch * 64 + kk * 32 + kg * 8);
                acc2[njo] = __builtin_amdgcn_mfma_f32_16x16x32_bf16(a2, b2, acc2[njo], 0, 0, 0);
            }
        }
    }
    #pragma unroll
    for (int r = 0; r < 4; r++) {
        size_t R = r0 + kg * 4 + r;
        int bh = (int)(R >> 10), t = (int)(R & 1023);
        int b = bh / 48, h = bh % 48;
        int n = h / 12, head = h % 12;
        float ps = psink[R];
        size_t base = ((size_t)((b * 4 + n) * 1024 + t)) * 768 + head * 64;
        #pragma unroll
        for (int njo = 0; njo < 4; njo++) {
            int d = njo * 16 + rf;
            float v = acc2[njo][r] + V2bias[d] + ps * vnulls[h * 64 + d];
            ctxb[base + d] = f2bf(v);
        }
    }
}

// ---------------------------------------------------------------------------
__global__ __launch_bounds__(256) void gemm_wo_mfma(
    const unsigned short* __restrict__ ctxb, const unsigned short* __restrict__ WOtb,
    const float* __restrict__ WOb, float* __restrict__ Out)
{
    __shared__ unsigned short sA[64 * 64];
    __shared__ unsigned short sB[64 * 64];
    int tid = threadIdx.x;
    int w = tid >> 6, lane = tid & 63;
    int wm = w >> 1, wn = w & 1;
    int rf = lane & 15, kg = lane >> 4;
    int m0 = blockIdx.x * 64, n0 = blockIdx.y * 64;
    int b = m0 >> 10, t0 = m0 & 1023;
    int c0 = tid * 2, c1 = tid * 2 + 1;
    int ra = c0 >> 3, ca = c0 & 7, rb = c1 >> 3, cb = c1 & 7;
    f32x4 acc[2][2] = {};
    for (int n = 0; n < 4; n++) {
        const unsigned short* Ab = ctxb + ((size_t)((b * 4 + n) * 1024 + t0)) * 768;
        const unsigned short* Bb = WOtb + (size_t)n * 768 * 768 + (size_t)n0 * 768;
        for (int k0 = 0; k0 < 768; k0 += 64) {
            __syncthreads();
            *(short8*)&sA[ra * 64 + ((ca ^ (ra & 7)) * 8)] = *(const short8*)(Ab + (size_t)ra * 768 + k0 + ca * 8);
            *(short8*)&sA[rb * 64 + ((cb ^ (rb & 7)) * 8)] = *(const short8*)(Ab + (size_t)rb * 768 + k0 + cb * 8);
            *(short8*)&sB[ra * 64 + ((ca ^ (ra & 7)) * 8)] = *(const short8*)(Bb + (size_t)ra * 768 + k0 + ca * 8);
            *(short8*)&sB[rb * 64 + ((cb ^ (rb & 7)) * 8)] = *(const short8*)(Bb + (size_t)rb * 768 + k0 + cb * 8);
            __syncthreads();
            #pragma unroll
            for (int kk = 0; kk < 2; kk++) {
                int kc = kk * 4 + kg;
                int rA0 = wm * 32 + rf, rA1 = wm * 32 + 16 + rf;
                int rB0 = wn * 32 + rf, rB1 = wn * 32 + 16 + rf;
                short8 a0v = *(const short8*)&sA[rA0 * 64 + ((kc ^ (rA0 & 7)) * 8)];
                short8 a1v = *(const short8*)&sA[rA1 * 64 + ((kc ^ (rA1 & 7)) * 8)];
                short8 b0v = *(const short8*)&sB[rB0 * 64 + ((kc ^ (rB0 & 7)) * 8)];
                short8 b1v = *(const short8*)&sB[rB1 * 64 + ((kc ^ (rB1 & 7)) * 8)];
                acc[0][0] = __builtin_amdgcn_mfma_f32_16x16x32_bf16(a0v, b0v, acc[0][0], 0, 0, 0);
                acc[0][1] = __builtin_amdgcn_mfma_f32_16x16x32_bf16(a0v, b1v, acc[0][1], 0, 0, 0);
                acc[1][0] = __builtin_amdgcn_mfma_f32_16x16x32_bf16(a1v, b0v, acc[1][0], 0, 0, 0);
                acc[1][1] = __builtin_amdgcn_mfma_f32_16x16x32_bf16(a1v, b1v, acc[1][1], 0, 0, 0);
            }
        }
    }
    #pragma unroll
    for (int nj = 0; nj < 2; nj++) {
        int col = n0 + wn * 32 + nj * 16 + rf;
        float bm = WOb[col] + WOb[768 + col] + WOb[1536 + col] + WOb[2304 + col];
        #pragma unroll
        for (int mi = 0; mi < 2; mi++)
            #pragma unroll
            for (int r = 0; r < 4; r++) {
                int row = m0 + wm * 32 + mi * 16 + kg * 4 + r;
                Out[(size_t)row * 768 + col] = 0.25f * (acc[mi][nj][r] + bm);
            }
    }
}

// ---------------------------------------------------------------------------
extern "C" void kernel_launch(void* const* d_in, const int* in_sizes, int n_in,
                              void* d_out, int out_size, void* d_ws, size_t ws_size,
                              hipStream_t stream) {
    const float* A      = (const float*)d_in[0];
    const float* X      = (const float*)d_in[1];
    const float* WKw    = (const float*)d_in[2];
    const float* WKb    = (const float*)d_in[3];
    const float* WQw    = (const float*)d_in[4];
    const float* wA     = (const float*)d_in[5];
    const float* wB     = (const float*)d_in[6];
    const float* sink   = (const float*)d_in[7];
    const float* vnulls = (const float*)d_in[8];
    const float* V1w    = (const float*)d_in[9];
    const float* V1b    = (const float*)d_in[10];
    const float* V2w    = (const float*)d_in[11];
    const float* V2b    = (const float*)d_in[12];
    const float* WOw    = (const float*)d_in[13];
    const float* WOb    = (const float*)d_in[14];
    float* out = (float*)d_out;
    (void)in_sizes; (void)n_in; (void)out_size; (void)ws_size;

    float* ws = (float*)d_ws;
    size_t off = 0;
    float* Qr   = ws + off;  off += 6291456;   // head-major fp32 Q (rope'd)
    float* Kr   = ws + off;  off += 6291456;   // head-major fp32 K (rope'd)
    float* trig = ws + off;  off += 65536;
    float* bcat = ws + off;  off += 2048;
    float* O2   = ws + off;  off += 3145728;   // [2048][1536]: y | x
    float* Wsp_f = ws + off; off += 5308416;   // 3 planes x 4608x768 ushort
    unsigned short* Wsp = (unsigned short*)Wsp_f;
    unsigned short* Asp = (unsigned short*)(ws + off); off += 2359296;  // 3 planes x 2048x768
    unsigned short* Xsp = (unsigned short*)(ws + off); off += 2359296;
    // overlays (dead-buffer reuse) — audited lifetimes:
    //   markerb = O2 (FULL 3,145,728 floats; O2 dead after k_finish)
    //   Kb16 = Wsp floats [0, 3145728); psink = Wsp floats [3145728, 3244032)
    unsigned short* markerb = (unsigned short*)O2;
    unsigned short* Kb16 = Wsp;
    float* psink = Wsp_f + 3145728;
    unsigned short* V1b16 = Xsp;                         // Xsp dead after proj
    unsigned short* V2b16 = V1b16 + 16384;
    unsigned short* WOtb  = Asp;                         // Asp dead after proj
    unsigned short* ctxb  = (unsigned short*)Qr;         // Qr dead after attn

    // prep: trig + folded/split weights + split activations
    trig_kernel<<<128, 256, 0, stream>>>(trig);
    fold_split_kernel<<<dim3(48, 6), 256, 0, stream>>>(WQw, wA, wB, Wsp, 0);
    fold_split_kernel<<<dim3(12, 6), 256, 0, stream>>>(WKw, wA, wB, Wsp, 1);
    kbias_kernel<<<6, 256, 0, stream>>>(WKb, wA, bcat);
    split_act_kernel<<<1536, 256, 0, stream>>>(A, X, Asp, Xsp);
    // split-precision MFMA projection, LDS-staged (Q -> rope -> Qr; Kcat -> O2)
    proj_mfma_kernel<<<576, 512, 0, stream>>>(Asp, Xsp, Wsp, bcat, trig, Qr, O2);
    // finish K: per-h bias wedge term + rope -> Kr fp32 + Kb16 bf16
    k_finish_kernel<<<3072, 256, 0, stream>>>(O2, trig, wB, Kr, Kb16);
    // attention: MFMA scores, packed-key shortlist, exact fp32 top-4
    attn_mfma_topk_kernel<<<dim3(96, 8), 256, 0, stream>>>(Qr, Kr, Kb16, sink, markerb, psink);
    // post-top-k smooth path (bf16/MFMA)
    cvt_bf16_kernel<<<16, 256, 0, stream>>>(V1w, V1b16, 4096);
    cvt_bf16_kernel<<<16, 256, 0, stream>>>(V2w, V2b16, 4096);
    wo_transpose_kernel<<<dim3(12, 12, 4), 256, 0, stream>>>(WOw, WOtb);
    mlp_mfma_kernel<<<1536, 256, 0, stream>>>(markerb, psink, V1b16, V1b, V2b16, V2b, vnulls, ctxb);
    gemm_wo_mfma<<<dim3(32, 12), 256, 0, stream>>>(ctxb, WOtb, WOb, out);
}

// Round 10
// 350.808 us; speedup vs baseline: 3.7005x; 1.0076x over previous
//
#include <hip/hip_runtime.h>
#include <math.h>

constexpr int Bq  = 2;
constexpr int Tq  = 1024;
constexpr int HTq = 48;
constexpr float SCALE = 0.125f;     // 64^-0.5

typedef __attribute__((ext_vector_type(8))) short short8;
typedef __attribute__((ext_vector_type(4))) float f32x4;

__device__ inline unsigned short f2bf(float x) {
    unsigned u = __float_as_uint(x);
    return (unsigned short)((u + 0x7FFF + ((u >> 16) & 1)) >> 16);
}

// exact 3-plane bf16 split: x = p0 + p1 + p2 + O(2^-27 |x|)
__device__ inline void split3(float x, unsigned short& p0, unsigned short& p1, unsigned short& p2) {
    p0 = f2bf(x);
    float f0 = __uint_as_float((unsigned)p0 << 16);
    float r0 = x - f0;
    p1 = f2bf(r0);
    float f1 = __uint_as_float((unsigned)p1 << 16);
    float r1 = r0 - f1;
    p2 = f2bf(r1);
}

// exact-erf GELU via Abramowitz-Stegun 7.1.26 (|eps_erf| <= 1.5e-7)
__device__ inline float gelu_f(float x) {
    float z = 0.70710678118654752f * x;
    float az = fabsf(z);
    float t = __frcp_rn(1.0f + 0.3275911f * az);
    float poly = t * (0.254829592f + t * (-0.284496736f + t * (1.421413741f
               + t * (-1.453152027f + t * 1.061405429f))));
    float er = 1.0f - poly * __expf(-az * az);
    er = (z < 0.0f) ? -er : er;
    return 0.5f * x * (1.0f + er);
}

// ---------------------------------------------------------------------------
// trig table: cos at [t*32+i], sin at [32768 + t*32+i].
// ---------------------------------------------------------------------------
__global__ void trig_kernel(float* __restrict__ trig) {
    int i = blockIdx.x * 256 + threadIdx.x;   // 32768
    int t = i >> 5, f = i & 31;
    float invf = powf(10000.0f, -(float)f * (1.0f / 32.0f));
    float ang = (float)t * invf;
    trig[i] = cosf(ang);
    trig[32768 + i] = sinf(ang);
}

// ---------------------------------------------------------------------------
// Weight fold + 3-plane split.  skew = wA - wA^T.
// ---------------------------------------------------------------------------
__global__ __launch_bounds__(256) void fold_split_kernel(
    const float* __restrict__ Wsrc, const float* __restrict__ wA,
    const float* __restrict__ wbias, unsigned short* __restrict__ Wsp, int mode)
{
    const size_t WPL = (size_t)4608 * 768;
    __shared__ float sw[64][132];
    __shared__ float sk[64][65];
    int h = blockIdx.x, cb = blockIdx.y;
    int tid = threadIdx.x;
    const float* Wh = Wsrc + (size_t)h * 64 * 768 + cb * 128;
    for (int l = tid; l < 64 * 32; l += 256) {
        int d = l >> 5, c4 = l & 31;
        *(float4*)&sw[d][c4 * 4] = *(const float4*)(Wh + (size_t)d * 768 + c4 * 4);
    }
    for (int l = tid; l < 4096; l += 256) {
        int d = l >> 6, e = l & 63;
        sk[d][e] = wA[l] - wA[e * 64 + d];
    }
    __syncthreads();
    int tx = tid & 15, ty = tid >> 4;
    float acc4[4][8] = {};
    for (int d = 0; d < 64; d++) {
        float s0 = sk[d][ty * 4 + 0], s1 = sk[d][ty * 4 + 1];
        float s2 = sk[d][ty * 4 + 2], s3 = sk[d][ty * 4 + 3];
        float w_[8];
        *(float4*)&w_[0] = *(const float4*)&sw[d][tx * 8];
        *(float4*)&w_[4] = *(const float4*)&sw[d][tx * 8 + 4];
        #pragma unroll
        for (int j = 0; j < 8; j++) {
            acc4[0][j] += s0 * w_[j];
            acc4[1][j] += s1 * w_[j];
            acc4[2][j] += s2 * w_[j];
            acc4[3][j] += s3 * w_[j];
        }
    }
    #pragma unroll
    for (int i = 0; i < 4; i++) {
        int e = ty * 4 + i;
        float scale = (mode == 0) ? (1.0f + wbias[h * 64 + e]) : 1.0f;
        size_t row = (mode == 0) ? (size_t)(h * 64 + e) : (size_t)(3072 + h * 64 + e);
        #pragma unroll
        for (int j = 0; j < 8; j++) {
            int cl = tx * 8 + j;
            float wv = sw[e][cl] * scale + acc4[i][j];
            unsigned short p0, p1, p2;
            split3(wv, p0, p1, p2);
            size_t idx = row * 768 + cb * 128 + cl;
            Wsp[idx] = p0; Wsp[WPL + idx] = p1; Wsp[2 * WPL + idx] = p2;
        }
        if (mode == 1) {
            size_t row2 = (size_t)(3840 + h * 64 + e);
            #pragma unroll
            for (int j = 0; j < 8; j++) {
                int cl = tx * 8 + j;
                unsigned short p0, p1, p2;
                split3(sw[e][cl], p0, p1, p2);
                size_t idx = row2 * 768 + cb * 128 + cl;
                Wsp[idx] = p0; Wsp[WPL + idx] = p1; Wsp[2 * WPL + idx] = p2;
            }
        }
    }
}

// ---------------------------------------------------------------------------
__global__ void kbias_kernel(const float* __restrict__ WKb, const float* __restrict__ wA,
                             float* __restrict__ bcat) {
    int e = blockIdx.x * 256 + threadIdx.x;   // 1536
    if (e < 768) {
        int hb = e >> 6, el = e & 63;
        float acc = 0.0f;
        for (int d = 0; d < 64; d++) {
            float sk = wA[d * 64 + el] - wA[el * 64 + d];
            acc += WKb[hb * 64 + d] * sk;
        }
        bcat[e] = WKb[e] + acc;
    } else if (e < 1536) {
        bcat[e] = WKb[e - 768];
    }
}

// ---------------------------------------------------------------------------
__global__ void split_act_kernel(const float* __restrict__ A, const float* __restrict__ X,
                                 unsigned short* __restrict__ Asp, unsigned short* __restrict__ Xsp)
{
    const size_t APL = (size_t)2048 * 768;
    int i = blockIdx.x * 256 + threadIdx.x;   // 393216 quads
    if (i >= 393216) return;
    float4 va = ((const float4*)A)[i];
    float4 vx = ((const float4*)X)[i];
    ushort4 a0, a1, a2, x0, x1, x2;
    split3(va.x, a0.x, a1.x, a2.x); split3(va.y, a0.y, a1.y, a2.y);
    split3(va.z, a0.z, a1.z, a2.z); split3(va.w, a0.w, a1.w, a2.w);
    split3(vx.x, x0.x, x1.x, x2.x); split3(vx.y, x0.y, x1.y, x2.y);
    split3(vx.z, x0.z, x1.z, x2.z); split3(vx.w, x0.w, x1.w, x2.w);
    ((ushort4*)(Asp))[i] = a0;
    ((ushort4*)(Asp + APL))[i] = a1;
    ((ushort4*)(Asp + 2 * APL))[i] = a2;
    ((ushort4*)(Xsp))[i] = x0;
    ((ushort4*)(Xsp + APL))[i] = x1;
    ((ushort4*)(Xsp + 2 * APL))[i] = x2;
}

// ---------------------------------------------------------------------------
// Projection GEMM via split-precision bf16 MFMA, LDS-staged.
// 128x128 tile, BK=32, 512 threads (8 waves, 2m x 4n, 64x32 per wave).
// LDS: 3 planes x 128 rows x 32 ushorts, 16B-slot XOR swizzle
//   slot' = slot ^ ((row>>1)&3)  -> bank base 16*(row&1)+4*slot' is hit
//   exactly 2x per 16 lanes on BOTH read and write sides (2-way = free).
// 48 KB total -> 3 blocks/CU.  Same data + same MFMA order as round 7-9
// (bitwise-identical output).
// ---------------------------------------------------------------------------
__global__ __launch_bounds__(512) void proj_mfma_kernel(
    const unsigned short* __restrict__ Asp, const unsigned short* __restrict__ Xsp,
    const unsigned short* __restrict__ Wsp, const float* __restrict__ bcat,
    const float* __restrict__ trig, float* __restrict__ Qr, float* __restrict__ O2)
{
    const size_t APL = (size_t)2048 * 768;
    const size_t WPL = (size_t)4608 * 768;
    __shared__ unsigned short sA[3 * 128 * 32];
    __shared__ unsigned short sB[3 * 128 * 32];
    int bid = blockIdx.x;
    int swz = (bid & 7) * 72 + (bid >> 3);
    int nb = swz >> 4;
    int mb = swz & 15;
    bool isQ = (nb < 24);
    const unsigned short* Ab = isQ ? Asp : Xsp;
    int m0 = mb * 128, n0 = nb * 128;
    int tid = threadIdx.x;
    int w = tid >> 6, lane = tid & 63;
    int wm = w & 1, wn = w >> 1;
    int rf = lane & 15, kg = lane >> 4;
    int mbase = m0 + wm * 64;

    // stage mapping: s = tid + i*512 in [0,1536): p = s>>9, r = (s>>2)&127, slot = s&3
    int sp_[3], sr_[3], ss_[3];
    #pragma unroll
    for (int i = 0; i < 3; i++) {
        int s = tid + i * 512;
        sp_[i] = s >> 9; sr_[i] = (s >> 2) & 127;
        ss_[i] = (s & 3) ^ ((sr_[i] >> 1) & 3);       // XOR-swizzled slot
    }

    f32x4 acc[4][2] = {};
    for (int k0 = 0; k0 < 768; k0 += 32) {
        __syncthreads();
        #pragma unroll
        for (int i = 0; i < 3; i++) {
            short8 va = *(const short8*)(Ab + (size_t)sp_[i] * APL + (size_t)(m0 + sr_[i]) * 768 + k0 + (tid & 3) * 8);
            short8 vb = *(const short8*)(Wsp + (size_t)sp_[i] * WPL + (size_t)(n0 + sr_[i]) * 768 + k0 + (tid & 3) * 8);
            *(short8*)&sA[sp_[i] * 4096 + sr_[i] * 32 + ss_[i] * 8] = va;
            *(short8*)&sB[sp_[i] * 4096 + sr_[i] * 32 + ss_[i] * 8] = vb;
        }
        __syncthreads();

        short8 a0[4], a1[4], a2[4], b0[2], b1[2], b2[2];
        #pragma unroll
        for (int mi = 0; mi < 4; mi++) {
            int row = wm * 64 + mi * 16 + rf;
            a0[mi] = *(const short8*)&sA[0 * 4096 + row * 32 + ((kg ^ ((row >> 1) & 3)) * 8)];
        }
        #pragma unroll
        for (int nj = 0; nj < 2; nj++) {
            int row = wn * 32 + nj * 16 + rf;
            b0[nj] = *(const short8*)&sB[0 * 4096 + row * 32 + ((kg ^ ((row >> 1) & 3)) * 8)];
        }
        #pragma unroll
        for (int mi = 0; mi < 4; mi++)
            #pragma unroll
            for (int nj = 0; nj < 2; nj++)
                acc[mi][nj] = __builtin_amdgcn_mfma_f32_16x16x32_bf16(a0[mi], b0[nj], acc[mi][nj], 0, 0, 0);
        #pragma unroll
        for (int nj = 0; nj < 2; nj++) {
            int row = wn * 32 + nj * 16 + rf;
            b1[nj] = *(const short8*)&sB[1 * 4096 + row * 32 + ((kg ^ ((row >> 1) & 3)) * 8)];
        }
        #pragma unroll
        for (int mi = 0; mi < 4; mi++)
            #pragma unroll
            for (int nj = 0; nj < 2; nj++)
                acc[mi][nj] = __builtin_amdgcn_mfma_f32_16x16x32_bf16(a0[mi], b1[nj], acc[mi][nj], 0, 0, 0);
        #pragma unroll
        for (int nj = 0; nj < 2; nj++) {
            int row = wn * 32 + nj * 16 + rf;
            b2[nj] = *(const short8*)&sB[2 * 4096 + row * 32 + ((kg ^ ((row >> 1) & 3)) * 8)];
        }
        #pragma unroll
        for (int mi = 0; mi < 4; mi++)
            #pragma unroll
            for (int nj = 0; nj < 2; nj++)
                acc[mi][nj] = __builtin_amdgcn_mfma_f32_16x16x32_bf16(a0[mi], b2[nj], acc[mi][nj], 0, 0, 0);
        #pragma unroll
        for (int mi = 0; mi < 4; mi++) {
            int row = wm * 64 + mi * 16 + rf;
            a1[mi] = *(const short8*)&sA[1 * 4096 + row * 32 + ((kg ^ ((row >> 1) & 3)) * 8)];
        }
        #pragma unroll
        for (int mi = 0; mi < 4; mi++)
            #pragma unroll
            for (int nj = 0; nj < 2; nj++)
                acc[mi][nj] = __builtin_amdgcn_mfma_f32_16x16x32_bf16(a1[mi], b0[nj], acc[mi][nj], 0, 0, 0);
        #pragma unroll
        for (int mi = 0; mi < 4; mi++)
            #pragma unroll
            for (int nj = 0; nj < 2; nj++)
                acc[mi][nj] = __builtin_amdgcn_mfma_f32_16x16x32_bf16(a1[mi], b1[nj], acc[mi][nj], 0, 0, 0);
        #pragma unroll
        for (int mi = 0; mi < 4; mi++) {
            int row = wm * 64 + mi * 16 + rf;
            a2[mi] = *(const short8*)&sA[2 * 4096 + row * 32 + ((kg ^ ((row >> 1) & 3)) * 8)];
        }
        #pragma unroll
        for (int mi = 0; mi < 4; mi++)
            #pragma unroll
            for (int nj = 0; nj < 2; nj++)
                acc[mi][nj] = __builtin_amdgcn_mfma_f32_16x16x32_bf16(a2[mi], b0[nj], acc[mi][nj], 0, 0, 0);
    }

    if (isQ) {
        #pragma unroll
        for (int mi = 0; mi < 4; mi++) {
            #pragma unroll
            for (int r = 0; r < 4; r++) {
                int m = mbase + mi * 16 + kg * 4 + r;
                int b_ = m >> 10, t = m & 1023;
                #pragma unroll
                for (int nj = 0; nj < 2; nj++) {
                    int col_local = wn * 32 + nj * 16 + rf;
                    int h = nb * 2 + (col_local >> 6);
                    int d = col_local & 63;
                    int i = d >> 1;
                    float v = acc[mi][nj][r];
                    float pv = __shfl_xor(v, 1);
                    float c = trig[t * 32 + i];
                    float s = trig[32768 + t * 32 + i];
                    float outv = (rf & 1) ? (pv * s + v * c) : (v * c - pv * s);
                    int col = (rf & 1) ? (32 + i) : i;
                    size_t base = ((size_t)(b_ * 48 + h) * 1024 + t) * 64;
                    Qr[base + col] = outv;
                }
            }
        }
    } else {
        #pragma unroll
        for (int nj = 0; nj < 2; nj++) {
            int col = (n0 - 3072) + wn * 32 + nj * 16 + rf;
            float bv = bcat[col];
            #pragma unroll
            for (int mi = 0; mi < 4; mi++)
                #pragma unroll
                for (int r = 0; r < 4; r++) {
                    int m = mbase + mi * 16 + kg * 4 + r;
                    O2[(size_t)m * 1536 + col] = acc[mi][nj][r] + bv;
                }
        }
    }
}

// ---------------------------------------------------------------------------
__global__ void k_finish_kernel(const float* __restrict__ O2, const float* __restrict__ trig,
                                const float* __restrict__ wbias,
                                float* __restrict__ Kr, unsigned short* __restrict__ Kb16)
{
    int idx = blockIdx.x * 256 + threadIdx.x;   // 786432
    int pr = idx & 31;
    int tmp = idx >> 5;
    int hb = tmp % 12;
    int bt = tmp / 12;
    int t = bt & 1023, b = bt >> 10;
    const float* yx = O2 + (size_t)bt * 1536 + hb * 64 + pr * 2;
    float y0 = yx[0], y1 = yx[1];
    float x0 = yx[768], x1 = yx[769];
    float cv = trig[t * 32 + pr], sv = trig[32768 + t * 32 + pr];
    #pragma unroll
    for (int r = 0; r < 4; r++) {
        int h = hb + 12 * r;
        float b0 = wbias[h * 64 + 2 * pr], b1 = wbias[h * 64 + 2 * pr + 1];
        float wz0 = y0 + x0 * b0;
        float wz1 = y1 + x1 * b1;
        float lo = wz0 * cv - wz1 * sv;
        float hi = wz0 * sv + wz1 * cv;
        size_t base = ((size_t)(b * 48 + h) * 1024 + t) * 64;
        Kr[base + pr] = lo;
        Kr[base + 32 + pr] = hi;
        Kb16[base + pr] = f2bf(lo);
        Kb16[base + 32 + pr] = f2bf(hi);
    }
}

// ---------------------------------------------------------------------------
// Attention core v2 (round-8 verbatim): packed-key top-4, diagonal peel,
// register prefetch, uniform qb pairing; exact fp32 re-score for final top-4.
// ---------------------------------------------------------------------------
__global__ __launch_bounds__(256) void attn_mfma_topk_kernel(
    const float* __restrict__ Qr, const float* __restrict__ Kr,
    const unsigned short* __restrict__ Kb, const float* __restrict__ sink,
    unsigned short* __restrict__ markerb, float* __restrict__ psink)
{
    const int bh = blockIdx.x;                 // 0..95
    const int y  = blockIdx.y;                 // 0..7
    const int w = threadIdx.x >> 6, lane = threadIdx.x & 63;
    const int rf = lane & 15, kg = lane >> 4;
    const int h = bh % HTq;
    const size_t rowbase = (size_t)bh * Tq;
    const unsigned short* Kbb = Kb + rowbase * 64;
    const float sk = sink[h];

    #pragma unroll 1
    for (int g = 0; g < 2; g++) {
        const int qb = g ? y : 15 - y;
        const int q0 = qb * 64 + w * 16;

        short8 a0, a1;
        {
            const float* qp = Qr + (rowbase + q0 + rf) * 64 + kg * 8;
            float4 u0 = *(const float4*)qp;
            float4 u1 = *(const float4*)(qp + 4);
            float4 u2 = *(const float4*)(qp + 32);
            float4 u3 = *(const float4*)(qp + 36);
            a0[0]=(short)f2bf(u0.x); a0[1]=(short)f2bf(u0.y); a0[2]=(short)f2bf(u0.z); a0[3]=(short)f2bf(u0.w);
            a0[4]=(short)f2bf(u1.x); a0[5]=(short)f2bf(u1.y); a0[6]=(short)f2bf(u1.z); a0[7]=(short)f2bf(u1.w);
            a1[0]=(short)f2bf(u2.x); a1[1]=(short)f2bf(u2.y); a1[2]=(short)f2bf(u2.z); a1[3]=(short)f2bf(u2.w);
            a1[4]=(short)f2bf(u3.x); a1[5]=(short)f2bf(u3.y); a1[6]=(short)f2bf(u3.z); a1[7]=(short)f2bf(u3.w);
        }

        float m_[4], Z_[4];
        unsigned t_[4][4];
        #pragma unroll
        for (int r = 0; r < 4; r++) {
            m_[r] = -1e30f; Z_[r] = 0.0f;
            t_[r][0] = 0u; t_[r][1] = 0u; t_[r][2] = 0u; t_[r][3] = 0u;
        }

        short8 cA0[4], cA1[4], cB0[4], cB1[4];
        {
            const unsigned short* p = Kbb + (size_t)rf * 64 + kg * 8;
            #pragma unroll
            for (int kc = 0; kc < 4; kc++) {
                cA0[kc] = *(const short8*)(p + kc * 1024);
                cA1[kc] = *(const short8*)(p + kc * 1024 + 32);
            }
        }

        auto body = [&](short8 (&cb0)[4], short8 (&cb1)[4],
                        short8 (&nb0)[4], short8 (&nb1)[4], int tile) {
            f32x4 accs[4];
            #pragma unroll
            for (int kc = 0; kc < 4; kc++) {
                f32x4 acc = {0.f, 0.f, 0.f, 0.f};
                acc = __builtin_amdgcn_mfma_f32_16x16x32_bf16(a0, cb0[kc], acc, 0, 0, 0);
                acc = __builtin_amdgcn_mfma_f32_16x16x32_bf16(a1, cb1[kc], acc, 0, 0, 0);
                accs[kc] = acc;
            }
            const unsigned short* np = Kbb + (size_t)((tile + 1) * 64 + rf) * 64 + kg * 8;
            #pragma unroll
            for (int kc = 0; kc < 4; kc++) {
                nb0[kc] = *(const short8*)(np + kc * 1024);
                nb1[kc] = *(const short8*)(np + kc * 1024 + 32);
            }
            const int s0 = tile << 6;
            #pragma unroll
            for (int r = 0; r < 4; r++) {
                float sv[4];
                #pragma unroll
                for (int kc = 0; kc < 4; kc++) sv[kc] = accs[kc][r] * SCALE;
                #pragma unroll
                for (int kc = 0; kc < 4; kc++) {
                    unsigned u = __float_as_uint(sv[kc]);
                    unsigned key = u ^ ((unsigned)(((int)u) >> 31) | 0x80000000u);
                    unsigned c = (key & 0xFFFFFC00u) | (unsigned)(s0 + kc * 16 + rf);
                    unsigned n;
                    n = t_[r][0] > c ? t_[r][0] : c;  c = t_[r][0] > c ? c : t_[r][0];  t_[r][0] = n;
                    n = t_[r][1] > c ? t_[r][1] : c;  c = t_[r][1] > c ? c : t_[r][1];  t_[r][1] = n;
                    n = t_[r][2] > c ? t_[r][2] : c;  c = t_[r][2] > c ? c : t_[r][2];  t_[r][2] = n;
                    t_[r][3] = t_[r][3] > c ? t_[r][3] : c;
                }
                float tm = fmaxf(fmaxf(sv[0], sv[1]), fmaxf(sv[2], sv[3]));
                float nm = fmaxf(m_[r], tm);
                float zz = Z_[r] * __expf(m_[r] - nm);
                #pragma unroll
                for (int kc = 0; kc < 4; kc++) zz += __expf(sv[kc] - nm);
                Z_[r] = zz; m_[r] = nm;
            }
        };

        int tile = 0;
        for (; tile + 1 < qb; tile += 2) {
            body(cA0, cA1, cB0, cB1, tile);
            body(cB0, cB1, cA0, cA1, tile + 1);
        }
        if (tile < qb) {
            body(cA0, cA1, cB0, cB1, tile);
            #pragma unroll
            for (int kc = 0; kc < 4; kc++) { cA0[kc] = cB0[kc]; cA1[kc] = cB1[kc]; }
        }

        {
            f32x4 accs[4];
            #pragma unroll
            for (int kc = 0; kc < 4; kc++) {
                f32x4 acc = {0.f, 0.f, 0.f, 0.f};
                acc = __builtin_amdgcn_mfma_f32_16x16x32_bf16(a0, cA0[kc], acc, 0, 0, 0);
                acc = __builtin_amdgcn_mfma_f32_16x16x32_bf16(a1, cA1[kc], acc, 0, 0, 0);
                accs[kc] = acc;
            }
            const int s0 = qb << 6;
            #pragma unroll
            for (int r = 0; r < 4; r++) {
                const int trow = q0 + kg * 4 + r;
                float sv[4];
                unsigned pk[4];
                #pragma unroll
                for (int kc = 0; kc < 4; kc++) {
                    int k = s0 + kc * 16 + rf;
                    bool ok = (k <= trow);
                    float s = accs[kc][r] * SCALE;
                    sv[kc] = ok ? s : -INFINITY;
                    unsigned u = __float_as_uint(s);
                    unsigned key = u ^ ((unsigned)(((int)u) >> 31) | 0x80000000u);
                    unsigned c = (key & 0xFFFFFC00u) | (unsigned)k;
                    pk[kc] = ok ? c : 0u;
                }
                #pragma unroll
                for (int kc = 0; kc < 4; kc++) {
                    unsigned c = pk[kc], n;
                    n = t_[r][0] > c ? t_[r][0] : c;  c = t_[r][0] > c ? c : t_[r][0];  t_[r][0] = n;
                    n = t_[r][1] > c ? t_[r][1] : c;  c = t_[r][1] > c ? c : t_[r][1];  t_[r][1] = n;
                    n = t_[r][2] > c ? t_[r][2] : c;  c = t_[r][2] > c ? c : t_[r][2];  t_[r][2] = n;
                    t_[r][3] = t_[r][3] > c ? t_[r][3] : c;
                }
                float tm = fmaxf(fmaxf(sv[0], sv[1]), fmaxf(sv[2], sv[3]));
                float nm = fmaxf(m_[r], tm);
                float zz = Z_[r] * __expf(m_[r] - nm);
                #pragma unroll
                for (int kc = 0; kc < 4; kc++) zz += __expf(sv[kc] - nm);
                Z_[r] = zz; m_[r] = nm;
            }
        }

        #pragma unroll 1
        for (int r = 0; r < 4; r++) {
            const int q = q0 + kg * 4 + r;
            float m = m_[r], Z = Z_[r];
            #pragma unroll
            for (int off = 1; off < 16; off <<= 1) {
                float om = __shfl_xor(m, off);
                float oz = __shfl_xor(Z, off);
                float nm = fmaxf(m, om);
                Z = Z * __expf(m - nm) + oz * __expf(om - nm);
                m = nm;
            }
            unsigned l0 = t_[r][0], l1 = t_[r][1], l2 = t_[r][2], l3 = t_[r][3];
            unsigned ck[8];
            #pragma unroll
            for (int rd = 0; rd < 8; rd++) {
                unsigned v = l0;
                #pragma unroll
                for (int off = 1; off < 16; off <<= 1) {
                    unsigned ov = (unsigned)__shfl_xor((int)v, off);
                    v = v > ov ? v : ov;
                }
                ck[rd] = v;
                bool own = (l0 == v);
                l0 = own ? l1 : l0;
                l1 = own ? l2 : l1;
                l2 = own ? l3 : l2;
                l3 = own ? 0u : l3;
            }
            const float4 qv = *(const float4*)(Qr + (rowbase + q) * 64 + rf * 4);
            float sc[8]; int ci[8];
            #pragma unroll
            for (int c = 0; c < 8; c++) {
                bool valid = (ck[c] != 0u);
                int idx = (int)(ck[c] & 1023u);
                int lidx = valid ? idx : 0;
                const float4 kv = *(const float4*)(Kr + (rowbase + lidx) * 64 + rf * 4);
                float p = qv.x * kv.x + qv.y * kv.y + qv.z * kv.z + qv.w * kv.w;
                #pragma unroll
                for (int off = 1; off < 16; off <<= 1) p += __shfl_xor(p, off);
                sc[c] = valid ? p * SCALE : -1e30f;
                ci[c] = valid ? idx : -1;
            }
            float bv[4]; int bi[4];
            #pragma unroll
            for (int rd = 0; rd < 4; rd++) {
                float v = sc[0]; int id = ci[0];
                #pragma unroll
                for (int c = 1; c < 8; c++) {
                    bool take = (sc[c] > v) || ((sc[c] == v) && ((unsigned)ci[c] < (unsigned)id));
                    v = take ? sc[c] : v; id = take ? ci[c] : id;
                }
                bv[rd] = v; bi[rd] = id;
                #pragma unroll
                for (int c = 0; c < 8; c++) {
                    bool kill = (ci[c] == id) && (sc[c] == v);
                    sc[c] = kill ? -3e30f : sc[c];
                }
            }
            float mf = fmaxf(m, sk);
            float Zf = Z * __expf(m - mf) + __expf(sk - mf);
            float e0 = __expf(bv[0] - mf), e1 = __expf(bv[1] - mf);
            float e2 = __expf(bv[2] - mf), e3 = __expf(bv[3] - mf);
            float wsum = e0 + e1 + e2 + e3 + Zf * 1e-9f;
            float w0 = e0 / wsum, w1 = e1 / wsum, w2 = e2 / wsum, w3 = e3 / wsum;
            int i0 = bi[0] < 0 ? 0 : bi[0];
            int i1 = bi[1] < 0 ? 0 : bi[1];
            int i2 = bi[2] < 0 ? 0 : bi[2];
            int i3 = bi[3] < 0 ? 0 : bi[3];
            const float4 k0 = *(const float4*)(Kr + (rowbase + i0) * 64 + rf * 4);
            const float4 k1 = *(const float4*)(Kr + (rowbase + i1) * 64 + rf * 4);
            const float4 k2 = *(const float4*)(Kr + (rowbase + i2) * 64 + rf * 4);
            const float4 k3 = *(const float4*)(Kr + (rowbase + i3) * 64 + rf * 4);
            float mx = w0 * k0.x + w1 * k1.x + w2 * k2.x + w3 * k3.x;
            float my = w0 * k0.y + w1 * k1.y + w2 * k2.y + w3 * k3.y;
            float mz = w0 * k0.z + w1 * k1.z + w2 * k2.z + w3 * k3.z;
            float mw = w0 * k0.w + w1 * k1.w + w2 * k2.w + w3 * k3.w;
            ushort4 mo;
            mo.x = f2bf(mx); mo.y = f2bf(my); mo.z = f2bf(mz); mo.w = f2bf(mw);
            *(ushort4*)(markerb + (rowbase + q) * 64 + rf * 4) = mo;
            if (rf == 0) psink[rowbase + q] = __expf(sk - mf) / Zf;
        }
    }
}

// ---------------------------------------------------------------------------
__global__ void cvt_bf16_kernel(const float* __restrict__ in,
                                unsigned short* __restrict__ out, int n4)
{
    int i = blockIdx.x * 256 + threadIdx.x;
    if (i < n4) {
        float4 v = ((const float4*)in)[i];
        ushort4 o;
        o.x = f2bf(v.x); o.y = f2bf(v.y); o.z = f2bf(v.z); o.w = f2bf(v.w);
        ((ushort4*)out)[i] = o;
    }
}

// ---------------------------------------------------------------------------
__global__ __launch_bounds__(256) void wo_transpose_kernel(
    const float* __restrict__ WOw, unsigned short* __restrict__ WOt)
{
    __shared__ float tl[64][65];
    int tid = threadIdx.x;
    int n = blockIdx.z;
    int c0 = blockIdx.x * 64, d0 = blockIdx.y * 64;
    const float* src = WOw + (size_t)n * 768 * 768;
    for (int l = tid; l < 64 * 16; l += 256) {
        int r = l >> 4, q = l & 15;
        float4 v = *(const float4*)(src + (size_t)(c0 + r) * 768 + d0 + q * 4);
        tl[r][q * 4 + 0] = v.x; tl[r][q * 4 + 1] = v.y;
        tl[r][q * 4 + 2] = v.z; tl[r][q * 4 + 3] = v.w;
    }
    __syncthreads();
    for (int l = tid; l < 64 * 16; l += 256) {
        int d = l >> 4, q = l & 15;
        ushort4 o;
        o.x = f2bf(tl[q * 4 + 0][d]); o.y = f2bf(tl[q * 4 + 1][d]);
        o.z = f2bf(tl[q * 4 + 2][d]); o.w = f2bf(tl[q * 4 + 3][d]);
        *(ushort4*)(WOt + (size_t)n * 768 * 768 + (size_t)(d0 + d) * 768 + c0 + q * 4) = o;
    }
}

// ---------------------------------------------------------------------------
__global__ __launch_bounds__(256) void mlp_mfma_kernel(
    const unsigned short* __restrict__ markerb, const float* __restrict__ psink,
    const unsigned short* __restrict__ V1b16, const float* __restrict__ V1bias,
    const unsigned short* __restrict__ V2b16, const float* __restrict__ V2bias,
    const float* __restrict__ vnulls, unsigned short* __restrict__ ctxb)
{
    __shared__ float h_lds[4][16][65];
    int tid = threadIdx.x;
    int w = tid >> 6, lane = tid & 63;
    int rf = lane & 15, kg = lane >> 4;
    size_t r0 = (size_t)blockIdx.x * 64 + 16 * w;

    short8 a1[2];
    #pragma unroll
    for (int kk = 0; kk < 2; kk++)
        a1[kk] = *(const short8*)(markerb + (r0 + rf) * 64 + kk * 32 + kg * 8);

    f32x4 acc2[4] = {};
    for (int ch = 0; ch < 4; ch++) {
        f32x4 acc1[4] = {};
        #pragma unroll
        for (int nj = 0; nj < 4; nj++)
            #pragma unroll
            for (int kk = 0; kk < 2; kk++) {
                short8 b1 = *(const short8*)(V1b16 + (size_t)(ch * 64 + nj * 16 + rf) * 64 + kk * 32 + kg * 8);
                acc1[nj] = __builtin_amdgcn_mfma_f32_16x16x32_bf16(a1[kk], b1, acc1[nj], 0, 0, 0);
            }
        __syncthreads();
        #pragma unroll
        for (int nj = 0; nj < 4; nj++) {
            float bb = V1bias[ch * 64 + nj * 16 + rf];
            #pragma unroll
            for (int r = 0; r < 4; r++) {
                float x = acc1[nj][r] + bb;
                h_lds[w][kg * 4 + r][nj * 16 + rf] = gelu_f(x);
            }
        }
        __syncthreads();
        #pragma unroll
        for (int kk = 0; kk < 2; kk++) {
            const float* hp = &h_lds[w][rf][kk * 32 + kg * 8];
            float4 p0 = *(const float4*)hp;
            float4 p1 = *(const float4*)(hp + 4);
            short8 a2;
            a2[0] = (short)f2bf(p0.x); a2[1] = (short)f2bf(p0.y);
            a2[2] = (short)f2bf(p0.z); a2[3] = (short)f2bf(p0.w);
            a2[4] = (short)f2bf(p1.x); a2[5] = (short)f2bf(p1.y);
            a2[6] = (short)f2bf(p1.z); a2[7] = (short)f2bf(p1.w);
            #pragma unroll
            for (int njo = 0; njo < 4; njo++) {
                short8 b2 = *(const short8*)(V2b16 + (size_t)(njo * 16 + rf) * 256 + ch * 64 + kk * 32 + kg * 8);
                acc2[njo] = __builtin_amdgcn_mfma_f32_16x16x32_bf16(a2, b2, acc2[njo], 0, 0, 0);
            }
        }
    }
    #pragma unroll
    for (int r = 0; r < 4; r++) {
        size_t R = r0 + kg * 4 + r;
        int bh = (int)(R >> 10), t = (int)(R & 1023);
        int b = bh / 48, h = bh % 48;
        int n = h / 12, head = h % 12;
        float ps = psink[R];
        size_t base = ((size_t)((b * 4 + n) * 1024 + t)) * 768 + head * 64;
        #pragma unroll
        for (int njo = 0; njo < 4; njo++) {
            int d = njo * 16 + rf;
            float v = acc2[njo][r] + V2bias[d] + ps * vnulls[h * 64 + d];
            ctxb[base + d] = f2bf(v);
        }
    }
}

// ---------------------------------------------------------------------------
__global__ __launch_bounds__(256) void gemm_wo_mfma(
    const unsigned short* __restrict__ ctxb, const unsigned short* __restrict__ WOtb,
    const float* __restrict__ WOb, float* __restrict__ Out)
{
    __shared__ unsigned short sA[64 * 64];
    __shared__ unsigned short sB[64 * 64];
    int tid = threadIdx.x;
    int w = tid >> 6, lane = tid & 63;
    int wm = w >> 1, wn = w & 1;
    int rf = lane & 15, kg = lane >> 4;
    int m0 = blockIdx.x * 64, n0 = blockIdx.y * 64;
    int b = m0 >> 10, t0 = m0 & 1023;
    int c0 = tid * 2, c1 = tid * 2 + 1;
    int ra = c0 >> 3, ca = c0 & 7, rb = c1 >> 3, cb = c1 & 7;
    f32x4 acc[2][2] = {};
    for (int n = 0; n < 4; n++) {
        const unsigned short* Ab = ctxb + ((size_t)((b * 4 + n) * 1024 + t0)) * 768;
        const unsigned short* Bb = WOtb + (size_t)n * 768 * 768 + (size_t)n0 * 768;
        for (int k0 = 0; k0 < 768; k0 += 64) {
            __syncthreads();
            *(short8*)&sA[ra * 64 + ((ca ^ (ra & 7)) * 8)] = *(const short8*)(Ab + (size_t)ra * 768 + k0 + ca * 8);
            *(short8*)&sA[rb * 64 + ((cb ^ (rb & 7)) * 8)] = *(const short8*)(Ab + (size_t)rb * 768 + k0 + cb * 8);
            *(short8*)&sB[ra * 64 + ((ca ^ (ra & 7)) * 8)] = *(const short8*)(Bb + (size_t)ra * 768 + k0 + ca * 8);
            *(short8*)&sB[rb * 64 + ((cb ^ (rb & 7)) * 8)] = *(const short8*)(Bb + (size_t)rb * 768 + k0 + cb * 8);
            __syncthreads();
            #pragma unroll
            for (int kk = 0; kk < 2; kk++) {
                int kc = kk * 4 + kg;
                int rA0 = wm * 32 + rf, rA1 = wm * 32 + 16 + rf;
                int rB0 = wn * 32 + rf, rB1 = wn * 32 + 16 + rf;
                short8 a0v = *(const short8*)&sA[rA0 * 64 + ((kc ^ (rA0 & 7)) * 8)];
                short8 a1v = *(const short8*)&sA[rA1 * 64 + ((kc ^ (rA1 & 7)) * 8)];
                short8 b0v = *(const short8*)&sB[rB0 * 64 + ((kc ^ (rB0 & 7)) * 8)];
                short8 b1v = *(const short8*)&sB[rB1 * 64 + ((kc ^ (rB1 & 7)) * 8)];
                acc[0][0] = __builtin_amdgcn_mfma_f32_16x16x32_bf16(a0v, b0v, acc[0][0], 0, 0, 0);
                acc[0][1] = __builtin_amdgcn_mfma_f32_16x16x32_bf16(a0v, b1v, acc[0][1], 0, 0, 0);
                acc[1][0] = __builtin_amdgcn_mfma_f32_16x16x32_bf16(a1v, b0v, acc[1][0], 0, 0, 0);
                acc[1][1] = __builtin_amdgcn_mfma_f32_16x16x32_bf16(a1v, b1v, acc[1][1], 0, 0, 0);
            }
        }
    }
    #pragma unroll
    for (int nj = 0; nj < 2; nj++) {
        int col = n0 + wn * 32 + nj * 16 + rf;
        float bm = WOb[col] + WOb[768 + col] + WOb[1536 + col] + WOb[2304 + col];
        #pragma unroll
        for (int mi = 0; mi < 2; mi++)
            #pragma unroll
            for (int r = 0; r < 4; r++) {
                int row = m0 + wm * 32 + mi * 16 + kg * 4 + r;
                Out[(size_t)row * 768 + col] = 0.25f * (acc[mi][nj][r] + bm);
            }
    }
}

// ---------------------------------------------------------------------------
extern "C" void kernel_launch(void* const* d_in, const int* in_sizes, int n_in,
                              void* d_out, int out_size, void* d_ws, size_t ws_size,
                              hipStream_t stream) {
    const float* A      = (const float*)d_in[0];
    const float* X      = (const float*)d_in[1];
    const float* WKw    = (const float*)d_in[2];
    const float* WKb    = (const float*)d_in[3];
    const float* WQw    = (const float*)d_in[4];
    const float* wA     = (const float*)d_in[5];
    const float* wB     = (const float*)d_in[6];
    const float* sink   = (const float*)d_in[7];
    const float* vnulls = (const float*)d_in[8];
    const float* V1w    = (const float*)d_in[9];
    const float* V1b    = (const float*)d_in[10];
    const float* V2w    = (const float*)d_in[11];
    const float* V2b    = (const float*)d_in[12];
    const float* WOw    = (const float*)d_in[13];
    const float* WOb    = (const float*)d_in[14];
    float* out = (float*)d_out;
    (void)in_sizes; (void)n_in; (void)out_size; (void)ws_size;

    float* ws = (float*)d_ws;
    size_t off = 0;
    float* Qr   = ws + off;  off += 6291456;   // head-major fp32 Q (rope'd)
    float* Kr   = ws + off;  off += 6291456;   // head-major fp32 K (rope'd)
    float* trig = ws + off;  off += 65536;
    float* bcat = ws + off;  off += 2048;
    float* O2   = ws + off;  off += 3145728;   // [2048][1536]: y | x
    float* Wsp_f = ws + off; off += 5308416;   // 3 planes x 4608x768 ushort
    unsigned short* Wsp = (unsigned short*)Wsp_f;
    unsigned short* Asp = (unsigned short*)(ws + off); off += 2359296;  // 3 planes x 2048x768
    unsigned short* Xsp = (unsigned short*)(ws + off); off += 2359296;
    // overlays (dead-buffer reuse) — audited lifetimes:
    //   markerb = O2 (FULL 3,145,728 floats; O2 dead after k_finish)
    //   Kb16 = Wsp floats [0, 3145728); psink = Wsp floats [3145728, 3244032)
    unsigned short* markerb = (unsigned short*)O2;
    unsigned short* Kb16 = Wsp;
    float* psink = Wsp_f + 3145728;
    unsigned short* V1b16 = Xsp;                         // Xsp dead after proj
    unsigned short* V2b16 = V1b16 + 16384;
    unsigned short* WOtb  = Asp;                         // Asp dead after proj
    unsigned short* ctxb  = (unsigned short*)Qr;         // Qr dead after attn

    // prep: trig + folded/split weights + split activations
    trig_kernel<<<128, 256, 0, stream>>>(trig);
    fold_split_kernel<<<dim3(48, 6), 256, 0, stream>>>(WQw, wA, wB, Wsp, 0);
    fold_split_kernel<<<dim3(12, 6), 256, 0, stream>>>(WKw, wA, wB, Wsp, 1);
    kbias_kernel<<<6, 256, 0, stream>>>(WKb, wA, bcat);
    split_act_kernel<<<1536, 256, 0, stream>>>(A, X, Asp, Xsp);
    // split-precision MFMA projection, LDS-staged + XOR-swizzled (no conflicts)
    proj_mfma_kernel<<<576, 512, 0, stream>>>(Asp, Xsp, Wsp, bcat, trig, Qr, O2);
    // finish K: per-h bias wedge term + rope -> Kr fp32 + Kb16 bf16
    k_finish_kernel<<<3072, 256, 0, stream>>>(O2, trig, wB, Kr, Kb16);
    // attention: MFMA scores, packed-key shortlist, exact fp32 top-4
    attn_mfma_topk_kernel<<<dim3(96, 8), 256, 0, stream>>>(Qr, Kr, Kb16, sink, markerb, psink);
    // post-top-k smooth path (bf16/MFMA)
    cvt_bf16_kernel<<<16, 256, 0, stream>>>(V1w, V1b16, 4096);
    cvt_bf16_kernel<<<16, 256, 0, stream>>>(V2w, V2b16, 4096);
    wo_transpose_kernel<<<dim3(12, 12, 4), 256, 0, stream>>>(WOw, WOtb);
    mlp_mfma_kernel<<<1536, 256, 0, stream>>>(markerb, psink, V1b16, V1b, V2b16, V2b, vnulls, ctxb);
    gemm_wo_mfma<<<dim3(32, 12), 256, 0, stream>>>(ctxb, WOtb, WOb, out);
}

// Round 11
// 345.444 us; speedup vs baseline: 3.7580x; 1.0155x over previous
//
#include <hip/hip_runtime.h>
#include <math.h>

constexpr int Bq  = 2;
constexpr int Tq  = 1024;
constexpr int HTq = 48;
constexpr float SCALE = 0.125f;     // 64^-0.5

typedef __attribute__((ext_vector_type(8))) short short8;
typedef __attribute__((ext_vector_type(4))) float f32x4;

__device__ inline unsigned short f2bf(float x) {
    unsigned u = __float_as_uint(x);
    return (unsigned short)((u + 0x7FFF + ((u >> 16) & 1)) >> 16);
}

// async global->LDS, 16B per lane; LDS dest = wave-uniform base + lane*16
__device__ inline void gload_lds16(const unsigned short* g, unsigned short* l) {
    __builtin_amdgcn_global_load_lds(
        (const __attribute__((address_space(1))) void*)g,
        (__attribute__((address_space(3))) void*)l,
        16, 0, 0);
}

// exact 3-plane bf16 split: x = p0 + p1 + p2 + O(2^-27 |x|)
__device__ inline void split3(float x, unsigned short& p0, unsigned short& p1, unsigned short& p2) {
    p0 = f2bf(x);
    float f0 = __uint_as_float((unsigned)p0 << 16);
    float r0 = x - f0;
    p1 = f2bf(r0);
    float f1 = __uint_as_float((unsigned)p1 << 16);
    float r1 = r0 - f1;
    p2 = f2bf(r1);
}

// exact-erf GELU via Abramowitz-Stegun 7.1.26 (|eps_erf| <= 1.5e-7)
__device__ inline float gelu_f(float x) {
    float z = 0.70710678118654752f * x;
    float az = fabsf(z);
    float t = __frcp_rn(1.0f + 0.3275911f * az);
    float poly = t * (0.254829592f + t * (-0.284496736f + t * (1.421413741f
               + t * (-1.453152027f + t * 1.061405429f))));
    float er = 1.0f - poly * __expf(-az * az);
    er = (z < 0.0f) ? -er : er;
    return 0.5f * x * (1.0f + er);
}

// ---------------------------------------------------------------------------
// trig table: cos at [t*32+i], sin at [32768 + t*32+i].
// ---------------------------------------------------------------------------
__global__ void trig_kernel(float* __restrict__ trig) {
    int i = blockIdx.x * 256 + threadIdx.x;   // 32768
    int t = i >> 5, f = i & 31;
    float invf = powf(10000.0f, -(float)f * (1.0f / 32.0f));
    float ang = (float)t * invf;
    trig[i] = cosf(ang);
    trig[32768 + i] = sinf(ang);
}

// ---------------------------------------------------------------------------
// Weight fold + 3-plane split.  skew = wA - wA^T.
// ---------------------------------------------------------------------------
__global__ __launch_bounds__(256) void fold_split_kernel(
    const float* __restrict__ Wsrc, const float* __restrict__ wA,
    const float* __restrict__ wbias, unsigned short* __restrict__ Wsp, int mode)
{
    const size_t WPL = (size_t)4608 * 768;
    __shared__ float sw[64][132];
    __shared__ float sk[64][65];
    int h = blockIdx.x, cb = blockIdx.y;
    int tid = threadIdx.x;
    const float* Wh = Wsrc + (size_t)h * 64 * 768 + cb * 128;
    for (int l = tid; l < 64 * 32; l += 256) {
        int d = l >> 5, c4 = l & 31;
        *(float4*)&sw[d][c4 * 4] = *(const float4*)(Wh + (size_t)d * 768 + c4 * 4);
    }
    for (int l = tid; l < 4096; l += 256) {
        int d = l >> 6, e = l & 63;
        sk[d][e] = wA[l] - wA[e * 64 + d];
    }
    __syncthreads();
    int tx = tid & 15, ty = tid >> 4;
    float acc4[4][8] = {};
    for (int d = 0; d < 64; d++) {
        float s0 = sk[d][ty * 4 + 0], s1 = sk[d][ty * 4 + 1];
        float s2 = sk[d][ty * 4 + 2], s3 = sk[d][ty * 4 + 3];
        float w_[8];
        *(float4*)&w_[0] = *(const float4*)&sw[d][tx * 8];
        *(float4*)&w_[4] = *(const float4*)&sw[d][tx * 8 + 4];
        #pragma unroll
        for (int j = 0; j < 8; j++) {
            acc4[0][j] += s0 * w_[j];
            acc4[1][j] += s1 * w_[j];
            acc4[2][j] += s2 * w_[j];
            acc4[3][j] += s3 * w_[j];
        }
    }
    #pragma unroll
    for (int i = 0; i < 4; i++) {
        int e = ty * 4 + i;
        float scale = (mode == 0) ? (1.0f + wbias[h * 64 + e]) : 1.0f;
        size_t row = (mode == 0) ? (size_t)(h * 64 + e) : (size_t)(3072 + h * 64 + e);
        #pragma unroll
        for (int j = 0; j < 8; j++) {
            int cl = tx * 8 + j;
            float wv = sw[e][cl] * scale + acc4[i][j];
            unsigned short p0, p1, p2;
            split3(wv, p0, p1, p2);
            size_t idx = row * 768 + cb * 128 + cl;
            Wsp[idx] = p0; Wsp[WPL + idx] = p1; Wsp[2 * WPL + idx] = p2;
        }
        if (mode == 1) {
            size_t row2 = (size_t)(3840 + h * 64 + e);
            #pragma unroll
            for (int j = 0; j < 8; j++) {
                int cl = tx * 8 + j;
                unsigned short p0, p1, p2;
                split3(sw[e][cl], p0, p1, p2);
                size_t idx = row2 * 768 + cb * 128 + cl;
                Wsp[idx] = p0; Wsp[WPL + idx] = p1; Wsp[2 * WPL + idx] = p2;
            }
        }
    }
}

// ---------------------------------------------------------------------------
__global__ void kbias_kernel(const float* __restrict__ WKb, const float* __restrict__ wA,
                             float* __restrict__ bcat) {
    int e = blockIdx.x * 256 + threadIdx.x;   // 1536
    if (e < 768) {
        int hb = e >> 6, el = e & 63;
        float acc = 0.0f;
        for (int d = 0; d < 64; d++) {
            float sk = wA[d * 64 + el] - wA[el * 64 + d];
            acc += WKb[hb * 64 + d] * sk;
        }
        bcat[e] = WKb[e] + acc;
    } else if (e < 1536) {
        bcat[e] = WKb[e - 768];
    }
}

// ---------------------------------------------------------------------------
__global__ void split_act_kernel(const float* __restrict__ A, const float* __restrict__ X,
                                 unsigned short* __restrict__ Asp, unsigned short* __restrict__ Xsp)
{
    const size_t APL = (size_t)2048 * 768;
    int i = blockIdx.x * 256 + threadIdx.x;   // 393216 quads
    if (i >= 393216) return;
    float4 va = ((const float4*)A)[i];
    float4 vx = ((const float4*)X)[i];
    ushort4 a0, a1, a2, x0, x1, x2;
    split3(va.x, a0.x, a1.x, a2.x); split3(va.y, a0.y, a1.y, a2.y);
    split3(va.z, a0.z, a1.z, a2.z); split3(va.w, a0.w, a1.w, a2.w);
    split3(vx.x, x0.x, x1.x, x2.x); split3(vx.y, x0.y, x1.y, x2.y);
    split3(vx.z, x0.z, x1.z, x2.z); split3(vx.w, x0.w, x1.w, x2.w);
    ((ushort4*)(Asp))[i] = a0;
    ((ushort4*)(Asp + APL))[i] = a1;
    ((ushort4*)(Asp + 2 * APL))[i] = a2;
    ((ushort4*)(Xsp))[i] = x0;
    ((ushort4*)(Xsp + APL))[i] = x1;
    ((ushort4*)(Xsp + 2 * APL))[i] = x2;
}

// ---------------------------------------------------------------------------
// Projection GEMM via split-precision bf16 MFMA, async global_load_lds staging.
// 128x128 tile, BK=32, 512 threads (8 waves, 2m x 4n, 64x32 per wave).
// LDS: 3 planes x 128 rows x 32 ushorts per operand (48 KB total, 3 blocks/CU).
// Staging: each wave issues 6x global_load_lds (16B/lane, 1KB regions
// reg = w + 8i of sA and sB); XOR swizzle is applied on the per-lane GLOBAL
// source slot ((l&3) ^ ((l>>3)&3)) with LINEAR LDS dest (rule #21), producing
// the exact same LDS image as round 10.  Read side + MFMA order unchanged ->
// bitwise-identical output.
// ---------------------------------------------------------------------------
__global__ __launch_bounds__(512) void proj_mfma_kernel(
    const unsigned short* __restrict__ Asp, const unsigned short* __restrict__ Xsp,
    const unsigned short* __restrict__ Wsp, const float* __restrict__ bcat,
    const float* __restrict__ trig, float* __restrict__ Qr, float* __restrict__ O2)
{
    const size_t APL = (size_t)2048 * 768;
    const size_t WPL = (size_t)4608 * 768;
    __shared__ unsigned short sA[3 * 128 * 32];
    __shared__ unsigned short sB[3 * 128 * 32];
    int bid = blockIdx.x;
    int swz = (bid & 7) * 72 + (bid >> 3);
    int nb = swz >> 4;
    int mb = swz & 15;
    bool isQ = (nb < 24);
    const unsigned short* Ab = isQ ? Asp : Xsp;
    int m0 = mb * 128, n0 = nb * 128;
    int tid = threadIdx.x;
    int w = tid >> 6, lane = tid & 63;
    int wm = w & 1, wn = w >> 1;
    int rf = lane & 15, kg = lane >> 4;
    int mbase = m0 + wm * 64;

    // per-lane pre-swizzled global source offsets for the 3 regions each of A/B
    int srcslot = (lane & 3) ^ ((lane >> 3) & 3);
    const unsigned short* gsrcA[3];
    const unsigned short* gsrcB[3];
    unsigned short* ldstA[3];
    unsigned short* ldstB[3];
    #pragma unroll
    for (int i = 0; i < 3; i++) {
        int reg = w + i * 8;            // 0..23
        int p = reg >> 3, rg = reg & 7; // plane, 16-row group
        int row = rg * 16 + (lane >> 2);
        gsrcA[i] = Ab  + (size_t)p * APL + (size_t)(m0 + row) * 768 + srcslot * 8;
        gsrcB[i] = Wsp + (size_t)p * WPL + (size_t)(n0 + row) * 768 + srcslot * 8;
        ldstA[i] = &sA[p * 4096 + rg * 512];
        ldstB[i] = &sB[p * 4096 + rg * 512];
    }

    f32x4 acc[4][2] = {};
    for (int k0 = 0; k0 < 768; k0 += 32) {
        __syncthreads();
        #pragma unroll
        for (int i = 0; i < 3; i++) {
            gload_lds16(gsrcA[i] + k0, ldstA[i]);
            gload_lds16(gsrcB[i] + k0, ldstB[i]);
        }
        __syncthreads();

        short8 a0[4], a1[4], a2[4], b0[2], b1[2], b2[2];
        #pragma unroll
        for (int mi = 0; mi < 4; mi++) {
            int row = wm * 64 + mi * 16 + rf;
            a0[mi] = *(const short8*)&sA[0 * 4096 + row * 32 + ((kg ^ ((row >> 1) & 3)) * 8)];
        }
        #pragma unroll
        for (int nj = 0; nj < 2; nj++) {
            int row = wn * 32 + nj * 16 + rf;
            b0[nj] = *(const short8*)&sB[0 * 4096 + row * 32 + ((kg ^ ((row >> 1) & 3)) * 8)];
        }
        #pragma unroll
        for (int mi = 0; mi < 4; mi++)
            #pragma unroll
            for (int nj = 0; nj < 2; nj++)
                acc[mi][nj] = __builtin_amdgcn_mfma_f32_16x16x32_bf16(a0[mi], b0[nj], acc[mi][nj], 0, 0, 0);
        #pragma unroll
        for (int nj = 0; nj < 2; nj++) {
            int row = wn * 32 + nj * 16 + rf;
            b1[nj] = *(const short8*)&sB[1 * 4096 + row * 32 + ((kg ^ ((row >> 1) & 3)) * 8)];
        }
        #pragma unroll
        for (int mi = 0; mi < 4; mi++)
            #pragma unroll
            for (int nj = 0; nj < 2; nj++)
                acc[mi][nj] = __builtin_amdgcn_mfma_f32_16x16x32_bf16(a0[mi], b1[nj], acc[mi][nj], 0, 0, 0);
        #pragma unroll
        for (int nj = 0; nj < 2; nj++) {
            int row = wn * 32 + nj * 16 + rf;
            b2[nj] = *(const short8*)&sB[2 * 4096 + row * 32 + ((kg ^ ((row >> 1) & 3)) * 8)];
        }
        #pragma unroll
        for (int mi = 0; mi < 4; mi++)
            #pragma unroll
            for (int nj = 0; nj < 2; nj++)
                acc[mi][nj] = __builtin_amdgcn_mfma_f32_16x16x32_bf16(a0[mi], b2[nj], acc[mi][nj], 0, 0, 0);
        #pragma unroll
        for (int mi = 0; mi < 4; mi++) {
            int row = wm * 64 + mi * 16 + rf;
            a1[mi] = *(const short8*)&sA[1 * 4096 + row * 32 + ((kg ^ ((row >> 1) & 3)) * 8)];
        }
        #pragma unroll
        for (int mi = 0; mi < 4; mi++)
            #pragma unroll
            for (int nj = 0; nj < 2; nj++)
                acc[mi][nj] = __builtin_amdgcn_mfma_f32_16x16x32_bf16(a1[mi], b0[nj], acc[mi][nj], 0, 0, 0);
        #pragma unroll
        for (int mi = 0; mi < 4; mi++)
            #pragma unroll
            for (int nj = 0; nj < 2; nj++)
                acc[mi][nj] = __builtin_amdgcn_mfma_f32_16x16x32_bf16(a1[mi], b1[nj], acc[mi][nj], 0, 0, 0);
        #pragma unroll
        for (int mi = 0; mi < 4; mi++) {
            int row = wm * 64 + mi * 16 + rf;
            a2[mi] = *(const short8*)&sA[2 * 4096 + row * 32 + ((kg ^ ((row >> 1) & 3)) * 8)];
        }
        #pragma unroll
        for (int mi = 0; mi < 4; mi++)
            #pragma unroll
            for (int nj = 0; nj < 2; nj++)
                acc[mi][nj] = __builtin_amdgcn_mfma_f32_16x16x32_bf16(a2[mi], b0[nj], acc[mi][nj], 0, 0, 0);
    }

    if (isQ) {
        #pragma unroll
        for (int mi = 0; mi < 4; mi++) {
            #pragma unroll
            for (int r = 0; r < 4; r++) {
                int m = mbase + mi * 16 + kg * 4 + r;
                int b_ = m >> 10, t = m & 1023;
                #pragma unroll
                for (int nj = 0; nj < 2; nj++) {
                    int col_local = wn * 32 + nj * 16 + rf;
                    int h = nb * 2 + (col_local >> 6);
                    int d = col_local & 63;
                    int i = d >> 1;
                    float v = acc[mi][nj][r];
                    float pv = __shfl_xor(v, 1);
                    float c = trig[t * 32 + i];
                    float s = trig[32768 + t * 32 + i];
                    float outv = (rf & 1) ? (pv * s + v * c) : (v * c - pv * s);
                    int col = (rf & 1) ? (32 + i) : i;
                    size_t base = ((size_t)(b_ * 48 + h) * 1024 + t) * 64;
                    Qr[base + col] = outv;
                }
            }
        }
    } else {
        #pragma unroll
        for (int nj = 0; nj < 2; nj++) {
            int col = (n0 - 3072) + wn * 32 + nj * 16 + rf;
            float bv = bcat[col];
            #pragma unroll
            for (int mi = 0; mi < 4; mi++)
                #pragma unroll
                for (int r = 0; r < 4; r++) {
                    int m = mbase + mi * 16 + kg * 4 + r;
                    O2[(size_t)m * 1536 + col] = acc[mi][nj][r] + bv;
                }
        }
    }
}

// ---------------------------------------------------------------------------
__global__ void k_finish_kernel(const float* __restrict__ O2, const float* __restrict__ trig,
                                const float* __restrict__ wbias,
                                float* __restrict__ Kr, unsigned short* __restrict__ Kb16)
{
    int idx = blockIdx.x * 256 + threadIdx.x;   // 786432
    int pr = idx & 31;
    int tmp = idx >> 5;
    int hb = tmp % 12;
    int bt = tmp / 12;
    int t = bt & 1023, b = bt >> 10;
    const float* yx = O2 + (size_t)bt * 1536 + hb * 64 + pr * 2;
    float y0 = yx[0], y1 = yx[1];
    float x0 = yx[768], x1 = yx[769];
    float cv = trig[t * 32 + pr], sv = trig[32768 + t * 32 + pr];
    #pragma unroll
    for (int r = 0; r < 4; r++) {
        int h = hb + 12 * r;
        float b0 = wbias[h * 64 + 2 * pr], b1 = wbias[h * 64 + 2 * pr + 1];
        float wz0 = y0 + x0 * b0;
        float wz1 = y1 + x1 * b1;
        float lo = wz0 * cv - wz1 * sv;
        float hi = wz0 * sv + wz1 * cv;
        size_t base = ((size_t)(b * 48 + h) * 1024 + t) * 64;
        Kr[base + pr] = lo;
        Kr[base + 32 + pr] = hi;
        Kb16[base + pr] = f2bf(lo);
        Kb16[base + 32 + pr] = f2bf(hi);
    }
}

// ---------------------------------------------------------------------------
// Attention core v2 (round-8 verbatim): packed-key top-4, diagonal peel,
// register prefetch, uniform qb pairing; exact fp32 re-score for final top-4.
// ---------------------------------------------------------------------------
__global__ __launch_bounds__(256) void attn_mfma_topk_kernel(
    const float* __restrict__ Qr, const float* __restrict__ Kr,
    const unsigned short* __restrict__ Kb, const float* __restrict__ sink,
    unsigned short* __restrict__ markerb, float* __restrict__ psink)
{
    const int bh = blockIdx.x;                 // 0..95
    const int y  = blockIdx.y;                 // 0..7
    const int w = threadIdx.x >> 6, lane = threadIdx.x & 63;
    const int rf = lane & 15, kg = lane >> 4;
    const int h = bh % HTq;
    const size_t rowbase = (size_t)bh * Tq;
    const unsigned short* Kbb = Kb + rowbase * 64;
    const float sk = sink[h];

    #pragma unroll 1
    for (int g = 0; g < 2; g++) {
        const int qb = g ? y : 15 - y;
        const int q0 = qb * 64 + w * 16;

        short8 a0, a1;
        {
            const float* qp = Qr + (rowbase + q0 + rf) * 64 + kg * 8;
            float4 u0 = *(const float4*)qp;
            float4 u1 = *(const float4*)(qp + 4);
            float4 u2 = *(const float4*)(qp + 32);
            float4 u3 = *(const float4*)(qp + 36);
            a0[0]=(short)f2bf(u0.x); a0[1]=(short)f2bf(u0.y); a0[2]=(short)f2bf(u0.z); a0[3]=(short)f2bf(u0.w);
            a0[4]=(short)f2bf(u1.x); a0[5]=(short)f2bf(u1.y); a0[6]=(short)f2bf(u1.z); a0[7]=(short)f2bf(u1.w);
            a1[0]=(short)f2bf(u2.x); a1[1]=(short)f2bf(u2.y); a1[2]=(short)f2bf(u2.z); a1[3]=(short)f2bf(u2.w);
            a1[4]=(short)f2bf(u3.x); a1[5]=(short)f2bf(u3.y); a1[6]=(short)f2bf(u3.z); a1[7]=(short)f2bf(u3.w);
        }

        float m_[4], Z_[4];
        unsigned t_[4][4];
        #pragma unroll
        for (int r = 0; r < 4; r++) {
            m_[r] = -1e30f; Z_[r] = 0.0f;
            t_[r][0] = 0u; t_[r][1] = 0u; t_[r][2] = 0u; t_[r][3] = 0u;
        }

        short8 cA0[4], cA1[4], cB0[4], cB1[4];
        {
            const unsigned short* p = Kbb + (size_t)rf * 64 + kg * 8;
            #pragma unroll
            for (int kc = 0; kc < 4; kc++) {
                cA0[kc] = *(const short8*)(p + kc * 1024);
                cA1[kc] = *(const short8*)(p + kc * 1024 + 32);
            }
        }

        auto body = [&](short8 (&cb0)[4], short8 (&cb1)[4],
                        short8 (&nb0)[4], short8 (&nb1)[4], int tile) {
            f32x4 accs[4];
            #pragma unroll
            for (int kc = 0; kc < 4; kc++) {
                f32x4 acc = {0.f, 0.f, 0.f, 0.f};
                acc = __builtin_amdgcn_mfma_f32_16x16x32_bf16(a0, cb0[kc], acc, 0, 0, 0);
                acc = __builtin_amdgcn_mfma_f32_16x16x32_bf16(a1, cb1[kc], acc, 0, 0, 0);
                accs[kc] = acc;
            }
            const unsigned short* np = Kbb + (size_t)((tile + 1) * 64 + rf) * 64 + kg * 8;
            #pragma unroll
            for (int kc = 0; kc < 4; kc++) {
                nb0[kc] = *(const short8*)(np + kc * 1024);
                nb1[kc] = *(const short8*)(np + kc * 1024 + 32);
            }
            const int s0 = tile << 6;
            #pragma unroll
            for (int r = 0; r < 4; r++) {
                float sv[4];
                #pragma unroll
                for (int kc = 0; kc < 4; kc++) sv[kc] = accs[kc][r] * SCALE;
                #pragma unroll
                for (int kc = 0; kc < 4; kc++) {
                    unsigned u = __float_as_uint(sv[kc]);
                    unsigned key = u ^ ((unsigned)(((int)u) >> 31) | 0x80000000u);
                    unsigned c = (key & 0xFFFFFC00u) | (unsigned)(s0 + kc * 16 + rf);
                    unsigned n;
                    n = t_[r][0] > c ? t_[r][0] : c;  c = t_[r][0] > c ? c : t_[r][0];  t_[r][0] = n;
                    n = t_[r][1] > c ? t_[r][1] : c;  c = t_[r][1] > c ? c : t_[r][1];  t_[r][1] = n;
                    n = t_[r][2] > c ? t_[r][2] : c;  c = t_[r][2] > c ? c : t_[r][2];  t_[r][2] = n;
                    t_[r][3] = t_[r][3] > c ? t_[r][3] : c;
                }
                float tm = fmaxf(fmaxf(sv[0], sv[1]), fmaxf(sv[2], sv[3]));
                float nm = fmaxf(m_[r], tm);
                float zz = Z_[r] * __expf(m_[r] - nm);
                #pragma unroll
                for (int kc = 0; kc < 4; kc++) zz += __expf(sv[kc] - nm);
                Z_[r] = zz; m_[r] = nm;
            }
        };

        int tile = 0;
        for (; tile + 1 < qb; tile += 2) {
            body(cA0, cA1, cB0, cB1, tile);
            body(cB0, cB1, cA0, cA1, tile + 1);
        }
        if (tile < qb) {
            body(cA0, cA1, cB0, cB1, tile);
            #pragma unroll
            for (int kc = 0; kc < 4; kc++) { cA0[kc] = cB0[kc]; cA1[kc] = cB1[kc]; }
        }

        {
            f32x4 accs[4];
            #pragma unroll
            for (int kc = 0; kc < 4; kc++) {
                f32x4 acc = {0.f, 0.f, 0.f, 0.f};
                acc = __builtin_amdgcn_mfma_f32_16x16x32_bf16(a0, cA0[kc], acc, 0, 0, 0);
                acc = __builtin_amdgcn_mfma_f32_16x16x32_bf16(a1, cA1[kc], acc, 0, 0, 0);
                accs[kc] = acc;
            }
            const int s0 = qb << 6;
            #pragma unroll
            for (int r = 0; r < 4; r++) {
                const int trow = q0 + kg * 4 + r;
                float sv[4];
                unsigned pk[4];
                #pragma unroll
                for (int kc = 0; kc < 4; kc++) {
                    int k = s0 + kc * 16 + rf;
                    bool ok = (k <= trow);
                    float s = accs[kc][r] * SCALE;
                    sv[kc] = ok ? s : -INFINITY;
                    unsigned u = __float_as_uint(s);
                    unsigned key = u ^ ((unsigned)(((int)u) >> 31) | 0x80000000u);
                    unsigned c = (key & 0xFFFFFC00u) | (unsigned)k;
                    pk[kc] = ok ? c : 0u;
                }
                #pragma unroll
                for (int kc = 0; kc < 4; kc++) {
                    unsigned c = pk[kc], n;
                    n = t_[r][0] > c ? t_[r][0] : c;  c = t_[r][0] > c ? c : t_[r][0];  t_[r][0] = n;
                    n = t_[r][1] > c ? t_[r][1] : c;  c = t_[r][1] > c ? c : t_[r][1];  t_[r][1] = n;
                    n = t_[r][2] > c ? t_[r][2] : c;  c = t_[r][2] > c ? c : t_[r][2];  t_[r][2] = n;
                    t_[r][3] = t_[r][3] > c ? t_[r][3] : c;
                }
                float tm = fmaxf(fmaxf(sv[0], sv[1]), fmaxf(sv[2], sv[3]));
                float nm = fmaxf(m_[r], tm);
                float zz = Z_[r] * __expf(m_[r] - nm);
                #pragma unroll
                for (int kc = 0; kc < 4; kc++) zz += __expf(sv[kc] - nm);
                Z_[r] = zz; m_[r] = nm;
            }
        }

        #pragma unroll 1
        for (int r = 0; r < 4; r++) {
            const int q = q0 + kg * 4 + r;
            float m = m_[r], Z = Z_[r];
            #pragma unroll
            for (int off = 1; off < 16; off <<= 1) {
                float om = __shfl_xor(m, off);
                float oz = __shfl_xor(Z, off);
                float nm = fmaxf(m, om);
                Z = Z * __expf(m - nm) + oz * __expf(om - nm);
                m = nm;
            }
            unsigned l0 = t_[r][0], l1 = t_[r][1], l2 = t_[r][2], l3 = t_[r][3];
            unsigned ck[8];
            #pragma unroll
            for (int rd = 0; rd < 8; rd++) {
                unsigned v = l0;
                #pragma unroll
                for (int off = 1; off < 16; off <<= 1) {
                    unsigned ov = (unsigned)__shfl_xor((int)v, off);
                    v = v > ov ? v : ov;
                }
                ck[rd] = v;
                bool own = (l0 == v);
                l0 = own ? l1 : l0;
                l1 = own ? l2 : l1;
                l2 = own ? l3 : l2;
                l3 = own ? 0u : l3;
            }
            const float4 qv = *(const float4*)(Qr + (rowbase + q) * 64 + rf * 4);
            float sc[8]; int ci[8];
            #pragma unroll
            for (int c = 0; c < 8; c++) {
                bool valid = (ck[c] != 0u);
                int idx = (int)(ck[c] & 1023u);
                int lidx = valid ? idx : 0;
                const float4 kv = *(const float4*)(Kr + (rowbase + lidx) * 64 + rf * 4);
                float p = qv.x * kv.x + qv.y * kv.y + qv.z * kv.z + qv.w * kv.w;
                #pragma unroll
                for (int off = 1; off < 16; off <<= 1) p += __shfl_xor(p, off);
                sc[c] = valid ? p * SCALE : -1e30f;
                ci[c] = valid ? idx : -1;
            }
            float bv[4]; int bi[4];
            #pragma unroll
            for (int rd = 0; rd < 4; rd++) {
                float v = sc[0]; int id = ci[0];
                #pragma unroll
                for (int c = 1; c < 8; c++) {
                    bool take = (sc[c] > v) || ((sc[c] == v) && ((unsigned)ci[c] < (unsigned)id));
                    v = take ? sc[c] : v; id = take ? ci[c] : id;
                }
                bv[rd] = v; bi[rd] = id;
                #pragma unroll
                for (int c = 0; c < 8; c++) {
                    bool kill = (ci[c] == id) && (sc[c] == v);
                    sc[c] = kill ? -3e30f : sc[c];
                }
            }
            float mf = fmaxf(m, sk);
            float Zf = Z * __expf(m - mf) + __expf(sk - mf);
            float e0 = __expf(bv[0] - mf), e1 = __expf(bv[1] - mf);
            float e2 = __expf(bv[2] - mf), e3 = __expf(bv[3] - mf);
            float wsum = e0 + e1 + e2 + e3 + Zf * 1e-9f;
            float w0 = e0 / wsum, w1 = e1 / wsum, w2 = e2 / wsum, w3 = e3 / wsum;
            int i0 = bi[0] < 0 ? 0 : bi[0];
            int i1 = bi[1] < 0 ? 0 : bi[1];
            int i2 = bi[2] < 0 ? 0 : bi[2];
            int i3 = bi[3] < 0 ? 0 : bi[3];
            const float4 k0 = *(const float4*)(Kr + (rowbase + i0) * 64 + rf * 4);
            const float4 k1 = *(const float4*)(Kr + (rowbase + i1) * 64 + rf * 4);
            const float4 k2 = *(const float4*)(Kr + (rowbase + i2) * 64 + rf * 4);
            const float4 k3 = *(const float4*)(Kr + (rowbase + i3) * 64 + rf * 4);
            float mx = w0 * k0.x + w1 * k1.x + w2 * k2.x + w3 * k3.x;
            float my = w0 * k0.y + w1 * k1.y + w2 * k2.y + w3 * k3.y;
            float mz = w0 * k0.z + w1 * k1.z + w2 * k2.z + w3 * k3.z;
            float mw = w0 * k0.w + w1 * k1.w + w2 * k2.w + w3 * k3.w;
            ushort4 mo;
            mo.x = f2bf(mx); mo.y = f2bf(my); mo.z = f2bf(mz); mo.w = f2bf(mw);
            *(ushort4*)(markerb + (rowbase + q) * 64 + rf * 4) = mo;
            if (rf == 0) psink[rowbase + q] = __expf(sk - mf) / Zf;
        }
    }
}

// ---------------------------------------------------------------------------
__global__ void cvt_bf16_kernel(const float* __restrict__ in,
                                unsigned short* __restrict__ out, int n4)
{
    int i = blockIdx.x * 256 + threadIdx.x;
    if (i < n4) {
        float4 v = ((const float4*)in)[i];
        ushort4 o;
        o.x = f2bf(v.x); o.y = f2bf(v.y); o.z = f2bf(v.z); o.w = f2bf(v.w);
        ((ushort4*)out)[i] = o;
    }
}

// ---------------------------------------------------------------------------
__global__ __launch_bounds__(256) void wo_transpose_kernel(
    const float* __restrict__ WOw, unsigned short* __restrict__ WOt)
{
    __shared__ float tl[64][65];
    int tid = threadIdx.x;
    int n = blockIdx.z;
    int c0 = blockIdx.x * 64, d0 = blockIdx.y * 64;
    const float* src = WOw + (size_t)n * 768 * 768;
    for (int l = tid; l < 64 * 16; l += 256) {
        int r = l >> 4, q = l & 15;
        float4 v = *(const float4*)(src + (size_t)(c0 + r) * 768 + d0 + q * 4);
        tl[r][q * 4 + 0] = v.x; tl[r][q * 4 + 1] = v.y;
        tl[r][q * 4 + 2] = v.z; tl[r][q * 4 + 3] = v.w;
    }
    __syncthreads();
    for (int l = tid; l < 64 * 16; l += 256) {
        int d = l >> 4, q = l & 15;
        ushort4 o;
        o.x = f2bf(tl[q * 4 + 0][d]); o.y = f2bf(tl[q * 4 + 1][d]);
        o.z = f2bf(tl[q * 4 + 2][d]); o.w = f2bf(tl[q * 4 + 3][d]);
        *(ushort4*)(WOt + (size_t)n * 768 * 768 + (size_t)(d0 + d) * 768 + c0 + q * 4) = o;
    }
}

// ---------------------------------------------------------------------------
__global__ __launch_bounds__(256) void mlp_mfma_kernel(
    const unsigned short* __restrict__ markerb, const float* __restrict__ psink,
    const unsigned short* __restrict__ V1b16, const float* __restrict__ V1bias,
    const unsigned short* __restrict__ V2b16, const float* __restrict__ V2bias,
    const float* __restrict__ vnulls, unsigned short* __restrict__ ctxb)
{
    __shared__ float h_lds[4][16][65];
    int tid = threadIdx.x;
    int w = tid >> 6, lane = tid & 63;
    int rf = lane & 15, kg = lane >> 4;
    size_t r0 = (size_t)blockIdx.x * 64 + 16 * w;

    short8 a1[2];
    #pragma unroll
    for (int kk = 0; kk < 2; kk++)
        a1[kk] = *(const short8*)(markerb + (r0 + rf) * 64 + kk * 32 + kg * 8);

    f32x4 acc2[4] = {};
    for (int ch = 0; ch < 4; ch++) {
        f32x4 acc1[4] = {};
        #pragma unroll
        for (int nj = 0; nj < 4; nj++)
            #pragma unroll
            for (int kk = 0; kk < 2; kk++) {
                short8 b1 = *(const short8*)(V1b16 + (size_t)(ch * 64 + nj * 16 + rf) * 64 + kk * 32 + kg * 8);
                acc1[nj] = __builtin_amdgcn_mfma_f32_16x16x32_bf16(a1[kk], b1, acc1[nj], 0, 0, 0);
            }
        __syncthreads();
        #pragma unroll
        for (int nj = 0; nj < 4; nj++) {
            float bb = V1bias[ch * 64 + nj * 16 + rf];
            #pragma unroll
            for (int r = 0; r < 4; r++) {
                float x = acc1[nj][r] + bb;
                h_lds[w][kg * 4 + r][nj * 16 + rf] = gelu_f(x);
            }
        }
        __syncthreads();
        #pragma unroll
        for (int kk = 0; kk < 2; kk++) {
            const float* hp = &h_lds[w][rf][kk * 32 + kg * 8];
            float4 p0 = *(const float4*)hp;
            float4 p1 = *(const float4*)(hp + 4);
            short8 a2;
            a2[0] = (short)f2bf(p0.x); a2[1] = (short)f2bf(p0.y);
            a2[2] = (short)f2bf(p0.z); a2[3] = (short)f2bf(p0.w);
            a2[4] = (short)f2bf(p1.x); a2[5] = (short)f2bf(p1.y);
            a2[6] = (short)f2bf(p1.z); a2[7] = (short)f2bf(p1.w);
            #pragma unroll
            for (int njo = 0; njo < 4; njo++) {
                short8 b2 = *(const short8*)(V2b16 + (size_t)(njo * 16 + rf) * 256 + ch * 64 + kk * 32 + kg * 8);
                acc2[njo] = __builtin_amdgcn_mfma_f32_16x16x32_bf16(a2, b2, acc2[njo], 0, 0, 0);
            }
        }
    }
    #pragma unroll
    for (int r = 0; r < 4; r++) {
        size_t R = r0 + kg * 4 + r;
        int bh = (int)(R >> 10), t = (int)(R & 1023);
        int b = bh / 48, h = bh % 48;
        int n = h / 12, head = h % 12;
        float ps = psink[R];
        size_t base = ((size_t)((b * 4 + n) * 1024 + t)) * 768 + head * 64;
        #pragma unroll
        for (int njo = 0; njo < 4; njo++) {
            int d = njo * 16 + rf;
            float v = acc2[njo][r] + V2bias[d] + ps * vnulls[h * 64 + d];
            ctxb[base + d] = f2bf(v);
        }
    }
}

// ---------------------------------------------------------------------------
__global__ __launch_bounds__(256) void gemm_wo_mfma(
    const unsigned short* __restrict__ ctxb, const unsigned short* __restrict__ WOtb,
    const float* __restrict__ WOb, float* __restrict__ Out)
{
    __shared__ unsigned short sA[64 * 64];
    __shared__ unsigned short sB[64 * 64];
    int tid = threadIdx.x;
    int w = tid >> 6, lane = tid & 63;
    int wm = w >> 1, wn = w & 1;
    int rf = lane & 15, kg = lane >> 4;
    int m0 = blockIdx.x * 64, n0 = blockIdx.y * 64;
    int b = m0 >> 10, t0 = m0 & 1023;
    int c0 = tid * 2, c1 = tid * 2 + 1;
    int ra = c0 >> 3, ca = c0 & 7, rb = c1 >> 3, cb = c1 & 7;
    f32x4 acc[2][2] = {};
    for (int n = 0; n < 4; n++) {
        const unsigned short* Ab = ctxb + ((size_t)((b * 4 + n) * 1024 + t0)) * 768;
        const unsigned short* Bb = WOtb + (size_t)n * 768 * 768 + (size_t)n0 * 768;
        for (int k0 = 0; k0 < 768; k0 += 64) {
            __syncthreads();
            *(short8*)&sA[ra * 64 + ((ca ^ (ra & 7)) * 8)] = *(const short8*)(Ab + (size_t)ra * 768 + k0 + ca * 8);
            *(short8*)&sA[rb * 64 + ((cb ^ (rb & 7)) * 8)] = *(const short8*)(Ab + (size_t)rb * 768 + k0 + cb * 8);
            *(short8*)&sB[ra * 64 + ((ca ^ (ra & 7)) * 8)] = *(const short8*)(Bb + (size_t)ra * 768 + k0 + ca * 8);
            *(short8*)&sB[rb * 64 + ((cb ^ (rb & 7)) * 8)] = *(const short8*)(Bb + (size_t)rb * 768 + k0 + cb * 8);
            __syncthreads();
            #pragma unroll
            for (int kk = 0; kk < 2; kk++) {
                int kc = kk * 4 + kg;
                int rA0 = wm * 32 + rf, rA1 = wm * 32 + 16 + rf;
                int rB0 = wn * 32 + rf, rB1 = wn * 32 + 16 + rf;
                short8 a0v = *(const short8*)&sA[rA0 * 64 + ((kc ^ (rA0 & 7)) * 8)];
                short8 a1v = *(const short8*)&sA[rA1 * 64 + ((kc ^ (rA1 & 7)) * 8)];
                short8 b0v = *(const short8*)&sB[rB0 * 64 + ((kc ^ (rB0 & 7)) * 8)];
                short8 b1v = *(const short8*)&sB[rB1 * 64 + ((kc ^ (rB1 & 7)) * 8)];
                acc[0][0] = __builtin_amdgcn_mfma_f32_16x16x32_bf16(a0v, b0v, acc[0][0], 0, 0, 0);
                acc[0][1] = __builtin_amdgcn_mfma_f32_16x16x32_bf16(a0v, b1v, acc[0][1], 0, 0, 0);
                acc[1][0] = __builtin_amdgcn_mfma_f32_16x16x32_bf16(a1v, b0v, acc[1][0], 0, 0, 0);
                acc[1][1] = __builtin_amdgcn_mfma_f32_16x16x32_bf16(a1v, b1v, acc[1][1], 0, 0, 0);
            }
        }
    }
    #pragma unroll
    for (int nj = 0; nj < 2; nj++) {
        int col = n0 + wn * 32 + nj * 16 + rf;
        float bm = WOb[col] + WOb[768 + col] + WOb[1536 + col] + WOb[2304 + col];
        #pragma unroll
        for (int mi = 0; mi < 2; mi++)
            #pragma unroll
            for (int r = 0; r < 4; r++) {
                int row = m0 + wm * 32 + mi * 16 + kg * 4 + r;
                Out[(size_t)row * 768 + col] = 0.25f * (acc[mi][nj][r] + bm);
            }
    }
}

// ---------------------------------------------------------------------------
extern "C" void kernel_launch(void* const* d_in, const int* in_sizes, int n_in,
                              void* d_out, int out_size, void* d_ws, size_t ws_size,
                              hipStream_t stream) {
    const float* A      = (const float*)d_in[0];
    const float* X      = (const float*)d_in[1];
    const float* WKw    = (const float*)d_in[2];
    const float* WKb    = (const float*)d_in[3];
    const float* WQw    = (const float*)d_in[4];
    const float* wA     = (const float*)d_in[5];
    const float* wB     = (const float*)d_in[6];
    const float* sink   = (const float*)d_in[7];
    const float* vnulls = (const float*)d_in[8];
    const float* V1w    = (const float*)d_in[9];
    const float* V1b    = (const float*)d_in[10];
    const float* V2w    = (const float*)d_in[11];
    const float* V2b    = (const float*)d_in[12];
    const float* WOw    = (const float*)d_in[13];
    const float* WOb    = (const float*)d_in[14];
    float* out = (float*)d_out;
    (void)in_sizes; (void)n_in; (void)out_size; (void)ws_size;

    float* ws = (float*)d_ws;
    size_t off = 0;
    float* Qr   = ws + off;  off += 6291456;   // head-major fp32 Q (rope'd)
    float* Kr   = ws + off;  off += 6291456;   // head-major fp32 K (rope'd)
    float* trig = ws + off;  off += 65536;
    float* bcat = ws + off;  off += 2048;
    float* O2   = ws + off;  off += 3145728;   // [2048][1536]: y | x
    float* Wsp_f = ws + off; off += 5308416;   // 3 planes x 4608x768 ushort
    unsigned short* Wsp = (unsigned short*)Wsp_f;
    unsigned short* Asp = (unsigned short*)(ws + off); off += 2359296;  // 3 planes x 2048x768
    unsigned short* Xsp = (unsigned short*)(ws + off); off += 2359296;
    // overlays (dead-buffer reuse) — audited lifetimes:
    //   markerb = O2 (FULL 3,145,728 floats; O2 dead after k_finish)
    //   Kb16 = Wsp floats [0, 3145728); psink = Wsp floats [3145728, 3244032)
    unsigned short* markerb = (unsigned short*)O2;
    unsigned short* Kb16 = Wsp;
    float* psink = Wsp_f + 3145728;
    unsigned short* V1b16 = Xsp;                         // Xsp dead after proj
    unsigned short* V2b16 = V1b16 + 16384;
    unsigned short* WOtb  = Asp;                         // Asp dead after proj
    unsigned short* ctxb  = (unsigned short*)Qr;         // Qr dead after attn

    // prep: trig + folded/split weights + split activations
    trig_kernel<<<128, 256, 0, stream>>>(trig);
    fold_split_kernel<<<dim3(48, 6), 256, 0, stream>>>(WQw, wA, wB, Wsp, 0);
    fold_split_kernel<<<dim3(12, 6), 256, 0, stream>>>(WKw, wA, wB, Wsp, 1);
    kbias_kernel<<<6, 256, 0, stream>>>(WKb, wA, bcat);
    split_act_kernel<<<1536, 256, 0, stream>>>(A, X, Asp, Xsp);
    // split-precision MFMA projection, async global_load_lds staging
    proj_mfma_kernel<<<576, 512, 0, stream>>>(Asp, Xsp, Wsp, bcat, trig, Qr, O2);
    // finish K: per-h bias wedge term + rope -> Kr fp32 + Kb16 bf16
    k_finish_kernel<<<3072, 256, 0, stream>>>(O2, trig, wB, Kr, Kb16);
    // attention: MFMA scores, packed-key shortlist, exact fp32 top-4
    attn_mfma_topk_kernel<<<dim3(96, 8), 256, 0, stream>>>(Qr, Kr, Kb16, sink, markerb, psink);
    // post-top-k smooth path (bf16/MFMA)
    cvt_bf16_kernel<<<16, 256, 0, stream>>>(V1w, V1b16, 4096);
    cvt_bf16_kernel<<<16, 256, 0, stream>>>(V2w, V2b16, 4096);
    wo_transpose_kernel<<<dim3(12, 12, 4), 256, 0, stream>>>(WOw, WOtb);
    mlp_mfma_kernel<<<1536, 256, 0, stream>>>(markerb, psink, V1b16, V1b, V2b16, V2b, vnulls, ctxb);
    gemm_wo_mfma<<<dim3(32, 12), 256, 0, stream>>>(ctxb, WOtb, WOb, out);
}

// Round 12
// 330.377 us; speedup vs baseline: 3.9294x; 1.0456x over previous
//
#include <hip/hip_runtime.h>
#include <math.h>

constexpr int Bq  = 2;
constexpr int Tq  = 1024;
constexpr int HTq = 48;
constexpr float SCALE = 0.125f;     // 64^-0.5
constexpr float EOFF = 8.0f;        // fixed softmax offset (shift-invariant)

typedef __attribute__((ext_vector_type(8))) short short8;
typedef __attribute__((ext_vector_type(4))) float f32x4;

__device__ inline unsigned short f2bf(float x) {
    unsigned u = __float_as_uint(x);
    return (unsigned short)((u + 0x7FFF + ((u >> 16) & 1)) >> 16);
}

// async global->LDS, 16B per lane; LDS dest = wave-uniform base + lane*16
__device__ inline void gload_lds16(const unsigned short* g, unsigned short* l) {
    __builtin_amdgcn_global_load_lds(
        (const __attribute__((address_space(1))) void*)g,
        (__attribute__((address_space(3))) void*)l,
        16, 0, 0);
}

// exact 3-plane bf16 split: x = p0 + p1 + p2 + O(2^-27 |x|)
__device__ inline void split3(float x, unsigned short& p0, unsigned short& p1, unsigned short& p2) {
    p0 = f2bf(x);
    float f0 = __uint_as_float((unsigned)p0 << 16);
    float r0 = x - f0;
    p1 = f2bf(r0);
    float f1 = __uint_as_float((unsigned)p1 << 16);
    float r1 = r0 - f1;
    p2 = f2bf(r1);
}

// exact-erf GELU via Abramowitz-Stegun 7.1.26 (|eps_erf| <= 1.5e-7)
__device__ inline float gelu_f(float x) {
    float z = 0.70710678118654752f * x;
    float az = fabsf(z);
    float t = __frcp_rn(1.0f + 0.3275911f * az);
    float poly = t * (0.254829592f + t * (-0.284496736f + t * (1.421413741f
               + t * (-1.453152027f + t * 1.061405429f))));
    float er = 1.0f - poly * __expf(-az * az);
    er = (z < 0.0f) ? -er : er;
    return 0.5f * x * (1.0f + er);
}

// ---------------------------------------------------------------------------
// trig table (cos @ [t*32+i], sin @ [32768+...]) + K-bias fold in one launch.
// ---------------------------------------------------------------------------
__global__ void trig_kbias_kernel(float* __restrict__ trig,
                                  const float* __restrict__ WKb,
                                  const float* __restrict__ wA,
                                  float* __restrict__ bcat) {
    int i = blockIdx.x * 256 + threadIdx.x;   // 32768
    int t = i >> 5, f = i & 31;
    float invf = powf(10000.0f, -(float)f * (1.0f / 32.0f));
    float ang = (float)t * invf;
    trig[i] = cosf(ang);
    trig[32768 + i] = sinf(ang);
    if (i < 768) {
        int hb = i >> 6, el = i & 63;
        float acc = 0.0f;
        for (int d = 0; d < 64; d++) {
            float sk = wA[d * 64 + el] - wA[el * 64 + d];
            acc += WKb[hb * 64 + d] * sk;
        }
        bcat[i] = WKb[i] + acc;
    } else if (i < 1536) {
        bcat[i] = WKb[i - 768];
    }
}

// ---------------------------------------------------------------------------
// Weight fold + 3-plane split, merged Q+K launch.  skew = wA - wA^T.
// blocks [0,48): Q mode; blocks [48,60): K mode (+ raw copy rows).
// ---------------------------------------------------------------------------
__global__ __launch_bounds__(256) void fold_split_kernel(
    const float* __restrict__ WQw, const float* __restrict__ WKw,
    const float* __restrict__ wA, const float* __restrict__ wbias,
    unsigned short* __restrict__ Wsp)
{
    const size_t WPL = (size_t)4608 * 768;
    __shared__ float sw[64][132];
    __shared__ float sk[64][65];
    int hb_ = blockIdx.x;
    int mode = (hb_ < 48) ? 0 : 1;
    int h = mode ? hb_ - 48 : hb_;
    const float* Wsrc = mode ? WKw : WQw;
    int cb = blockIdx.y;
    int tid = threadIdx.x;
    const float* Wh = Wsrc + (size_t)h * 64 * 768 + cb * 128;
    for (int l = tid; l < 64 * 32; l += 256) {
        int d = l >> 5, c4 = l & 31;
        *(float4*)&sw[d][c4 * 4] = *(const float4*)(Wh + (size_t)d * 768 + c4 * 4);
    }
    for (int l = tid; l < 4096; l += 256) {
        int d = l >> 6, e = l & 63;
        sk[d][e] = wA[l] - wA[e * 64 + d];
    }
    __syncthreads();
    int tx = tid & 15, ty = tid >> 4;
    float acc4[4][8] = {};
    for (int d = 0; d < 64; d++) {
        float s0 = sk[d][ty * 4 + 0], s1 = sk[d][ty * 4 + 1];
        float s2 = sk[d][ty * 4 + 2], s3 = sk[d][ty * 4 + 3];
        float w_[8];
        *(float4*)&w_[0] = *(const float4*)&sw[d][tx * 8];
        *(float4*)&w_[4] = *(const float4*)&sw[d][tx * 8 + 4];
        #pragma unroll
        for (int j = 0; j < 8; j++) {
            acc4[0][j] += s0 * w_[j];
            acc4[1][j] += s1 * w_[j];
            acc4[2][j] += s2 * w_[j];
            acc4[3][j] += s3 * w_[j];
        }
    }
    #pragma unroll
    for (int i = 0; i < 4; i++) {
        int e = ty * 4 + i;
        float scale = (mode == 0) ? (1.0f + wbias[h * 64 + e]) : 1.0f;
        size_t row = (mode == 0) ? (size_t)(h * 64 + e) : (size_t)(3072 + h * 64 + e);
        #pragma unroll
        for (int j = 0; j < 8; j++) {
            int cl = tx * 8 + j;
            float wv = sw[e][cl] * scale + acc4[i][j];
            unsigned short p0, p1, p2;
            split3(wv, p0, p1, p2);
            size_t idx = row * 768 + cb * 128 + cl;
            Wsp[idx] = p0; Wsp[WPL + idx] = p1; Wsp[2 * WPL + idx] = p2;
        }
        if (mode == 1) {
            size_t row2 = (size_t)(3840 + h * 64 + e);
            #pragma unroll
            for (int j = 0; j < 8; j++) {
                int cl = tx * 8 + j;
                unsigned short p0, p1, p2;
                split3(sw[e][cl], p0, p1, p2);
                size_t idx = row2 * 768 + cb * 128 + cl;
                Wsp[idx] = p0; Wsp[WPL + idx] = p1; Wsp[2 * WPL + idx] = p2;
            }
        }
    }
}

// ---------------------------------------------------------------------------
__global__ void split_act_kernel(const float* __restrict__ A, const float* __restrict__ X,
                                 unsigned short* __restrict__ Asp, unsigned short* __restrict__ Xsp)
{
    const size_t APL = (size_t)2048 * 768;
    int i = blockIdx.x * 256 + threadIdx.x;   // 393216 quads
    if (i >= 393216) return;
    float4 va = ((const float4*)A)[i];
    float4 vx = ((const float4*)X)[i];
    ushort4 a0, a1, a2, x0, x1, x2;
    split3(va.x, a0.x, a1.x, a2.x); split3(va.y, a0.y, a1.y, a2.y);
    split3(va.z, a0.z, a1.z, a2.z); split3(va.w, a0.w, a1.w, a2.w);
    split3(vx.x, x0.x, x1.x, x2.x); split3(vx.y, x0.y, x1.y, x2.y);
    split3(vx.z, x0.z, x1.z, x2.z); split3(vx.w, x0.w, x1.w, x2.w);
    ((ushort4*)(Asp))[i] = a0;
    ((ushort4*)(Asp + APL))[i] = a1;
    ((ushort4*)(Asp + 2 * APL))[i] = a2;
    ((ushort4*)(Xsp))[i] = x0;
    ((ushort4*)(Xsp + APL))[i] = x1;
    ((ushort4*)(Xsp + 2 * APL))[i] = x2;
}

// ---------------------------------------------------------------------------
// Projection GEMM (round-11 verbatim): split-precision bf16 MFMA,
// async global_load_lds staging, XOR-swizzled source, linear LDS dest.
// ---------------------------------------------------------------------------
__global__ __launch_bounds__(512) void proj_mfma_kernel(
    const unsigned short* __restrict__ Asp, const unsigned short* __restrict__ Xsp,
    const unsigned short* __restrict__ Wsp, const float* __restrict__ bcat,
    const float* __restrict__ trig, float* __restrict__ Qr, float* __restrict__ O2)
{
    const size_t APL = (size_t)2048 * 768;
    const size_t WPL = (size_t)4608 * 768;
    __shared__ unsigned short sA[3 * 128 * 32];
    __shared__ unsigned short sB[3 * 128 * 32];
    int bid = blockIdx.x;
    int swz = (bid & 7) * 72 + (bid >> 3);
    int nb = swz >> 4;
    int mb = swz & 15;
    bool isQ = (nb < 24);
    const unsigned short* Ab = isQ ? Asp : Xsp;
    int m0 = mb * 128, n0 = nb * 128;
    int tid = threadIdx.x;
    int w = tid >> 6, lane = tid & 63;
    int wm = w & 1, wn = w >> 1;
    int rf = lane & 15, kg = lane >> 4;
    int mbase = m0 + wm * 64;

    int srcslot = (lane & 3) ^ ((lane >> 3) & 3);
    const unsigned short* gsrcA[3];
    const unsigned short* gsrcB[3];
    unsigned short* ldstA[3];
    unsigned short* ldstB[3];
    #pragma unroll
    for (int i = 0; i < 3; i++) {
        int reg = w + i * 8;
        int p = reg >> 3, rg = reg & 7;
        int row = rg * 16 + (lane >> 2);
        gsrcA[i] = Ab  + (size_t)p * APL + (size_t)(m0 + row) * 768 + srcslot * 8;
        gsrcB[i] = Wsp + (size_t)p * WPL + (size_t)(n0 + row) * 768 + srcslot * 8;
        ldstA[i] = &sA[p * 4096 + rg * 512];
        ldstB[i] = &sB[p * 4096 + rg * 512];
    }

    f32x4 acc[4][2] = {};
    for (int k0 = 0; k0 < 768; k0 += 32) {
        __syncthreads();
        #pragma unroll
        for (int i = 0; i < 3; i++) {
            gload_lds16(gsrcA[i] + k0, ldstA[i]);
            gload_lds16(gsrcB[i] + k0, ldstB[i]);
        }
        __syncthreads();

        short8 a0[4], a1[4], a2[4], b0[2], b1[2], b2[2];
        #pragma unroll
        for (int mi = 0; mi < 4; mi++) {
            int row = wm * 64 + mi * 16 + rf;
            a0[mi] = *(const short8*)&sA[0 * 4096 + row * 32 + ((kg ^ ((row >> 1) & 3)) * 8)];
        }
        #pragma unroll
        for (int nj = 0; nj < 2; nj++) {
            int row = wn * 32 + nj * 16 + rf;
            b0[nj] = *(const short8*)&sB[0 * 4096 + row * 32 + ((kg ^ ((row >> 1) & 3)) * 8)];
        }
        #pragma unroll
        for (int mi = 0; mi < 4; mi++)
            #pragma unroll
            for (int nj = 0; nj < 2; nj++)
                acc[mi][nj] = __builtin_amdgcn_mfma_f32_16x16x32_bf16(a0[mi], b0[nj], acc[mi][nj], 0, 0, 0);
        #pragma unroll
        for (int nj = 0; nj < 2; nj++) {
            int row = wn * 32 + nj * 16 + rf;
            b1[nj] = *(const short8*)&sB[1 * 4096 + row * 32 + ((kg ^ ((row >> 1) & 3)) * 8)];
        }
        #pragma unroll
        for (int mi = 0; mi < 4; mi++)
            #pragma unroll
            for (int nj = 0; nj < 2; nj++)
                acc[mi][nj] = __builtin_amdgcn_mfma_f32_16x16x32_bf16(a0[mi], b1[nj], acc[mi][nj], 0, 0, 0);
        #pragma unroll
        for (int nj = 0; nj < 2; nj++) {
            int row = wn * 32 + nj * 16 + rf;
            b2[nj] = *(const short8*)&sB[2 * 4096 + row * 32 + ((kg ^ ((row >> 1) & 3)) * 8)];
        }
        #pragma unroll
        for (int mi = 0; mi < 4; mi++)
            #pragma unroll
            for (int nj = 0; nj < 2; nj++)
                acc[mi][nj] = __builtin_amdgcn_mfma_f32_16x16x32_bf16(a0[mi], b2[nj], acc[mi][nj], 0, 0, 0);
        #pragma unroll
        for (int mi = 0; mi < 4; mi++) {
            int row = wm * 64 + mi * 16 + rf;
            a1[mi] = *(const short8*)&sA[1 * 4096 + row * 32 + ((kg ^ ((row >> 1) & 3)) * 8)];
        }
        #pragma unroll
        for (int mi = 0; mi < 4; mi++)
            #pragma unroll
            for (int nj = 0; nj < 2; nj++)
                acc[mi][nj] = __builtin_amdgcn_mfma_f32_16x16x32_bf16(a1[mi], b0[nj], acc[mi][nj], 0, 0, 0);
        #pragma unroll
        for (int mi = 0; mi < 4; mi++)
            #pragma unroll
            for (int nj = 0; nj < 2; nj++)
                acc[mi][nj] = __builtin_amdgcn_mfma_f32_16x16x32_bf16(a1[mi], b1[nj], acc[mi][nj], 0, 0, 0);
        #pragma unroll
        for (int mi = 0; mi < 4; mi++) {
            int row = wm * 64 + mi * 16 + rf;
            a2[mi] = *(const short8*)&sA[2 * 4096 + row * 32 + ((kg ^ ((row >> 1) & 3)) * 8)];
        }
        #pragma unroll
        for (int mi = 0; mi < 4; mi++)
            #pragma unroll
            for (int nj = 0; nj < 2; nj++)
                acc[mi][nj] = __builtin_amdgcn_mfma_f32_16x16x32_bf16(a2[mi], b0[nj], acc[mi][nj], 0, 0, 0);
    }

    if (isQ) {
        #pragma unroll
        for (int mi = 0; mi < 4; mi++) {
            #pragma unroll
            for (int r = 0; r < 4; r++) {
                int m = mbase + mi * 16 + kg * 4 + r;
                int b_ = m >> 10, t = m & 1023;
                #pragma unroll
                for (int nj = 0; nj < 2; nj++) {
                    int col_local = wn * 32 + nj * 16 + rf;
                    int h = nb * 2 + (col_local >> 6);
                    int d = col_local & 63;
                    int i = d >> 1;
                    float v = acc[mi][nj][r];
                    float pv = __shfl_xor(v, 1);
                    float c = trig[t * 32 + i];
                    float s = trig[32768 + t * 32 + i];
                    float outv = (rf & 1) ? (pv * s + v * c) : (v * c - pv * s);
                    int col = (rf & 1) ? (32 + i) : i;
                    size_t base = ((size_t)(b_ * 48 + h) * 1024 + t) * 64;
                    Qr[base + col] = outv;
                }
            }
        }
    } else {
        #pragma unroll
        for (int nj = 0; nj < 2; nj++) {
            int col = (n0 - 3072) + wn * 32 + nj * 16 + rf;
            float bv = bcat[col];
            #pragma unroll
            for (int mi = 0; mi < 4; mi++)
                #pragma unroll
                for (int r = 0; r < 4; r++) {
                    int m = mbase + mi * 16 + kg * 4 + r;
                    O2[(size_t)m * 1536 + col] = acc[mi][nj][r] + bv;
                }
        }
    }
}

// ---------------------------------------------------------------------------
__global__ void k_finish_kernel(const float* __restrict__ O2, const float* __restrict__ trig,
                                const float* __restrict__ wbias,
                                float* __restrict__ Kr, unsigned short* __restrict__ Kb16)
{
    int idx = blockIdx.x * 256 + threadIdx.x;   // 786432
    int pr = idx & 31;
    int tmp = idx >> 5;
    int hb = tmp % 12;
    int bt = tmp / 12;
    int t = bt & 1023, b = bt >> 10;
    const float* yx = O2 + (size_t)bt * 1536 + hb * 64 + pr * 2;
    float y0 = yx[0], y1 = yx[1];
    float x0 = yx[768], x1 = yx[769];
    float cv = trig[t * 32 + pr], sv = trig[32768 + t * 32 + pr];
    #pragma unroll
    for (int r = 0; r < 4; r++) {
        int h = hb + 12 * r;
        float b0 = wbias[h * 64 + 2 * pr], b1 = wbias[h * 64 + 2 * pr + 1];
        float wz0 = y0 + x0 * b0;
        float wz1 = y1 + x1 * b1;
        float lo = wz0 * cv - wz1 * sv;
        float hi = wz0 * sv + wz1 * cv;
        size_t base = ((size_t)(b * 48 + h) * 1024 + t) * 64;
        Kr[base + pr] = lo;
        Kr[base + 32 + pr] = hi;
        Kb16[base + pr] = f2bf(lo);
        Kb16[base + 32 + pr] = f2bf(hi);
    }
}

// ---------------------------------------------------------------------------
// Attention core v3: FIXED-OFFSET softmax (Z = sum exp(s-8), shift-invariant,
// no max tracking -> no serial m-chain, no rescale, no cross-lane max merge).
// Packed-key top-4 + exact fp32 re-score unchanged (order preserved under the
// positive-slope affine transform).  Diagonal peel + register prefetch +
// uniform qb pairing as in round 8.
// ---------------------------------------------------------------------------
__global__ __launch_bounds__(256) void attn_mfma_topk_kernel(
    const float* __restrict__ Qr, const float* __restrict__ Kr,
    const unsigned short* __restrict__ Kb, const float* __restrict__ sink,
    unsigned short* __restrict__ markerb, float* __restrict__ psink)
{
    const int bh = blockIdx.x;                 // 0..95
    const int y  = blockIdx.y;                 // 0..7
    const int w = threadIdx.x >> 6, lane = threadIdx.x & 63;
    const int rf = lane & 15, kg = lane >> 4;
    const int h = bh % HTq;
    const size_t rowbase = (size_t)bh * Tq;
    const unsigned short* Kbb = Kb + rowbase * 64;
    const float sk = sink[h];

    #pragma unroll 1
    for (int g = 0; g < 2; g++) {
        const int qb = g ? y : 15 - y;
        const int q0 = qb * 64 + w * 16;

        short8 a0, a1;
        {
            const float* qp = Qr + (rowbase + q0 + rf) * 64 + kg * 8;
            float4 u0 = *(const float4*)qp;
            float4 u1 = *(const float4*)(qp + 4);
            float4 u2 = *(const float4*)(qp + 32);
            float4 u3 = *(const float4*)(qp + 36);
            a0[0]=(short)f2bf(u0.x); a0[1]=(short)f2bf(u0.y); a0[2]=(short)f2bf(u0.z); a0[3]=(short)f2bf(u0.w);
            a0[4]=(short)f2bf(u1.x); a0[5]=(short)f2bf(u1.y); a0[6]=(short)f2bf(u1.z); a0[7]=(short)f2bf(u1.w);
            a1[0]=(short)f2bf(u2.x); a1[1]=(short)f2bf(u2.y); a1[2]=(short)f2bf(u2.z); a1[3]=(short)f2bf(u2.w);
            a1[4]=(short)f2bf(u3.x); a1[5]=(short)f2bf(u3.y); a1[6]=(short)f2bf(u3.z); a1[7]=(short)f2bf(u3.w);
        }

        float Z_[4];
        unsigned t_[4][4];
        #pragma unroll
        for (int r = 0; r < 4; r++) {
            Z_[r] = 0.0f;
            t_[r][0] = 0u; t_[r][1] = 0u; t_[r][2] = 0u; t_[r][3] = 0u;
        }

        short8 cA0[4], cA1[4], cB0[4], cB1[4];
        {
            const unsigned short* p = Kbb + (size_t)rf * 64 + kg * 8;
            #pragma unroll
            for (int kc = 0; kc < 4; kc++) {
                cA0[kc] = *(const short8*)(p + kc * 1024);
                cA1[kc] = *(const short8*)(p + kc * 1024 + 32);
            }
        }

        auto body = [&](short8 (&cb0)[4], short8 (&cb1)[4],
                        short8 (&nb0)[4], short8 (&nb1)[4], int tile) {
            f32x4 accs[4];
            #pragma unroll
            for (int kc = 0; kc < 4; kc++) {
                f32x4 acc = {0.f, 0.f, 0.f, 0.f};
                acc = __builtin_amdgcn_mfma_f32_16x16x32_bf16(a0, cb0[kc], acc, 0, 0, 0);
                acc = __builtin_amdgcn_mfma_f32_16x16x32_bf16(a1, cb1[kc], acc, 0, 0, 0);
                accs[kc] = acc;
            }
            const unsigned short* np = Kbb + (size_t)((tile + 1) * 64 + rf) * 64 + kg * 8;
            #pragma unroll
            for (int kc = 0; kc < 4; kc++) {
                nb0[kc] = *(const short8*)(np + kc * 1024);
                nb1[kc] = *(const short8*)(np + kc * 1024 + 32);
            }
            const int s0 = tile << 6;
            #pragma unroll
            for (int r = 0; r < 4; r++) {
                float s8[4];
                #pragma unroll
                for (int kc = 0; kc < 4; kc++) s8[kc] = fmaf(accs[kc][r], SCALE, -EOFF);
                #pragma unroll
                for (int kc = 0; kc < 4; kc++) {
                    unsigned u = __float_as_uint(s8[kc]);
                    unsigned key = u ^ ((unsigned)(((int)u) >> 31) | 0x80000000u);
                    unsigned c = (key & 0xFFFFFC00u) | (unsigned)(s0 + kc * 16 + rf);
                    unsigned n;
                    n = t_[r][0] > c ? t_[r][0] : c;  c = t_[r][0] > c ? c : t_[r][0];  t_[r][0] = n;
                    n = t_[r][1] > c ? t_[r][1] : c;  c = t_[r][1] > c ? c : t_[r][1];  t_[r][1] = n;
                    n = t_[r][2] > c ? t_[r][2] : c;  c = t_[r][2] > c ? c : t_[r][2];  t_[r][2] = n;
                    t_[r][3] = t_[r][3] > c ? t_[r][3] : c;
                }
                float e0 = __expf(s8[0]), e1 = __expf(s8[1]);
                float e2 = __expf(s8[2]), e3 = __expf(s8[3]);
                Z_[r] += (e0 + e1) + (e2 + e3);
            }
        };

        int tile = 0;
        for (; tile + 1 < qb; tile += 2) {
            body(cA0, cA1, cB0, cB1, tile);
            body(cB0, cB1, cA0, cA1, tile + 1);
        }
        if (tile < qb) {
            body(cA0, cA1, cB0, cB1, tile);
            #pragma unroll
            for (int kc = 0; kc < 4; kc++) { cA0[kc] = cB0[kc]; cA1[kc] = cB1[kc]; }
        }

        // diagonal tile, masked
        {
            f32x4 accs[4];
            #pragma unroll
            for (int kc = 0; kc < 4; kc++) {
                f32x4 acc = {0.f, 0.f, 0.f, 0.f};
                acc = __builtin_amdgcn_mfma_f32_16x16x32_bf16(a0, cA0[kc], acc, 0, 0, 0);
                acc = __builtin_amdgcn_mfma_f32_16x16x32_bf16(a1, cA1[kc], acc, 0, 0, 0);
                accs[kc] = acc;
            }
            const int s0 = qb << 6;
            #pragma unroll
            for (int r = 0; r < 4; r++) {
                const int trow = q0 + kg * 4 + r;
                float ev[4];
                #pragma unroll
                for (int kc = 0; kc < 4; kc++) {
                    int k = s0 + kc * 16 + rf;
                    bool ok = (k <= trow);
                    float s8 = fmaf(accs[kc][r], SCALE, -EOFF);
                    unsigned u = __float_as_uint(s8);
                    unsigned key = u ^ ((unsigned)(((int)u) >> 31) | 0x80000000u);
                    unsigned c = (key & 0xFFFFFC00u) | (unsigned)k;
                    c = ok ? c : 0u;
                    unsigned n;
                    n = t_[r][0] > c ? t_[r][0] : c;  c = t_[r][0] > c ? c : t_[r][0];  t_[r][0] = n;
                    n = t_[r][1] > c ? t_[r][1] : c;  c = t_[r][1] > c ? c : t_[r][1];  t_[r][1] = n;
                    n = t_[r][2] > c ? t_[r][2] : c;  c = t_[r][2] > c ? c : t_[r][2];  t_[r][2] = n;
                    t_[r][3] = t_[r][3] > c ? t_[r][3] : c;
                    ev[kc] = ok ? __expf(s8) : 0.0f;
                }
                Z_[r] += (ev[0] + ev[1]) + (ev[2] + ev[3]);
            }
        }

        const float esk = __expf(sk - EOFF);
        #pragma unroll 1
        for (int r = 0; r < 4; r++) {
            const int q = q0 + kg * 4 + r;
            float Z = Z_[r];
            #pragma unroll
            for (int off = 1; off < 16; off <<= 1) Z += __shfl_xor(Z, off);
            float Zf = Z + esk;
            // merge 16 per-lane packed top-4 -> top-8 shortlist
            unsigned l0 = t_[r][0], l1 = t_[r][1], l2 = t_[r][2], l3 = t_[r][3];
            unsigned ck[8];
            #pragma unroll
            for (int rd = 0; rd < 8; rd++) {
                unsigned v = l0;
                #pragma unroll
                for (int off = 1; off < 16; off <<= 1) {
                    unsigned ov = (unsigned)__shfl_xor((int)v, off);
                    v = v > ov ? v : ov;
                }
                ck[rd] = v;
                bool own = (l0 == v);
                l0 = own ? l1 : l0;
                l1 = own ? l2 : l1;
                l2 = own ? l3 : l2;
                l3 = own ? 0u : l3;
            }
            // exact fp32 re-score of shortlist
            const float4 qv = *(const float4*)(Qr + (rowbase + q) * 64 + rf * 4);
            float sc[8]; int ci[8];
            #pragma unroll
            for (int c = 0; c < 8; c++) {
                bool valid = (ck[c] != 0u);
                int idx = (int)(ck[c] & 1023u);
                int lidx = valid ? idx : 0;
                const float4 kv = *(const float4*)(Kr + (rowbase + lidx) * 64 + rf * 4);
                float p = qv.x * kv.x + qv.y * kv.y + qv.z * kv.z + qv.w * kv.w;
                #pragma unroll
                for (int off = 1; off < 16; off <<= 1) p += __shfl_xor(p, off);
                sc[c] = valid ? p * SCALE : -1e30f;
                ci[c] = valid ? idx : -1;
            }
            // stable top-4 of the 8 exact scores (value desc, index asc)
            float bv[4]; int bi[4];
            #pragma unroll
            for (int rd = 0; rd < 4; rd++) {
                float v = sc[0]; int id = ci[0];
                #pragma unroll
                for (int c = 1; c < 8; c++) {
                    bool take = (sc[c] > v) || ((sc[c] == v) && ((unsigned)ci[c] < (unsigned)id));
                    v = take ? sc[c] : v; id = take ? ci[c] : id;
                }
                bv[rd] = v; bi[rd] = id;
                #pragma unroll
                for (int c = 0; c < 8; c++) {
                    bool kill = (ci[c] == id) && (sc[c] == v);
                    sc[c] = kill ? -3e30f : sc[c];
                }
            }
            float e0 = __expf(bv[0] - EOFF), e1 = __expf(bv[1] - EOFF);
            float e2 = __expf(bv[2] - EOFF), e3 = __expf(bv[3] - EOFF);
            float wsum = e0 + e1 + e2 + e3 + Zf * 1e-9f;
            float w0 = e0 / wsum, w1 = e1 / wsum, w2 = e2 / wsum, w3 = e3 / wsum;
            int i0 = bi[0] < 0 ? 0 : bi[0];
            int i1 = bi[1] < 0 ? 0 : bi[1];
            int i2 = bi[2] < 0 ? 0 : bi[2];
            int i3 = bi[3] < 0 ? 0 : bi[3];
            const float4 k0 = *(const float4*)(Kr + (rowbase + i0) * 64 + rf * 4);
            const float4 k1 = *(const float4*)(Kr + (rowbase + i1) * 64 + rf * 4);
            const float4 k2 = *(const float4*)(Kr + (rowbase + i2) * 64 + rf * 4);
            const float4 k3 = *(const float4*)(Kr + (rowbase + i3) * 64 + rf * 4);
            float mx = w0 * k0.x + w1 * k1.x + w2 * k2.x + w3 * k3.x;
            float my = w0 * k0.y + w1 * k1.y + w2 * k2.y + w3 * k3.y;
            float mz = w0 * k0.z + w1 * k1.z + w2 * k2.z + w3 * k3.z;
            float mw = w0 * k0.w + w1 * k1.w + w2 * k2.w + w3 * k3.w;
            ushort4 mo;
            mo.x = f2bf(mx); mo.y = f2bf(my); mo.z = f2bf(mz); mo.w = f2bf(mw);
            *(ushort4*)(markerb + (rowbase + q) * 64 + rf * 4) = mo;
            if (rf == 0) psink[rowbase + q] = esk / Zf;
        }
    }
}

// ---------------------------------------------------------------------------
// merged V1+V2 bf16 conversion (V1b16 and V2b16 contiguous)
// ---------------------------------------------------------------------------
__global__ void cvt_bf16_kernel(const float* __restrict__ V1w, const float* __restrict__ V2w,
                                unsigned short* __restrict__ outb)
{
    int i = blockIdx.x * 256 + threadIdx.x;   // 8192 quads
    if (i >= 8192) return;
    float4 v = (i < 4096) ? ((const float4*)V1w)[i] : ((const float4*)V2w)[i - 4096];
    ushort4 o;
    o.x = f2bf(v.x); o.y = f2bf(v.y); o.z = f2bf(v.z); o.w = f2bf(v.w);
    ((ushort4*)outb)[i] = o;
}

// ---------------------------------------------------------------------------
__global__ __launch_bounds__(256) void wo_transpose_kernel(
    const float* __restrict__ WOw, unsigned short* __restrict__ WOt)
{
    __shared__ float tl[64][65];
    int tid = threadIdx.x;
    int n = blockIdx.z;
    int c0 = blockIdx.x * 64, d0 = blockIdx.y * 64;
    const float* src = WOw + (size_t)n * 768 * 768;
    for (int l = tid; l < 64 * 16; l += 256) {
        int r = l >> 4, q = l & 15;
        float4 v = *(const float4*)(src + (size_t)(c0 + r) * 768 + d0 + q * 4);
        tl[r][q * 4 + 0] = v.x; tl[r][q * 4 + 1] = v.y;
        tl[r][q * 4 + 2] = v.z; tl[r][q * 4 + 3] = v.w;
    }
    __syncthreads();
    for (int l = tid; l < 64 * 16; l += 256) {
        int d = l >> 4, q = l & 15;
        ushort4 o;
        o.x = f2bf(tl[q * 4 + 0][d]); o.y = f2bf(tl[q * 4 + 1][d]);
        o.z = f2bf(tl[q * 4 + 2][d]); o.w = f2bf(tl[q * 4 + 3][d]);
        *(ushort4*)(WOt + (size_t)n * 768 * 768 + (size_t)(d0 + d) * 768 + c0 + q * 4) = o;
    }
}

// ---------------------------------------------------------------------------
__global__ __launch_bounds__(256) void mlp_mfma_kernel(
    const unsigned short* __restrict__ markerb, const float* __restrict__ psink,
    const unsigned short* __restrict__ V1b16, const float* __restrict__ V1bias,
    const unsigned short* __restrict__ V2b16, const float* __restrict__ V2bias,
    const float* __restrict__ vnulls, unsigned short* __restrict__ ctxb)
{
    __shared__ float h_lds[4][16][65];
    int tid = threadIdx.x;
    int w = tid >> 6, lane = tid & 63;
    int rf = lane & 15, kg = lane >> 4;
    size_t r0 = (size_t)blockIdx.x * 64 + 16 * w;

    short8 a1[2];
    #pragma unroll
    for (int kk = 0; kk < 2; kk++)
        a1[kk] = *(const short8*)(markerb + (r0 + rf) * 64 + kk * 32 + kg * 8);

    f32x4 acc2[4] = {};
    for (int ch = 0; ch < 4; ch++) {
        f32x4 acc1[4] = {};
        #pragma unroll
        for (int nj = 0; nj < 4; nj++)
            #pragma unroll
            for (int kk = 0; kk < 2; kk++) {
                short8 b1 = *(const short8*)(V1b16 + (size_t)(ch * 64 + nj * 16 + rf) * 64 + kk * 32 + kg * 8);
                acc1[nj] = __builtin_amdgcn_mfma_f32_16x16x32_bf16(a1[kk], b1, acc1[nj], 0, 0, 0);
            }
        __syncthreads();
        #pragma unroll
        for (int nj = 0; nj < 4; nj++) {
            float bb = V1bias[ch * 64 + nj * 16 + rf];
            #pragma unroll
            for (int r = 0; r < 4; r++) {
                float x = acc1[nj][r] + bb;
                h_lds[w][kg * 4 + r][nj * 16 + rf] = gelu_f(x);
            }
        }
        __syncthreads();
        #pragma unroll
        for (int kk = 0; kk < 2; kk++) {
            const float* hp = &h_lds[w][rf][kk * 32 + kg * 8];
            float4 p0 = *(const float4*)hp;
            float4 p1 = *(const float4*)(hp + 4);
            short8 a2;
            a2[0] = (short)f2bf(p0.x); a2[1] = (short)f2bf(p0.y);
            a2[2] = (short)f2bf(p0.z); a2[3] = (short)f2bf(p0.w);
            a2[4] = (short)f2bf(p1.x); a2[5] = (short)f2bf(p1.y);
            a2[6] = (short)f2bf(p1.z); a2[7] = (short)f2bf(p1.w);
            #pragma unroll
            for (int njo = 0; njo < 4; njo++) {
                short8 b2 = *(const short8*)(V2b16 + (size_t)(njo * 16 + rf) * 256 + ch * 64 + kk * 32 + kg * 8);
                acc2[njo] = __builtin_amdgcn_mfma_f32_16x16x32_bf16(a2, b2, acc2[njo], 0, 0, 0);
            }
        }
    }
    #pragma unroll
    for (int r = 0; r < 4; r++) {
        size_t R = r0 + kg * 4 + r;
        int bh = (int)(R >> 10), t = (int)(R & 1023);
        int b = bh / 48, h = bh % 48;
        int n = h / 12, head = h % 12;
        float ps = psink[R];
        size_t base = ((size_t)((b * 4 + n) * 1024 + t)) * 768 + head * 64;
        #pragma unroll
        for (int njo = 0; njo < 4; njo++) {
            int d = njo * 16 + rf;
            float v = acc2[njo][r] + V2bias[d] + ps * vnulls[h * 64 + d];
            ctxb[base + d] = f2bf(v);
        }
    }
}

// ---------------------------------------------------------------------------
__global__ __launch_bounds__(256) void gemm_wo_mfma(
    const unsigned short* __restrict__ ctxb, const unsigned short* __restrict__ WOtb,
    const float* __restrict__ WOb, float* __restrict__ Out)
{
    __shared__ unsigned short sA[64 * 64];
    __shared__ unsigned short sB[64 * 64];
    int tid = threadIdx.x;
    int w = tid >> 6, lane = tid & 63;
    int wm = w >> 1, wn = w & 1;
    int rf = lane & 15, kg = lane >> 4;
    int m0 = blockIdx.x * 64, n0 = blockIdx.y * 64;
    int b = m0 >> 10, t0 = m0 & 1023;
    int c0 = tid * 2, c1 = tid * 2 + 1;
    int ra = c0 >> 3, ca = c0 & 7, rb = c1 >> 3, cb = c1 & 7;
    f32x4 acc[2][2] = {};
    for (int n = 0; n < 4; n++) {
        const unsigned short* Ab = ctxb + ((size_t)((b * 4 + n) * 1024 + t0)) * 768;
        const unsigned short* Bb = WOtb + (size_t)n * 768 * 768 + (size_t)n0 * 768;
        for (int k0 = 0; k0 < 768; k0 += 64) {
            __syncthreads();
            *(short8*)&sA[ra * 64 + ((ca ^ (ra & 7)) * 8)] = *(const short8*)(Ab + (size_t)ra * 768 + k0 + ca * 8);
            *(short8*)&sA[rb * 64 + ((cb ^ (rb & 7)) * 8)] = *(const short8*)(Ab + (size_t)rb * 768 + k0 + cb * 8);
            *(short8*)&sB[ra * 64 + ((ca ^ (ra & 7)) * 8)] = *(const short8*)(Bb + (size_t)ra * 768 + k0 + ca * 8);
            *(short8*)&sB[rb * 64 + ((cb ^ (rb & 7)) * 8)] = *(const short8*)(Bb + (size_t)rb * 768 + k0 + cb * 8);
            __syncthreads();
            #pragma unroll
            for (int kk = 0; kk < 2; kk++) {
                int kc = kk * 4 + kg;
                int rA0 = wm * 32 + rf, rA1 = wm * 32 + 16 + rf;
                int rB0 = wn * 32 + rf, rB1 = wn * 32 + 16 + rf;
                short8 a0v = *(const short8*)&sA[rA0 * 64 + ((kc ^ (rA0 & 7)) * 8)];
                short8 a1v = *(const short8*)&sA[rA1 * 64 + ((kc ^ (rA1 & 7)) * 8)];
                short8 b0v = *(const short8*)&sB[rB0 * 64 + ((kc ^ (rB0 & 7)) * 8)];
                short8 b1v = *(const short8*)&sB[rB1 * 64 + ((kc ^ (rB1 & 7)) * 8)];
                acc[0][0] = __builtin_amdgcn_mfma_f32_16x16x32_bf16(a0v, b0v, acc[0][0], 0, 0, 0);
                acc[0][1] = __builtin_amdgcn_mfma_f32_16x16x32_bf16(a0v, b1v, acc[0][1], 0, 0, 0);
                acc[1][0] = __builtin_amdgcn_mfma_f32_16x16x32_bf16(a1v, b0v, acc[1][0], 0, 0, 0);
                acc[1][1] = __builtin_amdgcn_mfma_f32_16x16x32_bf16(a1v, b1v, acc[1][1], 0, 0, 0);
            }
        }
    }
    #pragma unroll
    for (int nj = 0; nj < 2; nj++) {
        int col = n0 + wn * 32 + nj * 16 + rf;
        float bm = WOb[col] + WOb[768 + col] + WOb[1536 + col] + WOb[2304 + col];
        #pragma unroll
        for (int mi = 0; mi < 2; mi++)
            #pragma unroll
            for (int r = 0; r < 4; r++) {
                int row = m0 + wm * 32 + mi * 16 + kg * 4 + r;
                Out[(size_t)row * 768 + col] = 0.25f * (acc[mi][nj][r] + bm);
            }
    }
}

// ---------------------------------------------------------------------------
extern "C" void kernel_launch(void* const* d_in, const int* in_sizes, int n_in,
                              void* d_out, int out_size, void* d_ws, size_t ws_size,
                              hipStream_t stream) {
    const float* A      = (const float*)d_in[0];
    const float* X      = (const float*)d_in[1];
    const float* WKw    = (const float*)d_in[2];
    const float* WKb    = (const float*)d_in[3];
    const float* WQw    = (const float*)d_in[4];
    const float* wA     = (const float*)d_in[5];
    const float* wB     = (const float*)d_in[6];
    const float* sink   = (const float*)d_in[7];
    const float* vnulls = (const float*)d_in[8];
    const float* V1w    = (const float*)d_in[9];
    const float* V1b    = (const float*)d_in[10];
    const float* V2w    = (const float*)d_in[11];
    const float* V2b    = (const float*)d_in[12];
    const float* WOw    = (const float*)d_in[13];
    const float* WOb    = (const float*)d_in[14];
    float* out = (float*)d_out;
    (void)in_sizes; (void)n_in; (void)out_size; (void)ws_size;

    float* ws = (float*)d_ws;
    size_t off = 0;
    float* Qr   = ws + off;  off += 6291456;   // head-major fp32 Q (rope'd)
    float* Kr   = ws + off;  off += 6291456;   // head-major fp32 K (rope'd)
    float* trig = ws + off;  off += 65536;
    float* bcat = ws + off;  off += 2048;
    float* O2   = ws + off;  off += 3145728;   // [2048][1536]: y | x
    float* Wsp_f = ws + off; off += 5308416;   // 3 planes x 4608x768 ushort
    unsigned short* Wsp = (unsigned short*)Wsp_f;
    unsigned short* Asp = (unsigned short*)(ws + off); off += 2359296;  // 3 planes x 2048x768
    unsigned short* Xsp = (unsigned short*)(ws + off); off += 2359296;
    // overlays (dead-buffer reuse) — audited lifetimes:
    //   markerb = O2 (FULL 3,145,728 floats; O2 dead after k_finish)
    //   Kb16 = Wsp floats [0, 3145728); psink = Wsp floats [3145728, 3244032)
    unsigned short* markerb = (unsigned short*)O2;
    unsigned short* Kb16 = Wsp;
    float* psink = Wsp_f + 3145728;
    unsigned short* V1b16 = Xsp;                         // Xsp dead after proj
    unsigned short* V2b16 = V1b16 + 16384;
    unsigned short* WOtb  = Asp;                         // Asp dead after proj
    unsigned short* ctxb  = (unsigned short*)Qr;         // Qr dead after attn

    // prep: trig+kbias, folded/split weights (Q+K in one launch), split acts
    trig_kbias_kernel<<<128, 256, 0, stream>>>(trig, WKb, wA, bcat);
    fold_split_kernel<<<dim3(60, 6), 256, 0, stream>>>(WQw, WKw, wA, wB, Wsp);
    split_act_kernel<<<1536, 256, 0, stream>>>(A, X, Asp, Xsp);
    // split-precision MFMA projection, async global_load_lds staging
    proj_mfma_kernel<<<576, 512, 0, stream>>>(Asp, Xsp, Wsp, bcat, trig, Qr, O2);
    // finish K: per-h bias wedge term + rope -> Kr fp32 + Kb16 bf16
    k_finish_kernel<<<3072, 256, 0, stream>>>(O2, trig, wB, Kr, Kb16);
    // attention: MFMA scores, fixed-offset softmax, packed-key shortlist,
    // exact fp32 top-4
    attn_mfma_topk_kernel<<<dim3(96, 8), 256, 0, stream>>>(Qr, Kr, Kb16, sink, markerb, psink);
    // post-top-k smooth path (bf16/MFMA)
    cvt_bf16_kernel<<<32, 256, 0, stream>>>(V1w, V2w, V1b16);
    wo_transpose_kernel<<<dim3(12, 12, 4), 256, 0, stream>>>(WOw, WOtb);
    mlp_mfma_kernel<<<1536, 256, 0, stream>>>(markerb, psink, V1b16, V1b, V2b16, V2b, vnulls, ctxb);
    gemm_wo_mfma<<<dim3(32, 12), 256, 0, stream>>>(ctxb, WOtb, WOb, out);
}

// Round 13
// 323.644 us; speedup vs baseline: 4.0111x; 1.0208x over previous
//
#include <hip/hip_runtime.h>
#include <math.h>

constexpr int Bq  = 2;
constexpr int Tq  = 1024;
constexpr int HTq = 48;
constexpr float SCALE = 0.125f;     // 64^-0.5
constexpr float EOFF = 8.0f;        // fixed softmax offset (shift-invariant)

typedef __attribute__((ext_vector_type(8))) short short8;
typedef __attribute__((ext_vector_type(4))) float f32x4;

__device__ inline unsigned short f2bf(float x) {
    unsigned u = __float_as_uint(x);
    return (unsigned short)((u + 0x7FFF + ((u >> 16) & 1)) >> 16);
}

__device__ inline unsigned umax_(unsigned a, unsigned b) { return a > b ? a : b; }
__device__ inline unsigned umin_(unsigned a, unsigned b) { return a > b ? b : a; }

// async global->LDS, 16B per lane; LDS dest = wave-uniform base + lane*16
__device__ inline void gload_lds16(const unsigned short* g, unsigned short* l) {
    __builtin_amdgcn_global_load_lds(
        (const __attribute__((address_space(1))) void*)g,
        (__attribute__((address_space(3))) void*)l,
        16, 0, 0);
}

// exact 3-plane bf16 split: x = p0 + p1 + p2 + O(2^-27 |x|)
__device__ inline void split3(float x, unsigned short& p0, unsigned short& p1, unsigned short& p2) {
    p0 = f2bf(x);
    float f0 = __uint_as_float((unsigned)p0 << 16);
    float r0 = x - f0;
    p1 = f2bf(r0);
    float f1 = __uint_as_float((unsigned)p1 << 16);
    float r1 = r0 - f1;
    p2 = f2bf(r1);
}

// exact-erf GELU via Abramowitz-Stegun 7.1.26 (|eps_erf| <= 1.5e-7)
__device__ inline float gelu_f(float x) {
    float z = 0.70710678118654752f * x;
    float az = fabsf(z);
    float t = __frcp_rn(1.0f + 0.3275911f * az);
    float poly = t * (0.254829592f + t * (-0.284496736f + t * (1.421413741f
               + t * (-1.453152027f + t * 1.061405429f))));
    float er = 1.0f - poly * __expf(-az * az);
    er = (z < 0.0f) ? -er : er;
    return 0.5f * x * (1.0f + er);
}

// ---------------------------------------------------------------------------
// trig table (cos @ [t*32+i], sin @ [32768+...]) + K-bias fold in one launch.
// ---------------------------------------------------------------------------
__global__ void trig_kbias_kernel(float* __restrict__ trig,
                                  const float* __restrict__ WKb,
                                  const float* __restrict__ wA,
                                  float* __restrict__ bcat) {
    int i = blockIdx.x * 256 + threadIdx.x;   // 32768
    int t = i >> 5, f = i & 31;
    float invf = powf(10000.0f, -(float)f * (1.0f / 32.0f));
    float ang = (float)t * invf;
    trig[i] = cosf(ang);
    trig[32768 + i] = sinf(ang);
    if (i < 768) {
        int hb = i >> 6, el = i & 63;
        float acc = 0.0f;
        for (int d = 0; d < 64; d++) {
            float sk = wA[d * 64 + el] - wA[el * 64 + d];
            acc += WKb[hb * 64 + d] * sk;
        }
        bcat[i] = WKb[i] + acc;
    } else if (i < 1536) {
        bcat[i] = WKb[i - 768];
    }
}

// ---------------------------------------------------------------------------
// Weight fold + 3-plane split, merged Q+K launch.  skew = wA - wA^T.
// ---------------------------------------------------------------------------
__global__ __launch_bounds__(256) void fold_split_kernel(
    const float* __restrict__ WQw, const float* __restrict__ WKw,
    const float* __restrict__ wA, const float* __restrict__ wbias,
    unsigned short* __restrict__ Wsp)
{
    const size_t WPL = (size_t)4608 * 768;
    __shared__ float sw[64][132];
    __shared__ float sk[64][65];
    int hb_ = blockIdx.x;
    int mode = (hb_ < 48) ? 0 : 1;
    int h = mode ? hb_ - 48 : hb_;
    const float* Wsrc = mode ? WKw : WQw;
    int cb = blockIdx.y;
    int tid = threadIdx.x;
    const float* Wh = Wsrc + (size_t)h * 64 * 768 + cb * 128;
    for (int l = tid; l < 64 * 32; l += 256) {
        int d = l >> 5, c4 = l & 31;
        *(float4*)&sw[d][c4 * 4] = *(const float4*)(Wh + (size_t)d * 768 + c4 * 4);
    }
    for (int l = tid; l < 4096; l += 256) {
        int d = l >> 6, e = l & 63;
        sk[d][e] = wA[l] - wA[e * 64 + d];
    }
    __syncthreads();
    int tx = tid & 15, ty = tid >> 4;
    float acc4[4][8] = {};
    for (int d = 0; d < 64; d++) {
        float s0 = sk[d][ty * 4 + 0], s1 = sk[d][ty * 4 + 1];
        float s2 = sk[d][ty * 4 + 2], s3 = sk[d][ty * 4 + 3];
        float w_[8];
        *(float4*)&w_[0] = *(const float4*)&sw[d][tx * 8];
        *(float4*)&w_[4] = *(const float4*)&sw[d][tx * 8 + 4];
        #pragma unroll
        for (int j = 0; j < 8; j++) {
            acc4[0][j] += s0 * w_[j];
            acc4[1][j] += s1 * w_[j];
            acc4[2][j] += s2 * w_[j];
            acc4[3][j] += s3 * w_[j];
        }
    }
    #pragma unroll
    for (int i = 0; i < 4; i++) {
        int e = ty * 4 + i;
        float scale = (mode == 0) ? (1.0f + wbias[h * 64 + e]) : 1.0f;
        size_t row = (mode == 0) ? (size_t)(h * 64 + e) : (size_t)(3072 + h * 64 + e);
        #pragma unroll
        for (int j = 0; j < 8; j++) {
            int cl = tx * 8 + j;
            float wv = sw[e][cl] * scale + acc4[i][j];
            unsigned short p0, p1, p2;
            split3(wv, p0, p1, p2);
            size_t idx = row * 768 + cb * 128 + cl;
            Wsp[idx] = p0; Wsp[WPL + idx] = p1; Wsp[2 * WPL + idx] = p2;
        }
        if (mode == 1) {
            size_t row2 = (size_t)(3840 + h * 64 + e);
            #pragma unroll
            for (int j = 0; j < 8; j++) {
                int cl = tx * 8 + j;
                unsigned short p0, p1, p2;
                split3(sw[e][cl], p0, p1, p2);
                size_t idx = row2 * 768 + cb * 128 + cl;
                Wsp[idx] = p0; Wsp[WPL + idx] = p1; Wsp[2 * WPL + idx] = p2;
            }
        }
    }
}

// ---------------------------------------------------------------------------
__global__ void split_act_kernel(const float* __restrict__ A, const float* __restrict__ X,
                                 unsigned short* __restrict__ Asp, unsigned short* __restrict__ Xsp)
{
    const size_t APL = (size_t)2048 * 768;
    int i = blockIdx.x * 256 + threadIdx.x;   // 393216 quads
    if (i >= 393216) return;
    float4 va = ((const float4*)A)[i];
    float4 vx = ((const float4*)X)[i];
    ushort4 a0, a1, a2, x0, x1, x2;
    split3(va.x, a0.x, a1.x, a2.x); split3(va.y, a0.y, a1.y, a2.y);
    split3(va.z, a0.z, a1.z, a2.z); split3(va.w, a0.w, a1.w, a2.w);
    split3(vx.x, x0.x, x1.x, x2.x); split3(vx.y, x0.y, x1.y, x2.y);
    split3(vx.z, x0.z, x1.z, x2.z); split3(vx.w, x0.w, x1.w, x2.w);
    ((ushort4*)(Asp))[i] = a0;
    ((ushort4*)(Asp + APL))[i] = a1;
    ((ushort4*)(Asp + 2 * APL))[i] = a2;
    ((ushort4*)(Xsp))[i] = x0;
    ((ushort4*)(Xsp + APL))[i] = x1;
    ((ushort4*)(Xsp + 2 * APL))[i] = x2;
}

// ---------------------------------------------------------------------------
// Projection GEMM (round-11 verbatim): split-precision bf16 MFMA,
// async global_load_lds staging, XOR-swizzled source, linear LDS dest.
// ---------------------------------------------------------------------------
__global__ __launch_bounds__(512) void proj_mfma_kernel(
    const unsigned short* __restrict__ Asp, const unsigned short* __restrict__ Xsp,
    const unsigned short* __restrict__ Wsp, const float* __restrict__ bcat,
    const float* __restrict__ trig, float* __restrict__ Qr, float* __restrict__ O2)
{
    const size_t APL = (size_t)2048 * 768;
    const size_t WPL = (size_t)4608 * 768;
    __shared__ unsigned short sA[3 * 128 * 32];
    __shared__ unsigned short sB[3 * 128 * 32];
    int bid = blockIdx.x;
    int swz = (bid & 7) * 72 + (bid >> 3);
    int nb = swz >> 4;
    int mb = swz & 15;
    bool isQ = (nb < 24);
    const unsigned short* Ab = isQ ? Asp : Xsp;
    int m0 = mb * 128, n0 = nb * 128;
    int tid = threadIdx.x;
    int w = tid >> 6, lane = tid & 63;
    int wm = w & 1, wn = w >> 1;
    int rf = lane & 15, kg = lane >> 4;
    int mbase = m0 + wm * 64;

    int srcslot = (lane & 3) ^ ((lane >> 3) & 3);
    const unsigned short* gsrcA[3];
    const unsigned short* gsrcB[3];
    unsigned short* ldstA[3];
    unsigned short* ldstB[3];
    #pragma unroll
    for (int i = 0; i < 3; i++) {
        int reg = w + i * 8;
        int p = reg >> 3, rg = reg & 7;
        int row = rg * 16 + (lane >> 2);
        gsrcA[i] = Ab  + (size_t)p * APL + (size_t)(m0 + row) * 768 + srcslot * 8;
        gsrcB[i] = Wsp + (size_t)p * WPL + (size_t)(n0 + row) * 768 + srcslot * 8;
        ldstA[i] = &sA[p * 4096 + rg * 512];
        ldstB[i] = &sB[p * 4096 + rg * 512];
    }

    f32x4 acc[4][2] = {};
    for (int k0 = 0; k0 < 768; k0 += 32) {
        __syncthreads();
        #pragma unroll
        for (int i = 0; i < 3; i++) {
            gload_lds16(gsrcA[i] + k0, ldstA[i]);
            gload_lds16(gsrcB[i] + k0, ldstB[i]);
        }
        __syncthreads();

        short8 a0[4], a1[4], a2[4], b0[2], b1[2], b2[2];
        #pragma unroll
        for (int mi = 0; mi < 4; mi++) {
            int row = wm * 64 + mi * 16 + rf;
            a0[mi] = *(const short8*)&sA[0 * 4096 + row * 32 + ((kg ^ ((row >> 1) & 3)) * 8)];
        }
        #pragma unroll
        for (int nj = 0; nj < 2; nj++) {
            int row = wn * 32 + nj * 16 + rf;
            b0[nj] = *(const short8*)&sB[0 * 4096 + row * 32 + ((kg ^ ((row >> 1) & 3)) * 8)];
        }
        #pragma unroll
        for (int mi = 0; mi < 4; mi++)
            #pragma unroll
            for (int nj = 0; nj < 2; nj++)
                acc[mi][nj] = __builtin_amdgcn_mfma_f32_16x16x32_bf16(a0[mi], b0[nj], acc[mi][nj], 0, 0, 0);
        #pragma unroll
        for (int nj = 0; nj < 2; nj++) {
            int row = wn * 32 + nj * 16 + rf;
            b1[nj] = *(const short8*)&sB[1 * 4096 + row * 32 + ((kg ^ ((row >> 1) & 3)) * 8)];
        }
        #pragma unroll
        for (int mi = 0; mi < 4; mi++)
            #pragma unroll
            for (int nj = 0; nj < 2; nj++)
                acc[mi][nj] = __builtin_amdgcn_mfma_f32_16x16x32_bf16(a0[mi], b1[nj], acc[mi][nj], 0, 0, 0);
        #pragma unroll
        for (int nj = 0; nj < 2; nj++) {
            int row = wn * 32 + nj * 16 + rf;
            b2[nj] = *(const short8*)&sB[2 * 4096 + row * 32 + ((kg ^ ((row >> 1) & 3)) * 8)];
        }
        #pragma unroll
        for (int mi = 0; mi < 4; mi++)
            #pragma unroll
            for (int nj = 0; nj < 2; nj++)
                acc[mi][nj] = __builtin_amdgcn_mfma_f32_16x16x32_bf16(a0[mi], b2[nj], acc[mi][nj], 0, 0, 0);
        #pragma unroll
        for (int mi = 0; mi < 4; mi++) {
            int row = wm * 64 + mi * 16 + rf;
            a1[mi] = *(const short8*)&sA[1 * 4096 + row * 32 + ((kg ^ ((row >> 1) & 3)) * 8)];
        }
        #pragma unroll
        for (int mi = 0; mi < 4; mi++)
            #pragma unroll
            for (int nj = 0; nj < 2; nj++)
                acc[mi][nj] = __builtin_amdgcn_mfma_f32_16x16x32_bf16(a1[mi], b0[nj], acc[mi][nj], 0, 0, 0);
        #pragma unroll
        for (int mi = 0; mi < 4; mi++)
            #pragma unroll
            for (int nj = 0; nj < 2; nj++)
                acc[mi][nj] = __builtin_amdgcn_mfma_f32_16x16x32_bf16(a1[mi], b1[nj], acc[mi][nj], 0, 0, 0);
        #pragma unroll
        for (int mi = 0; mi < 4; mi++) {
            int row = wm * 64 + mi * 16 + rf;
            a2[mi] = *(const short8*)&sA[2 * 4096 + row * 32 + ((kg ^ ((row >> 1) & 3)) * 8)];
        }
        #pragma unroll
        for (int mi = 0; mi < 4; mi++)
            #pragma unroll
            for (int nj = 0; nj < 2; nj++)
                acc[mi][nj] = __builtin_amdgcn_mfma_f32_16x16x32_bf16(a2[mi], b0[nj], acc[mi][nj], 0, 0, 0);
    }

    if (isQ) {
        #pragma unroll
        for (int mi = 0; mi < 4; mi++) {
            #pragma unroll
            for (int r = 0; r < 4; r++) {
                int m = mbase + mi * 16 + kg * 4 + r;
                int b_ = m >> 10, t = m & 1023;
                #pragma unroll
                for (int nj = 0; nj < 2; nj++) {
                    int col_local = wn * 32 + nj * 16 + rf;
                    int h = nb * 2 + (col_local >> 6);
                    int d = col_local & 63;
                    int i = d >> 1;
                    float v = acc[mi][nj][r];
                    float pv = __shfl_xor(v, 1);
                    float c = trig[t * 32 + i];
                    float s = trig[32768 + t * 32 + i];
                    float outv = (rf & 1) ? (pv * s + v * c) : (v * c - pv * s);
                    int col = (rf & 1) ? (32 + i) : i;
                    size_t base = ((size_t)(b_ * 48 + h) * 1024 + t) * 64;
                    Qr[base + col] = outv;
                }
            }
        }
    } else {
        #pragma unroll
        for (int nj = 0; nj < 2; nj++) {
            int col = (n0 - 3072) + wn * 32 + nj * 16 + rf;
            float bv = bcat[col];
            #pragma unroll
            for (int mi = 0; mi < 4; mi++)
                #pragma unroll
                for (int r = 0; r < 4; r++) {
                    int m = mbase + mi * 16 + kg * 4 + r;
                    O2[(size_t)m * 1536 + col] = acc[mi][nj][r] + bv;
                }
        }
    }
}

// ---------------------------------------------------------------------------
__global__ void k_finish_kernel(const float* __restrict__ O2, const float* __restrict__ trig,
                                const float* __restrict__ wbias,
                                float* __restrict__ Kr, unsigned short* __restrict__ Kb16)
{
    int idx = blockIdx.x * 256 + threadIdx.x;   // 786432
    int pr = idx & 31;
    int tmp = idx >> 5;
    int hb = tmp % 12;
    int bt = tmp / 12;
    int t = bt & 1023, b = bt >> 10;
    const float* yx = O2 + (size_t)bt * 1536 + hb * 64 + pr * 2;
    float y0 = yx[0], y1 = yx[1];
    float x0 = yx[768], x1 = yx[769];
    float cv = trig[t * 32 + pr], sv = trig[32768 + t * 32 + pr];
    #pragma unroll
    for (int r = 0; r < 4; r++) {
        int h = hb + 12 * r;
        float b0 = wbias[h * 64 + 2 * pr], b1 = wbias[h * 64 + 2 * pr + 1];
        float wz0 = y0 + x0 * b0;
        float wz1 = y1 + x1 * b1;
        float lo = wz0 * cv - wz1 * sv;
        float hi = wz0 * sv + wz1 * cv;
        size_t base = ((size_t)(b * 48 + h) * 1024 + t) * 64;
        Kr[base + pr] = lo;
        Kr[base + 32 + pr] = hi;
        Kb16[base + pr] = f2bf(lo);
        Kb16[base + 32 + pr] = f2bf(hi);
    }
}

// ---------------------------------------------------------------------------
// Attention core v4: fixed-offset softmax + BITONIC top-8 merge (same top-8
// set as the argmax-pop merge -> bit-identical output, ~3x fewer dependent
// shfl stages).  s_setprio around MFMA clusters (independent-wave regime).
// __launch_bounds__(256,4) pins VGPR <= 128 (occupancy bucket).
// ---------------------------------------------------------------------------
__global__ __launch_bounds__(256, 4) void attn_mfma_topk_kernel(
    const float* __restrict__ Qr, const float* __restrict__ Kr,
    const unsigned short* __restrict__ Kb, const float* __restrict__ sink,
    unsigned short* __restrict__ markerb, float* __restrict__ psink)
{
    const int bh = blockIdx.x;                 // 0..95
    const int y  = blockIdx.y;                 // 0..7
    const int w = threadIdx.x >> 6, lane = threadIdx.x & 63;
    const int rf = lane & 15, kg = lane >> 4;
    const int h = bh % HTq;
    const size_t rowbase = (size_t)bh * Tq;
    const unsigned short* Kbb = Kb + rowbase * 64;
    const float sk = sink[h];

    #pragma unroll 1
    for (int g = 0; g < 2; g++) {
        const int qb = g ? y : 15 - y;
        const int q0 = qb * 64 + w * 16;

        short8 a0, a1;
        {
            const float* qp = Qr + (rowbase + q0 + rf) * 64 + kg * 8;
            float4 u0 = *(const float4*)qp;
            float4 u1 = *(const float4*)(qp + 4);
            float4 u2 = *(const float4*)(qp + 32);
            float4 u3 = *(const float4*)(qp + 36);
            a0[0]=(short)f2bf(u0.x); a0[1]=(short)f2bf(u0.y); a0[2]=(short)f2bf(u0.z); a0[3]=(short)f2bf(u0.w);
            a0[4]=(short)f2bf(u1.x); a0[5]=(short)f2bf(u1.y); a0[6]=(short)f2bf(u1.z); a0[7]=(short)f2bf(u1.w);
            a1[0]=(short)f2bf(u2.x); a1[1]=(short)f2bf(u2.y); a1[2]=(short)f2bf(u2.z); a1[3]=(short)f2bf(u2.w);
            a1[4]=(short)f2bf(u3.x); a1[5]=(short)f2bf(u3.y); a1[6]=(short)f2bf(u3.z); a1[7]=(short)f2bf(u3.w);
        }

        float Z_[4];
        unsigned t_[4][4];
        #pragma unroll
        for (int r = 0; r < 4; r++) {
            Z_[r] = 0.0f;
            t_[r][0] = 0u; t_[r][1] = 0u; t_[r][2] = 0u; t_[r][3] = 0u;
        }

        short8 cA0[4], cA1[4], cB0[4], cB1[4];
        {
            const unsigned short* p = Kbb + (size_t)rf * 64 + kg * 8;
            #pragma unroll
            for (int kc = 0; kc < 4; kc++) {
                cA0[kc] = *(const short8*)(p + kc * 1024);
                cA1[kc] = *(const short8*)(p + kc * 1024 + 32);
            }
        }

        auto body = [&](short8 (&cb0)[4], short8 (&cb1)[4],
                        short8 (&nb0)[4], short8 (&nb1)[4], int tile) {
            f32x4 accs[4];
            __builtin_amdgcn_s_setprio(1);
            #pragma unroll
            for (int kc = 0; kc < 4; kc++) {
                f32x4 acc = {0.f, 0.f, 0.f, 0.f};
                acc = __builtin_amdgcn_mfma_f32_16x16x32_bf16(a0, cb0[kc], acc, 0, 0, 0);
                acc = __builtin_amdgcn_mfma_f32_16x16x32_bf16(a1, cb1[kc], acc, 0, 0, 0);
                accs[kc] = acc;
            }
            __builtin_amdgcn_s_setprio(0);
            const unsigned short* np = Kbb + (size_t)((tile + 1) * 64 + rf) * 64 + kg * 8;
            #pragma unroll
            for (int kc = 0; kc < 4; kc++) {
                nb0[kc] = *(const short8*)(np + kc * 1024);
                nb1[kc] = *(const short8*)(np + kc * 1024 + 32);
            }
            const int s0 = tile << 6;
            #pragma unroll
            for (int r = 0; r < 4; r++) {
                float s8[4];
                #pragma unroll
                for (int kc = 0; kc < 4; kc++) s8[kc] = fmaf(accs[kc][r], SCALE, -EOFF);
                #pragma unroll
                for (int kc = 0; kc < 4; kc++) {
                    unsigned u = __float_as_uint(s8[kc]);
                    unsigned key = u ^ ((unsigned)(((int)u) >> 31) | 0x80000000u);
                    unsigned c = (key & 0xFFFFFC00u) | (unsigned)(s0 + kc * 16 + rf);
                    unsigned n;
                    n = umax_(t_[r][0], c);  c = umin_(t_[r][0], c);  t_[r][0] = n;
                    n = umax_(t_[r][1], c);  c = umin_(t_[r][1], c);  t_[r][1] = n;
                    n = umax_(t_[r][2], c);  c = umin_(t_[r][2], c);  t_[r][2] = n;
                    t_[r][3] = umax_(t_[r][3], c);
                }
                float e0 = __expf(s8[0]), e1 = __expf(s8[1]);
                float e2 = __expf(s8[2]), e3 = __expf(s8[3]);
                Z_[r] += (e0 + e1) + (e2 + e3);
            }
        };

        int tile = 0;
        for (; tile + 1 < qb; tile += 2) {
            body(cA0, cA1, cB0, cB1, tile);
            body(cB0, cB1, cA0, cA1, tile + 1);
        }
        if (tile < qb) {
            body(cA0, cA1, cB0, cB1, tile);
            #pragma unroll
            for (int kc = 0; kc < 4; kc++) { cA0[kc] = cB0[kc]; cA1[kc] = cB1[kc]; }
        }

        // diagonal tile, masked
        {
            f32x4 accs[4];
            __builtin_amdgcn_s_setprio(1);
            #pragma unroll
            for (int kc = 0; kc < 4; kc++) {
                f32x4 acc = {0.f, 0.f, 0.f, 0.f};
                acc = __builtin_amdgcn_mfma_f32_16x16x32_bf16(a0, cA0[kc], acc, 0, 0, 0);
                acc = __builtin_amdgcn_mfma_f32_16x16x32_bf16(a1, cA1[kc], acc, 0, 0, 0);
                accs[kc] = acc;
            }
            __builtin_amdgcn_s_setprio(0);
            const int s0 = qb << 6;
            #pragma unroll
            for (int r = 0; r < 4; r++) {
                const int trow = q0 + kg * 4 + r;
                float ev[4];
                #pragma unroll
                for (int kc = 0; kc < 4; kc++) {
                    int k = s0 + kc * 16 + rf;
                    bool ok = (k <= trow);
                    float s8 = fmaf(accs[kc][r], SCALE, -EOFF);
                    unsigned u = __float_as_uint(s8);
                    unsigned key = u ^ ((unsigned)(((int)u) >> 31) | 0x80000000u);
                    unsigned c = (key & 0xFFFFFC00u) | (unsigned)k;
                    c = ok ? c : 0u;
                    unsigned n;
                    n = umax_(t_[r][0], c);  c = umin_(t_[r][0], c);  t_[r][0] = n;
                    n = umax_(t_[r][1], c);  c = umin_(t_[r][1], c);  t_[r][1] = n;
                    n = umax_(t_[r][2], c);  c = umin_(t_[r][2], c);  t_[r][2] = n;
                    t_[r][3] = umax_(t_[r][3], c);
                    ev[kc] = ok ? __expf(s8) : 0.0f;
                }
                Z_[r] += (ev[0] + ev[1]) + (ev[2] + ev[3]);
            }
        }

        const float esk = __expf(sk - EOFF);
        #pragma unroll 1
        for (int r = 0; r < 4; r++) {
            const int q = q0 + kg * 4 + r;
            float Z = Z_[r];
            #pragma unroll
            for (int off = 1; off < 16; off <<= 1) Z += __shfl_xor(Z, off);
            float Zf = Z + esk;

            // ---- bitonic merge: 16 sorted-4 lists -> identical sorted top-8
            unsigned e0, e1, e2, e3, e4, e5, e6, e7;
            {
                unsigned A0 = t_[r][0], A1 = t_[r][1], A2 = t_[r][2], A3 = t_[r][3];
                unsigned B0 = (unsigned)__shfl_xor((int)A0, 1);
                unsigned B1 = (unsigned)__shfl_xor((int)A1, 1);
                unsigned B2 = (unsigned)__shfl_xor((int)A2, 1);
                unsigned B3 = (unsigned)__shfl_xor((int)A3, 1);
                // merge sorted-4 + sorted-4 -> sorted-8 (desc)
                unsigned y0 = umax_(A0, B3), y4 = umin_(A0, B3);
                unsigned y1 = umax_(A1, B2), y5 = umin_(A1, B2);
                unsigned y2 = umax_(A2, B1), y6 = umin_(A2, B1);
                unsigned y3 = umax_(A3, B0), y7 = umin_(A3, B0);
                unsigned z0 = umax_(y0, y2), z2 = umin_(y0, y2);
                unsigned z1 = umax_(y1, y3), z3 = umin_(y1, y3);
                unsigned z4 = umax_(y4, y6), z6 = umin_(y4, y6);
                unsigned z5 = umax_(y5, y7), z7 = umin_(y5, y7);
                e0 = umax_(z0, z1); e1 = umin_(z0, z1);
                e2 = umax_(z2, z3); e3 = umin_(z2, z3);
                e4 = umax_(z4, z5); e5 = umin_(z4, z5);
                e6 = umax_(z6, z7); e7 = umin_(z6, z7);
            }
            auto merge8 = [&](int off) {
                unsigned f0 = (unsigned)__shfl_xor((int)e0, off);
                unsigned f1 = (unsigned)__shfl_xor((int)e1, off);
                unsigned f2 = (unsigned)__shfl_xor((int)e2, off);
                unsigned f3 = (unsigned)__shfl_xor((int)e3, off);
                unsigned f4 = (unsigned)__shfl_xor((int)e4, off);
                unsigned f5 = (unsigned)__shfl_xor((int)e5, off);
                unsigned f6 = (unsigned)__shfl_xor((int)e6, off);
                unsigned f7 = (unsigned)__shfl_xor((int)e7, off);
                unsigned m0 = umax_(e0, f7), m1 = umax_(e1, f6);
                unsigned m2 = umax_(e2, f5), m3 = umax_(e3, f4);
                unsigned m4 = umax_(e4, f3), m5 = umax_(e5, f2);
                unsigned m6 = umax_(e6, f1), m7 = umax_(e7, f0);
                unsigned p0 = umax_(m0, m4), p4 = umin_(m0, m4);
                unsigned p1 = umax_(m1, m5), p5 = umin_(m1, m5);
                unsigned p2 = umax_(m2, m6), p6 = umin_(m2, m6);
                unsigned p3 = umax_(m3, m7), p7 = umin_(m3, m7);
                unsigned q0_ = umax_(p0, p2), q2_ = umin_(p0, p2);
                unsigned q1_ = umax_(p1, p3), q3_ = umin_(p1, p3);
                unsigned q4_ = umax_(p4, p6), q6_ = umin_(p4, p6);
                unsigned q5_ = umax_(p5, p7), q7_ = umin_(p5, p7);
                e0 = umax_(q0_, q1_); e1 = umin_(q0_, q1_);
                e2 = umax_(q2_, q3_); e3 = umin_(q2_, q3_);
                e4 = umax_(q4_, q5_); e5 = umin_(q4_, q5_);
                e6 = umax_(q6_, q7_); e7 = umin_(q6_, q7_);
            };
            merge8(2); merge8(4); merge8(8);
            unsigned ck[8] = {e0, e1, e2, e3, e4, e5, e6, e7};

            // exact fp32 re-score of shortlist
            const float4 qv = *(const float4*)(Qr + (rowbase + q) * 64 + rf * 4);
            float sc[8]; int ci[8];
            #pragma unroll
            for (int c = 0; c < 8; c++) {
                bool valid = (ck[c] != 0u);
                int idx = (int)(ck[c] & 1023u);
                int lidx = valid ? idx : 0;
                const float4 kv = *(const float4*)(Kr + (rowbase + lidx) * 64 + rf * 4);
                float p = qv.x * kv.x + qv.y * kv.y + qv.z * kv.z + qv.w * kv.w;
                #pragma unroll
                for (int off = 1; off < 16; off <<= 1) p += __shfl_xor(p, off);
                sc[c] = valid ? p * SCALE : -1e30f;
                ci[c] = valid ? idx : -1;
            }
            // stable top-4 of the 8 exact scores (value desc, index asc)
            float bv[4]; int bi[4];
            #pragma unroll
            for (int rd = 0; rd < 4; rd++) {
                float v = sc[0]; int id = ci[0];
                #pragma unroll
                for (int c = 1; c < 8; c++) {
                    bool take = (sc[c] > v) || ((sc[c] == v) && ((unsigned)ci[c] < (unsigned)id));
                    v = take ? sc[c] : v; id = take ? ci[c] : id;
                }
                bv[rd] = v; bi[rd] = id;
                #pragma unroll
                for (int c = 0; c < 8; c++) {
                    bool kill = (ci[c] == id) && (sc[c] == v);
                    sc[c] = kill ? -3e30f : sc[c];
                }
            }
            float e0f = __expf(bv[0] - EOFF), e1f = __expf(bv[1] - EOFF);
            float e2f = __expf(bv[2] - EOFF), e3f = __expf(bv[3] - EOFF);
            float wsum = e0f + e1f + e2f + e3f + Zf * 1e-9f;
            float w0 = e0f / wsum, w1 = e1f / wsum, w2 = e2f / wsum, w3 = e3f / wsum;
            int i0 = bi[0] < 0 ? 0 : bi[0];
            int i1 = bi[1] < 0 ? 0 : bi[1];
            int i2 = bi[2] < 0 ? 0 : bi[2];
            int i3 = bi[3] < 0 ? 0 : bi[3];
            const float4 k0 = *(const float4*)(Kr + (rowbase + i0) * 64 + rf * 4);
            const float4 k1 = *(const float4*)(Kr + (rowbase + i1) * 64 + rf * 4);
            const float4 k2 = *(const float4*)(Kr + (rowbase + i2) * 64 + rf * 4);
            const float4 k3 = *(const float4*)(Kr + (rowbase + i3) * 64 + rf * 4);
            float mx = w0 * k0.x + w1 * k1.x + w2 * k2.x + w3 * k3.x;
            float my = w0 * k0.y + w1 * k1.y + w2 * k2.y + w3 * k3.y;
            float mz = w0 * k0.z + w1 * k1.z + w2 * k2.z + w3 * k3.z;
            float mw = w0 * k0.w + w1 * k1.w + w2 * k2.w + w3 * k3.w;
            ushort4 mo;
            mo.x = f2bf(mx); mo.y = f2bf(my); mo.z = f2bf(mz); mo.w = f2bf(mw);
            *(ushort4*)(markerb + (rowbase + q) * 64 + rf * 4) = mo;
            if (rf == 0) psink[rowbase + q] = esk / Zf;
        }
    }
}

// ---------------------------------------------------------------------------
// merged V1+V2 bf16 conversion (V1b16 and V2b16 contiguous)
// ---------------------------------------------------------------------------
__global__ void cvt_bf16_kernel(const float* __restrict__ V1w, const float* __restrict__ V2w,
                                unsigned short* __restrict__ outb)
{
    int i = blockIdx.x * 256 + threadIdx.x;   // 8192 quads
    if (i >= 8192) return;
    float4 v = (i < 4096) ? ((const float4*)V1w)[i] : ((const float4*)V2w)[i - 4096];
    ushort4 o;
    o.x = f2bf(v.x); o.y = f2bf(v.y); o.z = f2bf(v.z); o.w = f2bf(v.w);
    ((ushort4*)outb)[i] = o;
}

// ---------------------------------------------------------------------------
__global__ __launch_bounds__(256) void wo_transpose_kernel(
    const float* __restrict__ WOw, unsigned short* __restrict__ WOt)
{
    __shared__ float tl[64][65];
    int tid = threadIdx.x;
    int n = blockIdx.z;
    int c0 = blockIdx.x * 64, d0 = blockIdx.y * 64;
    const float* src = WOw + (size_t)n * 768 * 768;
    for (int l = tid; l < 64 * 16; l += 256) {
        int r = l >> 4, q = l & 15;
        float4 v = *(const float4*)(src + (size_t)(c0 + r) * 768 + d0 + q * 4);
        tl[r][q * 4 + 0] = v.x; tl[r][q * 4 + 1] = v.y;
        tl[r][q * 4 + 2] = v.z; tl[r][q * 4 + 3] = v.w;
    }
    __syncthreads();
    for (int l = tid; l < 64 * 16; l += 256) {
        int d = l >> 4, q = l & 15;
        ushort4 o;
        o.x = f2bf(tl[q * 4 + 0][d]); o.y = f2bf(tl[q * 4 + 1][d]);
        o.z = f2bf(tl[q * 4 + 2][d]); o.w = f2bf(tl[q * 4 + 3][d]);
        *(ushort4*)(WOt + (size_t)n * 768 * 768 + (size_t)(d0 + d) * 768 + c0 + q * 4) = o;
    }
}

// ---------------------------------------------------------------------------
__global__ __launch_bounds__(256) void mlp_mfma_kernel(
    const unsigned short* __restrict__ markerb, const float* __restrict__ psink,
    const unsigned short* __restrict__ V1b16, const float* __restrict__ V1bias,
    const unsigned short* __restrict__ V2b16, const float* __restrict__ V2bias,
    const float* __restrict__ vnulls, unsigned short* __restrict__ ctxb)
{
    __shared__ float h_lds[4][16][65];
    int tid = threadIdx.x;
    int w = tid >> 6, lane = tid & 63;
    int rf = lane & 15, kg = lane >> 4;
    size_t r0 = (size_t)blockIdx.x * 64 + 16 * w;

    short8 a1[2];
    #pragma unroll
    for (int kk = 0; kk < 2; kk++)
        a1[kk] = *(const short8*)(markerb + (r0 + rf) * 64 + kk * 32 + kg * 8);

    f32x4 acc2[4] = {};
    for (int ch = 0; ch < 4; ch++) {
        f32x4 acc1[4] = {};
        #pragma unroll
        for (int nj = 0; nj < 4; nj++)
            #pragma unroll
            for (int kk = 0; kk < 2; kk++) {
                short8 b1 = *(const short8*)(V1b16 + (size_t)(ch * 64 + nj * 16 + rf) * 64 + kk * 32 + kg * 8);
                acc1[nj] = __builtin_amdgcn_mfma_f32_16x16x32_bf16(a1[kk], b1, acc1[nj], 0, 0, 0);
            }
        __syncthreads();
        #pragma unroll
        for (int nj = 0; nj < 4; nj++) {
            float bb = V1bias[ch * 64 + nj * 16 + rf];
            #pragma unroll
            for (int r = 0; r < 4; r++) {
                float x = acc1[nj][r] + bb;
                h_lds[w][kg * 4 + r][nj * 16 + rf] = gelu_f(x);
            }
        }
        __syncthreads();
        #pragma unroll
        for (int kk = 0; kk < 2; kk++) {
            const float* hp = &h_lds[w][rf][kk * 32 + kg * 8];
            float4 p0 = *(const float4*)hp;
            float4 p1 = *(const float4*)(hp + 4);
            short8 a2;
            a2[0] = (short)f2bf(p0.x); a2[1] = (short)f2bf(p0.y);
            a2[2] = (short)f2bf(p0.z); a2[3] = (short)f2bf(p0.w);
            a2[4] = (short)f2bf(p1.x); a2[5] = (short)f2bf(p1.y);
            a2[6] = (short)f2bf(p1.z); a2[7] = (short)f2bf(p1.w);
            #pragma unroll
            for (int njo = 0; njo < 4; njo++) {
                short8 b2 = *(const short8*)(V2b16 + (size_t)(njo * 16 + rf) * 256 + ch * 64 + kk * 32 + kg * 8);
                acc2[njo] = __builtin_amdgcn_mfma_f32_16x16x32_bf16(a2, b2, acc2[njo], 0, 0, 0);
            }
        }
    }
    #pragma unroll
    for (int r = 0; r < 4; r++) {
        size_t R = r0 + kg * 4 + r;
        int bh = (int)(R >> 10), t = (int)(R & 1023);
        int b = bh / 48, h = bh % 48;
        int n = h / 12, head = h % 12;
        float ps = psink[R];
        size_t base = ((size_t)((b * 4 + n) * 1024 + t)) * 768 + head * 64;
        #pragma unroll
        for (int njo = 0; njo < 4; njo++) {
            int d = njo * 16 + rf;
            float v = acc2[njo][r] + V2bias[d] + ps * vnulls[h * 64 + d];
            ctxb[base + d] = f2bf(v);
        }
    }
}

// ---------------------------------------------------------------------------
__global__ __launch_bounds__(256) void gemm_wo_mfma(
    const unsigned short* __restrict__ ctxb, const unsigned short* __restrict__ WOtb,
    const float* __restrict__ WOb, float* __restrict__ Out)
{
    __shared__ unsigned short sA[64 * 64];
    __shared__ unsigned short sB[64 * 64];
    int tid = threadIdx.x;
    int w = tid >> 6, lane = tid & 63;
    int wm = w >> 1, wn = w & 1;
    int rf = lane & 15, kg = lane >> 4;
    int m0 = blockIdx.x * 64, n0 = blockIdx.y * 64;
    int b = m0 >> 10, t0 = m0 & 1023;
    int c0 = tid * 2, c1 = tid * 2 + 1;
    int ra = c0 >> 3, ca = c0 & 7, rb = c1 >> 3, cb = c1 & 7;
    f32x4 acc[2][2] = {};
    for (int n = 0; n < 4; n++) {
        const unsigned short* Ab = ctxb + ((size_t)((b * 4 + n) * 1024 + t0)) * 768;
        const unsigned short* Bb = WOtb + (size_t)n * 768 * 768 + (size_t)n0 * 768;
        for (int k0 = 0; k0 < 768; k0 += 64) {
            __syncthreads();
            *(short8*)&sA[ra * 64 + ((ca ^ (ra & 7)) * 8)] = *(const short8*)(Ab + (size_t)ra * 768 + k0 + ca * 8);
            *(short8*)&sA[rb * 64 + ((cb ^ (rb & 7)) * 8)] = *(const short8*)(Ab + (size_t)rb * 768 + k0 + cb * 8);
            *(short8*)&sB[ra * 64 + ((ca ^ (ra & 7)) * 8)] = *(const short8*)(Bb + (size_t)ra * 768 + k0 + ca * 8);
            *(short8*)&sB[rb * 64 + ((cb ^ (rb & 7)) * 8)] = *(const short8*)(Bb + (size_t)rb * 768 + k0 + cb * 8);
            __syncthreads();
            #pragma unroll
            for (int kk = 0; kk < 2; kk++) {
                int kc = kk * 4 + kg;
                int rA0 = wm * 32 + rf, rA1 = wm * 32 + 16 + rf;
                int rB0 = wn * 32 + rf, rB1 = wn * 32 + 16 + rf;
                short8 a0v = *(const short8*)&sA[rA0 * 64 + ((kc ^ (rA0 & 7)) * 8)];
                short8 a1v = *(const short8*)&sA[rA1 * 64 + ((kc ^ (rA1 & 7)) * 8)];
                short8 b0v = *(const short8*)&sB[rB0 * 64 + ((kc ^ (rB0 & 7)) * 8)];
                short8 b1v = *(const short8*)&sB[rB1 * 64 + ((kc ^ (rB1 & 7)) * 8)];
                acc[0][0] = __builtin_amdgcn_mfma_f32_16x16x32_bf16(a0v, b0v, acc[0][0], 0, 0, 0);
                acc[0][1] = __builtin_amdgcn_mfma_f32_16x16x32_bf16(a0v, b1v, acc[0][1], 0, 0, 0);
                acc[1][0] = __builtin_amdgcn_mfma_f32_16x16x32_bf16(a1v, b0v, acc[1][0], 0, 0, 0);
                acc[1][1] = __builtin_amdgcn_mfma_f32_16x16x32_bf16(a1v, b1v, acc[1][1], 0, 0, 0);
            }
        }
    }
    #pragma unroll
    for (int nj = 0; nj < 2; nj++) {
        int col = n0 + wn * 32 + nj * 16 + rf;
        float bm = WOb[col] + WOb[768 + col] + WOb[1536 + col] + WOb[2304 + col];
        #pragma unroll
        for (int mi = 0; mi < 2; mi++)
            #pragma unroll
            for (int r = 0; r < 4; r++) {
                int row = m0 + wm * 32 + mi * 16 + kg * 4 + r;
                Out[(size_t)row * 768 + col] = 0.25f * (acc[mi][nj][r] + bm);
            }
    }
}

// ---------------------------------------------------------------------------
extern "C" void kernel_launch(void* const* d_in, const int* in_sizes, int n_in,
                              void* d_out, int out_size, void* d_ws, size_t ws_size,
                              hipStream_t stream) {
    const float* A      = (const float*)d_in[0];
    const float* X      = (const float*)d_in[1];
    const float* WKw    = (const float*)d_in[2];
    const float* WKb    = (const float*)d_in[3];
    const float* WQw    = (const float*)d_in[4];
    const float* wA     = (const float*)d_in[5];
    const float* wB     = (const float*)d_in[6];
    const float* sink   = (const float*)d_in[7];
    const float* vnulls = (const float*)d_in[8];
    const float* V1w    = (const float*)d_in[9];
    const float* V1b    = (const float*)d_in[10];
    const float* V2w    = (const float*)d_in[11];
    const float* V2b    = (const float*)d_in[12];
    const float* WOw    = (const float*)d_in[13];
    const float* WOb    = (const float*)d_in[14];
    float* out = (float*)d_out;
    (void)in_sizes; (void)n_in; (void)out_size; (void)ws_size;

    float* ws = (float*)d_ws;
    size_t off = 0;
    float* Qr   = ws + off;  off += 6291456;   // head-major fp32 Q (rope'd)
    float* Kr   = ws + off;  off += 6291456;   // head-major fp32 K (rope'd)
    float* trig = ws + off;  off += 65536;
    float* bcat = ws + off;  off += 2048;
    float* O2   = ws + off;  off += 3145728;   // [2048][1536]: y | x
    float* Wsp_f = ws + off; off += 5308416;   // 3 planes x 4608x768 ushort
    unsigned short* Wsp = (unsigned short*)Wsp_f;
    unsigned short* Asp = (unsigned short*)(ws + off); off += 2359296;  // 3 planes x 2048x768
    unsigned short* Xsp = (unsigned short*)(ws + off); off += 2359296;
    // overlays (dead-buffer reuse) — audited lifetimes:
    //   markerb = O2 (FULL 3,145,728 floats; O2 dead after k_finish)
    //   Kb16 = Wsp floats [0, 3145728); psink = Wsp floats [3145728, 3244032)
    unsigned short* markerb = (unsigned short*)O2;
    unsigned short* Kb16 = Wsp;
    float* psink = Wsp_f + 3145728;
    unsigned short* V1b16 = Xsp;                         // Xsp dead after proj
    unsigned short* V2b16 = V1b16 + 16384;
    unsigned short* WOtb  = Asp;                         // Asp dead after proj
    unsigned short* ctxb  = (unsigned short*)Qr;         // Qr dead after attn

    // prep: trig+kbias, folded/split weights (Q+K in one launch), split acts
    trig_kbias_kernel<<<128, 256, 0, stream>>>(trig, WKb, wA, bcat);
    fold_split_kernel<<<dim3(60, 6), 256, 0, stream>>>(WQw, WKw, wA, wB, Wsp);
    split_act_kernel<<<1536, 256, 0, stream>>>(A, X, Asp, Xsp);
    // split-precision MFMA projection, async global_load_lds staging
    proj_mfma_kernel<<<576, 512, 0, stream>>>(Asp, Xsp, Wsp, bcat, trig, Qr, O2);
    // finish K: per-h bias wedge term + rope -> Kr fp32 + Kb16 bf16
    k_finish_kernel<<<3072, 256, 0, stream>>>(O2, trig, wB, Kr, Kb16);
    // attention: MFMA scores, fixed-offset softmax, bitonic top-8 shortlist,
    // exact fp32 top-4
    attn_mfma_topk_kernel<<<dim3(96, 8), 256, 0, stream>>>(Qr, Kr, Kb16, sink, markerb, psink);
    // post-top-k smooth path (bf16/MFMA)
    cvt_bf16_kernel<<<32, 256, 0, stream>>>(V1w, V2w, V1b16);
    wo_transpose_kernel<<<dim3(12, 12, 4), 256, 0, stream>>>(WOw, WOtb);
    mlp_mfma_kernel<<<1536, 256, 0, stream>>>(markerb, psink, V1b16, V1b, V2b16, V2b, vnulls, ctxb);
    gemm_wo_mfma<<<dim3(32, 12), 256, 0, stream>>>(ctxb, WOtb, WOb, out);
}